// Round 1
// baseline (3490.811 us; speedup 1.0000x reference)
//
#include <hip/hip_runtime.h>
#include <hip/hip_bf16.h>

// FrameTransformer: B=16, C=8, BINS=1024, W=256, FF=2048, NB=4
// tokens = B*W = 4096, feature width 1024, FF width 4096, head dim 256.

#define TOKENS 4096
#define WDIM   256
#define BINSD  1024
#define EPSF   1e-5f

// ---------------- wave/block reduction helpers ----------------
__device__ __forceinline__ float wred_sum(float v) {
#pragma unroll
    for (int off = 32; off; off >>= 1) v += __shfl_xor(v, off, 64);
    return v;
}
__device__ __forceinline__ float wred_max(float v) {
#pragma unroll
    for (int off = 32; off; off >>= 1) v = fmaxf(v, __shfl_xor(v, off, 64));
    return v;
}

// ---------------- stage 1: bottleneck 1x1 conv + BN + ReLU + transpose ----------------
// x: (B, 8, 1024, 256) -> xs: (B*W, 1024)  [xs[b*256+w][h]]
__global__ __launch_bounds__(256)
void bottleneck_k(const float* __restrict__ x, const float* __restrict__ bw,
                  const float* __restrict__ bn_g, const float* __restrict__ bn_b,
                  const float* __restrict__ bn_m, const float* __restrict__ bn_v,
                  float* __restrict__ xs)
{
    __shared__ float tile[32][33];
    const int b = blockIdx.z, h0 = blockIdx.y * 32, w0 = blockIdx.x * 32;
    const int tid = threadIdx.x, c = tid & 31, r = tid >> 5;  // r in [0,8)
    float wreg[8];
#pragma unroll
    for (int ch = 0; ch < 8; ++ch) wreg[ch] = bw[ch];
    const float sc = bn_g[0] * rsqrtf(bn_v[0] + EPSF);
    const float sh = bn_b[0] - bn_m[0] * sc;
#pragma unroll
    for (int it = 0; it < 4; ++it) {
        const int h = h0 + r + it * 8;
        const int w = w0 + c;
        float acc = 0.f;
#pragma unroll
        for (int ch = 0; ch < 8; ++ch)
            acc += x[(((long)b * 8 + ch) * 1024 + h) * 256 + w] * wreg[ch];
        tile[r + it * 8][c] = fmaxf(acc * sc + sh, 0.f);  // tile[h_local][w_local]
    }
    __syncthreads();
#pragma unroll
    for (int it = 0; it < 4; ++it) {
        const int wl = r + it * 8;
        xs[((long)b * 256 + w0 + wl) * 1024 + h0 + c] = tile[c][wl];
    }
}

// ---------------- generic tiled fp32 GEMM ----------------
// C[M,N] = A[M,K] @ B^T (BNT=0: B stored (N,K)) or A @ B (BNT=1: B stored (K,N))
// batched over blockIdx.z with z=(zb*4+zn) offsets.
// EPI==1: attention-scores epilogue: v*scale + |i-j|/2 * dw[zn,i] + qer[z,j,i]
template<int BNT, int ACT, int EPI>
__global__ __launch_bounds__(256)
void gemm_k(const float* __restrict__ A, const float* __restrict__ B,
            const float* __restrict__ bias, float* __restrict__ C,
            int K, int lda, int ldb, int ldc,
            long oAb, long oAn, long oBb, long oBn, long oCb, long oCn,
            const float* __restrict__ qer, const float* __restrict__ dwp,
            float scale)
{
    __shared__ float As[16][68];
    __shared__ float Bs[16][68];
    const int z = blockIdx.z;
    const int zb = z >> 2, zn = z & 3;
    const float* Ab = A + zb * oAb + zn * oAn;
    const float* Bb = B + zb * oBb + zn * oBn;
    float* Cb = C + zb * oCb + zn * oCn;
    const int m0 = blockIdx.y * 64, n0 = blockIdx.x * 64;
    const int tid = threadIdx.x;
    const int tx = tid & 15, ty = tid >> 4;
    float acc[4][4] = {};
    for (int k0 = 0; k0 < K; k0 += 16) {
#pragma unroll
        for (int jj = 0; jj < 4; ++jj) {
            const int e = tid + jj * 256;
            {   // A tile: kk-fast mapping (A is row-major in K)
                const int row = e >> 4, kk = e & 15;
                As[kk][row] = Ab[(long)(m0 + row) * lda + (k0 + kk)];
            }
            if (BNT) {  // B stored (K,N): col-fast mapping for coalescing
                const int kk = e >> 6, col = e & 63;
                Bs[kk][col] = Bb[(long)(k0 + kk) * ldb + (n0 + col)];
            } else {    // B stored (N,K): kk-fast mapping
                const int row = e >> 4, kk = e & 15;
                Bs[kk][row] = Bb[(long)(n0 + row) * ldb + (k0 + kk)];
            }
        }
        __syncthreads();
#pragma unroll
        for (int kk = 0; kk < 16; ++kk) {
            const float4 av = *(const float4*)&As[kk][ty * 4];
            const float4 bv = *(const float4*)&Bs[kk][tx * 4];
            const float a_[4] = {av.x, av.y, av.z, av.w};
            const float b_[4] = {bv.x, bv.y, bv.z, bv.w};
#pragma unroll
            for (int i = 0; i < 4; ++i)
#pragma unroll
                for (int j = 0; j < 4; ++j)
                    acc[i][j] += a_[i] * b_[j];
        }
        __syncthreads();
    }
#pragma unroll
    for (int i = 0; i < 4; ++i) {
        const int gi = m0 + ty * 4 + i;
        float o_[4];
#pragma unroll
        for (int j = 0; j < 4; ++j) {
            const int gj = n0 + tx * 4 + j;
            float v = acc[i][j];
            if (EPI == 1) {
                v = v * scale
                  + fabsf((float)(gi - gj)) * 0.5f * dwp[zn * WDIM + gi]
                  + qer[(long)z * 65536 + (long)gj * 256 + gi];
            } else if (bias) {
                v += bias[gj];
            }
            if (ACT == 1) v = fmaxf(v, 0.f);
            o_[j] = v;
        }
        *(float4*)&Cb[(long)gi * ldc + (n0 + tx * 4)] = make_float4(o_[0], o_[1], o_[2], o_[3]);
    }
}

// ---------------- conv1R as gathered GEMM: K'=3*1024, ReLU ----------------
// hR[t, o] = relu( sum_{ks,ci} xs[t + ks - 1, ci] * Wc[o, ci, ks] ), bounds in w
__global__ __launch_bounds__(256)
void conv3_gemm_k(const float* __restrict__ X, const float* __restrict__ Wc,
                  float* __restrict__ C)
{
    __shared__ float As[16][68];
    __shared__ float Bs[16][68];
    const int m0 = blockIdx.y * 64, n0 = blockIdx.x * 64;
    const int tid = threadIdx.x;
    const int tx = tid & 15, ty = tid >> 4;
    float acc[4][4] = {};
    for (int k0 = 0; k0 < 3072; k0 += 16) {
        const int ks = k0 >> 10;         // tile never crosses a 1024 boundary
        const int ci0 = k0 & 1023;
#pragma unroll
        for (int jj = 0; jj < 4; ++jj) {
            const int e = tid + jj * 256;
            const int row = e >> 4, kk = e & 15;
            const int t = m0 + row;
            const int w = t & 255;
            const int wp = w + ks - 1;
            float v = 0.f;
            if ((unsigned)wp < 256u) v = X[(long)(t + ks - 1) * 1024 + ci0 + kk];
            As[kk][row] = v;
            Bs[kk][row] = Wc[((long)(n0 + row) * 1024 + ci0 + kk) * 3 + ks];
        }
        __syncthreads();
#pragma unroll
        for (int kk = 0; kk < 16; ++kk) {
            const float4 av = *(const float4*)&As[kk][ty * 4];
            const float4 bv = *(const float4*)&Bs[kk][tx * 4];
            const float a_[4] = {av.x, av.y, av.z, av.w};
            const float b_[4] = {bv.x, bv.y, bv.z, bv.w};
#pragma unroll
            for (int i = 0; i < 4; ++i)
#pragma unroll
                for (int j = 0; j < 4; ++j)
                    acc[i][j] += a_[i] * b_[j];
        }
        __syncthreads();
    }
#pragma unroll
    for (int i = 0; i < 4; ++i) {
        const int gi = m0 + ty * 4 + i;
        float o_[4];
#pragma unroll
        for (int j = 0; j < 4; ++j) o_[j] = fmaxf(acc[i][j], 0.f);
        *(float4*)&C[(long)gi * 1024 + (n0 + tx * 4)] = make_float4(o_[0], o_[1], o_[2], o_[3]);
    }
}

// ---------------- GLU gate + residual + LN (width 1024) ----------------
__global__ __launch_bounds__(256)
void glu_ln_k(const float* __restrict__ xs0, const float* __restrict__ g2,
              const float* __restrict__ gam, const float* __restrict__ bet,
              float* __restrict__ out)
{
    const int t = blockIdx.x, tid = threadIdx.x;
    float vals[4];
    float s1 = 0.f, s2 = 0.f;
#pragma unroll
    for (int i = 0; i < 4; ++i) {
        const int f = tid + i * 256;
        const float xv = xs0[(long)t * 1024 + f];
        const float a  = g2[(long)t * 2048 + f];
        const float gt = g2[(long)t * 2048 + 1024 + f];
        const float v = xv + a / (1.f + expf(-gt));
        vals[i] = v; s1 += v; s2 += v * v;
    }
    __shared__ float red[8];
    s1 = wred_sum(s1); s2 = wred_sum(s2);
    const int lane = tid & 63, wid = tid >> 6;
    if (!lane) { red[wid] = s1; red[4 + wid] = s2; }
    __syncthreads();
    s1 = red[0] + red[1] + red[2] + red[3];
    s2 = red[4] + red[5] + red[6] + red[7];
    const float mean = s1 * (1.f / 1024.f);
    const float var  = s2 * (1.f / 1024.f) - mean * mean;
    const float rstd = rsqrtf(var + EPSF);
#pragma unroll
    for (int i = 0; i < 4; ++i) {
        const int f = tid + i * 256;
        out[(long)t * 1024 + f] = (vals[i] - mean) * rstd * gam[f] + bet[f];
    }
}

// ---------------- residual add + LN (templated width; B may be narrower) ----------------
template<int WIDTH>
__global__ __launch_bounds__(256)
void add_ln_k(const float* __restrict__ A, const float* __restrict__ Bv, int bwidth,
              const float* __restrict__ gam, const float* __restrict__ bet,
              float* __restrict__ out)
{
    constexpr int PT = WIDTH / 256;
    const int t = blockIdx.x, tid = threadIdx.x;
    float vals[PT];
    float s1 = 0.f, s2 = 0.f;
#pragma unroll
    for (int i = 0; i < PT; ++i) {
        const int f = tid + i * 256;
        float v = A[(long)t * WIDTH + f];
        if (f < bwidth) v += Bv[(long)t * bwidth + f];
        vals[i] = v; s1 += v; s2 += v * v;
    }
    __shared__ float red[8];
    s1 = wred_sum(s1); s2 = wred_sum(s2);
    const int lane = tid & 63, wid = tid >> 6;
    if (!lane) { red[wid] = s1; red[4 + wid] = s2; }
    __syncthreads();
    s1 = red[0] + red[1] + red[2] + red[3];
    s2 = red[4] + red[5] + red[6] + red[7];
    const float mean = s1 * (1.f / WIDTH);
    const float var  = s2 * (1.f / WIDTH) - mean * mean;
    const float rstd = rsqrtf(var + EPSF);
#pragma unroll
    for (int i = 0; i < PT; ++i) {
        const int f = tid + i * 256;
        out[(long)t * WIDTH + f] = (vals[i] - mean) * rstd * gam[f] + bet[f];
    }
}

// ---------------- depthwise conv width-9 over w ----------------
__global__ __launch_bounds__(256)
void dwconv_k(const float* __restrict__ h, const float* __restrict__ wdw,
              float* __restrict__ out)
{
    const long idx = (long)blockIdx.x * 256 + threadIdx.x;  // over 4096*4096
    const int c = (int)(idx & 4095);
    const int t = (int)(idx >> 12);
    const int w = t & 255;
    float acc = 0.f;
#pragma unroll
    for (int k = 0; k < 9; ++k) {
        const int wp = w + k - 4;
        if ((unsigned)wp < 256u)
            acc += h[(long)(t + k - 4) * 4096 + c] * wdw[c * 9 + k];
    }
    out[(long)t * 4096 + c] = acc;
}

// ---------------- softmax over rows of 256 ----------------
__global__ __launch_bounds__(256)
void softmax_k(float* __restrict__ s)
{
    const int row = blockIdx.x, tid = threadIdx.x;
    float v = s[(long)row * 256 + tid];
    __shared__ float red[4];
    __shared__ float red2[4];
    float m = wred_max(v);
    const int lane = tid & 63, wid = tid >> 6;
    if (!lane) red[wid] = m;
    __syncthreads();
    m = fmaxf(fmaxf(red[0], red[1]), fmaxf(red[2], red[3]));
    const float e = expf(v - m);
    float sum = wred_sum(e);
    if (!lane) red2[wid] = sum;
    __syncthreads();
    sum = red2[0] + red2[1] + red2[2] + red2[3];
    s[(long)row * 256 + tid] = e / sum;
}

// ---------------- final transpose (tokens,1024) -> (B,1,1024,256) ----------------
__global__ __launch_bounds__(256)
void transpose_out_k(const float* __restrict__ xs, float* __restrict__ out)
{
    __shared__ float tile[32][33];
    const int b = blockIdx.z, f0 = blockIdx.y * 32, w0 = blockIdx.x * 32;
    const int tid = threadIdx.x, c = tid & 31, r = tid >> 5;
#pragma unroll
    for (int it = 0; it < 4; ++it) {
        const int w = w0 + r + it * 8;
        tile[r + it * 8][c] = xs[((long)b * 256 + w) * 1024 + f0 + c];  // tile[w_l][f_l]
    }
    __syncthreads();
#pragma unroll
    for (int it = 0; it < 4; ++it) {
        const int fl = r + it * 8;
        out[((long)b * 1024 + f0 + fl) * 256 + w0 + c] = tile[c][fl];
    }
}

// =======================================================================
extern "C" void kernel_launch(void* const* d_in, const int* in_sizes, int n_in,
                              void* d_out, int out_size, void* d_ws, size_t ws_size,
                              hipStream_t stream)
{
    const float* x      = (const float*)d_in[0];
    const float* bott_w = (const float*)d_in[1];
    const float* bn_g   = (const float*)d_in[2];
    const float* bn_b   = (const float*)d_in[3];
    const float* bn_m   = (const float*)d_in[4];
    const float* bn_v   = (const float*)d_in[5];
    const float* glu_w  = (const float*)d_in[6];
    const float* n1g    = (const float*)d_in[7];
    const float* n1b    = (const float*)d_in[8];
    const float* c1L_w  = (const float*)d_in[9];
    const float* c1R_w  = (const float*)d_in[10];
    const float* n2g    = (const float*)d_in[11];
    const float* n2b    = (const float*)d_in[12];
    const float* c2dw_w = (const float*)d_in[13];
    const float* c2pw_w = (const float*)d_in[14];
    const float* n3g    = (const float*)d_in[15];
    const float* n3b    = (const float*)d_in[16];
    const float* qw     = (const float*)d_in[17];
    const float* qb     = (const float*)d_in[18];
    const float* kw     = (const float*)d_in[19];
    const float* kb     = (const float*)d_in[20];
    const float* vw     = (const float*)d_in[21];
    const float* vb     = (const float*)d_in[22];
    const float* ow     = (const float*)d_in[23];
    const float* ob     = (const float*)d_in[24];
    const float* er     = (const float*)d_in[25];
    const float* dist_w = (const float*)d_in[26];
    const float* n4g    = (const float*)d_in[27];
    const float* n4b    = (const float*)d_in[28];
    const float* c3_w   = (const float*)d_in[29];
    const float* c4_w   = (const float*)d_in[30];
    const float* n5g    = (const float*)d_in[31];
    const float* n5b    = (const float*)d_in[32];
    float* out = (float*)d_out;

    // ---- workspace layout (floats). total 48M floats = 192 MiB ----
    float* ws = (float*)d_ws;
    const long M4 = 1L << 22;       // 4M floats = one (4096 x 1024) buffer
    float* X0 = ws;                 // xs chain A
    float* X1 = ws + M4;            // xs chain B
    float* S0 = ws + 2 * M4;        // hR / attn scores
    float* S1 = ws + 3 * M4;        // c2pw out / attn o_concat / c4 out
    float* H0 = ws + 4 * M4;        // (4096 x 4096) buffer A (16M floats)
    float* H1 = ws + 20 * M4;       // (4096 x 4096) buffer B
    // attention-time aliases inside H0/H1 (dead by then):
    float* Q   = H0;
    float* Km  = H0 + 4 * M4 / 4 * 0 + M4;      // H0 + 4M floats
    float* V   = H0 + 2 * M4;
    float* QER = H0 + 3 * M4;
    float* PRJ = H1;

    const dim3 blk(256);
    const long Z0 = 0;

    // 1. bottleneck + BN + ReLU + transpose -> X1 (xs0)
    bottleneck_k<<<dim3(8, 32, 16), blk, 0, stream>>>(x, bott_w, bn_g, bn_b, bn_m, bn_v, X1);

    // 2. GLU matmul: X1 @ glu_w^T -> H0 (4096 x 2048)
    gemm_k<0,0,0><<<dim3(32, 64, 1), blk, 0, stream>>>(X1, glu_w, nullptr, H0,
        1024, 1024, 1024, 2048, Z0,Z0,Z0,Z0,Z0,Z0, nullptr, nullptr, 1.f);

    // 3. n1: LN(xs0 + a*sigmoid(g)) -> X0 (xs1)
    glu_ln_k<<<dim3(4096), blk, 0, stream>>>(X1, H0, n1g, n1b, X0);

    // 4. c1L: relu(X0 @ c1L_w^T) -> H0 (4096 x 4096)
    gemm_k<0,1,0><<<dim3(64, 64, 1), blk, 0, stream>>>(X0, c1L_w, nullptr, H0,
        1024, 1024, 1024, 4096, Z0,Z0,Z0,Z0,Z0,Z0, nullptr, nullptr, 1.f);

    // 5. c1R conv (as K=3072 GEMM), relu -> S0 (4096 x 1024)
    conv3_gemm_k<<<dim3(16, 64, 1), blk, 0, stream>>>(X0, c1R_w, S0);

    // 6. n2: LN(H0 + pad(S0)) -> H1
    add_ln_k<4096><<<dim3(4096), blk, 0, stream>>>(H0, S0, 1024, n2g, n2b, H1);

    // 7. depthwise conv9 over w: H1 -> H0
    dwconv_k<<<dim3(65536), blk, 0, stream>>>(H1, c2dw_w, H0);

    // 8. c2pw: H0 @ c2pw_w^T -> S1 (4096 x 1024)
    gemm_k<0,0,0><<<dim3(16, 64, 1), blk, 0, stream>>>(H0, c2pw_w, nullptr, S1,
        4096, 4096, 4096, 1024, Z0,Z0,Z0,Z0,Z0,Z0, nullptr, nullptr, 1.f);

    // 9. n3: LN(X0 + S1) -> X1 (xs2)
    add_ln_k<1024><<<dim3(4096), blk, 0, stream>>>(X0, S1, 1024, n3g, n3b, X1);

    // 10. q/k/v projections (+bias) from X1
    gemm_k<0,0,0><<<dim3(16, 64, 1), blk, 0, stream>>>(X1, qw, qb, Q,
        1024, 1024, 1024, 1024, Z0,Z0,Z0,Z0,Z0,Z0, nullptr, nullptr, 1.f);
    gemm_k<0,0,0><<<dim3(16, 64, 1), blk, 0, stream>>>(X1, kw, kb, Km,
        1024, 1024, 1024, 1024, Z0,Z0,Z0,Z0,Z0,Z0, nullptr, nullptr, 1.f);
    gemm_k<0,0,0><<<dim3(16, 64, 1), blk, 0, stream>>>(X1, vw, vb, V,
        1024, 1024, 1024, 1024, Z0,Z0,Z0,Z0,Z0,Z0, nullptr, nullptr, 1.f);

    // 11. qer[b,n,w,c] = Q_head @ er  (batched over z = b*4+n)
    gemm_k<1,0,0><<<dim3(4, 4, 64), blk, 0, stream>>>(Q, er, nullptr, QER,
        256, 1024, 256, 256,
        /*oAb*/ (long)256 * 1024, /*oAn*/ 256, Z0, Z0,
        /*oCb*/ (long)4 * 65536, /*oCn*/ 65536, nullptr, nullptr, 1.f);

    // 12. scores = QK^T/32 + dist*dist_w + qer^T -> S0 (batched)
    gemm_k<0,0,1><<<dim3(4, 4, 64), blk, 0, stream>>>(Q, Km, nullptr, S0,
        256, 1024, 1024, 256,
        (long)256 * 1024, 256, (long)256 * 1024, 256,
        (long)4 * 65536, 65536, QER, dist_w, 1.f / 32.f);

    // 13. softmax rows (64*256 rows of 256)
    softmax_k<<<dim3(16384), blk, 0, stream>>>(S0);

    // 14. o = A @ V, written in concat layout -> S1
    gemm_k<1,0,0><<<dim3(4, 4, 64), blk, 0, stream>>>(S0, V, nullptr, S1,
        256, 256, 1024, 1024,
        (long)4 * 65536, 65536, (long)256 * 1024, 256,
        (long)256 * 1024, 256, nullptr, nullptr, 1.f);

    // 15. output projection (+bias) -> PRJ (=H1)
    gemm_k<0,0,0><<<dim3(16, 64, 1), blk, 0, stream>>>(S1, ow, ob, PRJ,
        1024, 1024, 1024, 1024, Z0,Z0,Z0,Z0,Z0,Z0, nullptr, nullptr, 1.f);

    // 16. n4: LN(X1 + PRJ) -> X0 (xs3)
    add_ln_k<1024><<<dim3(4096), blk, 0, stream>>>(X1, PRJ, 1024, n4g, n4b, X0);

    // 17. c3: relu(X0 @ c3_w^T) -> H0
    gemm_k<0,1,0><<<dim3(64, 64, 1), blk, 0, stream>>>(X0, c3_w, nullptr, H0,
        1024, 1024, 1024, 4096, Z0,Z0,Z0,Z0,Z0,Z0, nullptr, nullptr, 1.f);

    // 18. c4: H0 @ c4_w^T -> S1
    gemm_k<0,0,0><<<dim3(16, 64, 1), blk, 0, stream>>>(H0, c4_w, nullptr, S1,
        4096, 4096, 4096, 1024, Z0,Z0,Z0,Z0,Z0,Z0, nullptr, nullptr, 1.f);

    // 19. n5: LN(X0 + S1) -> X1 (xs4)
    add_ln_k<1024><<<dim3(4096), blk, 0, stream>>>(X0, S1, 1024, n5g, n5b, X1);

    // 20. transpose to (B, 1, 1024, 256)
    transpose_out_k<<<dim3(8, 32, 16), blk, 0, stream>>>(X1, out);

    (void)in_sizes; (void)n_in; (void)out_size; (void)ws_size;
}

// Round 2
// 999.349 us; speedup vs baseline: 3.4931x; 3.4931x over previous
//
#include <hip/hip_runtime.h>
#include <hip/hip_bf16.h>

// FrameTransformer: B=16, C=8, BINS=1024, W=256, FF=2048, NB=4
// tokens = B*W = 4096, feature width 1024, FF width 4096, head dim 256.
#define EPSF 1e-5f

typedef unsigned short u16;
typedef unsigned int   u32;
typedef __attribute__((ext_vector_type(8))) short bf16x8;
typedef __attribute__((ext_vector_type(4))) float f32x4;

__device__ __forceinline__ u16 f2bf(float f) {
    u32 u = __builtin_bit_cast(u32, f);
    u32 r = u + 0x7fffu + ((u >> 16) & 1u);
    return (u16)(r >> 16);
}
__device__ __forceinline__ float bf2f(u16 h) {
    return __builtin_bit_cast(float, (u32)h << 16);
}
__device__ __forceinline__ void gld16(void* lds, const void* gsrc) {
    __builtin_amdgcn_global_load_lds(
        (const __attribute__((address_space(1))) u32*)gsrc,
        (__attribute__((address_space(3))) u32*)lds, 16, 0, 0);
}

__device__ __forceinline__ float wred_sum(float v) {
#pragma unroll
    for (int off = 32; off; off >>= 1) v += __shfl_xor(v, off, 64);
    return v;
}
__device__ __forceinline__ float wred_max(float v) {
#pragma unroll
    for (int off = 32; off; off >>= 1) v = fmaxf(v, __shfl_xor(v, off, 64));
    return v;
}
// two-value block reduction over 256 threads (4 waves)
__device__ __forceinline__ void block_red2(float& s1, float& s2, int tid) {
    __shared__ float red[8];
    s1 = wred_sum(s1); s2 = wred_sum(s2);
    const int lane = tid & 63, wid = tid >> 6;
    if (!lane) { red[wid] = s1; red[4 + wid] = s2; }
    __syncthreads();
    s1 = red[0] + red[1] + red[2] + red[3];
    s2 = red[4] + red[5] + red[6] + red[7];
}

// ---------------- weight converters ----------------
__global__ __launch_bounds__(256)
void wcvt_k(const float* __restrict__ src, u16* __restrict__ dst, int n4)
{
    const int i = blockIdx.x * 256 + threadIdx.x;
    if (i >= n4) return;
    const float4 v = ((const float4*)src)[i];
    ushort4 o; o.x = f2bf(v.x); o.y = f2bf(v.y); o.z = f2bf(v.z); o.w = f2bf(v.w);
    ((ushort4*)dst)[i] = o;
}
// c1R_w (o,ci,ks=3) -> Wt (o, ks, ci) bf16
__global__ __launch_bounds__(256)
void c1rcvt_k(const float* __restrict__ src, u16* __restrict__ dst)
{
    const int i = blockIdx.x * 256 + threadIdx.x;     // over 1024*3072
    const int q = i / 3072, rem = i - q * 3072;
    const int ks = rem >> 10, ci = rem & 1023;
    dst[i] = f2bf(src[((long)q * 1024 + ci) * 3 + ks]);
}
__global__ __launch_bounds__(256)
void zero_k(u16* __restrict__ p, int n)
{
    const int i = blockIdx.x * 256 + threadIdx.x;
    if (i < n) p[i] = 0;
}

// ---------------- stage 1: bottleneck 1x1 conv + BN + ReLU + transpose ----------------
__global__ __launch_bounds__(256)
void bottleneck_k(const float* __restrict__ x, const float* __restrict__ bw,
                  const float* __restrict__ bn_g, const float* __restrict__ bn_b,
                  const float* __restrict__ bn_m, const float* __restrict__ bn_v,
                  float* __restrict__ xs, u16* __restrict__ xsb)
{
    __shared__ float tile[32][33];
    const int b = blockIdx.z, h0 = blockIdx.y * 32, w0 = blockIdx.x * 32;
    const int tid = threadIdx.x, c = tid & 31, r = tid >> 5;
    float wreg[8];
#pragma unroll
    for (int ch = 0; ch < 8; ++ch) wreg[ch] = bw[ch];
    const float sc = bn_g[0] * rsqrtf(bn_v[0] + EPSF);
    const float sh = bn_b[0] - bn_m[0] * sc;
#pragma unroll
    for (int it = 0; it < 4; ++it) {
        const int h = h0 + r + it * 8;
        const int w = w0 + c;
        float acc = 0.f;
#pragma unroll
        for (int ch = 0; ch < 8; ++ch)
            acc += x[(((long)b * 8 + ch) * 1024 + h) * 256 + w] * wreg[ch];
        tile[r + it * 8][c] = fmaxf(acc * sc + sh, 0.f);
    }
    __syncthreads();
#pragma unroll
    for (int it = 0; it < 4; ++it) {
        const int wl = r + it * 8;
        const float v = tile[c][wl];
        const long o = ((long)b * 256 + w0 + wl) * 1024 + h0 + c;
        xs[o] = v;
        xsb[o] = f2bf(v);
    }
}

// ---------------- bf16 MFMA GEMM: C[M,N] = A[M,K] @ B[N,K]^T ----------------
// 128x128 block tile, 4 waves (2x2, 64x64 each), BK=64, global_load_lds staging.
template<int ACT, int OUTBF, int BIAS>
__global__ __launch_bounds__(256)
void gemm_bf16_k(const u16* __restrict__ A, const u16* __restrict__ B,
                 const float* __restrict__ bias, void* __restrict__ Cout,
                 int N, int K)
{
    __shared__ __align__(16) u16 As[8192];
    __shared__ __align__(16) u16 Bs[8192];
    const int m0 = blockIdx.y * 128, n0 = blockIdx.x * 128;
    const int tid = threadIdx.x;
    const int lane = tid & 63, wid = tid >> 6;
    const int wr = (wid >> 1) * 64, wc = (wid & 1) * 64;
    const int l15 = lane & 15, l4 = lane >> 4;
    f32x4 acc[4][4] = {};
    for (int k0 = 0; k0 < K; k0 += 64) {
#pragma unroll
        for (int it = 0; it < 4; ++it) {
            const int oe = it * 2048 + tid * 8;     // element offset in tile
            const int row = oe >> 6, col = oe & 63;
            gld16(&As[oe], A + (long)(m0 + row) * K + k0 + col);
            gld16(&Bs[oe], B + (long)(n0 + row) * K + k0 + col);
        }
        __syncthreads();
#pragma unroll
        for (int kk = 0; kk < 2; ++kk) {
            bf16x8 af[4], bf[4];
#pragma unroll
            for (int i = 0; i < 4; ++i) {
                af[i] = *(const bf16x8*)&As[(wr + i * 16 + l15) * 64 + kk * 32 + l4 * 8];
                bf[i] = *(const bf16x8*)&Bs[(wc + i * 16 + l15) * 64 + kk * 32 + l4 * 8];
            }
#pragma unroll
            for (int i = 0; i < 4; ++i)
#pragma unroll
                for (int j = 0; j < 4; ++j)
                    acc[i][j] = __builtin_amdgcn_mfma_f32_16x16x32_bf16(af[i], bf[j], acc[i][j], 0, 0, 0);
        }
        __syncthreads();
    }
    float* Cf = (float*)Cout;
    u16*   Cb = (u16*)Cout;
#pragma unroll
    for (int i = 0; i < 4; ++i)
#pragma unroll
        for (int j = 0; j < 4; ++j) {
            const int n = n0 + wc + j * 16 + l15;
            const float bv = BIAS ? bias[n] : 0.f;
#pragma unroll
            for (int q = 0; q < 4; ++q) {
                const int m = m0 + wr + i * 16 + l4 * 4 + q;
                float v = acc[i][j][q] + bv;
                if (ACT) v = fmaxf(v, 0.f);
                if (OUTBF) Cb[(long)m * N + n] = f2bf(v);
                else       Cf[(long)m * N + n] = v;
            }
        }
}

// ---------------- conv1R as gathered bf16 MFMA GEMM: M=4096,N=1024,K=3072 ----------------
__global__ __launch_bounds__(256)
void conv3_bf16_k(const u16* __restrict__ Xb, const u16* __restrict__ Wt,
                  const u16* __restrict__ zp, float* __restrict__ C)
{
    __shared__ __align__(16) u16 As[8192];
    __shared__ __align__(16) u16 Bs[8192];
    const int m0 = blockIdx.y * 128, n0 = blockIdx.x * 128;
    const int tid = threadIdx.x;
    const int lane = tid & 63, wid = tid >> 6;
    const int wr = (wid >> 1) * 64, wc = (wid & 1) * 64;
    const int l15 = lane & 15, l4 = lane >> 4;
    f32x4 acc[4][4] = {};
    for (int k0 = 0; k0 < 3072; k0 += 64) {
        const int ks = k0 >> 10, ci0 = k0 & 1023;
#pragma unroll
        for (int it = 0; it < 4; ++it) {
            const int oe = it * 2048 + tid * 8;
            const int row = oe >> 6, col = oe & 63;
            const int t = m0 + row;
            const int wp = (t & 255) + ks - 1;
            const u16* src = ((unsigned)wp < 256u)
                ? Xb + (long)(t + ks - 1) * 1024 + ci0 + col
                : zp;
            gld16(&As[oe], src);
            gld16(&Bs[oe], Wt + (long)(n0 + row) * 3072 + k0 + col);
        }
        __syncthreads();
#pragma unroll
        for (int kk = 0; kk < 2; ++kk) {
            bf16x8 af[4], bf[4];
#pragma unroll
            for (int i = 0; i < 4; ++i) {
                af[i] = *(const bf16x8*)&As[(wr + i * 16 + l15) * 64 + kk * 32 + l4 * 8];
                bf[i] = *(const bf16x8*)&Bs[(wc + i * 16 + l15) * 64 + kk * 32 + l4 * 8];
            }
#pragma unroll
            for (int i = 0; i < 4; ++i)
#pragma unroll
                for (int j = 0; j < 4; ++j)
                    acc[i][j] = __builtin_amdgcn_mfma_f32_16x16x32_bf16(af[i], bf[j], acc[i][j], 0, 0, 0);
        }
        __syncthreads();
    }
#pragma unroll
    for (int i = 0; i < 4; ++i)
#pragma unroll
        for (int j = 0; j < 4; ++j) {
            const int n = n0 + wc + j * 16 + l15;
#pragma unroll
            for (int q = 0; q < 4; ++q) {
                const int m = m0 + wr + i * 16 + l4 * 4 + q;
                C[(long)m * 1024 + n] = fmaxf(acc[i][j][q], 0.f);
            }
        }
}

// ---------------- fp32 tiled GEMM (attention per-head paths) ----------------
template<int BNT, int ACT, int EPI, int OUTBF>
__global__ __launch_bounds__(256)
void gemm_k(const float* __restrict__ A, const float* __restrict__ B,
            const float* __restrict__ bias, void* __restrict__ C,
            int K, int lda, int ldb, int ldc,
            long oAb, long oAn, long oBb, long oBn, long oCb, long oCn,
            const float* __restrict__ qer, const float* __restrict__ dwp,
            float scale)
{
    __shared__ float As[16][68];
    __shared__ float Bs[16][68];
    const int z = blockIdx.z;
    const int zb = z >> 2, zn = z & 3;
    const float* Ab = A + zb * oAb + zn * oAn;
    const float* Bb = B + zb * oBb + zn * oBn;
    const long coff = zb * oCb + zn * oCn;
    const int m0 = blockIdx.y * 64, n0 = blockIdx.x * 64;
    const int tid = threadIdx.x;
    const int tx = tid & 15, ty = tid >> 4;
    float acc[4][4] = {};
    for (int k0 = 0; k0 < K; k0 += 16) {
#pragma unroll
        for (int jj = 0; jj < 4; ++jj) {
            const int e = tid + jj * 256;
            {
                const int row = e >> 4, kk = e & 15;
                As[kk][row] = Ab[(long)(m0 + row) * lda + (k0 + kk)];
            }
            if (BNT) {
                const int kk = e >> 6, col = e & 63;
                Bs[kk][col] = Bb[(long)(k0 + kk) * ldb + (n0 + col)];
            } else {
                const int row = e >> 4, kk = e & 15;
                Bs[kk][row] = Bb[(long)(n0 + row) * ldb + (k0 + kk)];
            }
        }
        __syncthreads();
#pragma unroll
        for (int kk = 0; kk < 16; ++kk) {
            const float4 av = *(const float4*)&As[kk][ty * 4];
            const float4 bv = *(const float4*)&Bs[kk][tx * 4];
            const float a_[4] = {av.x, av.y, av.z, av.w};
            const float b_[4] = {bv.x, bv.y, bv.z, bv.w};
#pragma unroll
            for (int i = 0; i < 4; ++i)
#pragma unroll
                for (int j = 0; j < 4; ++j)
                    acc[i][j] += a_[i] * b_[j];
        }
        __syncthreads();
    }
#pragma unroll
    for (int i = 0; i < 4; ++i) {
        const int gi = m0 + ty * 4 + i;
        float o_[4];
#pragma unroll
        for (int j = 0; j < 4; ++j) {
            const int gj = n0 + tx * 4 + j;
            float v = acc[i][j];
            if (EPI == 1) {
                v = v * scale
                  + fabsf((float)(gi - gj)) * 0.5f * dwp[zn * 256 + gi]
                  + qer[(long)z * 65536 + (long)gj * 256 + gi];
            } else if (bias) {
                v += bias[gj];
            }
            if (ACT == 1) v = fmaxf(v, 0.f);
            o_[j] = v;
        }
        if (OUTBF) {
            u16* Cb = (u16*)C + coff;
            ushort4 st; st.x = f2bf(o_[0]); st.y = f2bf(o_[1]); st.z = f2bf(o_[2]); st.w = f2bf(o_[3]);
            *(ushort4*)&Cb[(long)gi * ldc + (n0 + tx * 4)] = st;
        } else {
            float* Cf = (float*)C + coff;
            *(float4*)&Cf[(long)gi * ldc + (n0 + tx * 4)] = make_float4(o_[0], o_[1], o_[2], o_[3]);
        }
    }
}

// ---------------- GLU gate + residual + LN (width 1024), fp32 + bf16 out ----------------
__global__ __launch_bounds__(256)
void glu_ln_k(const float* __restrict__ xs0, const float* __restrict__ g2,
              const float* __restrict__ gam, const float* __restrict__ bet,
              float* __restrict__ outf, u16* __restrict__ outb)
{
    const int t = blockIdx.x, tid = threadIdx.x;
    const int f0 = tid * 4;
    const float4 xv = *(const float4*)&xs0[(long)t * 1024 + f0];
    const float4 av = *(const float4*)&g2[(long)t * 2048 + f0];
    const float4 gv = *(const float4*)&g2[(long)t * 2048 + 1024 + f0];
    float vals[4];
    vals[0] = xv.x + av.x / (1.f + expf(-gv.x));
    vals[1] = xv.y + av.y / (1.f + expf(-gv.y));
    vals[2] = xv.z + av.z / (1.f + expf(-gv.z));
    vals[3] = xv.w + av.w / (1.f + expf(-gv.w));
    float s1 = vals[0] + vals[1] + vals[2] + vals[3];
    float s2 = vals[0]*vals[0] + vals[1]*vals[1] + vals[2]*vals[2] + vals[3]*vals[3];
    block_red2(s1, s2, tid);
    const float mean = s1 * (1.f / 1024.f);
    const float var  = s2 * (1.f / 1024.f) - mean * mean;
    const float rstd = rsqrtf(var + EPSF);
    const float4 gm = *(const float4*)&gam[f0];
    const float4 bt = *(const float4*)&bet[f0];
    float r0 = (vals[0] - mean) * rstd * gm.x + bt.x;
    float r1 = (vals[1] - mean) * rstd * gm.y + bt.y;
    float r2 = (vals[2] - mean) * rstd * gm.z + bt.z;
    float r3 = (vals[3] - mean) * rstd * gm.w + bt.w;
    *(float4*)&outf[(long)t * 1024 + f0] = make_float4(r0, r1, r2, r3);
    ushort4 ub; ub.x = f2bf(r0); ub.y = f2bf(r1); ub.z = f2bf(r2); ub.w = f2bf(r3);
    *(ushort4*)&outb[(long)t * 1024 + f0] = ub;
}

// ---------------- residual add + LN width 1024 ----------------
template<int WRITEBF>
__global__ __launch_bounds__(256)
void add_ln1024_k(const float* __restrict__ A, const float* __restrict__ Bv,
                  const float* __restrict__ gam, const float* __restrict__ bet,
                  float* __restrict__ outf, u16* __restrict__ outb)
{
    const int t = blockIdx.x, tid = threadIdx.x;
    const int f0 = tid * 4;
    const float4 a = *(const float4*)&A[(long)t * 1024 + f0];
    const float4 b = *(const float4*)&Bv[(long)t * 1024 + f0];
    float vals[4] = {a.x + b.x, a.y + b.y, a.z + b.z, a.w + b.w};
    float s1 = vals[0] + vals[1] + vals[2] + vals[3];
    float s2 = vals[0]*vals[0] + vals[1]*vals[1] + vals[2]*vals[2] + vals[3]*vals[3];
    block_red2(s1, s2, tid);
    const float mean = s1 * (1.f / 1024.f);
    const float var  = s2 * (1.f / 1024.f) - mean * mean;
    const float rstd = rsqrtf(var + EPSF);
    const float4 gm = *(const float4*)&gam[f0];
    const float4 bt = *(const float4*)&bet[f0];
    float r0 = (vals[0] - mean) * rstd * gm.x + bt.x;
    float r1 = (vals[1] - mean) * rstd * gm.y + bt.y;
    float r2 = (vals[2] - mean) * rstd * gm.z + bt.z;
    float r3 = (vals[3] - mean) * rstd * gm.w + bt.w;
    *(float4*)&outf[(long)t * 1024 + f0] = make_float4(r0, r1, r2, r3);
    if (WRITEBF) {
        ushort4 ub; ub.x = f2bf(r0); ub.y = f2bf(r1); ub.z = f2bf(r2); ub.w = f2bf(r3);
        *(ushort4*)&outb[(long)t * 1024 + f0] = ub;
    }
}

// ---------------- n2: LN(c1L + pad(conv3)) width 4096, bf16-only out ----------------
__global__ __launch_bounds__(256)
void add_ln4096_k(const float* __restrict__ A, const float* __restrict__ Bv,
                  const float* __restrict__ gam, const float* __restrict__ bet,
                  u16* __restrict__ outb)
{
    const int t = blockIdx.x, tid = threadIdx.x;
    float vals[16];
    float s1 = 0.f, s2 = 0.f;
#pragma unroll
    for (int c = 0; c < 4; ++c) {
        const int f0 = tid * 16 + c * 4;
        float4 a = *(const float4*)&A[(long)t * 4096 + f0];
        if (f0 < 1024) {
            const float4 b = *(const float4*)&Bv[(long)t * 1024 + f0];
            a.x += b.x; a.y += b.y; a.z += b.z; a.w += b.w;
        }
        vals[c*4+0] = a.x; vals[c*4+1] = a.y; vals[c*4+2] = a.z; vals[c*4+3] = a.w;
        s1 += a.x + a.y + a.z + a.w;
        s2 += a.x*a.x + a.y*a.y + a.z*a.z + a.w*a.w;
    }
    block_red2(s1, s2, tid);
    const float mean = s1 * (1.f / 4096.f);
    const float var  = s2 * (1.f / 4096.f) - mean * mean;
    const float rstd = rsqrtf(var + EPSF);
#pragma unroll
    for (int c = 0; c < 4; ++c) {
        const int f0 = tid * 16 + c * 4;
        const float4 gm = *(const float4*)&gam[f0];
        const float4 bt = *(const float4*)&bet[f0];
        ushort4 ub;
        ub.x = f2bf((vals[c*4+0] - mean) * rstd * gm.x + bt.x);
        ub.y = f2bf((vals[c*4+1] - mean) * rstd * gm.y + bt.y);
        ub.z = f2bf((vals[c*4+2] - mean) * rstd * gm.z + bt.z);
        ub.w = f2bf((vals[c*4+3] - mean) * rstd * gm.w + bt.w);
        *(ushort4*)&outb[(long)t * 4096 + f0] = ub;
    }
}

// ---------------- depthwise conv width-9 over w (bf16 in/out) ----------------
__global__ __launch_bounds__(256)
void dwconv_k(const u16* __restrict__ h, const float* __restrict__ wdw,
              u16* __restrict__ out)
{
    const long idx = (long)blockIdx.x * 256 + threadIdx.x;  // over 4096*4096
    const int c = (int)(idx & 4095);
    const int t = (int)(idx >> 12);
    const int w = t & 255;
    float acc = 0.f;
#pragma unroll
    for (int k = 0; k < 9; ++k) {
        const int wp = w + k - 4;
        if ((unsigned)wp < 256u)
            acc += bf2f(h[(long)(t + k - 4) * 4096 + c]) * wdw[c * 9 + k];
    }
    out[idx] = f2bf(acc);
}

// ---------------- softmax over rows of 256 ----------------
__global__ __launch_bounds__(256)
void softmax_k(float* __restrict__ s)
{
    const int row = blockIdx.x, tid = threadIdx.x;
    float v = s[(long)row * 256 + tid];
    __shared__ float red[4];
    __shared__ float red2[4];
    float m = wred_max(v);
    const int lane = tid & 63, wid = tid >> 6;
    if (!lane) red[wid] = m;
    __syncthreads();
    m = fmaxf(fmaxf(red[0], red[1]), fmaxf(red[2], red[3]));
    const float e = expf(v - m);
    float sum = wred_sum(e);
    if (!lane) red2[wid] = sum;
    __syncthreads();
    sum = red2[0] + red2[1] + red2[2] + red2[3];
    s[(long)row * 256 + tid] = e / sum;
}

// ---------------- final transpose (tokens,1024) -> (B,1,1024,256) ----------------
__global__ __launch_bounds__(256)
void transpose_out_k(const float* __restrict__ xs, float* __restrict__ out)
{
    __shared__ float tile[32][33];
    const int b = blockIdx.z, f0 = blockIdx.y * 32, w0 = blockIdx.x * 32;
    const int tid = threadIdx.x, c = tid & 31, r = tid >> 5;
#pragma unroll
    for (int it = 0; it < 4; ++it) {
        const int w = w0 + r + it * 8;
        tile[r + it * 8][c] = xs[((long)b * 256 + w) * 1024 + f0 + c];
    }
    __syncthreads();
#pragma unroll
    for (int it = 0; it < 4; ++it) {
        const int fl = r + it * 8;
        out[((long)b * 1024 + f0 + fl) * 256 + w0 + c] = tile[c][fl];
    }
}

// =======================================================================
extern "C" void kernel_launch(void* const* d_in, const int* in_sizes, int n_in,
                              void* d_out, int out_size, void* d_ws, size_t ws_size,
                              hipStream_t stream)
{
    const float* x      = (const float*)d_in[0];
    const float* bott_w = (const float*)d_in[1];
    const float* bn_g   = (const float*)d_in[2];
    const float* bn_b   = (const float*)d_in[3];
    const float* bn_m   = (const float*)d_in[4];
    const float* bn_v   = (const float*)d_in[5];
    const float* glu_w  = (const float*)d_in[6];
    const float* n1g    = (const float*)d_in[7];
    const float* n1b    = (const float*)d_in[8];
    const float* c1L_w  = (const float*)d_in[9];
    const float* c1R_w  = (const float*)d_in[10];
    const float* n2g    = (const float*)d_in[11];
    const float* n2b    = (const float*)d_in[12];
    const float* c2dw_w = (const float*)d_in[13];
    const float* c2pw_w = (const float*)d_in[14];
    const float* n3g    = (const float*)d_in[15];
    const float* n3b    = (const float*)d_in[16];
    const float* qw     = (const float*)d_in[17];
    const float* qb     = (const float*)d_in[18];
    const float* kw     = (const float*)d_in[19];
    const float* kb     = (const float*)d_in[20];
    const float* vw     = (const float*)d_in[21];
    const float* vb     = (const float*)d_in[22];
    const float* ow     = (const float*)d_in[23];
    const float* ob     = (const float*)d_in[24];
    const float* er     = (const float*)d_in[25];
    const float* dist_w = (const float*)d_in[26];
    const float* n4g    = (const float*)d_in[27];
    const float* n4b    = (const float*)d_in[28];
    const float* c3_w   = (const float*)d_in[29];
    const float* c4_w   = (const float*)d_in[30];
    const float* n5g    = (const float*)d_in[31];
    const float* n5b    = (const float*)d_in[32];
    float* out = (float*)d_out;

    // ---- workspace layout (MiB offsets; round 1 proved ws >= 384 MiB) ----
    char* Wb_ = (char*)d_ws;
    auto F  = [&](size_t mib) { return (float*)(Wb_ + (mib << 20)); };
    auto Bf = [&](size_t mib) { return (u16*)  (Wb_ + (mib << 20)); };
    float* X0  = F(0);    // xs chain A (4096x1024 f32)
    float* X1  = F(16);   // xs chain B
    float* S0  = F(32);   // conv3 out / scores / O-proj out
    float* S1  = F(48);   // c2pw out / c4 out
    float* H0  = F(64);   // GLU out (4096x2048) then c1L out (4096x4096)
    u16*   H0b = Bf(128); // c3 out bf16 (4096x4096)   [aliases H1b, dead by then]
    u16*   H1b = Bf(128); // n2 out bf16 (4096x4096)
    u16*   Hdw = Bf(160); // dwconv out bf16 (4096x4096)
    float* Q   = F(192);
    float* Km  = F(208);
    float* V   = F(224);
    float* QER = F(240);
    u16* X1b = Bf(256); u16* X0b = Bf(264); u16* X2b = Bf(272);
    u16* S1b = Bf(280); u16* X3b = Bf(288);
    u16* wGLU = Bf(296); u16* wC1L = Bf(301); u16* wC1R = Bf(310);
    u16* wC2P = Bf(317); u16* wQ = Bf(326);  u16* wK = Bf(329);
    u16* wV  = Bf(332);  u16* wO = Bf(335);  u16* wC3 = Bf(338); u16* wC4 = Bf(347);
    u16* zp  = Bf(356);

    const dim3 blk(256);
    const long Z0 = 0;

    // 0. weight conversions + zero page
    zero_k<<<dim3(32), blk, 0, stream>>>(zp, 8192);
    wcvt_k<<<dim3(2048), blk, 0, stream>>>(glu_w,  wGLU, 524288);
    wcvt_k<<<dim3(4096), blk, 0, stream>>>(c1L_w,  wC1L, 1048576);
    c1rcvt_k<<<dim3(12288), blk, 0, stream>>>(c1R_w, wC1R);
    wcvt_k<<<dim3(4096), blk, 0, stream>>>(c2pw_w, wC2P, 1048576);
    wcvt_k<<<dim3(1024), blk, 0, stream>>>(qw, wQ, 262144);
    wcvt_k<<<dim3(1024), blk, 0, stream>>>(kw, wK, 262144);
    wcvt_k<<<dim3(1024), blk, 0, stream>>>(vw, wV, 262144);
    wcvt_k<<<dim3(1024), blk, 0, stream>>>(ow, wO, 262144);
    wcvt_k<<<dim3(4096), blk, 0, stream>>>(c3_w, wC3, 1048576);
    wcvt_k<<<dim3(4096), blk, 0, stream>>>(c4_w, wC4, 1048576);

    // 1. bottleneck + BN + ReLU + transpose -> X1 (f32) + X1b (bf16)
    bottleneck_k<<<dim3(8, 32, 16), blk, 0, stream>>>(x, bott_w, bn_g, bn_b, bn_m, bn_v, X1, X1b);

    // 2. GLU matmul -> H0 (4096x2048 f32)
    gemm_bf16_k<0,0,0><<<dim3(16, 32), blk, 0, stream>>>(X1b, wGLU, nullptr, H0, 2048, 1024);

    // 3. n1: LN(xs0 + a*sigmoid(g)) -> X0 + X0b
    glu_ln_k<<<dim3(4096), blk, 0, stream>>>(X1, H0, n1g, n1b, X0, X0b);

    // 4. c1L: relu -> H0 (4096x4096 f32)
    gemm_bf16_k<1,0,0><<<dim3(32, 32), blk, 0, stream>>>(X0b, wC1L, nullptr, H0, 4096, 1024);

    // 5. c1R conv (K=3072 gathered GEMM), relu -> S0 f32
    conv3_bf16_k<<<dim3(8, 32), blk, 0, stream>>>(X0b, wC1R, zp, S0);

    // 6. n2: LN(H0 + pad(S0)) -> H1b bf16
    add_ln4096_k<<<dim3(4096), blk, 0, stream>>>(H0, S0, n2g, n2b, H1b);

    // 7. depthwise conv9: H1b -> Hdw
    dwconv_k<<<dim3(65536), blk, 0, stream>>>(H1b, c2dw_w, Hdw);

    // 8. c2pw -> S1 f32 (4096x1024)
    gemm_bf16_k<0,0,0><<<dim3(8, 32), blk, 0, stream>>>(Hdw, wC2P, nullptr, S1, 1024, 4096);

    // 9. n3: LN(X0 + S1) -> X1 + X2b
    add_ln1024_k<1><<<dim3(4096), blk, 0, stream>>>(X0, S1, n3g, n3b, X1, X2b);

    // 10. q/k/v projections (+bias)
    gemm_bf16_k<0,0,1><<<dim3(8, 32), blk, 0, stream>>>(X2b, wQ, qb, Q,  1024, 1024);
    gemm_bf16_k<0,0,1><<<dim3(8, 32), blk, 0, stream>>>(X2b, wK, kb, Km, 1024, 1024);
    gemm_bf16_k<0,0,1><<<dim3(8, 32), blk, 0, stream>>>(X2b, wV, vb, V,  1024, 1024);

    // 11. qer = Q_head @ er (fp32, batched z)
    gemm_k<1,0,0,0><<<dim3(4, 4, 64), blk, 0, stream>>>(Q, er, nullptr, QER,
        256, 1024, 256, 256,
        (long)256 * 1024, 256, Z0, Z0,
        (long)4 * 65536, 65536, nullptr, nullptr, 1.f);

    // 12. scores = QK^T/32 + dist*dist_w + qer^T -> S0
    gemm_k<0,0,1,0><<<dim3(4, 4, 64), blk, 0, stream>>>(Q, Km, nullptr, S0,
        256, 1024, 1024, 256,
        (long)256 * 1024, 256, (long)256 * 1024, 256,
        (long)4 * 65536, 65536, QER, dist_w, 1.f / 32.f);

    // 13. softmax rows
    softmax_k<<<dim3(16384), blk, 0, stream>>>(S0);

    // 14. o = A @ V -> S1b (bf16, concat layout)
    gemm_k<1,0,0,1><<<dim3(4, 4, 64), blk, 0, stream>>>(S0, V, nullptr, S1b,
        256, 256, 1024, 1024,
        (long)4 * 65536, 65536, (long)256 * 1024, 256,
        (long)256 * 1024, 256, nullptr, nullptr, 1.f);

    // 15. output projection (+bias) -> S0 f32
    gemm_bf16_k<0,0,1><<<dim3(8, 32), blk, 0, stream>>>(S1b, wO, ob, S0, 1024, 1024);

    // 16. n4: LN(X1 + S0) -> X0 + X3b
    add_ln1024_k<1><<<dim3(4096), blk, 0, stream>>>(X1, S0, n4g, n4b, X0, X3b);

    // 17. c3: relu -> H0b bf16 (4096x4096)
    gemm_bf16_k<1,1,0><<<dim3(32, 32), blk, 0, stream>>>(X3b, wC3, nullptr, H0b, 4096, 1024);

    // 18. c4 -> S1 f32
    gemm_bf16_k<0,0,0><<<dim3(8, 32), blk, 0, stream>>>(H0b, wC4, nullptr, S1, 1024, 4096);

    // 19. n5: LN(X0 + S1) -> X1 (f32 only)
    add_ln1024_k<0><<<dim3(4096), blk, 0, stream>>>(X0, S1, n5g, n5b, X1, nullptr);

    // 20. transpose to (B, 1, 1024, 256)
    transpose_out_k<<<dim3(8, 32, 16), blk, 0, stream>>>(X1, out);

    (void)in_sizes; (void)n_in; (void)out_size; (void)ws_size;
}

// Round 3
// 845.581 us; speedup vs baseline: 4.1283x; 1.1818x over previous
//
#include <hip/hip_runtime.h>
#include <hip/hip_bf16.h>

// FrameTransformer: B=16, C=8, BINS=1024, W=256, FF=2048, NB=4
// tokens = B*W = 4096, feature width 1024, FF width 4096, head dim 256.
#define EPSF 1e-5f

typedef unsigned short u16;
typedef unsigned int   u32;
typedef __attribute__((ext_vector_type(8))) short bf16x8;
typedef __attribute__((ext_vector_type(4))) float f32x4;

__device__ __forceinline__ u16 f2bf(float f) {
    u32 u = __builtin_bit_cast(u32, f);
    u32 r = u + 0x7fffu + ((u >> 16) & 1u);
    return (u16)(r >> 16);
}
__device__ __forceinline__ float bf2f(u16 h) {
    return __builtin_bit_cast(float, (u32)h << 16);
}
__device__ __forceinline__ void gld16(void* lds, const void* gsrc) {
    __builtin_amdgcn_global_load_lds(
        (const __attribute__((address_space(1))) u32*)gsrc,
        (__attribute__((address_space(3))) u32*)lds, 16, 0, 0);
}

__device__ __forceinline__ float wred_sum(float v) {
#pragma unroll
    for (int off = 32; off; off >>= 1) v += __shfl_xor(v, off, 64);
    return v;
}
__device__ __forceinline__ float wred_max(float v) {
#pragma unroll
    for (int off = 32; off; off >>= 1) v = fmaxf(v, __shfl_xor(v, off, 64));
    return v;
}
__device__ __forceinline__ void block_red2(float& s1, float& s2, int tid) {
    __shared__ float red[8];
    s1 = wred_sum(s1); s2 = wred_sum(s2);
    const int lane = tid & 63, wid = tid >> 6;
    if (!lane) { red[wid] = s1; red[4 + wid] = s2; }
    __syncthreads();
    s1 = red[0] + red[1] + red[2] + red[3];
    s2 = red[4] + red[5] + red[6] + red[7];
}

// ---------------- converters ----------------
__global__ __launch_bounds__(256)
void wcvt_k(const float* __restrict__ src, u16* __restrict__ dst, int n4)
{
    const int i = blockIdx.x * 256 + threadIdx.x;
    if (i >= n4) return;
    const float4 v = ((const float4*)src)[i];
    ushort4 o; o.x = f2bf(v.x); o.y = f2bf(v.y); o.z = f2bf(v.z); o.w = f2bf(v.w);
    ((ushort4*)dst)[i] = o;
}
// c1R_w (o,ci,ks=3) -> Wt (o, ks, ci) bf16
__global__ __launch_bounds__(256)
void c1rcvt_k(const float* __restrict__ src, u16* __restrict__ dst)
{
    const int i = blockIdx.x * 256 + threadIdx.x;     // over 1024*3072
    const int q = i / 3072, rem = i - q * 3072;
    const int ks = rem >> 10, ci = rem & 1023;
    dst[i] = f2bf(src[((long)q * 1024 + ci) * 3 + ks]);
}
// er (d=256, c=256) f32 -> erT (c, d) bf16
__global__ __launch_bounds__(256)
void ercvt_k(const float* __restrict__ er, u16* __restrict__ erT)
{
    const int i = blockIdx.x * 256 + threadIdx.x;     // over 65536
    const int c = i >> 8, d = i & 255;
    erT[i] = f2bf(er[d * 256 + c]);
}
// c2dw_w (c,1,9) -> wdwT (9, 4096) f32
__global__ __launch_bounds__(256)
void dwcvt_k(const float* __restrict__ src, float* __restrict__ dst)
{
    const int i = blockIdx.x * 256 + threadIdx.x;     // over 9*4096
    if (i >= 9 * 4096) return;
    const int k = i >> 12, c = i & 4095;
    dst[i] = src[c * 9 + k];
}
__global__ __launch_bounds__(256)
void zero_k(u16* __restrict__ p, int n)
{
    const int i = blockIdx.x * 256 + threadIdx.x;
    if (i < n) p[i] = 0;
}

// ---------------- stage 1: bottleneck 1x1 conv + BN + ReLU + transpose ----------------
__global__ __launch_bounds__(256)
void bottleneck_k(const float* __restrict__ x, const float* __restrict__ bw,
                  const float* __restrict__ bn_g, const float* __restrict__ bn_b,
                  const float* __restrict__ bn_m, const float* __restrict__ bn_v,
                  float* __restrict__ xs, u16* __restrict__ xsb)
{
    __shared__ float tile[32][33];
    const int b = blockIdx.z, h0 = blockIdx.y * 32, w0 = blockIdx.x * 32;
    const int tid = threadIdx.x, c = tid & 31, r = tid >> 5;
    float wreg[8];
#pragma unroll
    for (int ch = 0; ch < 8; ++ch) wreg[ch] = bw[ch];
    const float sc = bn_g[0] * rsqrtf(bn_v[0] + EPSF);
    const float sh = bn_b[0] - bn_m[0] * sc;
#pragma unroll
    for (int it = 0; it < 4; ++it) {
        const int h = h0 + r + it * 8;
        const int w = w0 + c;
        float acc = 0.f;
#pragma unroll
        for (int ch = 0; ch < 8; ++ch)
            acc += x[(((long)b * 8 + ch) * 1024 + h) * 256 + w] * wreg[ch];
        tile[r + it * 8][c] = fmaxf(acc * sc + sh, 0.f);
    }
    __syncthreads();
#pragma unroll
    for (int it = 0; it < 4; ++it) {
        const int wl = r + it * 8;
        const float v = tile[c][wl];
        const long o = ((long)b * 256 + w0 + wl) * 1024 + h0 + c;
        xs[o] = v;
        xsb[o] = f2bf(v);
    }
}

// ---------------- bf16 MFMA GEMM: C[M,N] = A[M,K] @ B[N,K]^T ----------------
template<int ACT, int OUTBF, int BIAS>
__global__ __launch_bounds__(256)
void gemm_bf16_k(const u16* __restrict__ A, const u16* __restrict__ B,
                 const float* __restrict__ bias, void* __restrict__ Cout,
                 int N, int K)
{
    __shared__ __align__(16) u16 As[8192];
    __shared__ __align__(16) u16 Bs[8192];
    const int m0 = blockIdx.y * 128, n0 = blockIdx.x * 128;
    const int tid = threadIdx.x;
    const int lane = tid & 63, wid = tid >> 6;
    const int wr = (wid >> 1) * 64, wc = (wid & 1) * 64;
    const int l15 = lane & 15, l4 = lane >> 4;
    f32x4 acc[4][4] = {};
    for (int k0 = 0; k0 < K; k0 += 64) {
#pragma unroll
        for (int it = 0; it < 4; ++it) {
            const int oe = it * 2048 + tid * 8;
            const int row = oe >> 6, col = oe & 63;
            gld16(&As[oe], A + (long)(m0 + row) * K + k0 + col);
            gld16(&Bs[oe], B + (long)(n0 + row) * K + k0 + col);
        }
        __syncthreads();
#pragma unroll
        for (int kk = 0; kk < 2; ++kk) {
            bf16x8 af[4], bf[4];
#pragma unroll
            for (int i = 0; i < 4; ++i) {
                af[i] = *(const bf16x8*)&As[(wr + i * 16 + l15) * 64 + kk * 32 + l4 * 8];
                bf[i] = *(const bf16x8*)&Bs[(wc + i * 16 + l15) * 64 + kk * 32 + l4 * 8];
            }
#pragma unroll
            for (int i = 0; i < 4; ++i)
#pragma unroll
                for (int j = 0; j < 4; ++j)
                    acc[i][j] = __builtin_amdgcn_mfma_f32_16x16x32_bf16(af[i], bf[j], acc[i][j], 0, 0, 0);
        }
        __syncthreads();
    }
    float* Cf = (float*)Cout;
    u16*   Cb = (u16*)Cout;
#pragma unroll
    for (int i = 0; i < 4; ++i)
#pragma unroll
        for (int j = 0; j < 4; ++j) {
            const int n = n0 + wc + j * 16 + l15;
            const float bv = BIAS ? bias[n] : 0.f;
#pragma unroll
            for (int q = 0; q < 4; ++q) {
                const int m = m0 + wr + i * 16 + l4 * 4 + q;
                float v = acc[i][j][q] + bv;
                if (ACT) v = fmaxf(v, 0.f);
                if (OUTBF) Cb[(long)m * N + n] = f2bf(v);
                else       Cf[(long)m * N + n] = v;
            }
        }
}

// ---------------- batched bf16 MFMA GEMM (attention heads, z = zb*4+zn) ----------------
// EPI==1: scores epilogue v*scale + |m-n|/2*dwp[zn,m] + qer[z, n, m]
template<int EPI, int OUTBF>
__global__ __launch_bounds__(256)
void gemm_bf16_bat_k(const u16* __restrict__ A, const u16* __restrict__ B,
                     void* __restrict__ Cout, int K, int lda, int ldb, int ldc,
                     long oAb, long oAn, long oBb, long oBn, long oCb, long oCn,
                     const float* __restrict__ qer, const float* __restrict__ dwp,
                     float scale)
{
    __shared__ __align__(16) u16 As[8192];
    __shared__ __align__(16) u16 Bs[8192];
    const int z = blockIdx.z, zb = z >> 2, zn = z & 3;
    const u16* Ab = A + zb * oAb + zn * oAn;
    const u16* Bb = B + zb * oBb + zn * oBn;
    const int m0 = blockIdx.y * 128, n0 = blockIdx.x * 128;
    const int tid = threadIdx.x;
    const int lane = tid & 63, wid = tid >> 6;
    const int wr = (wid >> 1) * 64, wc = (wid & 1) * 64;
    const int l15 = lane & 15, l4 = lane >> 4;
    f32x4 acc[4][4] = {};
    for (int k0 = 0; k0 < K; k0 += 64) {
#pragma unroll
        for (int it = 0; it < 4; ++it) {
            const int oe = it * 2048 + tid * 8;
            const int row = oe >> 6, col = oe & 63;
            gld16(&As[oe], Ab + (long)(m0 + row) * lda + k0 + col);
            gld16(&Bs[oe], Bb + (long)(n0 + row) * ldb + k0 + col);
        }
        __syncthreads();
#pragma unroll
        for (int kk = 0; kk < 2; ++kk) {
            bf16x8 af[4], bf[4];
#pragma unroll
            for (int i = 0; i < 4; ++i) {
                af[i] = *(const bf16x8*)&As[(wr + i * 16 + l15) * 64 + kk * 32 + l4 * 8];
                bf[i] = *(const bf16x8*)&Bs[(wc + i * 16 + l15) * 64 + kk * 32 + l4 * 8];
            }
#pragma unroll
            for (int i = 0; i < 4; ++i)
#pragma unroll
                for (int j = 0; j < 4; ++j)
                    acc[i][j] = __builtin_amdgcn_mfma_f32_16x16x32_bf16(af[i], bf[j], acc[i][j], 0, 0, 0);
        }
        __syncthreads();
    }
    float* Cf = (float*)Cout + zb * oCb + zn * oCn;
    u16*   Cb = (u16*)Cout + zb * oCb + zn * oCn;
#pragma unroll
    for (int i = 0; i < 4; ++i)
#pragma unroll
        for (int j = 0; j < 4; ++j) {
            const int n = n0 + wc + j * 16 + l15;
#pragma unroll
            for (int q = 0; q < 4; ++q) {
                const int m = m0 + wr + i * 16 + l4 * 4 + q;
                float v = acc[i][j][q];
                if (EPI)
                    v = v * scale
                      + fabsf((float)(m - n)) * 0.5f * dwp[zn * 256 + m]
                      + qer[(long)z * 65536 + (long)n * 256 + m];
                if (OUTBF) Cb[(long)m * ldc + n] = f2bf(v);
                else       Cf[(long)m * ldc + n] = v;
            }
        }
}

// ---------------- conv1R as gathered bf16 MFMA GEMM ----------------
__global__ __launch_bounds__(256)
void conv3_bf16_k(const u16* __restrict__ Xb, const u16* __restrict__ Wt,
                  const u16* __restrict__ zp, float* __restrict__ C)
{
    __shared__ __align__(16) u16 As[8192];
    __shared__ __align__(16) u16 Bs[8192];
    const int m0 = blockIdx.y * 128, n0 = blockIdx.x * 128;
    const int tid = threadIdx.x;
    const int lane = tid & 63, wid = tid >> 6;
    const int wr = (wid >> 1) * 64, wc = (wid & 1) * 64;
    const int l15 = lane & 15, l4 = lane >> 4;
    f32x4 acc[4][4] = {};
    for (int k0 = 0; k0 < 3072; k0 += 64) {
        const int ks = k0 >> 10, ci0 = k0 & 1023;
#pragma unroll
        for (int it = 0; it < 4; ++it) {
            const int oe = it * 2048 + tid * 8;
            const int row = oe >> 6, col = oe & 63;
            const int t = m0 + row;
            const int wp = (t & 255) + ks - 1;
            const u16* src = ((unsigned)wp < 256u)
                ? Xb + (long)(t + ks - 1) * 1024 + ci0 + col
                : zp;
            gld16(&As[oe], src);
            gld16(&Bs[oe], Wt + (long)(n0 + row) * 3072 + k0 + col);
        }
        __syncthreads();
#pragma unroll
        for (int kk = 0; kk < 2; ++kk) {
            bf16x8 af[4], bf[4];
#pragma unroll
            for (int i = 0; i < 4; ++i) {
                af[i] = *(const bf16x8*)&As[(wr + i * 16 + l15) * 64 + kk * 32 + l4 * 8];
                bf[i] = *(const bf16x8*)&Bs[(wc + i * 16 + l15) * 64 + kk * 32 + l4 * 8];
            }
#pragma unroll
            for (int i = 0; i < 4; ++i)
#pragma unroll
                for (int j = 0; j < 4; ++j)
                    acc[i][j] = __builtin_amdgcn_mfma_f32_16x16x32_bf16(af[i], bf[j], acc[i][j], 0, 0, 0);
        }
        __syncthreads();
    }
#pragma unroll
    for (int i = 0; i < 4; ++i)
#pragma unroll
        for (int j = 0; j < 4; ++j) {
            const int n = n0 + wc + j * 16 + l15;
#pragma unroll
            for (int q = 0; q < 4; ++q) {
                const int m = m0 + wr + i * 16 + l4 * 4 + q;
                C[(long)m * 1024 + n] = fmaxf(acc[i][j][q], 0.f);
            }
        }
}

// ---------------- GLU gate + residual + LN ----------------
__global__ __launch_bounds__(256)
void glu_ln_k(const float* __restrict__ xs0, const float* __restrict__ g2,
              const float* __restrict__ gam, const float* __restrict__ bet,
              float* __restrict__ outf, u16* __restrict__ outb)
{
    const int t = blockIdx.x, tid = threadIdx.x;
    const int f0 = tid * 4;
    const float4 xv = *(const float4*)&xs0[(long)t * 1024 + f0];
    const float4 av = *(const float4*)&g2[(long)t * 2048 + f0];
    const float4 gv = *(const float4*)&g2[(long)t * 2048 + 1024 + f0];
    float vals[4];
    vals[0] = xv.x + av.x / (1.f + expf(-gv.x));
    vals[1] = xv.y + av.y / (1.f + expf(-gv.y));
    vals[2] = xv.z + av.z / (1.f + expf(-gv.z));
    vals[3] = xv.w + av.w / (1.f + expf(-gv.w));
    float s1 = vals[0] + vals[1] + vals[2] + vals[3];
    float s2 = vals[0]*vals[0] + vals[1]*vals[1] + vals[2]*vals[2] + vals[3]*vals[3];
    block_red2(s1, s2, tid);
    const float mean = s1 * (1.f / 1024.f);
    const float var  = s2 * (1.f / 1024.f) - mean * mean;
    const float rstd = rsqrtf(var + EPSF);
    const float4 gm = *(const float4*)&gam[f0];
    const float4 bt = *(const float4*)&bet[f0];
    float r0 = (vals[0] - mean) * rstd * gm.x + bt.x;
    float r1 = (vals[1] - mean) * rstd * gm.y + bt.y;
    float r2 = (vals[2] - mean) * rstd * gm.z + bt.z;
    float r3 = (vals[3] - mean) * rstd * gm.w + bt.w;
    *(float4*)&outf[(long)t * 1024 + f0] = make_float4(r0, r1, r2, r3);
    ushort4 ub; ub.x = f2bf(r0); ub.y = f2bf(r1); ub.z = f2bf(r2); ub.w = f2bf(r3);
    *(ushort4*)&outb[(long)t * 1024 + f0] = ub;
}

// ---------------- residual add + LN width 1024 ----------------
template<int WRITEBF>
__global__ __launch_bounds__(256)
void add_ln1024_k(const float* __restrict__ A, const float* __restrict__ Bv,
                  const float* __restrict__ gam, const float* __restrict__ bet,
                  float* __restrict__ outf, u16* __restrict__ outb)
{
    const int t = blockIdx.x, tid = threadIdx.x;
    const int f0 = tid * 4;
    const float4 a = *(const float4*)&A[(long)t * 1024 + f0];
    const float4 b = *(const float4*)&Bv[(long)t * 1024 + f0];
    float vals[4] = {a.x + b.x, a.y + b.y, a.z + b.z, a.w + b.w};
    float s1 = vals[0] + vals[1] + vals[2] + vals[3];
    float s2 = vals[0]*vals[0] + vals[1]*vals[1] + vals[2]*vals[2] + vals[3]*vals[3];
    block_red2(s1, s2, tid);
    const float mean = s1 * (1.f / 1024.f);
    const float var  = s2 * (1.f / 1024.f) - mean * mean;
    const float rstd = rsqrtf(var + EPSF);
    const float4 gm = *(const float4*)&gam[f0];
    const float4 bt = *(const float4*)&bet[f0];
    float r0 = (vals[0] - mean) * rstd * gm.x + bt.x;
    float r1 = (vals[1] - mean) * rstd * gm.y + bt.y;
    float r2 = (vals[2] - mean) * rstd * gm.z + bt.z;
    float r3 = (vals[3] - mean) * rstd * gm.w + bt.w;
    *(float4*)&outf[(long)t * 1024 + f0] = make_float4(r0, r1, r2, r3);
    if (WRITEBF) {
        ushort4 ub; ub.x = f2bf(r0); ub.y = f2bf(r1); ub.z = f2bf(r2); ub.w = f2bf(r3);
        *(ushort4*)&outb[(long)t * 1024 + f0] = ub;
    }
}

// ---------------- n2: LN(c1L + pad(conv3)) width 4096 ----------------
__global__ __launch_bounds__(256)
void add_ln4096_k(const float* __restrict__ A, const float* __restrict__ Bv,
                  const float* __restrict__ gam, const float* __restrict__ bet,
                  u16* __restrict__ outb)
{
    const int t = blockIdx.x, tid = threadIdx.x;
    float vals[16];
    float s1 = 0.f, s2 = 0.f;
#pragma unroll
    for (int c = 0; c < 4; ++c) {
        const int f0 = tid * 16 + c * 4;
        float4 a = *(const float4*)&A[(long)t * 4096 + f0];
        if (f0 < 1024) {
            const float4 b = *(const float4*)&Bv[(long)t * 1024 + f0];
            a.x += b.x; a.y += b.y; a.z += b.z; a.w += b.w;
        }
        vals[c*4+0] = a.x; vals[c*4+1] = a.y; vals[c*4+2] = a.z; vals[c*4+3] = a.w;
        s1 += a.x + a.y + a.z + a.w;
        s2 += a.x*a.x + a.y*a.y + a.z*a.z + a.w*a.w;
    }
    block_red2(s1, s2, tid);
    const float mean = s1 * (1.f / 4096.f);
    const float var  = s2 * (1.f / 4096.f) - mean * mean;
    const float rstd = rsqrtf(var + EPSF);
#pragma unroll
    for (int c = 0; c < 4; ++c) {
        const int f0 = tid * 16 + c * 4;
        const float4 gm = *(const float4*)&gam[f0];
        const float4 bt = *(const float4*)&bet[f0];
        ushort4 ub;
        ub.x = f2bf((vals[c*4+0] - mean) * rstd * gm.x + bt.x);
        ub.y = f2bf((vals[c*4+1] - mean) * rstd * gm.y + bt.y);
        ub.z = f2bf((vals[c*4+2] - mean) * rstd * gm.z + bt.z);
        ub.w = f2bf((vals[c*4+3] - mean) * rstd * gm.w + bt.w);
        *(ushort4*)&outb[(long)t * 4096 + f0] = ub;
    }
}

// ---------------- depthwise conv width-9, 8 channels/thread ----------------
__global__ __launch_bounds__(256)
void dwconv8_k(const u16* __restrict__ h, const float* __restrict__ wT,
               u16* __restrict__ out)
{
    const long idx = (long)blockIdx.x * 256 + threadIdx.x;  // over 4096*512
    const int cg = (int)(idx & 511);
    const int t  = (int)(idx >> 9);
    const int w  = t & 255;
    const int c0 = cg * 8;
    float acc[8] = {};
#pragma unroll
    for (int k = 0; k < 9; ++k) {
        const int wp = w + k - 4;
        if ((unsigned)wp < 256u) {
            const bf16x8 hv = *(const bf16x8*)&h[(long)(t + k - 4) * 4096 + c0];
            const float4 w0 = *(const float4*)&wT[k * 4096 + c0];
            const float4 w1 = *(const float4*)&wT[k * 4096 + c0 + 4];
            acc[0] += bf2f((u16)hv[0]) * w0.x;
            acc[1] += bf2f((u16)hv[1]) * w0.y;
            acc[2] += bf2f((u16)hv[2]) * w0.z;
            acc[3] += bf2f((u16)hv[3]) * w0.w;
            acc[4] += bf2f((u16)hv[4]) * w1.x;
            acc[5] += bf2f((u16)hv[5]) * w1.y;
            acc[6] += bf2f((u16)hv[6]) * w1.z;
            acc[7] += bf2f((u16)hv[7]) * w1.w;
        }
    }
    bf16x8 res;
#pragma unroll
    for (int j = 0; j < 8; ++j) res[j] = (short)f2bf(acc[j]);
    *(bf16x8*)&out[(long)t * 4096 + c0] = res;
}

// ---------------- softmax over rows of 256, bf16 out ----------------
__global__ __launch_bounds__(256)
void softmax_k(const float* __restrict__ s, u16* __restrict__ p)
{
    const int row = blockIdx.x, tid = threadIdx.x;
    const float v = s[(long)row * 256 + tid];
    __shared__ float red[4];
    __shared__ float red2[4];
    float m = wred_max(v);
    const int lane = tid & 63, wid = tid >> 6;
    if (!lane) red[wid] = m;
    __syncthreads();
    m = fmaxf(fmaxf(red[0], red[1]), fmaxf(red[2], red[3]));
    const float e = expf(v - m);
    float sum = wred_sum(e);
    if (!lane) red2[wid] = sum;
    __syncthreads();
    sum = red2[0] + red2[1] + red2[2] + red2[3];
    p[(long)row * 256 + tid] = f2bf(e / sum);
}

// ---------------- V (token,feat) bf16 -> Vt (z, d, w) bf16 ----------------
__global__ __launch_bounds__(256)
void vtrans_k(const u16* __restrict__ Vb, u16* __restrict__ Vt)
{
    __shared__ u16 t[32][33];
    const int z = blockIdx.z, zb = z >> 2, zn = z & 3;
    const int w0 = blockIdx.x * 32, d0 = blockIdx.y * 32;
    const int tid = threadIdx.x, c = tid & 31, r = tid >> 5;
#pragma unroll
    for (int it = 0; it < 4; ++it) {
        const int wl = r + it * 8;
        t[wl][c] = Vb[(long)(zb * 256 + w0 + wl) * 1024 + zn * 256 + d0 + c];
    }
    __syncthreads();
#pragma unroll
    for (int it = 0; it < 4; ++it) {
        const int dl = r + it * 8;
        Vt[((long)z * 256 + d0 + dl) * 256 + w0 + c] = t[c][dl];
    }
}

// ---------------- final transpose (tokens,1024) -> (B,1,1024,256) ----------------
__global__ __launch_bounds__(256)
void transpose_out_k(const float* __restrict__ xs, float* __restrict__ out)
{
    __shared__ float tile[32][33];
    const int b = blockIdx.z, f0 = blockIdx.y * 32, w0 = blockIdx.x * 32;
    const int tid = threadIdx.x, c = tid & 31, r = tid >> 5;
#pragma unroll
    for (int it = 0; it < 4; ++it) {
        const int w = w0 + r + it * 8;
        tile[r + it * 8][c] = xs[((long)b * 256 + w) * 1024 + f0 + c];
    }
    __syncthreads();
#pragma unroll
    for (int it = 0; it < 4; ++it) {
        const int fl = r + it * 8;
        out[((long)b * 1024 + f0 + fl) * 256 + w0 + c] = tile[c][fl];
    }
}

// =======================================================================
extern "C" void kernel_launch(void* const* d_in, const int* in_sizes, int n_in,
                              void* d_out, int out_size, void* d_ws, size_t ws_size,
                              hipStream_t stream)
{
    const float* x      = (const float*)d_in[0];
    const float* bott_w = (const float*)d_in[1];
    const float* bn_g   = (const float*)d_in[2];
    const float* bn_b   = (const float*)d_in[3];
    const float* bn_m   = (const float*)d_in[4];
    const float* bn_v   = (const float*)d_in[5];
    const float* glu_w  = (const float*)d_in[6];
    const float* n1g    = (const float*)d_in[7];
    const float* n1b    = (const float*)d_in[8];
    const float* c1L_w  = (const float*)d_in[9];
    const float* c1R_w  = (const float*)d_in[10];
    const float* n2g    = (const float*)d_in[11];
    const float* n2b    = (const float*)d_in[12];
    const float* c2dw_w = (const float*)d_in[13];
    const float* c2pw_w = (const float*)d_in[14];
    const float* n3g    = (const float*)d_in[15];
    const float* n3b    = (const float*)d_in[16];
    const float* qw     = (const float*)d_in[17];
    const float* qb     = (const float*)d_in[18];
    const float* kw     = (const float*)d_in[19];
    const float* kb     = (const float*)d_in[20];
    const float* vw     = (const float*)d_in[21];
    const float* vb     = (const float*)d_in[22];
    const float* ow     = (const float*)d_in[23];
    const float* ob     = (const float*)d_in[24];
    const float* er     = (const float*)d_in[25];
    const float* dist_w = (const float*)d_in[26];
    const float* n4g    = (const float*)d_in[27];
    const float* n4b    = (const float*)d_in[28];
    const float* c3_w   = (const float*)d_in[29];
    const float* c4_w   = (const float*)d_in[30];
    const float* n5g    = (const float*)d_in[31];
    const float* n5b    = (const float*)d_in[32];
    float* out = (float*)d_out;

    // ---- workspace layout (MiB offsets) ----
    char* Wb_ = (char*)d_ws;
    auto F  = [&](size_t mib) { return (float*)(Wb_ + (mib << 20)); };
    auto Bf = [&](size_t mib) { return (u16*)  (Wb_ + (mib << 20)); };
    float* X0  = F(0);    // xs chain A (4096x1024 f32)
    float* X1  = F(16);   // xs chain B
    float* S0  = F(32);   // conv3 out / scores f32 (64x256x256)
    float* S1  = F(48);   // c2pw out / c4 out
    float* H0  = F(64);   // GLU out then c1L out (4096x4096 f32)
    u16*   H0b = Bf(128); // c3 out bf16 / n2 out bf16 (4096x4096)
    u16*   H1b = Bf(128);
    u16*   Hdw = Bf(160); // dwconv out bf16
    float* QER = F(192);  // 64x256x256 f32 (16 MiB)
    u16*   Qb  = Bf(208);
    u16*   Kb  = Bf(216);
    u16*   Vb  = Bf(224);
    u16*   Vt  = Bf(232);
    u16*   Pb  = Bf(240);
    u16* X1b = Bf(256); u16* X0b = Bf(264); u16* X2b = Bf(272);
    u16* S1b = Bf(280); u16* X3b = Bf(288);
    u16* wGLU = Bf(296); u16* wC1L = Bf(301); u16* wC1R = Bf(310);
    u16* wC2P = Bf(317); u16* wQ = Bf(326);  u16* wK = Bf(329);
    u16* wV  = Bf(332);  u16* wO = Bf(335);  u16* wC3 = Bf(338); u16* wC4 = Bf(347);
    u16* zp  = Bf(356);  u16* erT = Bf(357);
    float* wdwT = F(358);

    const dim3 blk(256);
    const long Z0 = 0;

    // 0. weight conversions + zero page
    zero_k<<<dim3(32), blk, 0, stream>>>(zp, 8192);
    wcvt_k<<<dim3(2048), blk, 0, stream>>>(glu_w,  wGLU, 524288);
    wcvt_k<<<dim3(4096), blk, 0, stream>>>(c1L_w,  wC1L, 1048576);
    c1rcvt_k<<<dim3(12288), blk, 0, stream>>>(c1R_w, wC1R);
    wcvt_k<<<dim3(4096), blk, 0, stream>>>(c2pw_w, wC2P, 1048576);
    wcvt_k<<<dim3(1024), blk, 0, stream>>>(qw, wQ, 262144);
    wcvt_k<<<dim3(1024), blk, 0, stream>>>(kw, wK, 262144);
    wcvt_k<<<dim3(1024), blk, 0, stream>>>(vw, wV, 262144);
    wcvt_k<<<dim3(1024), blk, 0, stream>>>(ow, wO, 262144);
    wcvt_k<<<dim3(4096), blk, 0, stream>>>(c3_w, wC3, 1048576);
    wcvt_k<<<dim3(4096), blk, 0, stream>>>(c4_w, wC4, 1048576);
    ercvt_k<<<dim3(256), blk, 0, stream>>>(er, erT);
    dwcvt_k<<<dim3(144), blk, 0, stream>>>(c2dw_w, wdwT);

    // 1. bottleneck + BN + ReLU + transpose
    bottleneck_k<<<dim3(8, 32, 16), blk, 0, stream>>>(x, bott_w, bn_g, bn_b, bn_m, bn_v, X1, X1b);

    // 2. GLU matmul -> H0 (4096x2048 f32)
    gemm_bf16_k<0,0,0><<<dim3(16, 32), blk, 0, stream>>>(X1b, wGLU, nullptr, H0, 2048, 1024);

    // 3. n1: LN(xs0 + a*sigmoid(g)) -> X0 + X0b
    glu_ln_k<<<dim3(4096), blk, 0, stream>>>(X1, H0, n1g, n1b, X0, X0b);

    // 4. c1L: relu -> H0 (4096x4096 f32)
    gemm_bf16_k<1,0,0><<<dim3(32, 32), blk, 0, stream>>>(X0b, wC1L, nullptr, H0, 4096, 1024);

    // 5. c1R conv, relu -> S0 f32
    conv3_bf16_k<<<dim3(8, 32), blk, 0, stream>>>(X0b, wC1R, zp, S0);

    // 6. n2: LN(H0 + pad(S0)) -> H1b bf16
    add_ln4096_k<<<dim3(4096), blk, 0, stream>>>(H0, S0, n2g, n2b, H1b);

    // 7. depthwise conv9 (vectorized x8): H1b -> Hdw
    dwconv8_k<<<dim3(8192), blk, 0, stream>>>(H1b, wdwT, Hdw);

    // 8. c2pw -> S1 f32 (4096x1024)
    gemm_bf16_k<0,0,0><<<dim3(8, 32), blk, 0, stream>>>(Hdw, wC2P, nullptr, S1, 1024, 4096);

    // 9. n3: LN(X0 + S1) -> X1 + X2b
    add_ln1024_k<1><<<dim3(4096), blk, 0, stream>>>(X0, S1, n3g, n3b, X1, X2b);

    // 10. q/k/v projections (+bias), bf16 outputs
    gemm_bf16_k<0,1,1><<<dim3(8, 32), blk, 0, stream>>>(X2b, wQ, qb, Qb, 1024, 1024);
    gemm_bf16_k<0,1,1><<<dim3(8, 32), blk, 0, stream>>>(X2b, wK, kb, Kb, 1024, 1024);
    gemm_bf16_k<0,1,1><<<dim3(8, 32), blk, 0, stream>>>(X2b, wV, vb, Vb, 1024, 1024);

    // 10b. V transpose per head -> Vt (z, d, w)
    vtrans_k<<<dim3(8, 8, 64), blk, 0, stream>>>(Vb, Vt);

    // 11. qer = Q_head @ erT^T -> QER f32 (z, w, c)
    gemm_bf16_bat_k<0,0><<<dim3(2, 2, 64), blk, 0, stream>>>(Qb, erT, QER,
        256, 1024, 256, 256,
        (long)256 * 1024, 256, Z0, Z0,
        (long)4 * 65536, 65536, nullptr, nullptr, 1.f);

    // 12. scores = QK^T/32 + dist*dist_w + qer^T -> S0 f32
    gemm_bf16_bat_k<1,0><<<dim3(2, 2, 64), blk, 0, stream>>>(Qb, Kb, S0,
        256, 1024, 1024, 256,
        (long)256 * 1024, 256, (long)256 * 1024, 256,
        (long)4 * 65536, 65536, QER, dist_w, 1.f / 32.f);

    // 13. softmax rows -> Pb bf16
    softmax_k<<<dim3(16384), blk, 0, stream>>>(S0, Pb);

    // 14. o = P @ Vt^T -> S1b bf16 (concat layout)
    gemm_bf16_bat_k<0,1><<<dim3(2, 2, 64), blk, 0, stream>>>(Pb, Vt, S1b,
        256, 256, 256, 1024,
        (long)4 * 65536, 65536, (long)4 * 65536, 65536,
        (long)256 * 1024, 256, nullptr, nullptr, 1.f);

    // 15. output projection (+bias) -> S0 f32
    gemm_bf16_k<0,0,1><<<dim3(8, 32), blk, 0, stream>>>(S1b, wO, ob, S0, 1024, 1024);

    // 16. n4: LN(X1 + S0) -> X0 + X3b
    add_ln1024_k<1><<<dim3(4096), blk, 0, stream>>>(X1, S0, n4g, n4b, X0, X3b);

    // 17. c3: relu -> H0b bf16 (4096x4096)
    gemm_bf16_k<1,1,0><<<dim3(32, 32), blk, 0, stream>>>(X3b, wC3, nullptr, H0b, 4096, 1024);

    // 18. c4 -> S1 f32
    gemm_bf16_k<0,0,0><<<dim3(8, 32), blk, 0, stream>>>(H0b, wC4, nullptr, S1, 1024, 4096);

    // 19. n5: LN(X0 + S1) -> X1 (f32 only)
    add_ln1024_k<0><<<dim3(4096), blk, 0, stream>>>(X0, S1, n5g, n5b, X1, nullptr);

    // 20. transpose to (B, 1, 1024, 256)
    transpose_out_k<<<dim3(8, 32, 16), blk, 0, stream>>>(X1, out);

    (void)in_sizes; (void)n_in; (void)out_size; (void)ws_size;
}

// Round 4
// 733.581 us; speedup vs baseline: 4.7586x; 1.1527x over previous
//
#include <hip/hip_runtime.h>
#include <hip/hip_bf16.h>

// FrameTransformer: B=16, C=8, BINS=1024, W=256, FF=2048, NB=4
// tokens = B*W = 4096, feature width 1024, FF width 4096, head dim 256.
#define EPSF 1e-5f

typedef unsigned short u16;
typedef unsigned int   u32;
typedef __attribute__((ext_vector_type(8))) short bf16x8;
typedef __attribute__((ext_vector_type(4))) float f32x4;

__device__ __forceinline__ u16 f2bf(float f) {
    u32 u = __builtin_bit_cast(u32, f);
    u32 r = u + 0x7fffu + ((u >> 16) & 1u);
    return (u16)(r >> 16);
}
__device__ __forceinline__ float bf2f(u16 h) {
    return __builtin_bit_cast(float, (u32)h << 16);
}
__device__ __forceinline__ void gld16(void* lds, const void* gsrc) {
    __builtin_amdgcn_global_load_lds(
        (const __attribute__((address_space(1))) u32*)gsrc,
        (__attribute__((address_space(3))) u32*)lds, 16, 0, 0);
}

__device__ __forceinline__ float wred_sum(float v) {
#pragma unroll
    for (int off = 32; off; off >>= 1) v += __shfl_xor(v, off, 64);
    return v;
}
__device__ __forceinline__ float wred_max(float v) {
#pragma unroll
    for (int off = 32; off; off >>= 1) v = fmaxf(v, __shfl_xor(v, off, 64));
    return v;
}
__device__ __forceinline__ void block_red2(float& s1, float& s2, int tid) {
    __shared__ float red[8];
    s1 = wred_sum(s1); s2 = wred_sum(s2);
    const int lane = tid & 63, wid = tid >> 6;
    if (!lane) { red[wid] = s1; red[4 + wid] = s2; }
    __syncthreads();
    s1 = red[0] + red[1] + red[2] + red[3];
    s2 = red[4] + red[5] + red[6] + red[7];
}

// ---------------- converters ----------------
__global__ __launch_bounds__(256)
void wcvt_k(const float* __restrict__ src, u16* __restrict__ dst, int n4)
{
    const int i = blockIdx.x * 256 + threadIdx.x;
    if (i >= n4) return;
    const float4 v = ((const float4*)src)[i];
    ushort4 o; o.x = f2bf(v.x); o.y = f2bf(v.y); o.z = f2bf(v.z); o.w = f2bf(v.w);
    ((ushort4*)dst)[i] = o;
}
// c1R_w (o,ci,ks=3) -> Wt (o, ks, ci) bf16
__global__ __launch_bounds__(256)
void c1rcvt_k(const float* __restrict__ src, u16* __restrict__ dst)
{
    const int i = blockIdx.x * 256 + threadIdx.x;     // over 1024*3072
    const int q = i / 3072, rem = i - q * 3072;
    const int ks = rem >> 10, ci = rem & 1023;
    dst[i] = f2bf(src[((long)q * 1024 + ci) * 3 + ks]);
}
// er (d=256, c=256) f32 -> erT (c, d) bf16
__global__ __launch_bounds__(256)
void ercvt_k(const float* __restrict__ er, u16* __restrict__ erT)
{
    const int i = blockIdx.x * 256 + threadIdx.x;     // over 65536
    const int c = i >> 8, d = i & 255;
    erT[i] = f2bf(er[d * 256 + c]);
}
// c2dw_w (c,1,9) -> wdwT (9, 4096) f32
__global__ __launch_bounds__(256)
void dwcvt_k(const float* __restrict__ src, float* __restrict__ dst)
{
    const int i = blockIdx.x * 256 + threadIdx.x;     // over 9*4096
    if (i >= 9 * 4096) return;
    const int k = i >> 12, c = i & 4095;
    dst[i] = src[c * 9 + k];
}
__global__ __launch_bounds__(256)
void zero_k(u16* __restrict__ p, int n)
{
    const int i = blockIdx.x * 256 + threadIdx.x;
    if (i < n) p[i] = 0;
}
// concat q/k/v biases -> 3072
__global__ __launch_bounds__(256)
void biascat_k(const float* __restrict__ b0, const float* __restrict__ b1,
               const float* __restrict__ b2, float* __restrict__ dst)
{
    const int i = blockIdx.x * 256 + threadIdx.x;     // over 3072
    const float* s = (i < 1024) ? b0 : ((i < 2048) ? b1 : b2);
    dst[i] = s[i & 1023];
}

// ---------------- stage 1: bottleneck 1x1 conv + BN + ReLU + transpose ----------------
__global__ __launch_bounds__(256)
void bottleneck_k(const float* __restrict__ x, const float* __restrict__ bw,
                  const float* __restrict__ bn_g, const float* __restrict__ bn_b,
                  const float* __restrict__ bn_m, const float* __restrict__ bn_v,
                  float* __restrict__ xs, u16* __restrict__ xsb)
{
    __shared__ float tile[32][33];
    const int b = blockIdx.z, h0 = blockIdx.y * 32, w0 = blockIdx.x * 32;
    const int tid = threadIdx.x, c = tid & 31, r = tid >> 5;
    float wreg[8];
#pragma unroll
    for (int ch = 0; ch < 8; ++ch) wreg[ch] = bw[ch];
    const float sc = bn_g[0] * rsqrtf(bn_v[0] + EPSF);
    const float sh = bn_b[0] - bn_m[0] * sc;
#pragma unroll
    for (int it = 0; it < 4; ++it) {
        const int h = h0 + r + it * 8;
        const int w = w0 + c;
        float acc = 0.f;
#pragma unroll
        for (int ch = 0; ch < 8; ++ch)
            acc += x[(((long)b * 8 + ch) * 1024 + h) * 256 + w] * wreg[ch];
        tile[r + it * 8][c] = fmaxf(acc * sc + sh, 0.f);
    }
    __syncthreads();
#pragma unroll
    for (int it = 0; it < 4; ++it) {
        const int wl = r + it * 8;
        const float v = tile[c][wl];
        const long o = ((long)b * 256 + w0 + wl) * 1024 + h0 + c;
        xs[o] = v;
        xsb[o] = f2bf(v);
    }
}

// ---------------- bf16 MFMA GEMM: C[M,N] = A[M,K] @ B[N,K]^T ----------------
// 128x128 tile, 4 waves. SPLITK>1: blockIdx.z = K-slice, f32 partial outputs.
template<int ACT, int OUTBF, int BIAS, int SPLITK>
__global__ __launch_bounds__(256)
void gemm_bf16_k(const u16* __restrict__ A, const u16* __restrict__ B,
                 const float* __restrict__ bias, void* __restrict__ Cout,
                 int N, int K /*per slice*/, int lda, int ldb, long partStride)
{
    __shared__ __align__(16) u16 As[8192];
    __shared__ __align__(16) u16 Bs[8192];
    const int m0 = blockIdx.y * 128, n0 = blockIdx.x * 128;
    const int koff = (SPLITK > 1) ? blockIdx.z * K : 0;
    const int tid = threadIdx.x;
    const int lane = tid & 63, wid = tid >> 6;
    const int wr = (wid >> 1) * 64, wc = (wid & 1) * 64;
    const int l15 = lane & 15, l4 = lane >> 4;
    f32x4 acc[4][4] = {};
    for (int k0 = 0; k0 < K; k0 += 64) {
#pragma unroll
        for (int it = 0; it < 4; ++it) {
            const int oe = it * 2048 + tid * 8;
            const int row = oe >> 6, col = oe & 63;
            gld16(&As[oe], A + (long)(m0 + row) * lda + koff + k0 + col);
            gld16(&Bs[oe], B + (long)(n0 + row) * ldb + koff + k0 + col);
        }
        __syncthreads();
#pragma unroll
        for (int kk = 0; kk < 2; ++kk) {
            bf16x8 af[4], bf[4];
#pragma unroll
            for (int i = 0; i < 4; ++i) {
                af[i] = *(const bf16x8*)&As[(wr + i * 16 + l15) * 64 + kk * 32 + l4 * 8];
                bf[i] = *(const bf16x8*)&Bs[(wc + i * 16 + l15) * 64 + kk * 32 + l4 * 8];
            }
#pragma unroll
            for (int i = 0; i < 4; ++i)
#pragma unroll
                for (int j = 0; j < 4; ++j)
                    acc[i][j] = __builtin_amdgcn_mfma_f32_16x16x32_bf16(af[i], bf[j], acc[i][j], 0, 0, 0);
        }
        __syncthreads();
    }
    float* Cf = (float*)Cout + ((SPLITK > 1) ? (long)blockIdx.z * partStride : 0);
    u16*   Cb = (u16*)Cout;
#pragma unroll
    for (int i = 0; i < 4; ++i)
#pragma unroll
        for (int j = 0; j < 4; ++j) {
            const int n = n0 + wc + j * 16 + l15;
            const float bv = BIAS ? bias[n] : 0.f;
#pragma unroll
            for (int q = 0; q < 4; ++q) {
                const int m = m0 + wr + i * 16 + l4 * 4 + q;
                float v = acc[i][j][q] + bv;
                if (ACT) v = fmaxf(v, 0.f);
                if (OUTBF) Cb[(long)m * N + n] = f2bf(v);
                else       Cf[(long)m * N + n] = v;
            }
        }
}

// ---------------- batched bf16 MFMA GEMM (attention heads, z = zb*4+zn) ----------------
template<int EPI, int OUTBF>
__global__ __launch_bounds__(256)
void gemm_bf16_bat_k(const u16* __restrict__ A, const u16* __restrict__ B,
                     void* __restrict__ Cout, int K, int lda, int ldb, int ldc,
                     long oAb, long oAn, long oBb, long oBn, long oCb, long oCn,
                     const float* __restrict__ qer, const float* __restrict__ dwp,
                     float scale)
{
    __shared__ __align__(16) u16 As[8192];
    __shared__ __align__(16) u16 Bs[8192];
    const int z = blockIdx.z, zb = z >> 2, zn = z & 3;
    const u16* Ab = A + zb * oAb + zn * oAn;
    const u16* Bb = B + zb * oBb + zn * oBn;
    const int m0 = blockIdx.y * 128, n0 = blockIdx.x * 128;
    const int tid = threadIdx.x;
    const int lane = tid & 63, wid = tid >> 6;
    const int wr = (wid >> 1) * 64, wc = (wid & 1) * 64;
    const int l15 = lane & 15, l4 = lane >> 4;
    f32x4 acc[4][4] = {};
    for (int k0 = 0; k0 < K; k0 += 64) {
#pragma unroll
        for (int it = 0; it < 4; ++it) {
            const int oe = it * 2048 + tid * 8;
            const int row = oe >> 6, col = oe & 63;
            gld16(&As[oe], Ab + (long)(m0 + row) * lda + k0 + col);
            gld16(&Bs[oe], Bb + (long)(n0 + row) * ldb + k0 + col);
        }
        __syncthreads();
#pragma unroll
        for (int kk = 0; kk < 2; ++kk) {
            bf16x8 af[4], bf[4];
#pragma unroll
            for (int i = 0; i < 4; ++i) {
                af[i] = *(const bf16x8*)&As[(wr + i * 16 + l15) * 64 + kk * 32 + l4 * 8];
                bf[i] = *(const bf16x8*)&Bs[(wc + i * 16 + l15) * 64 + kk * 32 + l4 * 8];
            }
#pragma unroll
            for (int i = 0; i < 4; ++i)
#pragma unroll
                for (int j = 0; j < 4; ++j)
                    acc[i][j] = __builtin_amdgcn_mfma_f32_16x16x32_bf16(af[i], bf[j], acc[i][j], 0, 0, 0);
        }
        __syncthreads();
    }
    float* Cf = (float*)Cout + zb * oCb + zn * oCn;
    u16*   Cb = (u16*)Cout + zb * oCb + zn * oCn;
#pragma unroll
    for (int i = 0; i < 4; ++i)
#pragma unroll
        for (int j = 0; j < 4; ++j) {
            const int n = n0 + wc + j * 16 + l15;
#pragma unroll
            for (int q = 0; q < 4; ++q) {
                const int m = m0 + wr + i * 16 + l4 * 4 + q;
                float v = acc[i][j][q];
                if (EPI)
                    v = v * scale
                      + fabsf((float)(m - n)) * 0.5f * dwp[zn * 256 + m]
                      + qer[(long)z * 65536 + (long)n * 256 + m];
                if (OUTBF) Cb[(long)m * ldc + n] = f2bf(v);
                else       Cf[(long)m * ldc + n] = v;
            }
        }
}

// ---------------- conv1R: per-tap K=1024 GEMM slices (blockIdx.z = tap) ----------------
__global__ __launch_bounds__(256)
void conv3s_bf16_k(const u16* __restrict__ Xb, const u16* __restrict__ Wt,
                   const u16* __restrict__ zp, float* __restrict__ C)
{
    __shared__ __align__(16) u16 As[8192];
    __shared__ __align__(16) u16 Bs[8192];
    const int ks = blockIdx.z;
    const int m0 = blockIdx.y * 128, n0 = blockIdx.x * 128;
    const int tid = threadIdx.x;
    const int lane = tid & 63, wid = tid >> 6;
    const int wr = (wid >> 1) * 64, wc = (wid & 1) * 64;
    const int l15 = lane & 15, l4 = lane >> 4;
    f32x4 acc[4][4] = {};
    for (int k0 = 0; k0 < 1024; k0 += 64) {
#pragma unroll
        for (int it = 0; it < 4; ++it) {
            const int oe = it * 2048 + tid * 8;
            const int row = oe >> 6, col = oe & 63;
            const int t = m0 + row;
            const int wp = (t & 255) + ks - 1;
            const u16* src = ((unsigned)wp < 256u)
                ? Xb + (long)(t + ks - 1) * 1024 + k0 + col
                : zp;
            gld16(&As[oe], src);
            gld16(&Bs[oe], Wt + (long)(n0 + row) * 3072 + ks * 1024 + k0 + col);
        }
        __syncthreads();
#pragma unroll
        for (int kk = 0; kk < 2; ++kk) {
            bf16x8 af[4], bf[4];
#pragma unroll
            for (int i = 0; i < 4; ++i) {
                af[i] = *(const bf16x8*)&As[(wr + i * 16 + l15) * 64 + kk * 32 + l4 * 8];
                bf[i] = *(const bf16x8*)&Bs[(wc + i * 16 + l15) * 64 + kk * 32 + l4 * 8];
            }
#pragma unroll
            for (int i = 0; i < 4; ++i)
#pragma unroll
                for (int j = 0; j < 4; ++j)
                    acc[i][j] = __builtin_amdgcn_mfma_f32_16x16x32_bf16(af[i], bf[j], acc[i][j], 0, 0, 0);
        }
        __syncthreads();
    }
    float* Cp = C + (long)ks * 4194304;   // 4096*1024 per tap
#pragma unroll
    for (int i = 0; i < 4; ++i)
#pragma unroll
        for (int j = 0; j < 4; ++j) {
            const int n = n0 + wc + j * 16 + l15;
#pragma unroll
            for (int q = 0; q < 4; ++q) {
                const int m = m0 + wr + i * 16 + l4 * 4 + q;
                Cp[(long)m * 1024 + n] = acc[i][j][q];   // relu applied in consumer
            }
        }
}

// ---------------- GLU gate + residual + LN (sum 2 GEMM partials) ----------------
__global__ __launch_bounds__(256)
void glu_ln_k(const float* __restrict__ xs0, const float* __restrict__ g2,
              const float* __restrict__ gam, const float* __restrict__ bet,
              float* __restrict__ outf, u16* __restrict__ outb)
{
    const int t = blockIdx.x, tid = threadIdx.x;
    const int f0 = tid * 4;
    const long PS = 8388608;   // 4096*2048
    const float4 xv = *(const float4*)&xs0[(long)t * 1024 + f0];
    float4 av = *(const float4*)&g2[(long)t * 2048 + f0];
    float4 gv = *(const float4*)&g2[(long)t * 2048 + 1024 + f0];
    const float4 av1 = *(const float4*)&g2[PS + (long)t * 2048 + f0];
    const float4 gv1 = *(const float4*)&g2[PS + (long)t * 2048 + 1024 + f0];
    av.x += av1.x; av.y += av1.y; av.z += av1.z; av.w += av1.w;
    gv.x += gv1.x; gv.y += gv1.y; gv.z += gv1.z; gv.w += gv1.w;
    float vals[4];
    vals[0] = xv.x + av.x / (1.f + expf(-gv.x));
    vals[1] = xv.y + av.y / (1.f + expf(-gv.y));
    vals[2] = xv.z + av.z / (1.f + expf(-gv.z));
    vals[3] = xv.w + av.w / (1.f + expf(-gv.w));
    float s1 = vals[0] + vals[1] + vals[2] + vals[3];
    float s2 = vals[0]*vals[0] + vals[1]*vals[1] + vals[2]*vals[2] + vals[3]*vals[3];
    block_red2(s1, s2, tid);
    const float mean = s1 * (1.f / 1024.f);
    const float var  = s2 * (1.f / 1024.f) - mean * mean;
    const float rstd = rsqrtf(var + EPSF);
    const float4 gm = *(const float4*)&gam[f0];
    const float4 bt = *(const float4*)&bet[f0];
    float r0 = (vals[0] - mean) * rstd * gm.x + bt.x;
    float r1 = (vals[1] - mean) * rstd * gm.y + bt.y;
    float r2 = (vals[2] - mean) * rstd * gm.z + bt.z;
    float r3 = (vals[3] - mean) * rstd * gm.w + bt.w;
    *(float4*)&outf[(long)t * 1024 + f0] = make_float4(r0, r1, r2, r3);
    ushort4 ub; ub.x = f2bf(r0); ub.y = f2bf(r1); ub.z = f2bf(r2); ub.w = f2bf(r3);
    *(ushort4*)&outb[(long)t * 1024 + f0] = ub;
}

// ---------------- residual add + LN width 1024, B = sum of P partials (+opt bias) ----------------
template<int P, int WRITEBF, int BIAS>
__global__ __launch_bounds__(256)
void add_ln1024_k(const float* __restrict__ A, const float* __restrict__ Bp,
                  const float* __restrict__ bias,
                  const float* __restrict__ gam, const float* __restrict__ bet,
                  float* __restrict__ outf, u16* __restrict__ outb)
{
    const int t = blockIdx.x, tid = threadIdx.x;
    const int f0 = tid * 4;
    const long PS = 4194304;   // 4096*1024
    const float4 a = *(const float4*)&A[(long)t * 1024 + f0];
    float4 b = *(const float4*)&Bp[(long)t * 1024 + f0];
#pragma unroll
    for (int p = 1; p < P; ++p) {
        const float4 bp = *(const float4*)&Bp[p * PS + (long)t * 1024 + f0];
        b.x += bp.x; b.y += bp.y; b.z += bp.z; b.w += bp.w;
    }
    if (BIAS) {
        const float4 bb = *(const float4*)&bias[f0];
        b.x += bb.x; b.y += bb.y; b.z += bb.z; b.w += bb.w;
    }
    float vals[4] = {a.x + b.x, a.y + b.y, a.z + b.z, a.w + b.w};
    float s1 = vals[0] + vals[1] + vals[2] + vals[3];
    float s2 = vals[0]*vals[0] + vals[1]*vals[1] + vals[2]*vals[2] + vals[3]*vals[3];
    block_red2(s1, s2, tid);
    const float mean = s1 * (1.f / 1024.f);
    const float var  = s2 * (1.f / 1024.f) - mean * mean;
    const float rstd = rsqrtf(var + EPSF);
    const float4 gm = *(const float4*)&gam[f0];
    const float4 bt = *(const float4*)&bet[f0];
    float r0 = (vals[0] - mean) * rstd * gm.x + bt.x;
    float r1 = (vals[1] - mean) * rstd * gm.y + bt.y;
    float r2 = (vals[2] - mean) * rstd * gm.z + bt.z;
    float r3 = (vals[3] - mean) * rstd * gm.w + bt.w;
    *(float4*)&outf[(long)t * 1024 + f0] = make_float4(r0, r1, r2, r3);
    if (WRITEBF) {
        ushort4 ub; ub.x = f2bf(r0); ub.y = f2bf(r1); ub.z = f2bf(r2); ub.w = f2bf(r3);
        *(ushort4*)&outb[(long)t * 1024 + f0] = ub;
    }
}

// ---------------- n2: LN(c1L + pad(relu(sum of 3 conv taps))) width 4096 ----------------
__global__ __launch_bounds__(256)
void add_ln4096_k(const float* __restrict__ A, const float* __restrict__ Bp,
                  const float* __restrict__ gam, const float* __restrict__ bet,
                  u16* __restrict__ outb)
{
    const int t = blockIdx.x, tid = threadIdx.x;
    const long PS = 4194304;   // 4096*1024
    float vals[16];
    float s1 = 0.f, s2 = 0.f;
#pragma unroll
    for (int c = 0; c < 4; ++c) {
        const int f0 = tid * 16 + c * 4;
        float4 a = *(const float4*)&A[(long)t * 4096 + f0];
        if (f0 < 1024) {
            float4 b = *(const float4*)&Bp[(long)t * 1024 + f0];
            const float4 b1 = *(const float4*)&Bp[PS + (long)t * 1024 + f0];
            const float4 b2 = *(const float4*)&Bp[2 * PS + (long)t * 1024 + f0];
            b.x = fmaxf(b.x + b1.x + b2.x, 0.f);
            b.y = fmaxf(b.y + b1.y + b2.y, 0.f);
            b.z = fmaxf(b.z + b1.z + b2.z, 0.f);
            b.w = fmaxf(b.w + b1.w + b2.w, 0.f);
            a.x += b.x; a.y += b.y; a.z += b.z; a.w += b.w;
        }
        vals[c*4+0] = a.x; vals[c*4+1] = a.y; vals[c*4+2] = a.z; vals[c*4+3] = a.w;
        s1 += a.x + a.y + a.z + a.w;
        s2 += a.x*a.x + a.y*a.y + a.z*a.z + a.w*a.w;
    }
    block_red2(s1, s2, tid);
    const float mean = s1 * (1.f / 4096.f);
    const float var  = s2 * (1.f / 4096.f) - mean * mean;
    const float rstd = rsqrtf(var + EPSF);
#pragma unroll
    for (int c = 0; c < 4; ++c) {
        const int f0 = tid * 16 + c * 4;
        const float4 gm = *(const float4*)&gam[f0];
        const float4 bt = *(const float4*)&bet[f0];
        ushort4 ub;
        ub.x = f2bf((vals[c*4+0] - mean) * rstd * gm.x + bt.x);
        ub.y = f2bf((vals[c*4+1] - mean) * rstd * gm.y + bt.y);
        ub.z = f2bf((vals[c*4+2] - mean) * rstd * gm.z + bt.z);
        ub.w = f2bf((vals[c*4+3] - mean) * rstd * gm.w + bt.w);
        *(ushort4*)&outb[(long)t * 4096 + f0] = ub;
    }
}

// ---------------- depthwise conv width-9, 8 channels/thread ----------------
__global__ __launch_bounds__(256)
void dwconv8_k(const u16* __restrict__ h, const float* __restrict__ wT,
               u16* __restrict__ out)
{
    const long idx = (long)blockIdx.x * 256 + threadIdx.x;  // over 4096*512
    const int cg = (int)(idx & 511);
    const int t  = (int)(idx >> 9);
    const int w  = t & 255;
    const int c0 = cg * 8;
    float acc[8] = {};
#pragma unroll
    for (int k = 0; k < 9; ++k) {
        const int wp = w + k - 4;
        if ((unsigned)wp < 256u) {
            const bf16x8 hv = *(const bf16x8*)&h[(long)(t + k - 4) * 4096 + c0];
            const float4 w0 = *(const float4*)&wT[k * 4096 + c0];
            const float4 w1 = *(const float4*)&wT[k * 4096 + c0 + 4];
            acc[0] += bf2f((u16)hv[0]) * w0.x;
            acc[1] += bf2f((u16)hv[1]) * w0.y;
            acc[2] += bf2f((u16)hv[2]) * w0.z;
            acc[3] += bf2f((u16)hv[3]) * w0.w;
            acc[4] += bf2f((u16)hv[4]) * w1.x;
            acc[5] += bf2f((u16)hv[5]) * w1.y;
            acc[6] += bf2f((u16)hv[6]) * w1.z;
            acc[7] += bf2f((u16)hv[7]) * w1.w;
        }
    }
    bf16x8 res;
#pragma unroll
    for (int j = 0; j < 8; ++j) res[j] = (short)f2bf(acc[j]);
    *(bf16x8*)&out[(long)t * 4096 + c0] = res;
}

// ---------------- softmax over rows of 256, bf16 out ----------------
__global__ __launch_bounds__(256)
void softmax_k(const float* __restrict__ s, u16* __restrict__ p)
{
    const int row = blockIdx.x, tid = threadIdx.x;
    const float v = s[(long)row * 256 + tid];
    __shared__ float red[4];
    __shared__ float red2[4];
    float m = wred_max(v);
    const int lane = tid & 63, wid = tid >> 6;
    if (!lane) red[wid] = m;
    __syncthreads();
    m = fmaxf(fmaxf(red[0], red[1]), fmaxf(red[2], red[3]));
    const float e = expf(v - m);
    float sum = wred_sum(e);
    if (!lane) red2[wid] = sum;
    __syncthreads();
    sum = red2[0] + red2[1] + red2[2] + red2[3];
    p[(long)row * 256 + tid] = f2bf(e / sum);
}

// ---------------- V slice of QKVb -> Vt (z, d, w) bf16 ----------------
__global__ __launch_bounds__(256)
void vtrans_k(const u16* __restrict__ QKVb, u16* __restrict__ Vt)
{
    __shared__ u16 t[32][33];
    const int z = blockIdx.z, zb = z >> 2, zn = z & 3;
    const int w0 = blockIdx.x * 32, d0 = blockIdx.y * 32;
    const int tid = threadIdx.x, c = tid & 31, r = tid >> 5;
#pragma unroll
    for (int it = 0; it < 4; ++it) {
        const int wl = r + it * 8;
        t[wl][c] = QKVb[(long)(zb * 256 + w0 + wl) * 3072 + 2048 + zn * 256 + d0 + c];
    }
    __syncthreads();
#pragma unroll
    for (int it = 0; it < 4; ++it) {
        const int dl = r + it * 8;
        Vt[((long)z * 256 + d0 + dl) * 256 + w0 + c] = t[c][dl];
    }
}

// ---------------- final transpose (tokens,1024) -> (B,1,1024,256) ----------------
__global__ __launch_bounds__(256)
void transpose_out_k(const float* __restrict__ xs, float* __restrict__ out)
{
    __shared__ float tile[32][33];
    const int b = blockIdx.z, f0 = blockIdx.y * 32, w0 = blockIdx.x * 32;
    const int tid = threadIdx.x, c = tid & 31, r = tid >> 5;
#pragma unroll
    for (int it = 0; it < 4; ++it) {
        const int w = w0 + r + it * 8;
        tile[r + it * 8][c] = xs[((long)b * 256 + w) * 1024 + f0 + c];
    }
    __syncthreads();
#pragma unroll
    for (int it = 0; it < 4; ++it) {
        const int fl = r + it * 8;
        out[((long)b * 1024 + f0 + fl) * 256 + w0 + c] = tile[c][fl];
    }
}

// =======================================================================
extern "C" void kernel_launch(void* const* d_in, const int* in_sizes, int n_in,
                              void* d_out, int out_size, void* d_ws, size_t ws_size,
                              hipStream_t stream)
{
    const float* x      = (const float*)d_in[0];
    const float* bott_w = (const float*)d_in[1];
    const float* bn_g   = (const float*)d_in[2];
    const float* bn_b   = (const float*)d_in[3];
    const float* bn_m   = (const float*)d_in[4];
    const float* bn_v   = (const float*)d_in[5];
    const float* glu_w  = (const float*)d_in[6];
    const float* n1g    = (const float*)d_in[7];
    const float* n1b    = (const float*)d_in[8];
    const float* c1L_w  = (const float*)d_in[9];
    const float* c1R_w  = (const float*)d_in[10];
    const float* n2g    = (const float*)d_in[11];
    const float* n2b    = (const float*)d_in[12];
    const float* c2dw_w = (const float*)d_in[13];
    const float* c2pw_w = (const float*)d_in[14];
    const float* n3g    = (const float*)d_in[15];
    const float* n3b    = (const float*)d_in[16];
    const float* qw     = (const float*)d_in[17];
    const float* qb     = (const float*)d_in[18];
    const float* kw     = (const float*)d_in[19];
    const float* kb     = (const float*)d_in[20];
    const float* vw     = (const float*)d_in[21];
    const float* vb     = (const float*)d_in[22];
    const float* ow     = (const float*)d_in[23];
    const float* ob     = (const float*)d_in[24];
    const float* er     = (const float*)d_in[25];
    const float* dist_w = (const float*)d_in[26];
    const float* n4g    = (const float*)d_in[27];
    const float* n4b    = (const float*)d_in[28];
    const float* c3_w   = (const float*)d_in[29];
    const float* c4_w   = (const float*)d_in[30];
    const float* n5g    = (const float*)d_in[31];
    const float* n5b    = (const float*)d_in[32];
    float* out = (float*)d_out;

    // ---- workspace layout (MiB offsets, lifetimes annotated; max ~371 MiB) ----
    char* Wb_ = (char*)d_ws;
    auto F  = [&](size_t mib) { return (float*)(Wb_ + (mib << 20)); };
    auto Bf = [&](size_t mib) { return (u16*)  (Wb_ + (mib << 20)); };
    float* X0   = F(0);     // xs chain A
    float* X1   = F(16);    // xs chain B
    float* H0   = F(32);    // c1L out f32 (4096x4096), stages 4-6
    float* Hglu = F(96);    // GLU 2 partials (2x32MB), stages 2-3
    float* C3p  = F(96);    // conv3 3 partials (3x16MB), stages 5-6
    float* P4   = F(96);    // c2pw/c4 4 partials (4x16MB), stages 8-9 & 18-19
    u16*   H1b  = Bf(160);  // n2 out bf16, stages 6-7
    u16*   H0b  = Bf(160);  // c3 out bf16, stages 17-18
    u16*   Hdw  = Bf(192);  // dwconv out bf16, stages 7-8
    u16*   QKVb = Bf(224);  // fused QKV out (4096x3072 bf16), stages 10-12
    u16*   Vt   = Bf(248);  // V transposed, stages 10b-14
    float* QER  = F(256);   // qer f32, stages 11-12
    float* P2   = F(256);   // O-proj 2 partials (2x16MB), stages 15-16
    float* S0   = F(272);   // scores f32, stages 12-13
    u16*   Pb   = Bf(288);  // softmax bf16, stages 13-14
    u16*   S1b  = Bf(296);  // attn concat bf16, stages 14-15
    u16*   XbA  = Bf(304);  // X1b (1-2), then X2b (9-10)
    u16*   XbB  = Bf(312);  // X0b (3-5), then X3b (16-17)
    u16* wGLU = Bf(320); u16* wC1L = Bf(324); u16* wC1R = Bf(332);
    u16* wC2P = Bf(338); u16* wQKV = Bf(346); u16* wO   = Bf(352);
    u16* wC3  = Bf(354); u16* wC4  = Bf(362);
    u16* erT  = Bf(370);
    u16* zp   = (u16*)(Wb_ + (370u << 20) + 131072);
    float* wdwT = (float*)(Wb_ + (370u << 20) + 131072 + 16384);
    float* bQKV = (float*)(Wb_ + (370u << 20) + 131072 + 16384 + 147456);

    const dim3 blk(256);
    const long PS1 = 4194304;   // 4096*1024

    // 0. weight conversions + zero page + bias concat
    zero_k<<<dim3(32), blk, 0, stream>>>(zp, 8192);
    wcvt_k<<<dim3(2048), blk, 0, stream>>>(glu_w,  wGLU, 524288);
    wcvt_k<<<dim3(4096), blk, 0, stream>>>(c1L_w,  wC1L, 1048576);
    c1rcvt_k<<<dim3(12288), blk, 0, stream>>>(c1R_w, wC1R);
    wcvt_k<<<dim3(4096), blk, 0, stream>>>(c2pw_w, wC2P, 1048576);
    wcvt_k<<<dim3(1024), blk, 0, stream>>>(qw, wQKV, 262144);
    wcvt_k<<<dim3(1024), blk, 0, stream>>>(kw, wQKV + 1048576, 262144);
    wcvt_k<<<dim3(1024), blk, 0, stream>>>(vw, wQKV + 2097152, 262144);
    wcvt_k<<<dim3(1024), blk, 0, stream>>>(ow, wO, 262144);
    wcvt_k<<<dim3(4096), blk, 0, stream>>>(c3_w, wC3, 1048576);
    wcvt_k<<<dim3(4096), blk, 0, stream>>>(c4_w, wC4, 1048576);
    ercvt_k<<<dim3(256), blk, 0, stream>>>(er, erT);
    dwcvt_k<<<dim3(144), blk, 0, stream>>>(c2dw_w, wdwT);
    biascat_k<<<dim3(12), blk, 0, stream>>>(qb, kb, vb, bQKV);

    // 1. bottleneck + BN + ReLU + transpose
    bottleneck_k<<<dim3(8, 32, 16), blk, 0, stream>>>(x, bott_w, bn_g, bn_b, bn_m, bn_v, X1, XbA);

    // 2. GLU matmul, split-K=2 -> Hglu partials
    gemm_bf16_k<0,0,0,2><<<dim3(16, 32, 2), blk, 0, stream>>>(XbA, wGLU, nullptr, Hglu,
        2048, 512, 1024, 1024, (long)4096 * 2048);

    // 3. n1: LN(xs0 + a*sigmoid(g)) -> X0 + X0b
    glu_ln_k<<<dim3(4096), blk, 0, stream>>>(X1, Hglu, n1g, n1b, X0, XbB);

    // 4. c1L: relu -> H0 f32 (unsplit, 1024 blocks)
    gemm_bf16_k<1,0,0,1><<<dim3(32, 32, 1), blk, 0, stream>>>(XbB, wC1L, nullptr, H0,
        4096, 1024, 1024, 1024, 0);

    // 5. c1R conv: 3 tap-slices -> C3p partials
    conv3s_bf16_k<<<dim3(8, 32, 3), blk, 0, stream>>>(XbB, wC1R, zp, C3p);

    // 6. n2: LN(H0 + pad(relu(sum taps))) -> H1b bf16
    add_ln4096_k<<<dim3(4096), blk, 0, stream>>>(H0, C3p, n2g, n2b, H1b);

    // 7. depthwise conv9 (vectorized x8): H1b -> Hdw
    dwconv8_k<<<dim3(8192), blk, 0, stream>>>(H1b, wdwT, Hdw);

    // 8. c2pw, split-K=4 -> P4 partials
    gemm_bf16_k<0,0,0,4><<<dim3(8, 32, 4), blk, 0, stream>>>(Hdw, wC2P, nullptr, P4,
        1024, 1024, 4096, 4096, PS1);

    // 9. n3: LN(X0 + sum P4) -> X1 + X2b
    add_ln1024_k<4,1,0><<<dim3(4096), blk, 0, stream>>>(X0, P4, nullptr, n3g, n3b, X1, XbA);

    // 10. fused QKV projection (+concat bias) -> QKVb bf16 (4096x3072)
    gemm_bf16_k<0,1,1,1><<<dim3(24, 32, 1), blk, 0, stream>>>(XbA, wQKV, bQKV, QKVb,
        3072, 1024, 1024, 1024, 0);

    // 10b. V transpose per head -> Vt (z, d, w)
    vtrans_k<<<dim3(8, 8, 64), blk, 0, stream>>>(QKVb, Vt);

    // 11. qer = Q_head @ erT^T -> QER f32
    gemm_bf16_bat_k<0,0><<<dim3(2, 2, 64), blk, 0, stream>>>(QKVb, erT, QER,
        256, 3072, 256, 256,
        (long)256 * 3072, 256, 0, 0,
        (long)4 * 65536, 65536, nullptr, nullptr, 1.f);

    // 12. scores = QK^T/32 + dist*dist_w + qer^T -> S0 f32
    gemm_bf16_bat_k<1,0><<<dim3(2, 2, 64), blk, 0, stream>>>(QKVb, QKVb + 1024, S0,
        256, 3072, 3072, 256,
        (long)256 * 3072, 256, (long)256 * 3072, 256,
        (long)4 * 65536, 65536, QER, dist_w, 1.f / 32.f);

    // 13. softmax rows -> Pb bf16
    softmax_k<<<dim3(16384), blk, 0, stream>>>(S0, Pb);

    // 14. o = P @ Vt^T -> S1b bf16 (concat layout)
    gemm_bf16_bat_k<0,1><<<dim3(2, 2, 64), blk, 0, stream>>>(Pb, Vt, S1b,
        256, 256, 256, 1024,
        (long)4 * 65536, 65536, (long)4 * 65536, 65536,
        (long)256 * 1024, 256, nullptr, nullptr, 1.f);

    // 15. output projection, split-K=2 -> P2 partials (bias added in n4)
    gemm_bf16_k<0,0,0,2><<<dim3(8, 32, 2), blk, 0, stream>>>(S1b, wO, nullptr, P2,
        1024, 512, 1024, 1024, PS1);

    // 16. n4: LN(X1 + sum P2 + ob) -> X0 + X3b
    add_ln1024_k<2,1,1><<<dim3(4096), blk, 0, stream>>>(X1, P2, ob, n4g, n4b, X0, XbB);

    // 17. c3: relu -> H0b bf16
    gemm_bf16_k<1,1,0,1><<<dim3(32, 32, 1), blk, 0, stream>>>(XbB, wC3, nullptr, H0b,
        4096, 1024, 1024, 1024, 0);

    // 18. c4, split-K=4 -> P4 partials
    gemm_bf16_k<0,0,0,4><<<dim3(8, 32, 4), blk, 0, stream>>>(H0b, wC4, nullptr, P4,
        1024, 1024, 4096, 4096, PS1);

    // 19. n5: LN(X0 + sum P4) -> X1 (f32 only)
    add_ln1024_k<4,0,0><<<dim3(4096), blk, 0, stream>>>(X0, P4, nullptr, n5g, n5b, X1, nullptr);

    // 20. transpose to (B, 1, 1024, 256)
    transpose_out_k<<<dim3(8, 32, 16), blk, 0, stream>>>(X1, out);

    (void)in_sizes; (void)n_in; (void)out_size; (void)ws_size;
}

// Round 5
// 617.341 us; speedup vs baseline: 5.6546x; 1.1883x over previous
//
#include <hip/hip_runtime.h>
#include <hip/hip_bf16.h>

// FrameTransformer: B=16, C=8, BINS=1024, W=256, FF=2048, NB=4
// tokens = B*W = 4096, feature width 1024, FF width 4096, head dim 256.
#define EPSF 1e-5f

typedef unsigned short u16;
typedef unsigned int   u32;
typedef __attribute__((ext_vector_type(8))) short bf16x8;
typedef __attribute__((ext_vector_type(4))) float f32x4;

__device__ __forceinline__ u16 f2bf(float f) {
    u32 u = __builtin_bit_cast(u32, f);
    u32 r = u + 0x7fffu + ((u >> 16) & 1u);
    return (u16)(r >> 16);
}
__device__ __forceinline__ float bf2f(u16 h) {
    return __builtin_bit_cast(float, (u32)h << 16);
}
__device__ __forceinline__ void gld16(void* lds, const void* gsrc) {
    __builtin_amdgcn_global_load_lds(
        (const __attribute__((address_space(1))) u32*)gsrc,
        (__attribute__((address_space(3))) u32*)lds, 16, 0, 0);
}

__device__ __forceinline__ float wred_sum(float v) {
#pragma unroll
    for (int off = 32; off; off >>= 1) v += __shfl_xor(v, off, 64);
    return v;
}
__device__ __forceinline__ float wred_max(float v) {
#pragma unroll
    for (int off = 32; off; off >>= 1) v = fmaxf(v, __shfl_xor(v, off, 64));
    return v;
}
__device__ __forceinline__ void block_red2(float& s1, float& s2, int tid) {
    __shared__ float red[8];
    s1 = wred_sum(s1); s2 = wred_sum(s2);
    const int lane = tid & 63, wid = tid >> 6;
    if (!lane) { red[wid] = s1; red[4 + wid] = s2; }
    __syncthreads();
    s1 = red[0] + red[1] + red[2] + red[3];
    s2 = red[4] + red[5] + red[6] + red[7];
}

// ---------------- converters ----------------
__global__ __launch_bounds__(256)
void wcvt_k(const float* __restrict__ src, u16* __restrict__ dst, int n4)
{
    const int i = blockIdx.x * 256 + threadIdx.x;
    if (i >= n4) return;
    const float4 v = ((const float4*)src)[i];
    ushort4 o; o.x = f2bf(v.x); o.y = f2bf(v.y); o.z = f2bf(v.z); o.w = f2bf(v.w);
    ((ushort4*)dst)[i] = o;
}
// c1R_w (o,ci,ks=3) -> Wt (o, ks, ci) bf16
__global__ __launch_bounds__(256)
void c1rcvt_k(const float* __restrict__ src, u16* __restrict__ dst)
{
    const int i = blockIdx.x * 256 + threadIdx.x;     // over 1024*3072
    const int q = i / 3072, rem = i - q * 3072;
    const int ks = rem >> 10, ci = rem & 1023;
    dst[i] = f2bf(src[((long)q * 1024 + ci) * 3 + ks]);
}
// er (d=256, c=256) f32 -> erT (c, d) bf16
__global__ __launch_bounds__(256)
void ercvt_k(const float* __restrict__ er, u16* __restrict__ erT)
{
    const int i = blockIdx.x * 256 + threadIdx.x;     // over 65536
    const int c = i >> 8, d = i & 255;
    erT[i] = f2bf(er[d * 256 + c]);
}
// c2dw_w (c,1,9) -> wdwT (9, 4096) f32
__global__ __launch_bounds__(256)
void dwcvt_k(const float* __restrict__ src, float* __restrict__ dst)
{
    const int i = blockIdx.x * 256 + threadIdx.x;     // over 9*4096
    if (i >= 9 * 4096) return;
    const int k = i >> 12, c = i & 4095;
    dst[i] = src[c * 9 + k];
}
__global__ __launch_bounds__(256)
void zero_k(u16* __restrict__ p, int n)
{
    const int i = blockIdx.x * 256 + threadIdx.x;
    if (i < n) p[i] = 0;
}
// concat q/k/v biases -> 3072
__global__ __launch_bounds__(256)
void biascat_k(const float* __restrict__ b0, const float* __restrict__ b1,
               const float* __restrict__ b2, float* __restrict__ dst)
{
    const int i = blockIdx.x * 256 + threadIdx.x;     // over 3072
    const float* s = (i < 1024) ? b0 : ((i < 2048) ? b1 : b2);
    dst[i] = s[i & 1023];
}

// ---------------- stage 1: bottleneck 1x1 conv + BN + ReLU + transpose ----------------
__global__ __launch_bounds__(256)
void bottleneck_k(const float* __restrict__ x, const float* __restrict__ bw,
                  const float* __restrict__ bn_g, const float* __restrict__ bn_b,
                  const float* __restrict__ bn_m, const float* __restrict__ bn_v,
                  float* __restrict__ xs, u16* __restrict__ xsb)
{
    __shared__ float tile[32][33];
    const int b = blockIdx.z, h0 = blockIdx.y * 32, w0 = blockIdx.x * 32;
    const int tid = threadIdx.x, c = tid & 31, r = tid >> 5;
    float wreg[8];
#pragma unroll
    for (int ch = 0; ch < 8; ++ch) wreg[ch] = bw[ch];
    const float sc = bn_g[0] * rsqrtf(bn_v[0] + EPSF);
    const float sh = bn_b[0] - bn_m[0] * sc;
#pragma unroll
    for (int it = 0; it < 4; ++it) {
        const int h = h0 + r + it * 8;
        const int w = w0 + c;
        float acc = 0.f;
#pragma unroll
        for (int ch = 0; ch < 8; ++ch)
            acc += x[(((long)b * 8 + ch) * 1024 + h) * 256 + w] * wreg[ch];
        tile[r + it * 8][c] = fmaxf(acc * sc + sh, 0.f);
    }
    __syncthreads();
#pragma unroll
    for (int it = 0; it < 4; ++it) {
        const int wl = r + it * 8;
        const float v = tile[c][wl];
        const long o = ((long)b * 256 + w0 + wl) * 1024 + h0 + c;
        xs[o] = v;
        xsb[o] = f2bf(v);
    }
}

// ============ 8-phase 256x256 bf16 MFMA GEMM (T2+T3+T4+T5) ============
// C[M,N] = A[M,K] @ B[N,K]^T. 512 threads = 8 waves (2M x 4N), BK=64,
// 128 KiB dynamic LDS (2 K-tile double buffer), st_16x32 swizzle via
// pre-swizzled global source + swizzled ds_read, counted vmcnt(6).
template<int ACT, int OUTBF, int BIAS, int SPLITK>
__global__ __launch_bounds__(512, 2)
void gemm8_k(const u16* __restrict__ A, const u16* __restrict__ B,
             const float* __restrict__ bias, void* __restrict__ Cout,
             int N, int K /*per slice*/, int lda, int ldb, long partStride)
{
    extern __shared__ u16 lds[];   // [A slot0|A slot1|B slot0|B slot1] x 16384 elems
    const int m0 = blockIdx.y * 256, n0 = blockIdx.x * 256;
    const int koff = (SPLITK > 1) ? blockIdx.z * K : 0;
    const int nt = K >> 6;
    const int tid = threadIdx.x;
    const int lane = tid & 63, wid = tid >> 6;
    const int wr = ((wid >> 2) & 1) * 128;   // wave row offset in tile
    const int wc = (wid & 3) * 64;           // wave col offset
    const int l15 = lane & 15, l4 = lane >> 4;

    const u16* Ag = A + (long)m0 * lda + koff;
    const u16* Bg = B + (long)n0 * ldb + koff;

    // stage one half-tile (128 rows x 64 cols) = 2 x gld16/thread.
    // LDS dest linear; global source pre-swizzled (XOR 32B block on row&4).
    auto stage = [&](const u16* g, int ld, int ldsbase, int kcol, int h) {
#pragma unroll
        for (int is = 0; is < 2; ++is) {
            const int r = h * 128 + is * 64 + (tid >> 3);
            const int sc = ((tid & 7) * 8) ^ (((r >> 2) & 1) << 4);
            gld16(&lds[ldsbase + h * 8192 + is * 4096 + tid * 8],
                  g + (long)r * ld + kcol + sc);
        }
    };
    // swizzled ds_read_b128 of one bf16x8 fragment
    auto frag = [&](int base, int row, int col) -> bf16x8 {
        return *(const bf16x8*)&lds[base + row * 64 + (col ^ (((row >> 2) & 1) << 4))];
    };

    f32x4 acc[8][4] = {};

    // ---- prologue: K0 (4 halves) + K1 (B-lo, B-hi, A-lo) ----
    stage(Ag, lda, 0, 0, 0);
    stage(Ag, lda, 0, 0, 1);
    stage(Bg, ldb, 32768, 0, 0);
    stage(Bg, ldb, 32768, 0, 1);
    if (nt > 1) {
        stage(Bg, ldb, 49152, 64, 0);
        stage(Bg, ldb, 49152, 64, 1);
        stage(Ag, lda, 16384, 64, 0);
        asm volatile("s_waitcnt vmcnt(6)" ::: "memory");
    } else {
        asm volatile("s_waitcnt vmcnt(0)" ::: "memory");
    }
    __builtin_amdgcn_s_barrier();

    for (int kt = 0; kt < nt; ++kt) {
        const int cs = kt & 1;
        const int ab = cs * 16384;            // A base, current slot
        const int bb = 32768 + cs * 16384;    // B base, current slot
        const int abn = (cs ^ 1) * 16384;     // A base, next slot
        const int kc1 = (kt + 1) * 64, kc2 = (kt + 2) * 64;
        bf16x8 alo[4][2], ahi[4][2], b01[2][2], b23[2][2];

        // ---- phase 0: read A i0-3 + B j0-1; stage A-hi(K_{t+1}) ----
#pragma unroll
        for (int i = 0; i < 4; ++i)
#pragma unroll
            for (int kk = 0; kk < 2; ++kk)
                alo[i][kk] = frag(ab, wr + i * 16 + l15, kk * 32 + l4 * 8);
#pragma unroll
        for (int j = 0; j < 2; ++j)
#pragma unroll
            for (int kk = 0; kk < 2; ++kk)
                b01[j][kk] = frag(bb, wc + j * 16 + l15, kk * 32 + l4 * 8);
        if (kt + 1 < nt) stage(Ag, lda, abn, kc1, 1);
        __builtin_amdgcn_s_barrier();
        asm volatile("s_waitcnt lgkmcnt(0)" ::: "memory");
        __builtin_amdgcn_s_setprio(1);
#pragma unroll
        for (int i = 0; i < 4; ++i)
#pragma unroll
            for (int j = 0; j < 2; ++j)
#pragma unroll
                for (int kk = 0; kk < 2; ++kk)
                    acc[i][j] = __builtin_amdgcn_mfma_f32_16x16x32_bf16(alo[i][kk], b01[j][kk], acc[i][j], 0, 0, 0);
        __builtin_amdgcn_s_setprio(0);
        __builtin_amdgcn_s_barrier();

        // ---- phase 1: read B j2-3; stage B-lo(K_{t+2}) ----
#pragma unroll
        for (int j = 0; j < 2; ++j)
#pragma unroll
            for (int kk = 0; kk < 2; ++kk)
                b23[j][kk] = frag(bb, wc + (j + 2) * 16 + l15, kk * 32 + l4 * 8);
        if (kt + 2 < nt) stage(Bg, ldb, bb, kc2, 0);
        __builtin_amdgcn_s_barrier();
        asm volatile("s_waitcnt lgkmcnt(0)" ::: "memory");
        __builtin_amdgcn_s_setprio(1);
#pragma unroll
        for (int i = 0; i < 4; ++i)
#pragma unroll
            for (int j = 0; j < 2; ++j)
#pragma unroll
                for (int kk = 0; kk < 2; ++kk)
                    acc[i][j + 2] = __builtin_amdgcn_mfma_f32_16x16x32_bf16(alo[i][kk], b23[j][kk], acc[i][j + 2], 0, 0, 0);
        __builtin_amdgcn_s_setprio(0);
        __builtin_amdgcn_s_barrier();

        // ---- phase 2: read A i4-7; stage B-hi(K_{t+2}) ----
#pragma unroll
        for (int i = 0; i < 4; ++i)
#pragma unroll
            for (int kk = 0; kk < 2; ++kk)
                ahi[i][kk] = frag(ab, wr + (i + 4) * 16 + l15, kk * 32 + l4 * 8);
        if (kt + 2 < nt) stage(Bg, ldb, bb, kc2, 1);
        __builtin_amdgcn_s_barrier();
        asm volatile("s_waitcnt lgkmcnt(0)" ::: "memory");
        __builtin_amdgcn_s_setprio(1);
#pragma unroll
        for (int i = 0; i < 4; ++i)
#pragma unroll
            for (int j = 0; j < 2; ++j)
#pragma unroll
                for (int kk = 0; kk < 2; ++kk)
                    acc[i + 4][j + 2] = __builtin_amdgcn_mfma_f32_16x16x32_bf16(ahi[i][kk], b23[j][kk], acc[i + 4][j + 2], 0, 0, 0);
        __builtin_amdgcn_s_setprio(0);
        __builtin_amdgcn_s_barrier();

        // ---- phase 3: stage A-lo(K_{t+2}); MFMA ahi x b01; counted vmcnt ----
        if (kt + 2 < nt) stage(Ag, lda, ab, kc2, 0);
        __builtin_amdgcn_s_barrier();
        __builtin_amdgcn_s_setprio(1);
#pragma unroll
        for (int i = 0; i < 4; ++i)
#pragma unroll
            for (int j = 0; j < 2; ++j)
#pragma unroll
                for (int kk = 0; kk < 2; ++kk)
                    acc[i + 4][j] = __builtin_amdgcn_mfma_f32_16x16x32_bf16(ahi[i][kk], b01[j][kk], acc[i + 4][j], 0, 0, 0);
        __builtin_amdgcn_s_setprio(0);
        if (kt + 2 < nt) {
            asm volatile("s_waitcnt vmcnt(6)" ::: "memory");
        } else {
            asm volatile("s_waitcnt vmcnt(0)" ::: "memory");
        }
        __builtin_amdgcn_s_barrier();
    }

    // ---- epilogue ----
    float* Cf = (float*)Cout + ((SPLITK > 1) ? (long)blockIdx.z * partStride : 0);
    u16*   Cb = (u16*)Cout;
#pragma unroll
    for (int i = 0; i < 8; ++i)
#pragma unroll
        for (int j = 0; j < 4; ++j) {
            const int n = n0 + wc + j * 16 + l15;
            const float bv = BIAS ? bias[n] : 0.f;
#pragma unroll
            for (int q = 0; q < 4; ++q) {
                const int m = m0 + wr + i * 16 + l4 * 4 + q;
                float v = acc[i][j][q] + bv;
                if (ACT) v = fmaxf(v, 0.f);
                if (OUTBF) Cb[(long)m * N + n] = f2bf(v);
                else       Cf[(long)m * N + n] = v;
            }
        }
}

// ---------------- batched bf16 MFMA GEMM (attention heads, z = zb*4+zn) ----------------
template<int EPI, int OUTBF>
__global__ __launch_bounds__(256)
void gemm_bf16_bat_k(const u16* __restrict__ A, const u16* __restrict__ B,
                     void* __restrict__ Cout, int K, int lda, int ldb, int ldc,
                     long oAb, long oAn, long oBb, long oBn, long oCb, long oCn,
                     const float* __restrict__ qer, const float* __restrict__ dwp,
                     float scale)
{
    __shared__ __align__(16) u16 As[8192];
    __shared__ __align__(16) u16 Bs[8192];
    const int z = blockIdx.z, zb = z >> 2, zn = z & 3;
    const u16* Ab = A + zb * oAb + zn * oAn;
    const u16* Bb = B + zb * oBb + zn * oBn;
    const int m0 = blockIdx.y * 128, n0 = blockIdx.x * 128;
    const int tid = threadIdx.x;
    const int lane = tid & 63, wid = tid >> 6;
    const int wr = (wid >> 1) * 64, wc = (wid & 1) * 64;
    const int l15 = lane & 15, l4 = lane >> 4;
    f32x4 acc[4][4] = {};
    for (int k0 = 0; k0 < K; k0 += 64) {
#pragma unroll
        for (int it = 0; it < 4; ++it) {
            const int oe = it * 2048 + tid * 8;
            const int row = oe >> 6, col = oe & 63;
            gld16(&As[oe], Ab + (long)(m0 + row) * lda + k0 + col);
            gld16(&Bs[oe], Bb + (long)(n0 + row) * ldb + k0 + col);
        }
        __syncthreads();
#pragma unroll
        for (int kk = 0; kk < 2; ++kk) {
            bf16x8 af[4], bf[4];
#pragma unroll
            for (int i = 0; i < 4; ++i) {
                af[i] = *(const bf16x8*)&As[(wr + i * 16 + l15) * 64 + kk * 32 + l4 * 8];
                bf[i] = *(const bf16x8*)&Bs[(wc + i * 16 + l15) * 64 + kk * 32 + l4 * 8];
            }
#pragma unroll
            for (int i = 0; i < 4; ++i)
#pragma unroll
                for (int j = 0; j < 4; ++j)
                    acc[i][j] = __builtin_amdgcn_mfma_f32_16x16x32_bf16(af[i], bf[j], acc[i][j], 0, 0, 0);
        }
        __syncthreads();
    }
    float* Cf = (float*)Cout + zb * oCb + zn * oCn;
    u16*   Cb = (u16*)Cout + zb * oCb + zn * oCn;
#pragma unroll
    for (int i = 0; i < 4; ++i)
#pragma unroll
        for (int j = 0; j < 4; ++j) {
            const int n = n0 + wc + j * 16 + l15;
#pragma unroll
            for (int q = 0; q < 4; ++q) {
                const int m = m0 + wr + i * 16 + l4 * 4 + q;
                float v = acc[i][j][q];
                if (EPI)
                    v = v * scale
                      + fabsf((float)(m - n)) * 0.5f * dwp[zn * 256 + m]
                      + qer[(long)z * 65536 + (long)n * 256 + m];
                if (OUTBF) Cb[(long)m * ldc + n] = f2bf(v);
                else       Cf[(long)m * ldc + n] = v;
            }
        }
}

// ---------------- conv1R: per-tap K=1024 GEMM slices (blockIdx.z = tap) ----------------
__global__ __launch_bounds__(256)
void conv3s_bf16_k(const u16* __restrict__ Xb, const u16* __restrict__ Wt,
                   const u16* __restrict__ zp, float* __restrict__ C)
{
    __shared__ __align__(16) u16 As[8192];
    __shared__ __align__(16) u16 Bs[8192];
    const int ks = blockIdx.z;
    const int m0 = blockIdx.y * 128, n0 = blockIdx.x * 128;
    const int tid = threadIdx.x;
    const int lane = tid & 63, wid = tid >> 6;
    const int wr = (wid >> 1) * 64, wc = (wid & 1) * 64;
    const int l15 = lane & 15, l4 = lane >> 4;
    f32x4 acc[4][4] = {};
    for (int k0 = 0; k0 < 1024; k0 += 64) {
#pragma unroll
        for (int it = 0; it < 4; ++it) {
            const int oe = it * 2048 + tid * 8;
            const int row = oe >> 6, col = oe & 63;
            const int t = m0 + row;
            const int wp = (t & 255) + ks - 1;
            const u16* src = ((unsigned)wp < 256u)
                ? Xb + (long)(t + ks - 1) * 1024 + k0 + col
                : zp;
            gld16(&As[oe], src);
            gld16(&Bs[oe], Wt + (long)(n0 + row) * 3072 + ks * 1024 + k0 + col);
        }
        __syncthreads();
#pragma unroll
        for (int kk = 0; kk < 2; ++kk) {
            bf16x8 af[4], bf[4];
#pragma unroll
            for (int i = 0; i < 4; ++i) {
                af[i] = *(const bf16x8*)&As[(wr + i * 16 + l15) * 64 + kk * 32 + l4 * 8];
                bf[i] = *(const bf16x8*)&Bs[(wc + i * 16 + l15) * 64 + kk * 32 + l4 * 8];
            }
#pragma unroll
            for (int i = 0; i < 4; ++i)
#pragma unroll
                for (int j = 0; j < 4; ++j)
                    acc[i][j] = __builtin_amdgcn_mfma_f32_16x16x32_bf16(af[i], bf[j], acc[i][j], 0, 0, 0);
        }
        __syncthreads();
    }
    float* Cp = C + (long)ks * 4194304;   // 4096*1024 per tap
#pragma unroll
    for (int i = 0; i < 4; ++i)
#pragma unroll
        for (int j = 0; j < 4; ++j) {
            const int n = n0 + wc + j * 16 + l15;
#pragma unroll
            for (int q = 0; q < 4; ++q) {
                const int m = m0 + wr + i * 16 + l4 * 4 + q;
                Cp[(long)m * 1024 + n] = acc[i][j][q];   // relu applied in consumer
            }
        }
}

// ---------------- GLU gate + residual + LN (sum 2 GEMM partials) ----------------
__global__ __launch_bounds__(256)
void glu_ln_k(const float* __restrict__ xs0, const float* __restrict__ g2,
              const float* __restrict__ gam, const float* __restrict__ bet,
              float* __restrict__ outf, u16* __restrict__ outb)
{
    const int t = blockIdx.x, tid = threadIdx.x;
    const int f0 = tid * 4;
    const long PS = 8388608;   // 4096*2048
    const float4 xv = *(const float4*)&xs0[(long)t * 1024 + f0];
    float4 av = *(const float4*)&g2[(long)t * 2048 + f0];
    float4 gv = *(const float4*)&g2[(long)t * 2048 + 1024 + f0];
    const float4 av1 = *(const float4*)&g2[PS + (long)t * 2048 + f0];
    const float4 gv1 = *(const float4*)&g2[PS + (long)t * 2048 + 1024 + f0];
    av.x += av1.x; av.y += av1.y; av.z += av1.z; av.w += av1.w;
    gv.x += gv1.x; gv.y += gv1.y; gv.z += gv1.z; gv.w += gv1.w;
    float vals[4];
    vals[0] = xv.x + av.x / (1.f + expf(-gv.x));
    vals[1] = xv.y + av.y / (1.f + expf(-gv.y));
    vals[2] = xv.z + av.z / (1.f + expf(-gv.z));
    vals[3] = xv.w + av.w / (1.f + expf(-gv.w));
    float s1 = vals[0] + vals[1] + vals[2] + vals[3];
    float s2 = vals[0]*vals[0] + vals[1]*vals[1] + vals[2]*vals[2] + vals[3]*vals[3];
    block_red2(s1, s2, tid);
    const float mean = s1 * (1.f / 1024.f);
    const float var  = s2 * (1.f / 1024.f) - mean * mean;
    const float rstd = rsqrtf(var + EPSF);
    const float4 gm = *(const float4*)&gam[f0];
    const float4 bt = *(const float4*)&bet[f0];
    float r0 = (vals[0] - mean) * rstd * gm.x + bt.x;
    float r1 = (vals[1] - mean) * rstd * gm.y + bt.y;
    float r2 = (vals[2] - mean) * rstd * gm.z + bt.z;
    float r3 = (vals[3] - mean) * rstd * gm.w + bt.w;
    *(float4*)&outf[(long)t * 1024 + f0] = make_float4(r0, r1, r2, r3);
    ushort4 ub; ub.x = f2bf(r0); ub.y = f2bf(r1); ub.z = f2bf(r2); ub.w = f2bf(r3);
    *(ushort4*)&outb[(long)t * 1024 + f0] = ub;
}

// ---------------- residual add + LN width 1024, B = sum of P partials (+opt bias) ----------------
template<int P, int WRITEBF, int BIAS>
__global__ __launch_bounds__(256)
void add_ln1024_k(const float* __restrict__ A, const float* __restrict__ Bp,
                  const float* __restrict__ bias,
                  const float* __restrict__ gam, const float* __restrict__ bet,
                  float* __restrict__ outf, u16* __restrict__ outb)
{
    const int t = blockIdx.x, tid = threadIdx.x;
    const int f0 = tid * 4;
    const long PS = 4194304;   // 4096*1024
    const float4 a = *(const float4*)&A[(long)t * 1024 + f0];
    float4 b = *(const float4*)&Bp[(long)t * 1024 + f0];
#pragma unroll
    for (int p = 1; p < P; ++p) {
        const float4 bp = *(const float4*)&Bp[p * PS + (long)t * 1024 + f0];
        b.x += bp.x; b.y += bp.y; b.z += bp.z; b.w += bp.w;
    }
    if (BIAS) {
        const float4 bb = *(const float4*)&bias[f0];
        b.x += bb.x; b.y += bb.y; b.z += bb.z; b.w += bb.w;
    }
    float vals[4] = {a.x + b.x, a.y + b.y, a.z + b.z, a.w + b.w};
    float s1 = vals[0] + vals[1] + vals[2] + vals[3];
    float s2 = vals[0]*vals[0] + vals[1]*vals[1] + vals[2]*vals[2] + vals[3]*vals[3];
    block_red2(s1, s2, tid);
    const float mean = s1 * (1.f / 1024.f);
    const float var  = s2 * (1.f / 1024.f) - mean * mean;
    const float rstd = rsqrtf(var + EPSF);
    const float4 gm = *(const float4*)&gam[f0];
    const float4 bt = *(const float4*)&bet[f0];
    float r0 = (vals[0] - mean) * rstd * gm.x + bt.x;
    float r1 = (vals[1] - mean) * rstd * gm.y + bt.y;
    float r2 = (vals[2] - mean) * rstd * gm.z + bt.z;
    float r3 = (vals[3] - mean) * rstd * gm.w + bt.w;
    *(float4*)&outf[(long)t * 1024 + f0] = make_float4(r0, r1, r2, r3);
    if (WRITEBF) {
        ushort4 ub; ub.x = f2bf(r0); ub.y = f2bf(r1); ub.z = f2bf(r2); ub.w = f2bf(r3);
        *(ushort4*)&outb[(long)t * 1024 + f0] = ub;
    }
}

// ---------------- n2: LN(c1L(bf16) + pad(relu(sum of 3 conv taps))) width 4096 ----------------
__global__ __launch_bounds__(256)
void add_ln4096_k(const u16* __restrict__ A, const float* __restrict__ Bp,
                  const float* __restrict__ gam, const float* __restrict__ bet,
                  u16* __restrict__ outb)
{
    const int t = blockIdx.x, tid = threadIdx.x;
    const long PS = 4194304;   // 4096*1024
    const int f0 = tid * 16;
    float vals[16];
    const bf16x8 a0 = *(const bf16x8*)&A[(long)t * 4096 + f0];
    const bf16x8 a1 = *(const bf16x8*)&A[(long)t * 4096 + f0 + 8];
#pragma unroll
    for (int e = 0; e < 8; ++e) { vals[e] = bf2f((u16)a0[e]); vals[8 + e] = bf2f((u16)a1[e]); }
    if (tid < 64) {   // first 1024 features get the conv residual
#pragma unroll
        for (int c = 0; c < 4; ++c) {
            const int fc = f0 + c * 4;
            float4 b  = *(const float4*)&Bp[(long)t * 1024 + fc];
            const float4 b1 = *(const float4*)&Bp[PS + (long)t * 1024 + fc];
            const float4 b2 = *(const float4*)&Bp[2 * PS + (long)t * 1024 + fc];
            vals[c*4+0] += fmaxf(b.x + b1.x + b2.x, 0.f);
            vals[c*4+1] += fmaxf(b.y + b1.y + b2.y, 0.f);
            vals[c*4+2] += fmaxf(b.z + b1.z + b2.z, 0.f);
            vals[c*4+3] += fmaxf(b.w + b1.w + b2.w, 0.f);
        }
    }
    float s1 = 0.f, s2 = 0.f;
#pragma unroll
    for (int e = 0; e < 16; ++e) { s1 += vals[e]; s2 += vals[e] * vals[e]; }
    block_red2(s1, s2, tid);
    const float mean = s1 * (1.f / 4096.f);
    const float var  = s2 * (1.f / 4096.f) - mean * mean;
    const float rstd = rsqrtf(var + EPSF);
#pragma unroll
    for (int c = 0; c < 4; ++c) {
        const int fc = f0 + c * 4;
        const float4 gm = *(const float4*)&gam[fc];
        const float4 bt = *(const float4*)&bet[fc];
        ushort4 ub;
        ub.x = f2bf((vals[c*4+0] - mean) * rstd * gm.x + bt.x);
        ub.y = f2bf((vals[c*4+1] - mean) * rstd * gm.y + bt.y);
        ub.z = f2bf((vals[c*4+2] - mean) * rstd * gm.z + bt.z);
        ub.w = f2bf((vals[c*4+3] - mean) * rstd * gm.w + bt.w);
        *(ushort4*)&outb[(long)t * 4096 + fc] = ub;
    }
}

// ---------------- depthwise conv width-9, 8 channels/thread ----------------
__global__ __launch_bounds__(256)
void dwconv8_k(const u16* __restrict__ h, const float* __restrict__ wT,
               u16* __restrict__ out)
{
    const long idx = (long)blockIdx.x * 256 + threadIdx.x;  // over 4096*512
    const int cg = (int)(idx & 511);
    const int t  = (int)(idx >> 9);
    const int w  = t & 255;
    const int c0 = cg * 8;
    float acc[8] = {};
#pragma unroll
    for (int k = 0; k < 9; ++k) {
        const int wp = w + k - 4;
        if ((unsigned)wp < 256u) {
            const bf16x8 hv = *(const bf16x8*)&h[(long)(t + k - 4) * 4096 + c0];
            const float4 w0 = *(const float4*)&wT[k * 4096 + c0];
            const float4 w1 = *(const float4*)&wT[k * 4096 + c0 + 4];
            acc[0] += bf2f((u16)hv[0]) * w0.x;
            acc[1] += bf2f((u16)hv[1]) * w0.y;
            acc[2] += bf2f((u16)hv[2]) * w0.z;
            acc[3] += bf2f((u16)hv[3]) * w0.w;
            acc[4] += bf2f((u16)hv[4]) * w1.x;
            acc[5] += bf2f((u16)hv[5]) * w1.y;
            acc[6] += bf2f((u16)hv[6]) * w1.z;
            acc[7] += bf2f((u16)hv[7]) * w1.w;
        }
    }
    bf16x8 res;
#pragma unroll
    for (int j = 0; j < 8; ++j) res[j] = (short)f2bf(acc[j]);
    *(bf16x8*)&out[(long)t * 4096 + c0] = res;
}

// ---------------- softmax over rows of 256, bf16 out ----------------
__global__ __launch_bounds__(256)
void softmax_k(const float* __restrict__ s, u16* __restrict__ p)
{
    const int row = blockIdx.x, tid = threadIdx.x;
    const float v = s[(long)row * 256 + tid];
    __shared__ float red[4];
    __shared__ float red2[4];
    float m = wred_max(v);
    const int lane = tid & 63, wid = tid >> 6;
    if (!lane) red[wid] = m;
    __syncthreads();
    m = fmaxf(fmaxf(red[0], red[1]), fmaxf(red[2], red[3]));
    const float e = expf(v - m);
    float sum = wred_sum(e);
    if (!lane) red2[wid] = sum;
    __syncthreads();
    sum = red2[0] + red2[1] + red2[2] + red2[3];
    p[(long)row * 256 + tid] = f2bf(e / sum);
}

// ---------------- V slice of QKVb -> Vt (z, d, w) bf16 ----------------
__global__ __launch_bounds__(256)
void vtrans_k(const u16* __restrict__ QKVb, u16* __restrict__ Vt)
{
    __shared__ u16 t[32][33];
    const int z = blockIdx.z, zb = z >> 2, zn = z & 3;
    const int w0 = blockIdx.x * 32, d0 = blockIdx.y * 32;
    const int tid = threadIdx.x, c = tid & 31, r = tid >> 5;
#pragma unroll
    for (int it = 0; it < 4; ++it) {
        const int wl = r + it * 8;
        t[wl][c] = QKVb[(long)(zb * 256 + w0 + wl) * 3072 + 2048 + zn * 256 + d0 + c];
    }
    __syncthreads();
#pragma unroll
    for (int it = 0; it < 4; ++it) {
        const int dl = r + it * 8;
        Vt[((long)z * 256 + d0 + dl) * 256 + w0 + c] = t[c][dl];
    }
}

// ---------------- final transpose (tokens,1024) -> (B,1,1024,256) ----------------
__global__ __launch_bounds__(256)
void transpose_out_k(const float* __restrict__ xs, float* __restrict__ out)
{
    __shared__ float tile[32][33];
    const int b = blockIdx.z, f0 = blockIdx.y * 32, w0 = blockIdx.x * 32;
    const int tid = threadIdx.x, c = tid & 31, r = tid >> 5;
#pragma unroll
    for (int it = 0; it < 4; ++it) {
        const int w = w0 + r + it * 8;
        tile[r + it * 8][c] = xs[((long)b * 256 + w) * 1024 + f0 + c];
    }
    __syncthreads();
#pragma unroll
    for (int it = 0; it < 4; ++it) {
        const int fl = r + it * 8;
        out[((long)b * 1024 + f0 + fl) * 256 + w0 + c] = tile[c][fl];
    }
}

// =======================================================================
extern "C" void kernel_launch(void* const* d_in, const int* in_sizes, int n_in,
                              void* d_out, int out_size, void* d_ws, size_t ws_size,
                              hipStream_t stream)
{
    const float* x      = (const float*)d_in[0];
    const float* bott_w = (const float*)d_in[1];
    const float* bn_g   = (const float*)d_in[2];
    const float* bn_b   = (const float*)d_in[3];
    const float* bn_m   = (const float*)d_in[4];
    const float* bn_v   = (const float*)d_in[5];
    const float* glu_w  = (const float*)d_in[6];
    const float* n1g    = (const float*)d_in[7];
    const float* n1b    = (const float*)d_in[8];
    const float* c1L_w  = (const float*)d_in[9];
    const float* c1R_w  = (const float*)d_in[10];
    const float* n2g    = (const float*)d_in[11];
    const float* n2b    = (const float*)d_in[12];
    const float* c2dw_w = (const float*)d_in[13];
    const float* c2pw_w = (const float*)d_in[14];
    const float* n3g    = (const float*)d_in[15];
    const float* n3b    = (const float*)d_in[16];
    const float* qw     = (const float*)d_in[17];
    const float* qb     = (const float*)d_in[18];
    const float* kw     = (const float*)d_in[19];
    const float* kb     = (const float*)d_in[20];
    const float* vw     = (const float*)d_in[21];
    const float* vb     = (const float*)d_in[22];
    const float* ow     = (const float*)d_in[23];
    const float* ob     = (const float*)d_in[24];
    const float* er     = (const float*)d_in[25];
    const float* dist_w = (const float*)d_in[26];
    const float* n4g    = (const float*)d_in[27];
    const float* n4b    = (const float*)d_in[28];
    const float* c3_w   = (const float*)d_in[29];
    const float* c4_w   = (const float*)d_in[30];
    const float* n5g    = (const float*)d_in[31];
    const float* n5b    = (const float*)d_in[32];
    float* out = (float*)d_out;

    // ---- workspace layout (MiB offsets, lifetimes annotated) ----
    char* Wb_ = (char*)d_ws;
    auto F  = [&](size_t mib) { return (float*)(Wb_ + (mib << 20)); };
    auto Bf = [&](size_t mib) { return (u16*)  (Wb_ + (mib << 20)); };
    float* X0   = F(0);     // xs chain A
    float* X1   = F(16);    // xs chain B
    u16*   H0b  = Bf(32);   // c1L bf16 out (stages 4-6) / c3 bf16 out (17-18)
    float* Hglu = F(64);    // GLU 2 partials (stages 2-3)
    float* C3p  = F(64);    // conv3 3 partials (stages 5-6)
    float* P4   = F(64);    // c2pw/O-proj/c4 4 partials (8-9, 15-16, 18-19)
    u16*   H1b  = Bf(128);  // n2 out bf16 (stages 6-7)
    u16*   Hdw  = Bf(160);  // dwconv out bf16 (7-8)
    u16*   QKVb = Bf(192);  // fused QKV out 4096x3072 bf16 (10-12)
    u16*   Vt   = Bf(216);  // V transposed (10b-14)
    float* QER  = F(224);   // qer f32 (11-12)
    float* S0   = F(240);   // scores f32 (12-13)
    u16*   Pb   = Bf(256);  // softmax bf16 (13-14)
    u16*   S1b  = Bf(264);  // attn concat bf16 (14-15)
    u16*   XbA  = Bf(280);  // X1b (1-2), X2b (9-10)
    u16*   XbB  = Bf(288);  // X0b (3-5), X3b (16-17)
    u16* wGLU = Bf(296); u16* wC1L = Bf(300); u16* wC1R = Bf(308);
    u16* wC2P = Bf(314); u16* wQKV = Bf(322); u16* wO   = Bf(328);
    u16* wC3  = Bf(330); u16* wC4  = Bf(338);
    u16* erT  = Bf(346);
    u16* zp   = (u16*)(Wb_ + (346u << 20) + 131072);
    float* wdwT = (float*)(Wb_ + (346u << 20) + 131072 + 16384);
    float* bQKV = (float*)(Wb_ + (346u << 20) + 131072 + 16384 + 147456);

    const dim3 blk(256);
    const dim3 blk8(512);
    const long PS1 = 4194304;   // 4096*1024
    const size_t SH8 = 131072;  // 128 KiB dynamic LDS for gemm8

    // 0. weight conversions + zero page + bias concat
    zero_k<<<dim3(32), blk, 0, stream>>>(zp, 8192);
    wcvt_k<<<dim3(2048), blk, 0, stream>>>(glu_w,  wGLU, 524288);
    wcvt_k<<<dim3(4096), blk, 0, stream>>>(c1L_w,  wC1L, 1048576);
    c1rcvt_k<<<dim3(12288), blk, 0, stream>>>(c1R_w, wC1R);
    wcvt_k<<<dim3(4096), blk, 0, stream>>>(c2pw_w, wC2P, 1048576);
    wcvt_k<<<dim3(1024), blk, 0, stream>>>(qw, wQKV, 262144);
    wcvt_k<<<dim3(1024), blk, 0, stream>>>(kw, wQKV + 1048576, 262144);
    wcvt_k<<<dim3(1024), blk, 0, stream>>>(vw, wQKV + 2097152, 262144);
    wcvt_k<<<dim3(1024), blk, 0, stream>>>(ow, wO, 262144);
    wcvt_k<<<dim3(4096), blk, 0, stream>>>(c3_w, wC3, 1048576);
    wcvt_k<<<dim3(4096), blk, 0, stream>>>(c4_w, wC4, 1048576);
    ercvt_k<<<dim3(256), blk, 0, stream>>>(er, erT);
    dwcvt_k<<<dim3(144), blk, 0, stream>>>(c2dw_w, wdwT);
    biascat_k<<<dim3(12), blk, 0, stream>>>(qb, kb, vb, bQKV);

    // 1. bottleneck + BN + ReLU + transpose
    bottleneck_k<<<dim3(8, 32, 16), blk, 0, stream>>>(x, bott_w, bn_g, bn_b, bn_m, bn_v, X1, XbA);

    // 2. GLU matmul, split-K=2 -> Hglu partials
    gemm8_k<0,0,0,2><<<dim3(8, 16, 2), blk8, SH8, stream>>>(XbA, wGLU, nullptr, Hglu,
        2048, 512, 1024, 1024, (long)4096 * 2048);

    // 3. n1: LN(xs0 + a*sigmoid(g)) -> X0 + X0b
    glu_ln_k<<<dim3(4096), blk, 0, stream>>>(X1, Hglu, n1g, n1b, X0, XbB);

    // 4. c1L: relu -> H0b bf16 (4096x4096)
    gemm8_k<1,1,0,1><<<dim3(16, 16, 1), blk8, SH8, stream>>>(XbB, wC1L, nullptr, H0b,
        4096, 1024, 1024, 1024, 0);

    // 5. c1R conv: 3 tap-slices -> C3p partials
    conv3s_bf16_k<<<dim3(8, 32, 3), blk, 0, stream>>>(XbB, wC1R, zp, C3p);

    // 6. n2: LN(H0b + pad(relu(sum taps))) -> H1b bf16
    add_ln4096_k<<<dim3(4096), blk, 0, stream>>>(H0b, C3p, n2g, n2b, H1b);

    // 7. depthwise conv9 (vectorized x8): H1b -> Hdw
    dwconv8_k<<<dim3(8192), blk, 0, stream>>>(H1b, wdwT, Hdw);

    // 8. c2pw, split-K=4 -> P4 partials
    gemm8_k<0,0,0,4><<<dim3(4, 16, 4), blk8, SH8, stream>>>(Hdw, wC2P, nullptr, P4,
        1024, 1024, 4096, 4096, PS1);

    // 9. n3: LN(X0 + sum P4) -> X1 + X2b
    add_ln1024_k<4,1,0><<<dim3(4096), blk, 0, stream>>>(X0, P4, nullptr, n3g, n3b, X1, XbA);

    // 10. fused QKV projection (+concat bias) -> QKVb bf16 (4096x3072)
    gemm8_k<0,1,1,1><<<dim3(12, 16, 1), blk8, SH8, stream>>>(XbA, wQKV, bQKV, QKVb,
        3072, 1024, 1024, 1024, 0);

    // 10b. V transpose per head -> Vt (z, d, w)
    vtrans_k<<<dim3(8, 8, 64), blk, 0, stream>>>(QKVb, Vt);

    // 11. qer = Q_head @ erT^T -> QER f32
    gemm_bf16_bat_k<0,0><<<dim3(2, 2, 64), blk, 0, stream>>>(QKVb, erT, QER,
        256, 3072, 256, 256,
        (long)256 * 3072, 256, 0, 0,
        (long)4 * 65536, 65536, nullptr, nullptr, 1.f);

    // 12. scores = QK^T/32 + dist*dist_w + qer^T -> S0 f32
    gemm_bf16_bat_k<1,0><<<dim3(2, 2, 64), blk, 0, stream>>>(QKVb, QKVb + 1024, S0,
        256, 3072, 3072, 256,
        (long)256 * 3072, 256, (long)256 * 3072, 256,
        (long)4 * 65536, 65536, QER, dist_w, 1.f / 32.f);

    // 13. softmax rows -> Pb bf16
    softmax_k<<<dim3(16384), blk, 0, stream>>>(S0, Pb);

    // 14. o = P @ Vt^T -> S1b bf16 (concat layout)
    gemm_bf16_bat_k<0,1><<<dim3(2, 2, 64), blk, 0, stream>>>(Pb, Vt, S1b,
        256, 256, 256, 1024,
        (long)4 * 65536, 65536, (long)4 * 65536, 65536,
        (long)256 * 1024, 256, nullptr, nullptr, 1.f);

    // 15. output projection, split-K=4 -> P4 partials (bias added in n4)
    gemm8_k<0,0,0,4><<<dim3(4, 16, 4), blk8, SH8, stream>>>(S1b, wO, nullptr, P4,
        1024, 256, 1024, 1024, PS1);

    // 16. n4: LN(X1 + sum P4 + ob) -> X0 + X3b
    add_ln1024_k<4,1,1><<<dim3(4096), blk, 0, stream>>>(X1, P4, ob, n4g, n4b, X0, XbB);

    // 17. c3: relu -> H0b bf16
    gemm8_k<1,1,0,1><<<dim3(16, 16, 1), blk8, SH8, stream>>>(XbB, wC3, nullptr, H0b,
        4096, 1024, 1024, 1024, 0);

    // 18. c4, split-K=4 -> P4 partials
    gemm8_k<0,0,0,4><<<dim3(4, 16, 4), blk8, SH8, stream>>>(H0b, wC4, nullptr, P4,
        1024, 1024, 4096, 4096, PS1);

    // 19. n5: LN(X0 + sum P4) -> X1 (f32 only)
    add_ln1024_k<4,0,0><<<dim3(4096), blk, 0, stream>>>(X0, P4, nullptr, n5g, n5b, X1, nullptr);

    // 20. transpose to (B, 1, 1024, 256)
    transpose_out_k<<<dim3(8, 32, 16), blk, 0, stream>>>(X1, out);

    (void)in_sizes; (void)n_in; (void)out_size; (void)ws_size;
}

// Round 6
// 553.822 us; speedup vs baseline: 6.3031x; 1.1147x over previous
//
#include <hip/hip_runtime.h>
#include <hip/hip_bf16.h>

// FrameTransformer: B=16, C=8, BINS=1024, W=256, FF=2048, NB=4
// tokens = B*W = 4096, feature width 1024, FF width 4096, head dim 256.
#define EPSF 1e-5f

typedef unsigned short u16;
typedef unsigned int   u32;
typedef __attribute__((ext_vector_type(8))) short bf16x8;
typedef __attribute__((ext_vector_type(4))) float f32x4;

__device__ __forceinline__ u16 f2bf(float f) {
    u32 u = __builtin_bit_cast(u32, f);
    u32 r = u + 0x7fffu + ((u >> 16) & 1u);
    return (u16)(r >> 16);
}
__device__ __forceinline__ float bf2f(u16 h) {
    return __builtin_bit_cast(float, (u32)h << 16);
}
__device__ __forceinline__ void gld16(void* lds, const void* gsrc) {
    __builtin_amdgcn_global_load_lds(
        (const __attribute__((address_space(1))) u32*)gsrc,
        (__attribute__((address_space(3))) u32*)lds, 16, 0, 0);
}

__device__ __forceinline__ float wred_sum(float v) {
#pragma unroll
    for (int off = 32; off; off >>= 1) v += __shfl_xor(v, off, 64);
    return v;
}
__device__ __forceinline__ void block_red2(float& s1, float& s2, int tid) {
    __shared__ float red[8];
    s1 = wred_sum(s1); s2 = wred_sum(s2);
    const int lane = tid & 63, wid = tid >> 6;
    if (!lane) { red[wid] = s1; red[4 + wid] = s2; }
    __syncthreads();
    s1 = red[0] + red[1] + red[2] + red[3];
    s2 = red[4] + red[5] + red[6] + red[7];
}

// ---------------- converters ----------------
struct Cvt9 { const float* s[9]; u16* d[9]; int n[9]; };
__global__ __launch_bounds__(256)
void wcvt9_k(Cvt9 a)
{
    const int seg = blockIdx.y;
    const int i = blockIdx.x * 256 + threadIdx.x;
    if (i >= a.n[seg]) return;
    const float4 v = ((const float4*)a.s[seg])[i];
    ushort4 o; o.x = f2bf(v.x); o.y = f2bf(v.y); o.z = f2bf(v.z); o.w = f2bf(v.w);
    ((ushort4*)a.d[seg])[i] = o;
}
// c1R_w (o,ci,ks=3) -> Wt (o, ks, ci) bf16
__global__ __launch_bounds__(256)
void c1rcvt_k(const float* __restrict__ src, u16* __restrict__ dst)
{
    const int i = blockIdx.x * 256 + threadIdx.x;     // over 1024*3072
    const int q = i / 3072, rem = i - q * 3072;
    const int ks = rem >> 10, ci = rem & 1023;
    dst[i] = f2bf(src[((long)q * 1024 + ci) * 3 + ks]);
}
// er (d=256, c=256) f32 -> erT (c, d) bf16
__global__ __launch_bounds__(256)
void ercvt_k(const float* __restrict__ er, u16* __restrict__ erT)
{
    const int i = blockIdx.x * 256 + threadIdx.x;     // over 65536
    const int c = i >> 8, d = i & 255;
    erT[i] = f2bf(er[d * 256 + c]);
}
// c2dw_w (c,1,9) -> wdwT (9, 4096) f32
__global__ __launch_bounds__(256)
void dwcvt_k(const float* __restrict__ src, float* __restrict__ dst)
{
    const int i = blockIdx.x * 256 + threadIdx.x;     // over 9*4096
    if (i >= 9 * 4096) return;
    const int k = i >> 12, c = i & 4095;
    dst[i] = src[c * 9 + k];
}
__global__ __launch_bounds__(256)
void zero_k(u16* __restrict__ p, int n)
{
    const int i = blockIdx.x * 256 + threadIdx.x;
    if (i < n) p[i] = 0;
}
// concat q/k/v biases -> 3072
__global__ __launch_bounds__(256)
void biascat_k(const float* __restrict__ b0, const float* __restrict__ b1,
               const float* __restrict__ b2, float* __restrict__ dst)
{
    const int i = blockIdx.x * 256 + threadIdx.x;     // over 3072
    const float* s = (i < 1024) ? b0 : ((i < 2048) ? b1 : b2);
    dst[i] = s[i & 1023];
}

// ---------------- stage 1: bottleneck 1x1 conv + BN + ReLU + transpose ----------------
__global__ __launch_bounds__(256)
void bottleneck_k(const float* __restrict__ x, const float* __restrict__ bw,
                  const float* __restrict__ bn_g, const float* __restrict__ bn_b,
                  const float* __restrict__ bn_m, const float* __restrict__ bn_v,
                  float* __restrict__ xs, u16* __restrict__ xsb)
{
    __shared__ float tile[32][33];
    const int b = blockIdx.z, h0 = blockIdx.y * 32, w0 = blockIdx.x * 32;
    const int tid = threadIdx.x, c = tid & 31, r = tid >> 5;
    float wreg[8];
#pragma unroll
    for (int ch = 0; ch < 8; ++ch) wreg[ch] = bw[ch];
    const float sc = bn_g[0] * rsqrtf(bn_v[0] + EPSF);
    const float sh = bn_b[0] - bn_m[0] * sc;
#pragma unroll
    for (int it = 0; it < 4; ++it) {
        const int h = h0 + r + it * 8;
        const int w = w0 + c;
        float acc = 0.f;
#pragma unroll
        for (int ch = 0; ch < 8; ++ch)
            acc += x[(((long)b * 8 + ch) * 1024 + h) * 256 + w] * wreg[ch];
        tile[r + it * 8][c] = fmaxf(acc * sc + sh, 0.f);
    }
    __syncthreads();
#pragma unroll
    for (int it = 0; it < 4; ++it) {
        const int wl = r + it * 8;
        const float v = tile[c][wl];
        const long o = ((long)b * 256 + w0 + wl) * 1024 + h0 + c;
        xs[o] = v;
        xsb[o] = f2bf(v);
    }
}

// ============ 8-phase 256x256 bf16 MFMA GEMM (T2+T3+T4+T5) ============
template<int ACT, int OUTBF, int BIAS, int SPLITK>
__global__ __launch_bounds__(512, 2)
void gemm8_k(const u16* __restrict__ A, const u16* __restrict__ B,
             const float* __restrict__ bias, void* __restrict__ Cout,
             int N, int K /*per slice*/, int lda, int ldb, long partStride)
{
    extern __shared__ u16 lds[];
    const int m0 = blockIdx.y * 256, n0 = blockIdx.x * 256;
    const int koff = (SPLITK > 1) ? blockIdx.z * K : 0;
    const int nt = K >> 6;
    const int tid = threadIdx.x;
    const int lane = tid & 63, wid = tid >> 6;
    const int wr = ((wid >> 2) & 1) * 128;
    const int wc = (wid & 3) * 64;
    const int l15 = lane & 15, l4 = lane >> 4;

    const u16* Ag = A + (long)m0 * lda + koff;
    const u16* Bg = B + (long)n0 * ldb + koff;

    auto stage = [&](const u16* g, int ld, int ldsbase, int kcol, int h) {
#pragma unroll
        for (int is = 0; is < 2; ++is) {
            const int r = h * 128 + is * 64 + (tid >> 3);
            const int sc = ((tid & 7) * 8) ^ (((r >> 2) & 1) << 4);
            gld16(&lds[ldsbase + h * 8192 + is * 4096 + tid * 8],
                  g + (long)r * ld + kcol + sc);
        }
    };
    auto frag = [&](int base, int row, int col) -> bf16x8 {
        return *(const bf16x8*)&lds[base + row * 64 + (col ^ (((row >> 2) & 1) << 4))];
    };

    f32x4 acc[8][4] = {};

    stage(Ag, lda, 0, 0, 0);
    stage(Ag, lda, 0, 0, 1);
    stage(Bg, ldb, 32768, 0, 0);
    stage(Bg, ldb, 32768, 0, 1);
    if (nt > 1) {
        stage(Bg, ldb, 49152, 64, 0);
        stage(Bg, ldb, 49152, 64, 1);
        stage(Ag, lda, 16384, 64, 0);
        asm volatile("s_waitcnt vmcnt(6)" ::: "memory");
    } else {
        asm volatile("s_waitcnt vmcnt(0)" ::: "memory");
    }
    __builtin_amdgcn_s_barrier();

    for (int kt = 0; kt < nt; ++kt) {
        const int cs = kt & 1;
        const int ab = cs * 16384;
        const int bb = 32768 + cs * 16384;
        const int abn = (cs ^ 1) * 16384;
        const int kc1 = (kt + 1) * 64, kc2 = (kt + 2) * 64;
        bf16x8 alo[4][2], ahi[4][2], b01[2][2], b23[2][2];

#pragma unroll
        for (int i = 0; i < 4; ++i)
#pragma unroll
            for (int kk = 0; kk < 2; ++kk)
                alo[i][kk] = frag(ab, wr + i * 16 + l15, kk * 32 + l4 * 8);
#pragma unroll
        for (int j = 0; j < 2; ++j)
#pragma unroll
            for (int kk = 0; kk < 2; ++kk)
                b01[j][kk] = frag(bb, wc + j * 16 + l15, kk * 32 + l4 * 8);
        if (kt + 1 < nt) stage(Ag, lda, abn, kc1, 1);
        __builtin_amdgcn_s_barrier();
        asm volatile("s_waitcnt lgkmcnt(0)" ::: "memory");
        __builtin_amdgcn_s_setprio(1);
#pragma unroll
        for (int i = 0; i < 4; ++i)
#pragma unroll
            for (int j = 0; j < 2; ++j)
#pragma unroll
                for (int kk = 0; kk < 2; ++kk)
                    acc[i][j] = __builtin_amdgcn_mfma_f32_16x16x32_bf16(alo[i][kk], b01[j][kk], acc[i][j], 0, 0, 0);
        __builtin_amdgcn_s_setprio(0);
        __builtin_amdgcn_s_barrier();

#pragma unroll
        for (int j = 0; j < 2; ++j)
#pragma unroll
            for (int kk = 0; kk < 2; ++kk)
                b23[j][kk] = frag(bb, wc + (j + 2) * 16 + l15, kk * 32 + l4 * 8);
        if (kt + 2 < nt) stage(Bg, ldb, bb, kc2, 0);
        __builtin_amdgcn_s_barrier();
        asm volatile("s_waitcnt lgkmcnt(0)" ::: "memory");
        __builtin_amdgcn_s_setprio(1);
#pragma unroll
        for (int i = 0; i < 4; ++i)
#pragma unroll
            for (int j = 0; j < 2; ++j)
#pragma unroll
                for (int kk = 0; kk < 2; ++kk)
                    acc[i][j + 2] = __builtin_amdgcn_mfma_f32_16x16x32_bf16(alo[i][kk], b23[j][kk], acc[i][j + 2], 0, 0, 0);
        __builtin_amdgcn_s_setprio(0);
        __builtin_amdgcn_s_barrier();

#pragma unroll
        for (int i = 0; i < 4; ++i)
#pragma unroll
            for (int kk = 0; kk < 2; ++kk)
                ahi[i][kk] = frag(ab, wr + (i + 4) * 16 + l15, kk * 32 + l4 * 8);
        if (kt + 2 < nt) stage(Bg, ldb, bb, kc2, 1);
        __builtin_amdgcn_s_barrier();
        asm volatile("s_waitcnt lgkmcnt(0)" ::: "memory");
        __builtin_amdgcn_s_setprio(1);
#pragma unroll
        for (int i = 0; i < 4; ++i)
#pragma unroll
            for (int j = 0; j < 2; ++j)
#pragma unroll
                for (int kk = 0; kk < 2; ++kk)
                    acc[i + 4][j + 2] = __builtin_amdgcn_mfma_f32_16x16x32_bf16(ahi[i][kk], b23[j][kk], acc[i + 4][j + 2], 0, 0, 0);
        __builtin_amdgcn_s_setprio(0);
        __builtin_amdgcn_s_barrier();

        if (kt + 2 < nt) stage(Ag, lda, ab, kc2, 0);
        __builtin_amdgcn_s_barrier();
        __builtin_amdgcn_s_setprio(1);
#pragma unroll
        for (int i = 0; i < 4; ++i)
#pragma unroll
            for (int j = 0; j < 2; ++j)
#pragma unroll
                for (int kk = 0; kk < 2; ++kk)
                    acc[i + 4][j] = __builtin_amdgcn_mfma_f32_16x16x32_bf16(ahi[i][kk], b01[j][kk], acc[i + 4][j], 0, 0, 0);
        __builtin_amdgcn_s_setprio(0);
        if (kt + 2 < nt) {
            asm volatile("s_waitcnt vmcnt(6)" ::: "memory");
        } else {
            asm volatile("s_waitcnt vmcnt(0)" ::: "memory");
        }
        __builtin_amdgcn_s_barrier();
    }

    float* Cf = (float*)Cout + ((SPLITK > 1) ? (long)blockIdx.z * partStride : 0);
    u16*   Cb = (u16*)Cout;
#pragma unroll
    for (int i = 0; i < 8; ++i)
#pragma unroll
        for (int j = 0; j < 4; ++j) {
            const int n = n0 + wc + j * 16 + l15;
            const float bv = BIAS ? bias[n] : 0.f;
#pragma unroll
            for (int q = 0; q < 4; ++q) {
                const int m = m0 + wr + i * 16 + l4 * 4 + q;
                float v = acc[i][j][q] + bv;
                if (ACT) v = fmaxf(v, 0.f);
                if (OUTBF) Cb[(long)m * N + n] = f2bf(v);
                else       Cf[(long)m * N + n] = v;
            }
        }
}

// ============ conv1R on the 8-phase body: per-tap z, row-shifted A with OOB redirect ============
__global__ __launch_bounds__(512, 2)
void conv38_k(const u16* __restrict__ Xb, const u16* __restrict__ Wt,
              const u16* __restrict__ zp, float* __restrict__ C)
{
    extern __shared__ u16 lds[];
    const int ks = blockIdx.z;
    const int m0 = blockIdx.y * 256, n0 = blockIdx.x * 256;
    const int nt = 16;   // K = 1024
    const int tid = threadIdx.x;
    const int lane = tid & 63, wid = tid >> 6;
    const int wr = ((wid >> 2) & 1) * 128;
    const int wc = (wid & 3) * 64;
    const int l15 = lane & 15, l4 = lane >> 4;

    auto stageA = [&](int ldsbase, int kcol, int h) {
#pragma unroll
        for (int is = 0; is < 2; ++is) {
            const int r = h * 128 + is * 64 + (tid >> 3);
            const int sc = ((tid & 7) * 8) ^ (((r >> 2) & 1) << 4);
            const int t = m0 + r;
            const int wp = (t & 255) + ks - 1;
            const u16* src = ((unsigned)wp < 256u)
                ? Xb + (long)(t + ks - 1) * 1024 + kcol + sc
                : zp;
            gld16(&lds[ldsbase + h * 8192 + is * 4096 + tid * 8], src);
        }
    };
    auto stageB = [&](int ldsbase, int kcol, int h) {
#pragma unroll
        for (int is = 0; is < 2; ++is) {
            const int r = h * 128 + is * 64 + (tid >> 3);
            const int sc = ((tid & 7) * 8) ^ (((r >> 2) & 1) << 4);
            gld16(&lds[ldsbase + h * 8192 + is * 4096 + tid * 8],
                  Wt + (long)(n0 + r) * 3072 + ks * 1024 + kcol + sc);
        }
    };
    auto frag = [&](int base, int row, int col) -> bf16x8 {
        return *(const bf16x8*)&lds[base + row * 64 + (col ^ (((row >> 2) & 1) << 4))];
    };

    f32x4 acc[8][4] = {};

    stageA(0, 0, 0);
    stageA(0, 0, 1);
    stageB(32768, 0, 0);
    stageB(32768, 0, 1);
    stageB(49152, 64, 0);
    stageB(49152, 64, 1);
    stageA(16384, 64, 0);
    asm volatile("s_waitcnt vmcnt(6)" ::: "memory");
    __builtin_amdgcn_s_barrier();

    for (int kt = 0; kt < nt; ++kt) {
        const int cs = kt & 1;
        const int ab = cs * 16384;
        const int bb = 32768 + cs * 16384;
        const int abn = (cs ^ 1) * 16384;
        const int kc1 = (kt + 1) * 64, kc2 = (kt + 2) * 64;
        bf16x8 alo[4][2], ahi[4][2], b01[2][2], b23[2][2];

#pragma unroll
        for (int i = 0; i < 4; ++i)
#pragma unroll
            for (int kk = 0; kk < 2; ++kk)
                alo[i][kk] = frag(ab, wr + i * 16 + l15, kk * 32 + l4 * 8);
#pragma unroll
        for (int j = 0; j < 2; ++j)
#pragma unroll
            for (int kk = 0; kk < 2; ++kk)
                b01[j][kk] = frag(bb, wc + j * 16 + l15, kk * 32 + l4 * 8);
        if (kt + 1 < nt) stageA(abn, kc1, 1);
        __builtin_amdgcn_s_barrier();
        asm volatile("s_waitcnt lgkmcnt(0)" ::: "memory");
        __builtin_amdgcn_s_setprio(1);
#pragma unroll
        for (int i = 0; i < 4; ++i)
#pragma unroll
            for (int j = 0; j < 2; ++j)
#pragma unroll
                for (int kk = 0; kk < 2; ++kk)
                    acc[i][j] = __builtin_amdgcn_mfma_f32_16x16x32_bf16(alo[i][kk], b01[j][kk], acc[i][j], 0, 0, 0);
        __builtin_amdgcn_s_setprio(0);
        __builtin_amdgcn_s_barrier();

#pragma unroll
        for (int j = 0; j < 2; ++j)
#pragma unroll
            for (int kk = 0; kk < 2; ++kk)
                b23[j][kk] = frag(bb, wc + (j + 2) * 16 + l15, kk * 32 + l4 * 8);
        if (kt + 2 < nt) stageB(bb, kc2, 0);
        __builtin_amdgcn_s_barrier();
        asm volatile("s_waitcnt lgkmcnt(0)" ::: "memory");
        __builtin_amdgcn_s_setprio(1);
#pragma unroll
        for (int i = 0; i < 4; ++i)
#pragma unroll
            for (int j = 0; j < 2; ++j)
#pragma unroll
                for (int kk = 0; kk < 2; ++kk)
                    acc[i][j + 2] = __builtin_amdgcn_mfma_f32_16x16x32_bf16(alo[i][kk], b23[j][kk], acc[i][j + 2], 0, 0, 0);
        __builtin_amdgcn_s_setprio(0);
        __builtin_amdgcn_s_barrier();

#pragma unroll
        for (int i = 0; i < 4; ++i)
#pragma unroll
            for (int kk = 0; kk < 2; ++kk)
                ahi[i][kk] = frag(ab, wr + (i + 4) * 16 + l15, kk * 32 + l4 * 8);
        if (kt + 2 < nt) stageB(bb, kc2, 1);
        __builtin_amdgcn_s_barrier();
        asm volatile("s_waitcnt lgkmcnt(0)" ::: "memory");
        __builtin_amdgcn_s_setprio(1);
#pragma unroll
        for (int i = 0; i < 4; ++i)
#pragma unroll
            for (int j = 0; j < 2; ++j)
#pragma unroll
                for (int kk = 0; kk < 2; ++kk)
                    acc[i + 4][j + 2] = __builtin_amdgcn_mfma_f32_16x16x32_bf16(ahi[i][kk], b23[j][kk], acc[i + 4][j + 2], 0, 0, 0);
        __builtin_amdgcn_s_setprio(0);
        __builtin_amdgcn_s_barrier();

        if (kt + 2 < nt) stageA(ab, kc2, 0);
        __builtin_amdgcn_s_barrier();
        __builtin_amdgcn_s_setprio(1);
#pragma unroll
        for (int i = 0; i < 4; ++i)
#pragma unroll
            for (int j = 0; j < 2; ++j)
#pragma unroll
                for (int kk = 0; kk < 2; ++kk)
                    acc[i + 4][j] = __builtin_amdgcn_mfma_f32_16x16x32_bf16(ahi[i][kk], b01[j][kk], acc[i + 4][j], 0, 0, 0);
        __builtin_amdgcn_s_setprio(0);
        if (kt + 2 < nt) {
            asm volatile("s_waitcnt vmcnt(6)" ::: "memory");
        } else {
            asm volatile("s_waitcnt vmcnt(0)" ::: "memory");
        }
        __builtin_amdgcn_s_barrier();
    }

    float* Cp = C + (long)ks * 4194304;
#pragma unroll
    for (int i = 0; i < 8; ++i)
#pragma unroll
        for (int j = 0; j < 4; ++j) {
            const int n = n0 + wc + j * 16 + l15;
#pragma unroll
            for (int q = 0; q < 4; ++q) {
                const int m = m0 + wr + i * 16 + l4 * 4 + q;
                Cp[(long)m * 1024 + n] = acc[i][j][q];
            }
        }
}

// ============ fused attention: scores(QK/32 + erT@Q^T + dist) -> softmax -> P@Vt^T ============
// grid (4, 64): blockIdx.x = 64-row q-tile, blockIdx.y = head z. 256 threads = 4 waves (n/d split).
__global__ __launch_bounds__(256, 2)
void attn_fused_k(const u16* __restrict__ QKVb, const u16* __restrict__ erT,
                  const u16* __restrict__ Vt, const float* __restrict__ dwp,
                  u16* __restrict__ Oc)
{
    __shared__ __align__(16) u16 As[4096];    // 64 x 64
    __shared__ __align__(16) u16 Bs[16384];   // 256 x 64
    __shared__ __align__(16) u16 Pl[16384];   // 4 chunks x 64 x 64
    __shared__ float redM[4][64];
    __shared__ float redS[4][64];
    const int z = blockIdx.y, zb = z >> 2, zn = z & 3;
    const int m0 = blockIdx.x * 64;
    const int tid = threadIdx.x;
    const int lane = tid & 63, wid = tid >> 6;
    const int l15 = lane & 15, l4 = lane >> 4;

    const u16* Qg = QKVb + (long)(zb * 256) * 3072 + zn * 256;
    const u16* Kg = Qg + 1024;

    auto stageA64 = [&](const u16* g, long ld) {
#pragma unroll
        for (int p = 0; p < 2; ++p) {
            const int e = p * 2048 + tid * 8;
            const int r = e >> 6, c = e & 63;
            const int sc = c ^ (((r >> 2) & 1) << 4);
            gld16(&As[e], g + (long)r * ld + sc);
        }
    };
    auto stageB256 = [&](const u16* g, long ld) {
#pragma unroll
        for (int p = 0; p < 8; ++p) {
            const int e = p * 2048 + tid * 8;
            const int r = e >> 6, c = e & 63;
            const int sc = c ^ (((r >> 2) & 1) << 4);
            gld16(&Bs[e], g + (long)r * ld + sc);
        }
    };
    auto fragA = [&](int i, int kk) -> bf16x8 {
        const int row = i * 16 + l15, col = kk * 32 + l4 * 8;
        return *(const bf16x8*)&As[row * 64 + (col ^ (((row >> 2) & 1) << 4))];
    };
    auto fragB = [&](int j, int kk) -> bf16x8 {
        const int row = wid * 64 + j * 16 + l15, col = kk * 32 + l4 * 8;
        return *(const bf16x8*)&Bs[row * 64 + (col ^ (((row >> 2) & 1) << 4))];
    };
    auto fragP = [&](int kc, int i, int kk) -> bf16x8 {
        const int row = i * 16 + l15, col = kk * 32 + l4 * 8;
        return *(const bf16x8*)&Pl[kc * 4096 + row * 64 + (col ^ (((row >> 2) & 1) << 4))];
    };

    f32x4 acc1[4][4] = {};   // QK^T
    f32x4 acc2[4][4] = {};   // erT @ Q^T  (skew term)

    // loop 1: QK^T over K=256
    for (int kc = 0; kc < 4; ++kc) {
        __syncthreads();
        stageA64(Qg + (long)m0 * 3072 + kc * 64, 3072);
        stageB256(Kg + kc * 64, 3072);
        __syncthreads();
#pragma unroll
        for (int i = 0; i < 4; ++i) {
            const bf16x8 a0 = fragA(i, 0), a1 = fragA(i, 1);
#pragma unroll
            for (int j = 0; j < 4; ++j) {
                acc1[i][j] = __builtin_amdgcn_mfma_f32_16x16x32_bf16(a0, fragB(j, 0), acc1[i][j], 0, 0, 0);
                acc1[i][j] = __builtin_amdgcn_mfma_f32_16x16x32_bf16(a1, fragB(j, 1), acc1[i][j], 0, 0, 0);
            }
        }
    }
    // loop 2: skew[m,n] = qer[n,m] = erT[m,:] . Q[n,:]
    for (int kc = 0; kc < 4; ++kc) {
        __syncthreads();
        stageA64(erT + (long)m0 * 256 + kc * 64, 256);
        stageB256(Qg + kc * 64, 3072);
        __syncthreads();
#pragma unroll
        for (int i = 0; i < 4; ++i) {
            const bf16x8 a0 = fragA(i, 0), a1 = fragA(i, 1);
#pragma unroll
            for (int j = 0; j < 4; ++j) {
                acc2[i][j] = __builtin_amdgcn_mfma_f32_16x16x32_bf16(a0, fragB(j, 0), acc2[i][j], 0, 0, 0);
                acc2[i][j] = __builtin_amdgcn_mfma_f32_16x16x32_bf16(a1, fragB(j, 1), acc2[i][j], 0, 0, 0);
            }
        }
    }

    // scores
    const float inv32 = 1.f / 32.f;
#pragma unroll
    for (int i = 0; i < 4; ++i)
#pragma unroll
        for (int q = 0; q < 4; ++q) {
            const int mg = m0 + i * 16 + l4 * 4 + q;
            const float dw = dwp[zn * 256 + mg];
#pragma unroll
            for (int j = 0; j < 4; ++j) {
                const int ng = wid * 64 + j * 16 + l15;
                acc1[i][j][q] = acc1[i][j][q] * inv32 + acc2[i][j][q]
                              + fabsf((float)(mg - ng)) * 0.5f * dw;
            }
        }

    // row max (over n): per-thread j-reduce, shfl over l15 group, cross-wave via LDS
    float rmax[4][4], rsum[4][4];
#pragma unroll
    for (int i = 0; i < 4; ++i)
#pragma unroll
        for (int q = 0; q < 4; ++q) {
            float mv = fmaxf(fmaxf(acc1[i][0][q], acc1[i][1][q]),
                             fmaxf(acc1[i][2][q], acc1[i][3][q]));
#pragma unroll
            for (int off = 1; off <= 8; off <<= 1) mv = fmaxf(mv, __shfl_xor(mv, off, 64));
            rmax[i][q] = mv;
        }
    if (l15 == 0) {
#pragma unroll
        for (int i = 0; i < 4; ++i)
#pragma unroll
            for (int q = 0; q < 4; ++q)
                redM[wid][i * 16 + l4 * 4 + q] = rmax[i][q];
    }
    __syncthreads();
#pragma unroll
    for (int i = 0; i < 4; ++i)
#pragma unroll
        for (int q = 0; q < 4; ++q) {
            const int ml = i * 16 + l4 * 4 + q;
            rmax[i][q] = fmaxf(fmaxf(redM[0][ml], redM[1][ml]), fmaxf(redM[2][ml], redM[3][ml]));
        }
    // exp + row sum
#pragma unroll
    for (int i = 0; i < 4; ++i)
#pragma unroll
        for (int q = 0; q < 4; ++q) {
            float sv = 0.f;
#pragma unroll
            for (int j = 0; j < 4; ++j) {
                const float e = __expf(acc1[i][j][q] - rmax[i][q]);
                acc1[i][j][q] = e;
                sv += e;
            }
#pragma unroll
            for (int off = 1; off <= 8; off <<= 1) sv += __shfl_xor(sv, off, 64);
            rsum[i][q] = sv;
        }
    if (l15 == 0) {
#pragma unroll
        for (int i = 0; i < 4; ++i)
#pragma unroll
            for (int q = 0; q < 4; ++q)
                redS[wid][i * 16 + l4 * 4 + q] = rsum[i][q];
    }
    __syncthreads();
#pragma unroll
    for (int i = 0; i < 4; ++i)
#pragma unroll
        for (int q = 0; q < 4; ++q) {
            const int ml = i * 16 + l4 * 4 + q;
            rsum[i][q] = redS[0][ml] + redS[1][ml] + redS[2][ml] + redS[3][ml];
        }
    // P -> LDS (bf16, chunked+swizzled for the PV A-reads)
#pragma unroll
    for (int i = 0; i < 4; ++i)
#pragma unroll
        for (int q = 0; q < 4; ++q) {
            const float rinv = 1.f / rsum[i][q];
            const int ml = i * 16 + l4 * 4 + q;
#pragma unroll
            for (int j = 0; j < 4; ++j) {
                const int nc = j * 16 + l15;
                Pl[wid * 4096 + ml * 64 + (nc ^ (((ml >> 2) & 1) << 4))] = f2bf(acc1[i][j][q] * rinv);
            }
        }
    __syncthreads();

    // PV: o[m, d] = sum_n P[m,n] * Vt[d, n]
    f32x4 accO[4][4] = {};
    for (int kc = 0; kc < 4; ++kc) {
        __syncthreads();
        stageB256(Vt + (long)(z * 256) * 256 + kc * 64, 256);
        __syncthreads();
#pragma unroll
        for (int i = 0; i < 4; ++i) {
            const bf16x8 a0 = fragP(kc, i, 0), a1 = fragP(kc, i, 1);
#pragma unroll
            for (int j = 0; j < 4; ++j) {
                accO[i][j] = __builtin_amdgcn_mfma_f32_16x16x32_bf16(a0, fragB(j, 0), accO[i][j], 0, 0, 0);
                accO[i][j] = __builtin_amdgcn_mfma_f32_16x16x32_bf16(a1, fragB(j, 1), accO[i][j], 0, 0, 0);
            }
        }
    }

    // write concat layout: Oc[(zb*256 + m)*1024 + zn*256 + d]
#pragma unroll
    for (int i = 0; i < 4; ++i)
#pragma unroll
        for (int j = 0; j < 4; ++j) {
            const int d = wid * 64 + j * 16 + l15;
#pragma unroll
            for (int q = 0; q < 4; ++q) {
                const int mg = m0 + i * 16 + l4 * 4 + q;
                Oc[(long)(zb * 256 + mg) * 1024 + zn * 256 + d] = f2bf(accO[i][j][q]);
            }
        }
}

// ---------------- GLU gate + residual + LN (sum 2 GEMM partials) ----------------
__global__ __launch_bounds__(256)
void glu_ln_k(const float* __restrict__ xs0, const float* __restrict__ g2,
              const float* __restrict__ gam, const float* __restrict__ bet,
              float* __restrict__ outf, u16* __restrict__ outb)
{
    const int t = blockIdx.x, tid = threadIdx.x;
    const int f0 = tid * 4;
    const long PS = 8388608;   // 4096*2048
    const float4 xv = *(const float4*)&xs0[(long)t * 1024 + f0];
    float4 av = *(const float4*)&g2[(long)t * 2048 + f0];
    float4 gv = *(const float4*)&g2[(long)t * 2048 + 1024 + f0];
    const float4 av1 = *(const float4*)&g2[PS + (long)t * 2048 + f0];
    const float4 gv1 = *(const float4*)&g2[PS + (long)t * 2048 + 1024 + f0];
    av.x += av1.x; av.y += av1.y; av.z += av1.z; av.w += av1.w;
    gv.x += gv1.x; gv.y += gv1.y; gv.z += gv1.z; gv.w += gv1.w;
    float vals[4];
    vals[0] = xv.x + av.x / (1.f + expf(-gv.x));
    vals[1] = xv.y + av.y / (1.f + expf(-gv.y));
    vals[2] = xv.z + av.z / (1.f + expf(-gv.z));
    vals[3] = xv.w + av.w / (1.f + expf(-gv.w));
    float s1 = vals[0] + vals[1] + vals[2] + vals[3];
    float s2 = vals[0]*vals[0] + vals[1]*vals[1] + vals[2]*vals[2] + vals[3]*vals[3];
    block_red2(s1, s2, tid);
    const float mean = s1 * (1.f / 1024.f);
    const float var  = s2 * (1.f / 1024.f) - mean * mean;
    const float rstd = rsqrtf(var + EPSF);
    const float4 gm = *(const float4*)&gam[f0];
    const float4 bt = *(const float4*)&bet[f0];
    float r0 = (vals[0] - mean) * rstd * gm.x + bt.x;
    float r1 = (vals[1] - mean) * rstd * gm.y + bt.y;
    float r2 = (vals[2] - mean) * rstd * gm.z + bt.z;
    float r3 = (vals[3] - mean) * rstd * gm.w + bt.w;
    *(float4*)&outf[(long)t * 1024 + f0] = make_float4(r0, r1, r2, r3);
    ushort4 ub; ub.x = f2bf(r0); ub.y = f2bf(r1); ub.z = f2bf(r2); ub.w = f2bf(r3);
    *(ushort4*)&outb[(long)t * 1024 + f0] = ub;
}

// ---------------- residual add + LN width 1024, B = sum of P partials (+opt bias) ----------------
template<int P, int WRITEBF, int BIAS>
__global__ __launch_bounds__(256)
void add_ln1024_k(const float* __restrict__ A, const float* __restrict__ Bp,
                  const float* __restrict__ bias,
                  const float* __restrict__ gam, const float* __restrict__ bet,
                  float* __restrict__ outf, u16* __restrict__ outb)
{
    const int t = blockIdx.x, tid = threadIdx.x;
    const int f0 = tid * 4;
    const long PS = 4194304;   // 4096*1024
    const float4 a = *(const float4*)&A[(long)t * 1024 + f0];
    float4 b = *(const float4*)&Bp[(long)t * 1024 + f0];
#pragma unroll
    for (int p = 1; p < P; ++p) {
        const float4 bp = *(const float4*)&Bp[p * PS + (long)t * 1024 + f0];
        b.x += bp.x; b.y += bp.y; b.z += bp.z; b.w += bp.w;
    }
    if (BIAS) {
        const float4 bb = *(const float4*)&bias[f0];
        b.x += bb.x; b.y += bb.y; b.z += bb.z; b.w += bb.w;
    }
    float vals[4] = {a.x + b.x, a.y + b.y, a.z + b.z, a.w + b.w};
    float s1 = vals[0] + vals[1] + vals[2] + vals[3];
    float s2 = vals[0]*vals[0] + vals[1]*vals[1] + vals[2]*vals[2] + vals[3]*vals[3];
    block_red2(s1, s2, tid);
    const float mean = s1 * (1.f / 1024.f);
    const float var  = s2 * (1.f / 1024.f) - mean * mean;
    const float rstd = rsqrtf(var + EPSF);
    const float4 gm = *(const float4*)&gam[f0];
    const float4 bt = *(const float4*)&bet[f0];
    float r0 = (vals[0] - mean) * rstd * gm.x + bt.x;
    float r1 = (vals[1] - mean) * rstd * gm.y + bt.y;
    float r2 = (vals[2] - mean) * rstd * gm.z + bt.z;
    float r3 = (vals[3] - mean) * rstd * gm.w + bt.w;
    *(float4*)&outf[(long)t * 1024 + f0] = make_float4(r0, r1, r2, r3);
    if (WRITEBF) {
        ushort4 ub; ub.x = f2bf(r0); ub.y = f2bf(r1); ub.z = f2bf(r2); ub.w = f2bf(r3);
        *(ushort4*)&outb[(long)t * 1024 + f0] = ub;
    }
}

// ---------------- n2: LN(c1L(bf16) + pad(relu(sum of 3 conv taps))) width 4096 ----------------
__global__ __launch_bounds__(256)
void add_ln4096_k(const u16* __restrict__ A, const float* __restrict__ Bp,
                  const float* __restrict__ gam, const float* __restrict__ bet,
                  u16* __restrict__ outb)
{
    const int t = blockIdx.x, tid = threadIdx.x;
    const long PS = 4194304;   // 4096*1024
    const int f0 = tid * 16;
    float vals[16];
    const bf16x8 a0 = *(const bf16x8*)&A[(long)t * 4096 + f0];
    const bf16x8 a1 = *(const bf16x8*)&A[(long)t * 4096 + f0 + 8];
#pragma unroll
    for (int e = 0; e < 8; ++e) { vals[e] = bf2f((u16)a0[e]); vals[8 + e] = bf2f((u16)a1[e]); }
    if (tid < 64) {
#pragma unroll
        for (int c = 0; c < 4; ++c) {
            const int fc = f0 + c * 4;
            float4 b  = *(const float4*)&Bp[(long)t * 1024 + fc];
            const float4 b1 = *(const float4*)&Bp[PS + (long)t * 1024 + fc];
            const float4 b2 = *(const float4*)&Bp[2 * PS + (long)t * 1024 + fc];
            vals[c*4+0] += fmaxf(b.x + b1.x + b2.x, 0.f);
            vals[c*4+1] += fmaxf(b.y + b1.y + b2.y, 0.f);
            vals[c*4+2] += fmaxf(b.z + b1.z + b2.z, 0.f);
            vals[c*4+3] += fmaxf(b.w + b1.w + b2.w, 0.f);
        }
    }
    float s1 = 0.f, s2 = 0.f;
#pragma unroll
    for (int e = 0; e < 16; ++e) { s1 += vals[e]; s2 += vals[e] * vals[e]; }
    block_red2(s1, s2, tid);
    const float mean = s1 * (1.f / 4096.f);
    const float var  = s2 * (1.f / 4096.f) - mean * mean;
    const float rstd = rsqrtf(var + EPSF);
#pragma unroll
    for (int c = 0; c < 4; ++c) {
        const int fc = f0 + c * 4;
        const float4 gm = *(const float4*)&gam[fc];
        const float4 bt = *(const float4*)&bet[fc];
        ushort4 ub;
        ub.x = f2bf((vals[c*4+0] - mean) * rstd * gm.x + bt.x);
        ub.y = f2bf((vals[c*4+1] - mean) * rstd * gm.y + bt.y);
        ub.z = f2bf((vals[c*4+2] - mean) * rstd * gm.z + bt.z);
        ub.w = f2bf((vals[c*4+3] - mean) * rstd * gm.w + bt.w);
        *(ushort4*)&outb[(long)t * 4096 + fc] = ub;
    }
}

// ---------------- depthwise conv width-9, 8 channels/thread ----------------
__global__ __launch_bounds__(256)
void dwconv8_k(const u16* __restrict__ h, const float* __restrict__ wT,
               u16* __restrict__ out)
{
    const long idx = (long)blockIdx.x * 256 + threadIdx.x;  // over 4096*512
    const int cg = (int)(idx & 511);
    const int t  = (int)(idx >> 9);
    const int w  = t & 255;
    const int c0 = cg * 8;
    float acc[8] = {};
#pragma unroll
    for (int k = 0; k < 9; ++k) {
        const int wp = w + k - 4;
        if ((unsigned)wp < 256u) {
            const bf16x8 hv = *(const bf16x8*)&h[(long)(t + k - 4) * 4096 + c0];
            const float4 w0 = *(const float4*)&wT[k * 4096 + c0];
            const float4 w1 = *(const float4*)&wT[k * 4096 + c0 + 4];
            acc[0] += bf2f((u16)hv[0]) * w0.x;
            acc[1] += bf2f((u16)hv[1]) * w0.y;
            acc[2] += bf2f((u16)hv[2]) * w0.z;
            acc[3] += bf2f((u16)hv[3]) * w0.w;
            acc[4] += bf2f((u16)hv[4]) * w1.x;
            acc[5] += bf2f((u16)hv[5]) * w1.y;
            acc[6] += bf2f((u16)hv[6]) * w1.z;
            acc[7] += bf2f((u16)hv[7]) * w1.w;
        }
    }
    bf16x8 res;
#pragma unroll
    for (int j = 0; j < 8; ++j) res[j] = (short)f2bf(acc[j]);
    *(bf16x8*)&out[(long)t * 4096 + c0] = res;
}

// ---------------- V slice of QKVb -> Vt (z, d, w) bf16 ----------------
__global__ __launch_bounds__(256)
void vtrans_k(const u16* __restrict__ QKVb, u16* __restrict__ Vt)
{
    __shared__ u16 t[32][33];
    const int z = blockIdx.z, zb = z >> 2, zn = z & 3;
    const int w0 = blockIdx.x * 32, d0 = blockIdx.y * 32;
    const int tid = threadIdx.x, c = tid & 31, r = tid >> 5;
#pragma unroll
    for (int it = 0; it < 4; ++it) {
        const int wl = r + it * 8;
        t[wl][c] = QKVb[(long)(zb * 256 + w0 + wl) * 3072 + 2048 + zn * 256 + d0 + c];
    }
    __syncthreads();
#pragma unroll
    for (int it = 0; it < 4; ++it) {
        const int dl = r + it * 8;
        Vt[((long)z * 256 + d0 + dl) * 256 + w0 + c] = t[c][dl];
    }
}

// ---------------- final transpose (tokens,1024) -> (B,1,1024,256) ----------------
__global__ __launch_bounds__(256)
void transpose_out_k(const float* __restrict__ xs, float* __restrict__ out)
{
    __shared__ float tile[32][33];
    const int b = blockIdx.z, f0 = blockIdx.y * 32, w0 = blockIdx.x * 32;
    const int tid = threadIdx.x, c = tid & 31, r = tid >> 5;
#pragma unroll
    for (int it = 0; it < 4; ++it) {
        const int w = w0 + r + it * 8;
        tile[r + it * 8][c] = xs[((long)b * 256 + w) * 1024 + f0 + c];
    }
    __syncthreads();
#pragma unroll
    for (int it = 0; it < 4; ++it) {
        const int fl = r + it * 8;
        out[((long)b * 1024 + f0 + fl) * 256 + w0 + c] = tile[c][fl];
    }
}

// =======================================================================
extern "C" void kernel_launch(void* const* d_in, const int* in_sizes, int n_in,
                              void* d_out, int out_size, void* d_ws, size_t ws_size,
                              hipStream_t stream)
{
    const float* x      = (const float*)d_in[0];
    const float* bott_w = (const float*)d_in[1];
    const float* bn_g   = (const float*)d_in[2];
    const float* bn_b   = (const float*)d_in[3];
    const float* bn_m   = (const float*)d_in[4];
    const float* bn_v   = (const float*)d_in[5];
    const float* glu_w  = (const float*)d_in[6];
    const float* n1g    = (const float*)d_in[7];
    const float* n1b    = (const float*)d_in[8];
    const float* c1L_w  = (const float*)d_in[9];
    const float* c1R_w  = (const float*)d_in[10];
    const float* n2g    = (const float*)d_in[11];
    const float* n2b    = (const float*)d_in[12];
    const float* c2dw_w = (const float*)d_in[13];
    const float* c2pw_w = (const float*)d_in[14];
    const float* n3g    = (const float*)d_in[15];
    const float* n3b    = (const float*)d_in[16];
    const float* qw     = (const float*)d_in[17];
    const float* qb     = (const float*)d_in[18];
    const float* kw     = (const float*)d_in[19];
    const float* kb     = (const float*)d_in[20];
    const float* vw     = (const float*)d_in[21];
    const float* vb     = (const float*)d_in[22];
    const float* ow     = (const float*)d_in[23];
    const float* ob     = (const float*)d_in[24];
    const float* er     = (const float*)d_in[25];
    const float* dist_w = (const float*)d_in[26];
    const float* n4g    = (const float*)d_in[27];
    const float* n4b    = (const float*)d_in[28];
    const float* c3_w   = (const float*)d_in[29];
    const float* c4_w   = (const float*)d_in[30];
    const float* n5g    = (const float*)d_in[31];
    const float* n5b    = (const float*)d_in[32];
    float* out = (float*)d_out;

    // ---- workspace layout (MiB offsets, lifetimes annotated) ----
    char* Wb_ = (char*)d_ws;
    auto F  = [&](size_t mib) { return (float*)(Wb_ + (mib << 20)); };
    auto Bf = [&](size_t mib) { return (u16*)  (Wb_ + (mib << 20)); };
    float* X0   = F(0);     // xs chain A
    float* X1   = F(16);    // xs chain B
    u16*   H0b  = Bf(32);   // c1L bf16 out (4-6) / c3 bf16 out (14-15)
    float* Hglu = F(64);    // GLU 2 partials (2-3)
    float* C3p  = F(64);    // conv3 3 partials (5-6)
    float* P4   = F(64);    // c2pw/O-proj/c4 4 partials
    u16*   H1b  = Bf(128);  // n2 out bf16 (6-7)
    u16*   Hdw  = Bf(160);  // dwconv out bf16 (7-8)
    u16*   QKVb = Bf(192);  // fused QKV out 4096x3072 bf16 (10-11)
    u16*   Vt   = Bf(216);  // V transposed (10b-11)
    u16*   S1b  = Bf(264);  // attn concat bf16 (11-12)
    u16*   XbA  = Bf(280);  // X1b (1-2), X2b (9-10)
    u16*   XbB  = Bf(288);  // X0b (3-5), X3b (13-14)
    u16* wGLU = Bf(296); u16* wC1L = Bf(300); u16* wC1R = Bf(308);
    u16* wC2P = Bf(314); u16* wQKV = Bf(322); u16* wO   = Bf(328);
    u16* wC3  = Bf(330); u16* wC4  = Bf(338);
    u16* erT  = Bf(346);
    u16* zp   = (u16*)(Wb_ + (346u << 20) + 131072);
    float* wdwT = (float*)(Wb_ + (346u << 20) + 131072 + 16384);
    float* bQKV = (float*)(Wb_ + (346u << 20) + 131072 + 16384 + 147456);

    const dim3 blk(256);
    const dim3 blk8(512);
    const long PS1 = 4194304;   // 4096*1024
    const size_t SH8 = 131072;  // 128 KiB dynamic LDS for gemm8/conv38

    // 0. weight conversions (merged) + specials
    zero_k<<<dim3(32), blk, 0, stream>>>(zp, 8192);
    Cvt9 cv;
    cv.s[0] = glu_w;  cv.d[0] = wGLU;            cv.n[0] = 524288;
    cv.s[1] = c1L_w;  cv.d[1] = wC1L;            cv.n[1] = 1048576;
    cv.s[2] = c2pw_w; cv.d[2] = wC2P;            cv.n[2] = 1048576;
    cv.s[3] = c3_w;   cv.d[3] = wC3;             cv.n[3] = 1048576;
    cv.s[4] = c4_w;   cv.d[4] = wC4;             cv.n[4] = 1048576;
    cv.s[5] = qw;     cv.d[5] = wQKV;            cv.n[5] = 262144;
    cv.s[6] = kw;     cv.d[6] = wQKV + 1048576;  cv.n[6] = 262144;
    cv.s[7] = vw;     cv.d[7] = wQKV + 2097152;  cv.n[7] = 262144;
    cv.s[8] = ow;     cv.d[8] = wO;              cv.n[8] = 262144;
    wcvt9_k<<<dim3(4096, 9), blk, 0, stream>>>(cv);
    c1rcvt_k<<<dim3(12288), blk, 0, stream>>>(c1R_w, wC1R);
    ercvt_k<<<dim3(256), blk, 0, stream>>>(er, erT);
    dwcvt_k<<<dim3(144), blk, 0, stream>>>(c2dw_w, wdwT);
    biascat_k<<<dim3(12), blk, 0, stream>>>(qb, kb, vb, bQKV);

    // 1. bottleneck + BN + ReLU + transpose
    bottleneck_k<<<dim3(8, 32, 16), blk, 0, stream>>>(x, bott_w, bn_g, bn_b, bn_m, bn_v, X1, XbA);

    // 2. GLU matmul, split-K=2 -> Hglu partials
    gemm8_k<0,0,0,2><<<dim3(8, 16, 2), blk8, SH8, stream>>>(XbA, wGLU, nullptr, Hglu,
        2048, 512, 1024, 1024, (long)4096 * 2048);

    // 3. n1: LN(xs0 + a*sigmoid(g)) -> X0 + X0b
    glu_ln_k<<<dim3(4096), blk, 0, stream>>>(X1, Hglu, n1g, n1b, X0, XbB);

    // 4. c1L: relu -> H0b bf16 (4096x4096)
    gemm8_k<1,1,0,1><<<dim3(16, 16, 1), blk8, SH8, stream>>>(XbB, wC1L, nullptr, H0b,
        4096, 1024, 1024, 1024, 0);

    // 5. c1R conv on the 8-phase body: 3 tap-slices -> C3p partials
    conv38_k<<<dim3(4, 16, 3), blk8, SH8, stream>>>(XbB, wC1R, zp, C3p);

    // 6. n2: LN(H0b + pad(relu(sum taps))) -> H1b bf16
    add_ln4096_k<<<dim3(4096), blk, 0, stream>>>(H0b, C3p, n2g, n2b, H1b);

    // 7. depthwise conv9 (vectorized x8): H1b -> Hdw
    dwconv8_k<<<dim3(8192), blk, 0, stream>>>(H1b, wdwT, Hdw);

    // 8. c2pw, split-K=4 -> P4 partials
    gemm8_k<0,0,0,4><<<dim3(4, 16, 4), blk8, SH8, stream>>>(Hdw, wC2P, nullptr, P4,
        1024, 1024, 4096, 4096, PS1);

    // 9. n3: LN(X0 + sum P4) -> X1 + X2b
    add_ln1024_k<4,1,0><<<dim3(4096), blk, 0, stream>>>(X0, P4, nullptr, n3g, n3b, X1, XbA);

    // 10. fused QKV projection (+concat bias) -> QKVb bf16 (4096x3072)
    gemm8_k<0,1,1,1><<<dim3(12, 16, 1), blk8, SH8, stream>>>(XbA, wQKV, bQKV, QKVb,
        3072, 1024, 1024, 1024, 0);

    // 10b. V transpose per head -> Vt (z, d, w)
    vtrans_k<<<dim3(8, 8, 64), blk, 0, stream>>>(QKVb, Vt);

    // 11. fused attention: scores + softmax + PV -> S1b (concat layout)
    attn_fused_k<<<dim3(4, 64), blk, 0, stream>>>(QKVb, erT, Vt, dist_w, S1b);

    // 12. output projection, split-K=4 -> P4 partials (bias added in n4)
    gemm8_k<0,0,0,4><<<dim3(4, 16, 4), blk8, SH8, stream>>>(S1b, wO, nullptr, P4,
        1024, 256, 1024, 1024, PS1);

    // 13. n4: LN(X1 + sum P4 + ob) -> X0 + X3b
    add_ln1024_k<4,1,1><<<dim3(4096), blk, 0, stream>>>(X1, P4, ob, n4g, n4b, X0, XbB);

    // 14. c3: relu -> H0b bf16
    gemm8_k<1,1,0,1><<<dim3(16, 16, 1), blk8, SH8, stream>>>(XbB, wC3, nullptr, H0b,
        4096, 1024, 1024, 1024, 0);

    // 15. c4, split-K=4 -> P4 partials
    gemm8_k<0,0,0,4><<<dim3(4, 16, 4), blk8, SH8, stream>>>(H0b, wC4, nullptr, P4,
        1024, 1024, 4096, 4096, PS1);

    // 16. n5: LN(X0 + sum P4) -> X1 (f32 only)
    add_ln1024_k<4,0,0><<<dim3(4096), blk, 0, stream>>>(X0, P4, nullptr, n5g, n5b, X1, nullptr);

    // 17. transpose to (B, 1, 1024, 256)
    transpose_out_k<<<dim3(8, 32, 16), blk, 0, stream>>>(X1, out);

    (void)in_sizes; (void)n_in; (void)out_size; (void)ws_size;
}

// Round 7
// 512.709 us; speedup vs baseline: 6.8086x; 1.0802x over previous
//
#include <hip/hip_runtime.h>
#include <hip/hip_bf16.h>

// FrameTransformer: B=16, C=8, BINS=1024, W=256, FF=2048, NB=4
// tokens = B*W = 4096, feature width 1024, FF width 4096, head dim 256.
#define EPSF 1e-5f

typedef unsigned short u16;
typedef unsigned int   u32;
typedef __attribute__((ext_vector_type(8))) short bf16x8;
typedef __attribute__((ext_vector_type(4))) float f32x4;

__device__ __forceinline__ u16 f2bf(float f) {
    u32 u = __builtin_bit_cast(u32, f);
    u32 r = u + 0x7fffu + ((u >> 16) & 1u);
    return (u16)(r >> 16);
}
__device__ __forceinline__ float bf2f(u16 h) {
    return __builtin_bit_cast(float, (u32)h << 16);
}
__device__ __forceinline__ float4 bf4f(ushort4 v) {
    return make_float4(bf2f(v.x), bf2f(v.y), bf2f(v.z), bf2f(v.w));
}
__device__ __forceinline__ void gld16(void* lds, const void* gsrc) {
    __builtin_amdgcn_global_load_lds(
        (const __attribute__((address_space(1))) u32*)gsrc,
        (__attribute__((address_space(3))) u32*)lds, 16, 0, 0);
}

__device__ __forceinline__ float wred_sum(float v) {
#pragma unroll
    for (int off = 32; off; off >>= 1) v += __shfl_xor(v, off, 64);
    return v;
}
__device__ __forceinline__ void block_red2(float& s1, float& s2, int tid) {
    __shared__ float red[8];
    s1 = wred_sum(s1); s2 = wred_sum(s2);
    const int lane = tid & 63, wid = tid >> 6;
    if (!lane) { red[wid] = s1; red[4 + wid] = s2; }
    __syncthreads();
    s1 = red[0] + red[1] + red[2] + red[3];
    s2 = red[4] + red[5] + red[6] + red[7];
}

// ---------------- merged setup: all weight conversions in one launch ----------------
struct SetupArgs {
    const float* ws[9]; u16* wd[9]; int wn[9];     // plain f32x4 -> bf16x4
    const float* c1r; u16* c1rd;
    const float* er;  u16* erd;
    const float* dw;  float* dwd;
    const float* qb;  const float* kb; const float* vb; float* bcat;
    u16* zp;
    int off[15];                                    // block-offset prefix, off[14]=total
};
__global__ __launch_bounds__(256)
void setup_k(SetupArgs a)
{
    const int b = blockIdx.x;
    int seg = 0;
    while (seg < 13 && b >= a.off[seg + 1]) ++seg;
    const int i = (b - a.off[seg]) * 256 + threadIdx.x;
    if (seg < 9) {
        if (i < a.wn[seg]) {
            const float4 v = ((const float4*)a.ws[seg])[i];
            ushort4 o; o.x = f2bf(v.x); o.y = f2bf(v.y); o.z = f2bf(v.z); o.w = f2bf(v.w);
            ((ushort4*)a.wd[seg])[i] = o;
        }
    } else if (seg == 9) {            // c1R (o,ci,3) -> (o,ks,ci)
        if (i < 3145728) {
            const int q = i / 3072, rem = i - q * 3072;
            const int ks = rem >> 10, ci = rem & 1023;
            a.c1rd[i] = f2bf(a.c1r[((long)q * 1024 + ci) * 3 + ks]);
        }
    } else if (seg == 10) {           // er (d,c) -> erT (c,d)
        if (i < 65536) { const int c = i >> 8, d = i & 255; a.erd[i] = f2bf(a.er[d * 256 + c]); }
    } else if (seg == 11) {           // c2dw (c,1,9) -> (9,c)
        if (i < 36864) { const int k = i >> 12, c = i & 4095; a.dwd[i] = a.dw[c * 9 + k]; }
    } else if (seg == 12) {           // qkv bias concat
        if (i < 3072) { const float* s = (i < 1024) ? a.qb : ((i < 2048) ? a.kb : a.vb); a.bcat[i] = s[i & 1023]; }
    } else {                          // zero page
        if (i < 8192) a.zp[i] = 0;
    }
}

// ---------------- stage 1: bottleneck 1x1 conv + BN + ReLU + transpose ----------------
__global__ __launch_bounds__(256)
void bottleneck_k(const float* __restrict__ x, const float* __restrict__ bw,
                  const float* __restrict__ bn_g, const float* __restrict__ bn_b,
                  const float* __restrict__ bn_m, const float* __restrict__ bn_v,
                  float* __restrict__ xs, u16* __restrict__ xsb)
{
    __shared__ float tile[32][33];
    const int b = blockIdx.z, h0 = blockIdx.y * 32, w0 = blockIdx.x * 32;
    const int tid = threadIdx.x, c = tid & 31, r = tid >> 5;
    float wreg[8];
#pragma unroll
    for (int ch = 0; ch < 8; ++ch) wreg[ch] = bw[ch];
    const float sc = bn_g[0] * rsqrtf(bn_v[0] + EPSF);
    const float sh = bn_b[0] - bn_m[0] * sc;
#pragma unroll
    for (int it = 0; it < 4; ++it) {
        const int h = h0 + r + it * 8;
        const int w = w0 + c;
        float acc = 0.f;
#pragma unroll
        for (int ch = 0; ch < 8; ++ch)
            acc += x[(((long)b * 8 + ch) * 1024 + h) * 256 + w] * wreg[ch];
        tile[r + it * 8][c] = fmaxf(acc * sc + sh, 0.f);
    }
    __syncthreads();
#pragma unroll
    for (int it = 0; it < 4; ++it) {
        const int wl = r + it * 8;
        const float v = tile[c][wl];
        const long o = ((long)b * 256 + w0 + wl) * 1024 + h0 + c;
        xs[o] = v;
        xsb[o] = f2bf(v);
    }
}

// ============ 8-phase 256x256 bf16 MFMA GEMM (T2+T3+T4+T5) ============
// SPLITK>1: writes bf16 partials to Cout + z*partStride (elements).
template<int ACT, int OUTBF, int BIAS, int SPLITK>
__global__ __launch_bounds__(512, 2)
void gemm8_k(const u16* __restrict__ A, const u16* __restrict__ B,
             const float* __restrict__ bias, void* __restrict__ Cout,
             int N, int K /*per slice*/, int lda, int ldb, long partStride)
{
    extern __shared__ u16 lds[];
    const int m0 = blockIdx.y * 256, n0 = blockIdx.x * 256;
    const int koff = (SPLITK > 1) ? blockIdx.z * K : 0;
    const int nt = K >> 6;
    const int tid = threadIdx.x;
    const int lane = tid & 63, wid = tid >> 6;
    const int wr = ((wid >> 2) & 1) * 128;
    const int wc = (wid & 3) * 64;
    const int l15 = lane & 15, l4 = lane >> 4;

    const u16* Ag = A + (long)m0 * lda + koff;
    const u16* Bg = B + (long)n0 * ldb + koff;

    auto stage = [&](const u16* g, int ld, int ldsbase, int kcol, int h) {
#pragma unroll
        for (int is = 0; is < 2; ++is) {
            const int r = h * 128 + is * 64 + (tid >> 3);
            const int sc = ((tid & 7) * 8) ^ (((r >> 2) & 1) << 4);
            gld16(&lds[ldsbase + h * 8192 + is * 4096 + tid * 8],
                  g + (long)r * ld + kcol + sc);
        }
    };
    auto frag = [&](int base, int row, int col) -> bf16x8 {
        return *(const bf16x8*)&lds[base + row * 64 + (col ^ (((row >> 2) & 1) << 4))];
    };

    f32x4 acc[8][4] = {};

    stage(Ag, lda, 0, 0, 0);
    stage(Ag, lda, 0, 0, 1);
    stage(Bg, ldb, 32768, 0, 0);
    stage(Bg, ldb, 32768, 0, 1);
    if (nt > 1) {
        stage(Bg, ldb, 49152, 64, 0);
        stage(Bg, ldb, 49152, 64, 1);
        stage(Ag, lda, 16384, 64, 0);
        asm volatile("s_waitcnt vmcnt(6)" ::: "memory");
    } else {
        asm volatile("s_waitcnt vmcnt(0)" ::: "memory");
    }
    __builtin_amdgcn_s_barrier();

    for (int kt = 0; kt < nt; ++kt) {
        const int cs = kt & 1;
        const int ab = cs * 16384;
        const int bb = 32768 + cs * 16384;
        const int abn = (cs ^ 1) * 16384;
        const int kc1 = (kt + 1) * 64, kc2 = (kt + 2) * 64;
        bf16x8 alo[4][2], ahi[4][2], b01[2][2], b23[2][2];

#pragma unroll
        for (int i = 0; i < 4; ++i)
#pragma unroll
            for (int kk = 0; kk < 2; ++kk)
                alo[i][kk] = frag(ab, wr + i * 16 + l15, kk * 32 + l4 * 8);
#pragma unroll
        for (int j = 0; j < 2; ++j)
#pragma unroll
            for (int kk = 0; kk < 2; ++kk)
                b01[j][kk] = frag(bb, wc + j * 16 + l15, kk * 32 + l4 * 8);
        if (kt + 1 < nt) stage(Ag, lda, abn, kc1, 1);
        __builtin_amdgcn_s_barrier();
        asm volatile("s_waitcnt lgkmcnt(0)" ::: "memory");
        __builtin_amdgcn_s_setprio(1);
#pragma unroll
        for (int i = 0; i < 4; ++i)
#pragma unroll
            for (int j = 0; j < 2; ++j)
#pragma unroll
                for (int kk = 0; kk < 2; ++kk)
                    acc[i][j] = __builtin_amdgcn_mfma_f32_16x16x32_bf16(alo[i][kk], b01[j][kk], acc[i][j], 0, 0, 0);
        __builtin_amdgcn_s_setprio(0);
        __builtin_amdgcn_s_barrier();

#pragma unroll
        for (int j = 0; j < 2; ++j)
#pragma unroll
            for (int kk = 0; kk < 2; ++kk)
                b23[j][kk] = frag(bb, wc + (j + 2) * 16 + l15, kk * 32 + l4 * 8);
        if (kt + 2 < nt) stage(Bg, ldb, bb, kc2, 0);
        __builtin_amdgcn_s_barrier();
        asm volatile("s_waitcnt lgkmcnt(0)" ::: "memory");
        __builtin_amdgcn_s_setprio(1);
#pragma unroll
        for (int i = 0; i < 4; ++i)
#pragma unroll
            for (int j = 0; j < 2; ++j)
#pragma unroll
                for (int kk = 0; kk < 2; ++kk)
                    acc[i][j + 2] = __builtin_amdgcn_mfma_f32_16x16x32_bf16(alo[i][kk], b23[j][kk], acc[i][j + 2], 0, 0, 0);
        __builtin_amdgcn_s_setprio(0);
        __builtin_amdgcn_s_barrier();

#pragma unroll
        for (int i = 0; i < 4; ++i)
#pragma unroll
            for (int kk = 0; kk < 2; ++kk)
                ahi[i][kk] = frag(ab, wr + (i + 4) * 16 + l15, kk * 32 + l4 * 8);
        if (kt + 2 < nt) stage(Bg, ldb, bb, kc2, 1);
        __builtin_amdgcn_s_barrier();
        asm volatile("s_waitcnt lgkmcnt(0)" ::: "memory");
        __builtin_amdgcn_s_setprio(1);
#pragma unroll
        for (int i = 0; i < 4; ++i)
#pragma unroll
            for (int j = 0; j < 2; ++j)
#pragma unroll
                for (int kk = 0; kk < 2; ++kk)
                    acc[i + 4][j + 2] = __builtin_amdgcn_mfma_f32_16x16x32_bf16(ahi[i][kk], b23[j][kk], acc[i + 4][j + 2], 0, 0, 0);
        __builtin_amdgcn_s_setprio(0);
        __builtin_amdgcn_s_barrier();

        if (kt + 2 < nt) stage(Ag, lda, ab, kc2, 0);
        __builtin_amdgcn_s_barrier();
        __builtin_amdgcn_s_setprio(1);
#pragma unroll
        for (int i = 0; i < 4; ++i)
#pragma unroll
            for (int j = 0; j < 2; ++j)
#pragma unroll
                for (int kk = 0; kk < 2; ++kk)
                    acc[i + 4][j] = __builtin_amdgcn_mfma_f32_16x16x32_bf16(ahi[i][kk], b01[j][kk], acc[i + 4][j], 0, 0, 0);
        __builtin_amdgcn_s_setprio(0);
        if (kt + 2 < nt) {
            asm volatile("s_waitcnt vmcnt(6)" ::: "memory");
        } else {
            asm volatile("s_waitcnt vmcnt(0)" ::: "memory");
        }
        __builtin_amdgcn_s_barrier();
    }

    if (SPLITK > 1) {   // bf16 partials
        u16* Cp = (u16*)Cout + (long)blockIdx.z * partStride;
#pragma unroll
        for (int i = 0; i < 8; ++i)
#pragma unroll
            for (int j = 0; j < 4; ++j) {
                const int n = n0 + wc + j * 16 + l15;
#pragma unroll
                for (int q = 0; q < 4; ++q) {
                    const int m = m0 + wr + i * 16 + l4 * 4 + q;
                    Cp[(long)m * N + n] = f2bf(acc[i][j][q]);
                }
            }
    } else {
        float* Cf = (float*)Cout;
        u16*   Cb = (u16*)Cout;
#pragma unroll
        for (int i = 0; i < 8; ++i)
#pragma unroll
            for (int j = 0; j < 4; ++j) {
                const int n = n0 + wc + j * 16 + l15;
                const float bv = BIAS ? bias[n] : 0.f;
#pragma unroll
                for (int q = 0; q < 4; ++q) {
                    const int m = m0 + wr + i * 16 + l4 * 4 + q;
                    float v = acc[i][j][q] + bv;
                    if (ACT) v = fmaxf(v, 0.f);
                    if (OUTBF) Cb[(long)m * N + n] = f2bf(v);
                    else       Cf[(long)m * N + n] = v;
                }
            }
    }
}

// ============ conv1R on the 8-phase body: per-tap z, bf16 partials out ============
__global__ __launch_bounds__(512, 2)
void conv38_k(const u16* __restrict__ Xb, const u16* __restrict__ Wt,
              const u16* __restrict__ zp, u16* __restrict__ C)
{
    extern __shared__ u16 lds[];
    const int ks = blockIdx.z;
    const int m0 = blockIdx.y * 256, n0 = blockIdx.x * 256;
    const int nt = 16;   // K = 1024
    const int tid = threadIdx.x;
    const int lane = tid & 63, wid = tid >> 6;
    const int wr = ((wid >> 2) & 1) * 128;
    const int wc = (wid & 3) * 64;
    const int l15 = lane & 15, l4 = lane >> 4;

    auto stageA = [&](int ldsbase, int kcol, int h) {
#pragma unroll
        for (int is = 0; is < 2; ++is) {
            const int r = h * 128 + is * 64 + (tid >> 3);
            const int sc = ((tid & 7) * 8) ^ (((r >> 2) & 1) << 4);
            const int t = m0 + r;
            const int wp = (t & 255) + ks - 1;
            const u16* src = ((unsigned)wp < 256u)
                ? Xb + (long)(t + ks - 1) * 1024 + kcol + sc
                : zp;
            gld16(&lds[ldsbase + h * 8192 + is * 4096 + tid * 8], src);
        }
    };
    auto stageB = [&](int ldsbase, int kcol, int h) {
#pragma unroll
        for (int is = 0; is < 2; ++is) {
            const int r = h * 128 + is * 64 + (tid >> 3);
            const int sc = ((tid & 7) * 8) ^ (((r >> 2) & 1) << 4);
            gld16(&lds[ldsbase + h * 8192 + is * 4096 + tid * 8],
                  Wt + (long)(n0 + r) * 3072 + ks * 1024 + kcol + sc);
        }
    };
    auto frag = [&](int base, int row, int col) -> bf16x8 {
        return *(const bf16x8*)&lds[base + row * 64 + (col ^ (((row >> 2) & 1) << 4))];
    };

    f32x4 acc[8][4] = {};

    stageA(0, 0, 0);
    stageA(0, 0, 1);
    stageB(32768, 0, 0);
    stageB(32768, 0, 1);
    stageB(49152, 64, 0);
    stageB(49152, 64, 1);
    stageA(16384, 64, 0);
    asm volatile("s_waitcnt vmcnt(6)" ::: "memory");
    __builtin_amdgcn_s_barrier();

    for (int kt = 0; kt < nt; ++kt) {
        const int cs = kt & 1;
        const int ab = cs * 16384;
        const int bb = 32768 + cs * 16384;
        const int abn = (cs ^ 1) * 16384;
        const int kc1 = (kt + 1) * 64, kc2 = (kt + 2) * 64;
        bf16x8 alo[4][2], ahi[4][2], b01[2][2], b23[2][2];

#pragma unroll
        for (int i = 0; i < 4; ++i)
#pragma unroll
            for (int kk = 0; kk < 2; ++kk)
                alo[i][kk] = frag(ab, wr + i * 16 + l15, kk * 32 + l4 * 8);
#pragma unroll
        for (int j = 0; j < 2; ++j)
#pragma unroll
            for (int kk = 0; kk < 2; ++kk)
                b01[j][kk] = frag(bb, wc + j * 16 + l15, kk * 32 + l4 * 8);
        if (kt + 1 < nt) stageA(abn, kc1, 1);
        __builtin_amdgcn_s_barrier();
        asm volatile("s_waitcnt lgkmcnt(0)" ::: "memory");
        __builtin_amdgcn_s_setprio(1);
#pragma unroll
        for (int i = 0; i < 4; ++i)
#pragma unroll
            for (int j = 0; j < 2; ++j)
#pragma unroll
                for (int kk = 0; kk < 2; ++kk)
                    acc[i][j] = __builtin_amdgcn_mfma_f32_16x16x32_bf16(alo[i][kk], b01[j][kk], acc[i][j], 0, 0, 0);
        __builtin_amdgcn_s_setprio(0);
        __builtin_amdgcn_s_barrier();

#pragma unroll
        for (int j = 0; j < 2; ++j)
#pragma unroll
            for (int kk = 0; kk < 2; ++kk)
                b23[j][kk] = frag(bb, wc + (j + 2) * 16 + l15, kk * 32 + l4 * 8);
        if (kt + 2 < nt) stageB(bb, kc2, 0);
        __builtin_amdgcn_s_barrier();
        asm volatile("s_waitcnt lgkmcnt(0)" ::: "memory");
        __builtin_amdgcn_s_setprio(1);
#pragma unroll
        for (int i = 0; i < 4; ++i)
#pragma unroll
            for (int j = 0; j < 2; ++j)
#pragma unroll
                for (int kk = 0; kk < 2; ++kk)
                    acc[i][j + 2] = __builtin_amdgcn_mfma_f32_16x16x32_bf16(alo[i][kk], b23[j][kk], acc[i][j + 2], 0, 0, 0);
        __builtin_amdgcn_s_setprio(0);
        __builtin_amdgcn_s_barrier();

#pragma unroll
        for (int i = 0; i < 4; ++i)
#pragma unroll
            for (int kk = 0; kk < 2; ++kk)
                ahi[i][kk] = frag(ab, wr + (i + 4) * 16 + l15, kk * 32 + l4 * 8);
        if (kt + 2 < nt) stageB(bb, kc2, 1);
        __builtin_amdgcn_s_barrier();
        asm volatile("s_waitcnt lgkmcnt(0)" ::: "memory");
        __builtin_amdgcn_s_setprio(1);
#pragma unroll
        for (int i = 0; i < 4; ++i)
#pragma unroll
            for (int j = 0; j < 2; ++j)
#pragma unroll
                for (int kk = 0; kk < 2; ++kk)
                    acc[i + 4][j + 2] = __builtin_amdgcn_mfma_f32_16x16x32_bf16(ahi[i][kk], b23[j][kk], acc[i + 4][j + 2], 0, 0, 0);
        __builtin_amdgcn_s_setprio(0);
        __builtin_amdgcn_s_barrier();

        if (kt + 2 < nt) stageA(ab, kc2, 0);
        __builtin_amdgcn_s_barrier();
        __builtin_amdgcn_s_setprio(1);
#pragma unroll
        for (int i = 0; i < 4; ++i)
#pragma unroll
            for (int j = 0; j < 2; ++j)
#pragma unroll
                for (int kk = 0; kk < 2; ++kk)
                    acc[i + 4][j] = __builtin_amdgcn_mfma_f32_16x16x32_bf16(ahi[i][kk], b01[j][kk], acc[i + 4][j], 0, 0, 0);
        __builtin_amdgcn_s_setprio(0);
        if (kt + 2 < nt) {
            asm volatile("s_waitcnt vmcnt(6)" ::: "memory");
        } else {
            asm volatile("s_waitcnt vmcnt(0)" ::: "memory");
        }
        __builtin_amdgcn_s_barrier();
    }

    u16* Cp = C + (long)ks * 4194304;
#pragma unroll
    for (int i = 0; i < 8; ++i)
#pragma unroll
        for (int j = 0; j < 4; ++j) {
            const int n = n0 + wc + j * 16 + l15;
#pragma unroll
            for (int q = 0; q < 4; ++q) {
                const int m = m0 + wr + i * 16 + l4 * 4 + q;
                Cp[(long)m * 1024 + n] = f2bf(acc[i][j][q]);
            }
        }
}

// ============ fused attention: scores(QK/32 + erT@Q^T + dist) -> softmax -> P@Vt^T ============
__global__ __launch_bounds__(256, 2)
void attn_fused_k(const u16* __restrict__ QKVb, const u16* __restrict__ erT,
                  const u16* __restrict__ Vt, const float* __restrict__ dwp,
                  u16* __restrict__ Oc)
{
    __shared__ __align__(16) u16 As[4096];
    __shared__ __align__(16) u16 Bs[16384];
    __shared__ __align__(16) u16 Pl[16384];
    __shared__ float redM[4][64];
    __shared__ float redS[4][64];
    const int z = blockIdx.y, zb = z >> 2, zn = z & 3;
    const int m0 = blockIdx.x * 64;
    const int tid = threadIdx.x;
    const int lane = tid & 63, wid = tid >> 6;
    const int l15 = lane & 15, l4 = lane >> 4;

    const u16* Qg = QKVb + (long)(zb * 256) * 3072 + zn * 256;
    const u16* Kg = Qg + 1024;

    auto stageA64 = [&](const u16* g, long ld) {
#pragma unroll
        for (int p = 0; p < 2; ++p) {
            const int e = p * 2048 + tid * 8;
            const int r = e >> 6, c = e & 63;
            const int sc = c ^ (((r >> 2) & 1) << 4);
            gld16(&As[e], g + (long)r * ld + sc);
        }
    };
    auto stageB256 = [&](const u16* g, long ld) {
#pragma unroll
        for (int p = 0; p < 8; ++p) {
            const int e = p * 2048 + tid * 8;
            const int r = e >> 6, c = e & 63;
            const int sc = c ^ (((r >> 2) & 1) << 4);
            gld16(&Bs[e], g + (long)r * ld + sc);
        }
    };
    auto fragA = [&](int i, int kk) -> bf16x8 {
        const int row = i * 16 + l15, col = kk * 32 + l4 * 8;
        return *(const bf16x8*)&As[row * 64 + (col ^ (((row >> 2) & 1) << 4))];
    };
    auto fragB = [&](int j, int kk) -> bf16x8 {
        const int row = wid * 64 + j * 16 + l15, col = kk * 32 + l4 * 8;
        return *(const bf16x8*)&Bs[row * 64 + (col ^ (((row >> 2) & 1) << 4))];
    };
    auto fragP = [&](int kc, int i, int kk) -> bf16x8 {
        const int row = i * 16 + l15, col = kk * 32 + l4 * 8;
        return *(const bf16x8*)&Pl[kc * 4096 + row * 64 + (col ^ (((row >> 2) & 1) << 4))];
    };

    f32x4 acc1[4][4] = {};
    f32x4 acc2[4][4] = {};

    for (int kc = 0; kc < 4; ++kc) {
        __syncthreads();
        stageA64(Qg + (long)m0 * 3072 + kc * 64, 3072);
        stageB256(Kg + kc * 64, 3072);
        __syncthreads();
#pragma unroll
        for (int i = 0; i < 4; ++i) {
            const bf16x8 a0 = fragA(i, 0), a1 = fragA(i, 1);
#pragma unroll
            for (int j = 0; j < 4; ++j) {
                acc1[i][j] = __builtin_amdgcn_mfma_f32_16x16x32_bf16(a0, fragB(j, 0), acc1[i][j], 0, 0, 0);
                acc1[i][j] = __builtin_amdgcn_mfma_f32_16x16x32_bf16(a1, fragB(j, 1), acc1[i][j], 0, 0, 0);
            }
        }
    }
    for (int kc = 0; kc < 4; ++kc) {
        __syncthreads();
        stageA64(erT + (long)m0 * 256 + kc * 64, 256);
        stageB256(Qg + kc * 64, 3072);
        __syncthreads();
#pragma unroll
        for (int i = 0; i < 4; ++i) {
            const bf16x8 a0 = fragA(i, 0), a1 = fragA(i, 1);
#pragma unroll
            for (int j = 0; j < 4; ++j) {
                acc2[i][j] = __builtin_amdgcn_mfma_f32_16x16x32_bf16(a0, fragB(j, 0), acc2[i][j], 0, 0, 0);
                acc2[i][j] = __builtin_amdgcn_mfma_f32_16x16x32_bf16(a1, fragB(j, 1), acc2[i][j], 0, 0, 0);
            }
        }
    }

    const float inv32 = 1.f / 32.f;
#pragma unroll
    for (int i = 0; i < 4; ++i)
#pragma unroll
        for (int q = 0; q < 4; ++q) {
            const int mg = m0 + i * 16 + l4 * 4 + q;
            const float dw = dwp[zn * 256 + mg];
#pragma unroll
            for (int j = 0; j < 4; ++j) {
                const int ng = wid * 64 + j * 16 + l15;
                acc1[i][j][q] = acc1[i][j][q] * inv32 + acc2[i][j][q]
                              + fabsf((float)(mg - ng)) * 0.5f * dw;
            }
        }

    float rmax[4][4], rsum[4][4];
#pragma unroll
    for (int i = 0; i < 4; ++i)
#pragma unroll
        for (int q = 0; q < 4; ++q) {
            float mv = fmaxf(fmaxf(acc1[i][0][q], acc1[i][1][q]),
                             fmaxf(acc1[i][2][q], acc1[i][3][q]));
#pragma unroll
            for (int off = 1; off <= 8; off <<= 1) mv = fmaxf(mv, __shfl_xor(mv, off, 64));
            rmax[i][q] = mv;
        }
    if (l15 == 0) {
#pragma unroll
        for (int i = 0; i < 4; ++i)
#pragma unroll
            for (int q = 0; q < 4; ++q)
                redM[wid][i * 16 + l4 * 4 + q] = rmax[i][q];
    }
    __syncthreads();
#pragma unroll
    for (int i = 0; i < 4; ++i)
#pragma unroll
        for (int q = 0; q < 4; ++q) {
            const int ml = i * 16 + l4 * 4 + q;
            rmax[i][q] = fmaxf(fmaxf(redM[0][ml], redM[1][ml]), fmaxf(redM[2][ml], redM[3][ml]));
        }
#pragma unroll
    for (int i = 0; i < 4; ++i)
#pragma unroll
        for (int q = 0; q < 4; ++q) {
            float sv = 0.f;
#pragma unroll
            for (int j = 0; j < 4; ++j) {
                const float e = __expf(acc1[i][j][q] - rmax[i][q]);
                acc1[i][j][q] = e;
                sv += e;
            }
#pragma unroll
            for (int off = 1; off <= 8; off <<= 1) sv += __shfl_xor(sv, off, 64);
            rsum[i][q] = sv;
        }
    if (l15 == 0) {
#pragma unroll
        for (int i = 0; i < 4; ++i)
#pragma unroll
            for (int q = 0; q < 4; ++q)
                redS[wid][i * 16 + l4 * 4 + q] = rsum[i][q];
    }
    __syncthreads();
#pragma unroll
    for (int i = 0; i < 4; ++i)
#pragma unroll
        for (int q = 0; q < 4; ++q) {
            const int ml = i * 16 + l4 * 4 + q;
            rsum[i][q] = redS[0][ml] + redS[1][ml] + redS[2][ml] + redS[3][ml];
        }
#pragma unroll
    for (int i = 0; i < 4; ++i)
#pragma unroll
        for (int q = 0; q < 4; ++q) {
            const float rinv = 1.f / rsum[i][q];
            const int ml = i * 16 + l4 * 4 + q;
#pragma unroll
            for (int j = 0; j < 4; ++j) {
                const int nc = j * 16 + l15;
                Pl[wid * 4096 + ml * 64 + (nc ^ (((ml >> 2) & 1) << 4))] = f2bf(acc1[i][j][q] * rinv);
            }
        }
    __syncthreads();

    f32x4 accO[4][4] = {};
    for (int kc = 0; kc < 4; ++kc) {
        __syncthreads();
        stageB256(Vt + (long)(z * 256) * 256 + kc * 64, 256);
        __syncthreads();
#pragma unroll
        for (int i = 0; i < 4; ++i) {
            const bf16x8 a0 = fragP(kc, i, 0), a1 = fragP(kc, i, 1);
#pragma unroll
            for (int j = 0; j < 4; ++j) {
                accO[i][j] = __builtin_amdgcn_mfma_f32_16x16x32_bf16(a0, fragB(j, 0), accO[i][j], 0, 0, 0);
                accO[i][j] = __builtin_amdgcn_mfma_f32_16x16x32_bf16(a1, fragB(j, 1), accO[i][j], 0, 0, 0);
            }
        }
    }

#pragma unroll
    for (int i = 0; i < 4; ++i)
#pragma unroll
        for (int j = 0; j < 4; ++j) {
            const int d = wid * 64 + j * 16 + l15;
#pragma unroll
            for (int q = 0; q < 4; ++q) {
                const int mg = m0 + i * 16 + l4 * 4 + q;
                Oc[(long)(zb * 256 + mg) * 1024 + zn * 256 + d] = f2bf(accO[i][j][q]);
            }
        }
}

// ---------------- GLU gate + residual + LN (sum 2 bf16 partials) ----------------
__global__ __launch_bounds__(256)
void glu_ln_k(const float* __restrict__ xs0, const u16* __restrict__ g2,
              const float* __restrict__ gam, const float* __restrict__ bet,
              float* __restrict__ outf, u16* __restrict__ outb)
{
    const int t = blockIdx.x, tid = threadIdx.x;
    const int f0 = tid * 4;
    const long PS = 8388608;   // 4096*2048 elements
    const float4 xv = *(const float4*)&xs0[(long)t * 1024 + f0];
    const float4 a0 = bf4f(*(const ushort4*)&g2[(long)t * 2048 + f0]);
    const float4 g0 = bf4f(*(const ushort4*)&g2[(long)t * 2048 + 1024 + f0]);
    const float4 a1 = bf4f(*(const ushort4*)&g2[PS + (long)t * 2048 + f0]);
    const float4 g1 = bf4f(*(const ushort4*)&g2[PS + (long)t * 2048 + 1024 + f0]);
    const float ax = a0.x + a1.x, ay = a0.y + a1.y, az = a0.z + a1.z, aw = a0.w + a1.w;
    const float gx = g0.x + g1.x, gy = g0.y + g1.y, gz = g0.z + g1.z, gw = g0.w + g1.w;
    float vals[4];
    vals[0] = xv.x + ax / (1.f + expf(-gx));
    vals[1] = xv.y + ay / (1.f + expf(-gy));
    vals[2] = xv.z + az / (1.f + expf(-gz));
    vals[3] = xv.w + aw / (1.f + expf(-gw));
    float s1 = vals[0] + vals[1] + vals[2] + vals[3];
    float s2 = vals[0]*vals[0] + vals[1]*vals[1] + vals[2]*vals[2] + vals[3]*vals[3];
    block_red2(s1, s2, tid);
    const float mean = s1 * (1.f / 1024.f);
    const float var  = s2 * (1.f / 1024.f) - mean * mean;
    const float rstd = rsqrtf(var + EPSF);
    const float4 gm = *(const float4*)&gam[f0];
    const float4 bt = *(const float4*)&bet[f0];
    float r0 = (vals[0] - mean) * rstd * gm.x + bt.x;
    float r1 = (vals[1] - mean) * rstd * gm.y + bt.y;
    float r2 = (vals[2] - mean) * rstd * gm.z + bt.z;
    float r3 = (vals[3] - mean) * rstd * gm.w + bt.w;
    *(float4*)&outf[(long)t * 1024 + f0] = make_float4(r0, r1, r2, r3);
    ushort4 ub; ub.x = f2bf(r0); ub.y = f2bf(r1); ub.z = f2bf(r2); ub.w = f2bf(r3);
    *(ushort4*)&outb[(long)t * 1024 + f0] = ub;
}

// ---------------- residual add + LN width 1024, B = sum of P bf16 partials (+opt bias) ----------------
template<int P, int WRITEBF, int BIAS>
__global__ __launch_bounds__(256)
void add_ln1024_k(const float* __restrict__ A, const u16* __restrict__ Bp,
                  const float* __restrict__ bias,
                  const float* __restrict__ gam, const float* __restrict__ bet,
                  float* __restrict__ outf, u16* __restrict__ outb)
{
    const int t = blockIdx.x, tid = threadIdx.x;
    const int f0 = tid * 4;
    const long PS = 4194304;   // 4096*1024 elements
    const float4 a = *(const float4*)&A[(long)t * 1024 + f0];
    float4 b = bf4f(*(const ushort4*)&Bp[(long)t * 1024 + f0]);
#pragma unroll
    for (int p = 1; p < P; ++p) {
        const float4 bp = bf4f(*(const ushort4*)&Bp[p * PS + (long)t * 1024 + f0]);
        b.x += bp.x; b.y += bp.y; b.z += bp.z; b.w += bp.w;
    }
    if (BIAS) {
        const float4 bb = *(const float4*)&bias[f0];
        b.x += bb.x; b.y += bb.y; b.z += bb.z; b.w += bb.w;
    }
    float vals[4] = {a.x + b.x, a.y + b.y, a.z + b.z, a.w + b.w};
    float s1 = vals[0] + vals[1] + vals[2] + vals[3];
    float s2 = vals[0]*vals[0] + vals[1]*vals[1] + vals[2]*vals[2] + vals[3]*vals[3];
    block_red2(s1, s2, tid);
    const float mean = s1 * (1.f / 1024.f);
    const float var  = s2 * (1.f / 1024.f) - mean * mean;
    const float rstd = rsqrtf(var + EPSF);
    const float4 gm = *(const float4*)&gam[f0];
    const float4 bt = *(const float4*)&bet[f0];
    float r0 = (vals[0] - mean) * rstd * gm.x + bt.x;
    float r1 = (vals[1] - mean) * rstd * gm.y + bt.y;
    float r2 = (vals[2] - mean) * rstd * gm.z + bt.z;
    float r3 = (vals[3] - mean) * rstd * gm.w + bt.w;
    *(float4*)&outf[(long)t * 1024 + f0] = make_float4(r0, r1, r2, r3);
    if (WRITEBF) {
        ushort4 ub; ub.x = f2bf(r0); ub.y = f2bf(r1); ub.z = f2bf(r2); ub.w = f2bf(r3);
        *(ushort4*)&outb[(long)t * 1024 + f0] = ub;
    }
}

// ---------------- n2: LN(c1L(bf16) + pad(relu(sum of 3 bf16 conv taps))) width 4096 ----------------
__global__ __launch_bounds__(256)
void add_ln4096_k(const u16* __restrict__ A, const u16* __restrict__ Bp,
                  const float* __restrict__ gam, const float* __restrict__ bet,
                  u16* __restrict__ outb)
{
    const int t = blockIdx.x, tid = threadIdx.x;
    const long PS = 4194304;   // 4096*1024 elements
    const int f0 = tid * 16;
    float vals[16];
    const bf16x8 a0 = *(const bf16x8*)&A[(long)t * 4096 + f0];
    const bf16x8 a1 = *(const bf16x8*)&A[(long)t * 4096 + f0 + 8];
#pragma unroll
    for (int e = 0; e < 8; ++e) { vals[e] = bf2f((u16)a0[e]); vals[8 + e] = bf2f((u16)a1[e]); }
    if (tid < 64) {
#pragma unroll
        for (int c = 0; c < 4; ++c) {
            const int fc = f0 + c * 4;
            const float4 b0 = bf4f(*(const ushort4*)&Bp[(long)t * 1024 + fc]);
            const float4 b1 = bf4f(*(const ushort4*)&Bp[PS + (long)t * 1024 + fc]);
            const float4 b2 = bf4f(*(const ushort4*)&Bp[2 * PS + (long)t * 1024 + fc]);
            vals[c*4+0] += fmaxf(b0.x + b1.x + b2.x, 0.f);
            vals[c*4+1] += fmaxf(b0.y + b1.y + b2.y, 0.f);
            vals[c*4+2] += fmaxf(b0.z + b1.z + b2.z, 0.f);
            vals[c*4+3] += fmaxf(b0.w + b1.w + b2.w, 0.f);
        }
    }
    float s1 = 0.f, s2 = 0.f;
#pragma unroll
    for (int e = 0; e < 16; ++e) { s1 += vals[e]; s2 += vals[e] * vals[e]; }
    block_red2(s1, s2, tid);
    const float mean = s1 * (1.f / 4096.f);
    const float var  = s2 * (1.f / 4096.f) - mean * mean;
    const float rstd = rsqrtf(var + EPSF);
#pragma unroll
    for (int c = 0; c < 4; ++c) {
        const int fc = f0 + c * 4;
        const float4 gm = *(const float4*)&gam[fc];
        const float4 bt = *(const float4*)&bet[fc];
        ushort4 ub;
        ub.x = f2bf((vals[c*4+0] - mean) * rstd * gm.x + bt.x);
        ub.y = f2bf((vals[c*4+1] - mean) * rstd * gm.y + bt.y);
        ub.z = f2bf((vals[c*4+2] - mean) * rstd * gm.z + bt.z);
        ub.w = f2bf((vals[c*4+3] - mean) * rstd * gm.w + bt.w);
        *(ushort4*)&outb[(long)t * 4096 + fc] = ub;
    }
}

// ---------------- depthwise conv width-9, 8 channels/thread ----------------
__global__ __launch_bounds__(256)
void dwconv8_k(const u16* __restrict__ h, const float* __restrict__ wT,
               u16* __restrict__ out)
{
    const long idx = (long)blockIdx.x * 256 + threadIdx.x;
    const int cg = (int)(idx & 511);
    const int t  = (int)(idx >> 9);
    const int w  = t & 255;
    const int c0 = cg * 8;
    float acc[8] = {};
#pragma unroll
    for (int k = 0; k < 9; ++k) {
        const int wp = w + k - 4;
        if ((unsigned)wp < 256u) {
            const bf16x8 hv = *(const bf16x8*)&h[(long)(t + k - 4) * 4096 + c0];
            const float4 w0 = *(const float4*)&wT[k * 4096 + c0];
            const float4 w1 = *(const float4*)&wT[k * 4096 + c0 + 4];
            acc[0] += bf2f((u16)hv[0]) * w0.x;
            acc[1] += bf2f((u16)hv[1]) * w0.y;
            acc[2] += bf2f((u16)hv[2]) * w0.z;
            acc[3] += bf2f((u16)hv[3]) * w0.w;
            acc[4] += bf2f((u16)hv[4]) * w1.x;
            acc[5] += bf2f((u16)hv[5]) * w1.y;
            acc[6] += bf2f((u16)hv[6]) * w1.z;
            acc[7] += bf2f((u16)hv[7]) * w1.w;
        }
    }
    bf16x8 res;
#pragma unroll
    for (int j = 0; j < 8; ++j) res[j] = (short)f2bf(acc[j]);
    *(bf16x8*)&out[(long)t * 4096 + c0] = res;
}

// ---------------- V slice of QKVb -> Vt (z, d, w) bf16 ----------------
__global__ __launch_bounds__(256)
void vtrans_k(const u16* __restrict__ QKVb, u16* __restrict__ Vt)
{
    __shared__ u16 t[32][33];
    const int z = blockIdx.z, zb = z >> 2, zn = z & 3;
    const int w0 = blockIdx.x * 32, d0 = blockIdx.y * 32;
    const int tid = threadIdx.x, c = tid & 31, r = tid >> 5;
#pragma unroll
    for (int it = 0; it < 4; ++it) {
        const int wl = r + it * 8;
        t[wl][c] = QKVb[(long)(zb * 256 + w0 + wl) * 3072 + 2048 + zn * 256 + d0 + c];
    }
    __syncthreads();
#pragma unroll
    for (int it = 0; it < 4; ++it) {
        const int dl = r + it * 8;
        Vt[((long)z * 256 + d0 + dl) * 256 + w0 + c] = t[c][dl];
    }
}

// ---------------- final transpose (tokens,1024) -> (B,1,1024,256) ----------------
__global__ __launch_bounds__(256)
void transpose_out_k(const float* __restrict__ xs, float* __restrict__ out)
{
    __shared__ float tile[32][33];
    const int b = blockIdx.z, f0 = blockIdx.y * 32, w0 = blockIdx.x * 32;
    const int tid = threadIdx.x, c = tid & 31, r = tid >> 5;
#pragma unroll
    for (int it = 0; it < 4; ++it) {
        const int w = w0 + r + it * 8;
        tile[r + it * 8][c] = xs[((long)b * 256 + w) * 1024 + f0 + c];
    }
    __syncthreads();
#pragma unroll
    for (int it = 0; it < 4; ++it) {
        const int fl = r + it * 8;
        out[((long)b * 1024 + f0 + fl) * 256 + w0 + c] = tile[c][fl];
    }
}

// =======================================================================
extern "C" void kernel_launch(void* const* d_in, const int* in_sizes, int n_in,
                              void* d_out, int out_size, void* d_ws, size_t ws_size,
                              hipStream_t stream)
{
    const float* x      = (const float*)d_in[0];
    const float* bott_w = (const float*)d_in[1];
    const float* bn_g   = (const float*)d_in[2];
    const float* bn_b   = (const float*)d_in[3];
    const float* bn_m   = (const float*)d_in[4];
    const float* bn_v   = (const float*)d_in[5];
    const float* glu_w  = (const float*)d_in[6];
    const float* n1g    = (const float*)d_in[7];
    const float* n1b    = (const float*)d_in[8];
    const float* c1L_w  = (const float*)d_in[9];
    const float* c1R_w  = (const float*)d_in[10];
    const float* n2g    = (const float*)d_in[11];
    const float* n2b    = (const float*)d_in[12];
    const float* c2dw_w = (const float*)d_in[13];
    const float* c2pw_w = (const float*)d_in[14];
    const float* n3g    = (const float*)d_in[15];
    const float* n3b    = (const float*)d_in[16];
    const float* qw     = (const float*)d_in[17];
    const float* qb     = (const float*)d_in[18];
    const float* kw     = (const float*)d_in[19];
    const float* kb     = (const float*)d_in[20];
    const float* vw     = (const float*)d_in[21];
    const float* vb     = (const float*)d_in[22];
    const float* ow     = (const float*)d_in[23];
    const float* ob     = (const float*)d_in[24];
    const float* er     = (const float*)d_in[25];
    const float* dist_w = (const float*)d_in[26];
    const float* n4g    = (const float*)d_in[27];
    const float* n4b    = (const float*)d_in[28];
    const float* c3_w   = (const float*)d_in[29];
    const float* c4_w   = (const float*)d_in[30];
    const float* n5g    = (const float*)d_in[31];
    const float* n5b    = (const float*)d_in[32];
    float* out = (float*)d_out;

    // ---- workspace layout (MiB offsets, lifetimes annotated) ----
    char* Wb_ = (char*)d_ws;
    auto F  = [&](size_t mib) { return (float*)(Wb_ + (mib << 20)); };
    auto Bf = [&](size_t mib) { return (u16*)  (Wb_ + (mib << 20)); };
    float* X0   = F(0);     // xs chain A
    float* X1   = F(16);    // xs chain B
    u16*   H0b  = Bf(32);   // c1L bf16 out (4-6) / c3 bf16 out (14-15)
    u16*   Hglu = Bf(64);   // GLU 2 bf16 partials (2x16MB)
    u16*   C3p  = Bf(64);   // conv3 3 bf16 partials (3x8MB)
    u16*   P4   = Bf(64);   // c2pw/O-proj/c4 4 bf16 partials (4x8MB)
    u16*   H1b  = Bf(128);  // n2 out bf16 (6-7)
    u16*   Hdw  = Bf(160);  // dwconv out bf16 (7-8)
    u16*   QKVb = Bf(192);  // fused QKV out 4096x3072 bf16 (10-11)
    u16*   Vt   = Bf(216);  // V transposed (10b-11)
    u16*   S1b  = Bf(264);  // attn concat bf16 (11-12)
    u16*   XbA  = Bf(280);  // X1b (1-2), X2b (9-10)
    u16*   XbB  = Bf(288);  // X0b (3-5), X3b (13-14)
    u16* wGLU = Bf(296); u16* wC1L = Bf(300); u16* wC1R = Bf(308);
    u16* wC2P = Bf(314); u16* wQKV = Bf(322); u16* wO   = Bf(328);
    u16* wC3  = Bf(330); u16* wC4  = Bf(338);
    u16* erT  = Bf(346);
    u16* zp   = (u16*)(Wb_ + (346u << 20) + 131072);
    float* wdwT = (float*)(Wb_ + (346u << 20) + 131072 + 16384);
    float* bQKV = (float*)(Wb_ + (346u << 20) + 131072 + 16384 + 147456);

    const dim3 blk(256);
    const dim3 blk8(512);
    const long PS1 = 4194304;   // 4096*1024 elements
    const size_t SH8 = 131072;  // 128 KiB dynamic LDS for gemm8/conv38

    // 0. merged setup (one launch)
    SetupArgs sa;
    sa.ws[0] = glu_w;  sa.wd[0] = wGLU;            sa.wn[0] = 524288;
    sa.ws[1] = c1L_w;  sa.wd[1] = wC1L;            sa.wn[1] = 1048576;
    sa.ws[2] = c2pw_w; sa.wd[2] = wC2P;            sa.wn[2] = 1048576;
    sa.ws[3] = c3_w;   sa.wd[3] = wC3;             sa.wn[3] = 1048576;
    sa.ws[4] = c4_w;   sa.wd[4] = wC4;             sa.wn[4] = 1048576;
    sa.ws[5] = qw;     sa.wd[5] = wQKV;            sa.wn[5] = 262144;
    sa.ws[6] = kw;     sa.wd[6] = wQKV + 1048576;  sa.wn[6] = 262144;
    sa.ws[7] = vw;     sa.wd[7] = wQKV + 2097152;  sa.wn[7] = 262144;
    sa.ws[8] = ow;     sa.wd[8] = wO;              sa.wn[8] = 262144;
    sa.c1r = c1R_w; sa.c1rd = wC1R;
    sa.er  = er;    sa.erd  = erT;
    sa.dw  = c2dw_w; sa.dwd = wdwT;
    sa.qb = qb; sa.kb = kb; sa.vb = vb; sa.bcat = bQKV;
    sa.zp = zp;
    {
        int bc[14] = {2048, 4096, 4096, 4096, 4096, 1024, 1024, 1024, 1024,
                      12288, 256, 144, 12, 32};
        int acc = 0;
        for (int s = 0; s < 14; ++s) { sa.off[s] = acc; acc += bc[s]; }
        sa.off[14] = acc;
        setup_k<<<dim3(acc), blk, 0, stream>>>(sa);
    }

    // 1. bottleneck + BN + ReLU + transpose
    bottleneck_k<<<dim3(8, 32, 16), blk, 0, stream>>>(x, bott_w, bn_g, bn_b, bn_m, bn_v, X1, XbA);

    // 2. GLU matmul, split-K=2 -> Hglu bf16 partials
    gemm8_k<0,0,0,2><<<dim3(8, 16, 2), blk8, SH8, stream>>>(XbA, wGLU, nullptr, Hglu,
        2048, 512, 1024, 1024, (long)4096 * 2048);

    // 3. n1: LN(xs0 + a*sigmoid(g)) -> X0 + X0b
    glu_ln_k<<<dim3(4096), blk, 0, stream>>>(X1, Hglu, n1g, n1b, X0, XbB);

    // 4. c1L: relu -> H0b bf16 (4096x4096)
    gemm8_k<1,1,0,1><<<dim3(16, 16, 1), blk8, SH8, stream>>>(XbB, wC1L, nullptr, H0b,
        4096, 1024, 1024, 1024, 0);

    // 5. c1R conv: 3 tap-slices -> C3p bf16 partials
    conv38_k<<<dim3(4, 16, 3), blk8, SH8, stream>>>(XbB, wC1R, zp, C3p);

    // 6. n2: LN(H0b + pad(relu(sum taps))) -> H1b bf16
    add_ln4096_k<<<dim3(4096), blk, 0, stream>>>(H0b, C3p, n2g, n2b, H1b);

    // 7. depthwise conv9 (vectorized x8): H1b -> Hdw
    dwconv8_k<<<dim3(8192), blk, 0, stream>>>(H1b, wdwT, Hdw);

    // 8. c2pw, split-K=4 -> P4 bf16 partials
    gemm8_k<0,0,0,4><<<dim3(4, 16, 4), blk8, SH8, stream>>>(Hdw, wC2P, nullptr, P4,
        1024, 1024, 4096, 4096, PS1);

    // 9. n3: LN(X0 + sum P4) -> X1 + X2b
    add_ln1024_k<4,1,0><<<dim3(4096), blk, 0, stream>>>(X0, P4, nullptr, n3g, n3b, X1, XbA);

    // 10. fused QKV projection (+concat bias) -> QKVb bf16 (4096x3072)
    gemm8_k<0,1,1,1><<<dim3(12, 16, 1), blk8, SH8, stream>>>(XbA, wQKV, bQKV, QKVb,
        3072, 1024, 1024, 1024, 0);

    // 10b. V transpose per head -> Vt (z, d, w)
    vtrans_k<<<dim3(8, 8, 64), blk, 0, stream>>>(QKVb, Vt);

    // 11. fused attention: scores + softmax + PV -> S1b (concat layout)
    attn_fused_k<<<dim3(4, 64), blk, 0, stream>>>(QKVb, erT, Vt, dist_w, S1b);

    // 12. output projection, split-K=4 -> P4 bf16 partials (bias added in n4)
    gemm8_k<0,0,0,4><<<dim3(4, 16, 4), blk8, SH8, stream>>>(S1b, wO, nullptr, P4,
        1024, 256, 1024, 1024, PS1);

    // 13. n4: LN(X1 + sum P4 + ob) -> X0 + X3b
    add_ln1024_k<4,1,1><<<dim3(4096), blk, 0, stream>>>(X1, P4, ob, n4g, n4b, X0, XbB);

    // 14. c3: relu -> H0b bf16
    gemm8_k<1,1,0,1><<<dim3(16, 16, 1), blk8, SH8, stream>>>(XbB, wC3, nullptr, H0b,
        4096, 1024, 1024, 1024, 0);

    // 15. c4, split-K=4 -> P4 bf16 partials
    gemm8_k<0,0,0,4><<<dim3(4, 16, 4), blk8, SH8, stream>>>(H0b, wC4, nullptr, P4,
        1024, 1024, 4096, 4096, PS1);

    // 16. n5: LN(X0 + sum P4) -> X1 (f32 only)
    add_ln1024_k<4,0,0><<<dim3(4096), blk, 0, stream>>>(X0, P4, nullptr, n5g, n5b, X1, nullptr);

    // 17. transpose to (B, 1, 1024, 256)
    transpose_out_k<<<dim3(8, 32, 16), blk, 0, stream>>>(X1, out);

    (void)in_sizes; (void)n_in; (void)out_size; (void)ws_size;
}

// Round 8
// 496.409 us; speedup vs baseline: 7.0321x; 1.0328x over previous
//
#include <hip/hip_runtime.h>
#include <hip/hip_bf16.h>

// FrameTransformer: B=16, C=8, BINS=1024, W=256, FF=2048, NB=4
// tokens = B*W = 4096, feature width 1024, FF width 4096, head dim 256.
#define EPSF 1e-5f

typedef unsigned short u16;
typedef unsigned int   u32;
typedef __attribute__((ext_vector_type(8))) short bf16x8;
typedef __attribute__((ext_vector_type(4))) float f32x4;

__device__ __forceinline__ u16 f2bf(float f) {
    u32 u = __builtin_bit_cast(u32, f);
    u32 r = u + 0x7fffu + ((u >> 16) & 1u);
    return (u16)(r >> 16);
}
__device__ __forceinline__ float bf2f(u16 h) {
    return __builtin_bit_cast(float, (u32)h << 16);
}
__device__ __forceinline__ float4 bf4f(ushort4 v) {
    return make_float4(bf2f(v.x), bf2f(v.y), bf2f(v.z), bf2f(v.w));
}
__device__ __forceinline__ ushort4 f4bf(float a, float b, float c, float d) {
    ushort4 o; o.x = f2bf(a); o.y = f2bf(b); o.z = f2bf(c); o.w = f2bf(d); return o;
}
__device__ __forceinline__ void gld16(void* lds, const void* gsrc) {
    __builtin_amdgcn_global_load_lds(
        (const __attribute__((address_space(1))) u32*)gsrc,
        (__attribute__((address_space(3))) u32*)lds, 16, 0, 0);
}

__device__ __forceinline__ float wred_sum(float v) {
#pragma unroll
    for (int off = 32; off; off >>= 1) v += __shfl_xor(v, off, 64);
    return v;
}
__device__ __forceinline__ void block_red2(float& s1, float& s2, int tid) {
    __shared__ float red[8];
    s1 = wred_sum(s1); s2 = wred_sum(s2);
    const int lane = tid & 63, wid = tid >> 6;
    if (!lane) { red[wid] = s1; red[4 + wid] = s2; }
    __syncthreads();
    s1 = red[0] + red[1] + red[2] + red[3];
    s2 = red[4] + red[5] + red[6] + red[7];
}

// ---------------- merged setup: all weight conversions in one launch ----------------
struct SetupArgs {
    const float* ws[9]; u16* wd[9]; int wn[9];     // plain f32x4 -> bf16x4
    const float* c1r; u16* c1rd;
    const float* er;  u16* erd;
    const float* dw;  float* dwd;
    const float* qb;  const float* kb; const float* vb; float* bcat;
    u16* zp;
    int off[15];
};
__global__ __launch_bounds__(256)
void setup_k(SetupArgs a)
{
    const int b = blockIdx.x;
    int seg = 0;
    while (seg < 13 && b >= a.off[seg + 1]) ++seg;
    const int i = (b - a.off[seg]) * 256 + threadIdx.x;
    if (seg < 9) {
        if (i < a.wn[seg]) {
            const float4 v = ((const float4*)a.ws[seg])[i];
            ((ushort4*)a.wd[seg])[i] = f4bf(v.x, v.y, v.z, v.w);
        }
    } else if (seg == 9) {
        if (i < 3145728) {
            const int q = i / 3072, rem = i - q * 3072;
            const int ks = rem >> 10, ci = rem & 1023;
            a.c1rd[i] = f2bf(a.c1r[((long)q * 1024 + ci) * 3 + ks]);
        }
    } else if (seg == 10) {
        if (i < 65536) { const int c = i >> 8, d = i & 255; a.erd[i] = f2bf(a.er[d * 256 + c]); }
    } else if (seg == 11) {
        if (i < 36864) { const int k = i >> 12, c = i & 4095; a.dwd[i] = a.dw[c * 9 + k]; }
    } else if (seg == 12) {
        if (i < 3072) { const float* s = (i < 1024) ? a.qb : ((i < 2048) ? a.kb : a.vb); a.bcat[i] = s[i & 1023]; }
    } else {
        if (i < 8192) a.zp[i] = 0;
    }
}

// ---------------- stage 1: bottleneck 1x1 conv + BN + ReLU + transpose (bf16 out) ----------------
__global__ __launch_bounds__(256)
void bottleneck_k(const float* __restrict__ x, const float* __restrict__ bw,
                  const float* __restrict__ bn_g, const float* __restrict__ bn_b,
                  const float* __restrict__ bn_m, const float* __restrict__ bn_v,
                  u16* __restrict__ xsb)
{
    __shared__ float tile[32][33];
    const int b = blockIdx.z, h0 = blockIdx.y * 32, w0 = blockIdx.x * 32;
    const int tid = threadIdx.x, c = tid & 31, r = tid >> 5;
    float wreg[8];
#pragma unroll
    for (int ch = 0; ch < 8; ++ch) wreg[ch] = bw[ch];
    const float sc = bn_g[0] * rsqrtf(bn_v[0] + EPSF);
    const float sh = bn_b[0] - bn_m[0] * sc;
#pragma unroll
    for (int it = 0; it < 4; ++it) {
        const int h = h0 + r + it * 8;
        const int w = w0 + c;
        float acc = 0.f;
#pragma unroll
        for (int ch = 0; ch < 8; ++ch)
            acc += x[(((long)b * 8 + ch) * 1024 + h) * 256 + w] * wreg[ch];
        tile[r + it * 8][c] = fmaxf(acc * sc + sh, 0.f);
    }
    __syncthreads();
#pragma unroll
    for (int it = 0; it < 4; ++it) {
        const int wl = r + it * 8;
        xsb[((long)b * 256 + w0 + wl) * 1024 + h0 + c] = f2bf(tile[c][wl]);
    }
}

// ============ 8-phase 256x256 bf16 MFMA GEMM (T2+T3+T4+T5) ============
template<int ACT, int OUTBF, int BIAS, int SPLITK>
__global__ __launch_bounds__(512, 2)
void gemm8_k(const u16* __restrict__ A, const u16* __restrict__ B,
             const float* __restrict__ bias, void* __restrict__ Cout,
             int N, int K /*per slice*/, int lda, int ldb, long partStride)
{
    extern __shared__ u16 lds[];
    const int m0 = blockIdx.y * 256, n0 = blockIdx.x * 256;
    const int koff = (SPLITK > 1) ? blockIdx.z * K : 0;
    const int nt = K >> 6;
    const int tid = threadIdx.x;
    const int lane = tid & 63, wid = tid >> 6;
    const int wr = ((wid >> 2) & 1) * 128;
    const int wc = (wid & 3) * 64;
    const int l15 = lane & 15, l4 = lane >> 4;

    const u16* Ag = A + (long)m0 * lda + koff;
    const u16* Bg = B + (long)n0 * ldb + koff;

    auto stage = [&](const u16* g, int ld, int ldsbase, int kcol, int h) {
#pragma unroll
        for (int is = 0; is < 2; ++is) {
            const int r = h * 128 + is * 64 + (tid >> 3);
            const int sc = ((tid & 7) * 8) ^ (((r >> 2) & 1) << 4);
            gld16(&lds[ldsbase + h * 8192 + is * 4096 + tid * 8],
                  g + (long)r * ld + kcol + sc);
        }
    };
    auto frag = [&](int base, int row, int col) -> bf16x8 {
        return *(const bf16x8*)&lds[base + row * 64 + (col ^ (((row >> 2) & 1) << 4))];
    };

    f32x4 acc[8][4] = {};

    stage(Ag, lda, 0, 0, 0);
    stage(Ag, lda, 0, 0, 1);
    stage(Bg, ldb, 32768, 0, 0);
    stage(Bg, ldb, 32768, 0, 1);
    if (nt > 1) {
        stage(Bg, ldb, 49152, 64, 0);
        stage(Bg, ldb, 49152, 64, 1);
        stage(Ag, lda, 16384, 64, 0);
        asm volatile("s_waitcnt vmcnt(6)" ::: "memory");
    } else {
        asm volatile("s_waitcnt vmcnt(0)" ::: "memory");
    }
    __builtin_amdgcn_s_barrier();

    for (int kt = 0; kt < nt; ++kt) {
        const int cs = kt & 1;
        const int ab = cs * 16384;
        const int bb = 32768 + cs * 16384;
        const int abn = (cs ^ 1) * 16384;
        const int kc1 = (kt + 1) * 64, kc2 = (kt + 2) * 64;
        bf16x8 alo[4][2], ahi[4][2], b01[2][2], b23[2][2];

#pragma unroll
        for (int i = 0; i < 4; ++i)
#pragma unroll
            for (int kk = 0; kk < 2; ++kk)
                alo[i][kk] = frag(ab, wr + i * 16 + l15, kk * 32 + l4 * 8);
#pragma unroll
        for (int j = 0; j < 2; ++j)
#pragma unroll
            for (int kk = 0; kk < 2; ++kk)
                b01[j][kk] = frag(bb, wc + j * 16 + l15, kk * 32 + l4 * 8);
        if (kt + 1 < nt) stage(Ag, lda, abn, kc1, 1);
        __builtin_amdgcn_s_barrier();
        asm volatile("s_waitcnt lgkmcnt(0)" ::: "memory");
        __builtin_amdgcn_s_setprio(1);
#pragma unroll
        for (int i = 0; i < 4; ++i)
#pragma unroll
            for (int j = 0; j < 2; ++j)
#pragma unroll
                for (int kk = 0; kk < 2; ++kk)
                    acc[i][j] = __builtin_amdgcn_mfma_f32_16x16x32_bf16(alo[i][kk], b01[j][kk], acc[i][j], 0, 0, 0);
        __builtin_amdgcn_s_setprio(0);
        __builtin_amdgcn_s_barrier();

#pragma unroll
        for (int j = 0; j < 2; ++j)
#pragma unroll
            for (int kk = 0; kk < 2; ++kk)
                b23[j][kk] = frag(bb, wc + (j + 2) * 16 + l15, kk * 32 + l4 * 8);
        if (kt + 2 < nt) stage(Bg, ldb, bb, kc2, 0);
        __builtin_amdgcn_s_barrier();
        asm volatile("s_waitcnt lgkmcnt(0)" ::: "memory");
        __builtin_amdgcn_s_setprio(1);
#pragma unroll
        for (int i = 0; i < 4; ++i)
#pragma unroll
            for (int j = 0; j < 2; ++j)
#pragma unroll
                for (int kk = 0; kk < 2; ++kk)
                    acc[i][j + 2] = __builtin_amdgcn_mfma_f32_16x16x32_bf16(alo[i][kk], b23[j][kk], acc[i][j + 2], 0, 0, 0);
        __builtin_amdgcn_s_setprio(0);
        __builtin_amdgcn_s_barrier();

#pragma unroll
        for (int i = 0; i < 4; ++i)
#pragma unroll
            for (int kk = 0; kk < 2; ++kk)
                ahi[i][kk] = frag(ab, wr + (i + 4) * 16 + l15, kk * 32 + l4 * 8);
        if (kt + 2 < nt) stage(Bg, ldb, bb, kc2, 1);
        __builtin_amdgcn_s_barrier();
        asm volatile("s_waitcnt lgkmcnt(0)" ::: "memory");
        __builtin_amdgcn_s_setprio(1);
#pragma unroll
        for (int i = 0; i < 4; ++i)
#pragma unroll
            for (int j = 0; j < 2; ++j)
#pragma unroll
                for (int kk = 0; kk < 2; ++kk)
                    acc[i + 4][j + 2] = __builtin_amdgcn_mfma_f32_16x16x32_bf16(ahi[i][kk], b23[j][kk], acc[i + 4][j + 2], 0, 0, 0);
        __builtin_amdgcn_s_setprio(0);
        __builtin_amdgcn_s_barrier();

        if (kt + 2 < nt) stage(Ag, lda, ab, kc2, 0);
        __builtin_amdgcn_s_barrier();
        __builtin_amdgcn_s_setprio(1);
#pragma unroll
        for (int i = 0; i < 4; ++i)
#pragma unroll
            for (int j = 0; j < 2; ++j)
#pragma unroll
                for (int kk = 0; kk < 2; ++kk)
                    acc[i + 4][j] = __builtin_amdgcn_mfma_f32_16x16x32_bf16(ahi[i][kk], b01[j][kk], acc[i + 4][j], 0, 0, 0);
        __builtin_amdgcn_s_setprio(0);
        if (kt + 2 < nt) {
            asm volatile("s_waitcnt vmcnt(6)" ::: "memory");
        } else {
            asm volatile("s_waitcnt vmcnt(0)" ::: "memory");
        }
        __builtin_amdgcn_s_barrier();
    }

    if (SPLITK > 1) {
        u16* Cp = (u16*)Cout + (long)blockIdx.z * partStride;
#pragma unroll
        for (int i = 0; i < 8; ++i)
#pragma unroll
            for (int j = 0; j < 4; ++j) {
                const int n = n0 + wc + j * 16 + l15;
#pragma unroll
                for (int q = 0; q < 4; ++q) {
                    const int m = m0 + wr + i * 16 + l4 * 4 + q;
                    Cp[(long)m * N + n] = f2bf(acc[i][j][q]);
                }
            }
    } else {
        float* Cf = (float*)Cout;
        u16*   Cb = (u16*)Cout;
#pragma unroll
        for (int i = 0; i < 8; ++i)
#pragma unroll
            for (int j = 0; j < 4; ++j) {
                const int n = n0 + wc + j * 16 + l15;
                const float bv = BIAS ? bias[n] : 0.f;
#pragma unroll
                for (int q = 0; q < 4; ++q) {
                    const int m = m0 + wr + i * 16 + l4 * 4 + q;
                    float v = acc[i][j][q] + bv;
                    if (ACT) v = fmaxf(v, 0.f);
                    if (OUTBF) Cb[(long)m * N + n] = f2bf(v);
                    else       Cf[(long)m * N + n] = v;
                }
            }
    }
}

// ============ conv1R on the 8-phase body: per-tap z, bf16 partials out ============
__global__ __launch_bounds__(512, 2)
void conv38_k(const u16* __restrict__ Xb, const u16* __restrict__ Wt,
              const u16* __restrict__ zp, u16* __restrict__ C)
{
    extern __shared__ u16 lds[];
    const int ks = blockIdx.z;
    const int m0 = blockIdx.y * 256, n0 = blockIdx.x * 256;
    const int nt = 16;
    const int tid = threadIdx.x;
    const int lane = tid & 63, wid = tid >> 6;
    const int wr = ((wid >> 2) & 1) * 128;
    const int wc = (wid & 3) * 64;
    const int l15 = lane & 15, l4 = lane >> 4;

    auto stageA = [&](int ldsbase, int kcol, int h) {
#pragma unroll
        for (int is = 0; is < 2; ++is) {
            const int r = h * 128 + is * 64 + (tid >> 3);
            const int sc = ((tid & 7) * 8) ^ (((r >> 2) & 1) << 4);
            const int t = m0 + r;
            const int wp = (t & 255) + ks - 1;
            const u16* src = ((unsigned)wp < 256u)
                ? Xb + (long)(t + ks - 1) * 1024 + kcol + sc
                : zp;
            gld16(&lds[ldsbase + h * 8192 + is * 4096 + tid * 8], src);
        }
    };
    auto stageB = [&](int ldsbase, int kcol, int h) {
#pragma unroll
        for (int is = 0; is < 2; ++is) {
            const int r = h * 128 + is * 64 + (tid >> 3);
            const int sc = ((tid & 7) * 8) ^ (((r >> 2) & 1) << 4);
            gld16(&lds[ldsbase + h * 8192 + is * 4096 + tid * 8],
                  Wt + (long)(n0 + r) * 3072 + ks * 1024 + kcol + sc);
        }
    };
    auto frag = [&](int base, int row, int col) -> bf16x8 {
        return *(const bf16x8*)&lds[base + row * 64 + (col ^ (((row >> 2) & 1) << 4))];
    };

    f32x4 acc[8][4] = {};

    stageA(0, 0, 0);
    stageA(0, 0, 1);
    stageB(32768, 0, 0);
    stageB(32768, 0, 1);
    stageB(49152, 64, 0);
    stageB(49152, 64, 1);
    stageA(16384, 64, 0);
    asm volatile("s_waitcnt vmcnt(6)" ::: "memory");
    __builtin_amdgcn_s_barrier();

    for (int kt = 0; kt < nt; ++kt) {
        const int cs = kt & 1;
        const int ab = cs * 16384;
        const int bb = 32768 + cs * 16384;
        const int abn = (cs ^ 1) * 16384;
        const int kc1 = (kt + 1) * 64, kc2 = (kt + 2) * 64;
        bf16x8 alo[4][2], ahi[4][2], b01[2][2], b23[2][2];

#pragma unroll
        for (int i = 0; i < 4; ++i)
#pragma unroll
            for (int kk = 0; kk < 2; ++kk)
                alo[i][kk] = frag(ab, wr + i * 16 + l15, kk * 32 + l4 * 8);
#pragma unroll
        for (int j = 0; j < 2; ++j)
#pragma unroll
            for (int kk = 0; kk < 2; ++kk)
                b01[j][kk] = frag(bb, wc + j * 16 + l15, kk * 32 + l4 * 8);
        if (kt + 1 < nt) stageA(abn, kc1, 1);
        __builtin_amdgcn_s_barrier();
        asm volatile("s_waitcnt lgkmcnt(0)" ::: "memory");
        __builtin_amdgcn_s_setprio(1);
#pragma unroll
        for (int i = 0; i < 4; ++i)
#pragma unroll
            for (int j = 0; j < 2; ++j)
#pragma unroll
                for (int kk = 0; kk < 2; ++kk)
                    acc[i][j] = __builtin_amdgcn_mfma_f32_16x16x32_bf16(alo[i][kk], b01[j][kk], acc[i][j], 0, 0, 0);
        __builtin_amdgcn_s_setprio(0);
        __builtin_amdgcn_s_barrier();

#pragma unroll
        for (int j = 0; j < 2; ++j)
#pragma unroll
            for (int kk = 0; kk < 2; ++kk)
                b23[j][kk] = frag(bb, wc + (j + 2) * 16 + l15, kk * 32 + l4 * 8);
        if (kt + 2 < nt) stageB(bb, kc2, 0);
        __builtin_amdgcn_s_barrier();
        asm volatile("s_waitcnt lgkmcnt(0)" ::: "memory");
        __builtin_amdgcn_s_setprio(1);
#pragma unroll
        for (int i = 0; i < 4; ++i)
#pragma unroll
            for (int j = 0; j < 2; ++j)
#pragma unroll
                for (int kk = 0; kk < 2; ++kk)
                    acc[i][j + 2] = __builtin_amdgcn_mfma_f32_16x16x32_bf16(alo[i][kk], b23[j][kk], acc[i][j + 2], 0, 0, 0);
        __builtin_amdgcn_s_setprio(0);
        __builtin_amdgcn_s_barrier();

#pragma unroll
        for (int i = 0; i < 4; ++i)
#pragma unroll
            for (int kk = 0; kk < 2; ++kk)
                ahi[i][kk] = frag(ab, wr + (i + 4) * 16 + l15, kk * 32 + l4 * 8);
        if (kt + 2 < nt) stageB(bb, kc2, 1);
        __builtin_amdgcn_s_barrier();
        asm volatile("s_waitcnt lgkmcnt(0)" ::: "memory");
        __builtin_amdgcn_s_setprio(1);
#pragma unroll
        for (int i = 0; i < 4; ++i)
#pragma unroll
            for (int j = 0; j < 2; ++j)
#pragma unroll
                for (int kk = 0; kk < 2; ++kk)
                    acc[i + 4][j + 2] = __builtin_amdgcn_mfma_f32_16x16x32_bf16(ahi[i][kk], b23[j][kk], acc[i + 4][j + 2], 0, 0, 0);
        __builtin_amdgcn_s_setprio(0);
        __builtin_amdgcn_s_barrier();

        if (kt + 2 < nt) stageA(ab, kc2, 0);
        __builtin_amdgcn_s_barrier();
        __builtin_amdgcn_s_setprio(1);
#pragma unroll
        for (int i = 0; i < 4; ++i)
#pragma unroll
            for (int j = 0; j < 2; ++j)
#pragma unroll
                for (int kk = 0; kk < 2; ++kk)
                    acc[i + 4][j] = __builtin_amdgcn_mfma_f32_16x16x32_bf16(ahi[i][kk], b01[j][kk], acc[i + 4][j], 0, 0, 0);
        __builtin_amdgcn_s_setprio(0);
        if (kt + 2 < nt) {
            asm volatile("s_waitcnt vmcnt(6)" ::: "memory");
        } else {
            asm volatile("s_waitcnt vmcnt(0)" ::: "memory");
        }
        __builtin_amdgcn_s_barrier();
    }

    u16* Cp = C + (long)ks * 4194304;
#pragma unroll
    for (int i = 0; i < 8; ++i)
#pragma unroll
        for (int j = 0; j < 4; ++j) {
            const int n = n0 + wc + j * 16 + l15;
#pragma unroll
            for (int q = 0; q < 4; ++q) {
                const int m = m0 + wr + i * 16 + l4 * 4 + q;
                Cp[(long)m * 1024 + n] = f2bf(acc[i][j][q]);
            }
        }
}

// ============ fused attention: scores(QK/32 + erT@Q^T + dist) -> softmax -> P@Vt^T ============
__global__ __launch_bounds__(256, 2)
void attn_fused_k(const u16* __restrict__ QKVb, const u16* __restrict__ erT,
                  const u16* __restrict__ Vt, const float* __restrict__ dwp,
                  u16* __restrict__ Oc)
{
    __shared__ __align__(16) u16 As[4096];
    __shared__ __align__(16) u16 Bs[16384];
    __shared__ __align__(16) u16 Pl[16384];
    __shared__ float redM[4][64];
    __shared__ float redS[4][64];
    const int z = blockIdx.y, zb = z >> 2, zn = z & 3;
    const int m0 = blockIdx.x * 64;
    const int tid = threadIdx.x;
    const int lane = tid & 63, wid = tid >> 6;
    const int l15 = lane & 15, l4 = lane >> 4;

    const u16* Qg = QKVb + (long)(zb * 256) * 3072 + zn * 256;
    const u16* Kg = Qg + 1024;

    auto stageA64 = [&](const u16* g, long ld) {
#pragma unroll
        for (int p = 0; p < 2; ++p) {
            const int e = p * 2048 + tid * 8;
            const int r = e >> 6, c = e & 63;
            const int sc = c ^ (((r >> 2) & 1) << 4);
            gld16(&As[e], g + (long)r * ld + sc);
        }
    };
    auto stageB256 = [&](const u16* g, long ld) {
#pragma unroll
        for (int p = 0; p < 8; ++p) {
            const int e = p * 2048 + tid * 8;
            const int r = e >> 6, c = e & 63;
            const int sc = c ^ (((r >> 2) & 1) << 4);
            gld16(&Bs[e], g + (long)r * ld + sc);
        }
    };
    auto fragA = [&](int i, int kk) -> bf16x8 {
        const int row = i * 16 + l15, col = kk * 32 + l4 * 8;
        return *(const bf16x8*)&As[row * 64 + (col ^ (((row >> 2) & 1) << 4))];
    };
    auto fragB = [&](int j, int kk) -> bf16x8 {
        const int row = wid * 64 + j * 16 + l15, col = kk * 32 + l4 * 8;
        return *(const bf16x8*)&Bs[row * 64 + (col ^ (((row >> 2) & 1) << 4))];
    };
    auto fragP = [&](int kc, int i, int kk) -> bf16x8 {
        const int row = i * 16 + l15, col = kk * 32 + l4 * 8;
        return *(const bf16x8*)&Pl[kc * 4096 + row * 64 + (col ^ (((row >> 2) & 1) << 4))];
    };

    f32x4 acc1[4][4] = {};
    f32x4 acc2[4][4] = {};

    for (int kc = 0; kc < 4; ++kc) {
        __syncthreads();
        stageA64(Qg + (long)m0 * 3072 + kc * 64, 3072);
        stageB256(Kg + kc * 64, 3072);
        __syncthreads();
#pragma unroll
        for (int i = 0; i < 4; ++i) {
            const bf16x8 a0 = fragA(i, 0), a1 = fragA(i, 1);
#pragma unroll
            for (int j = 0; j < 4; ++j) {
                acc1[i][j] = __builtin_amdgcn_mfma_f32_16x16x32_bf16(a0, fragB(j, 0), acc1[i][j], 0, 0, 0);
                acc1[i][j] = __builtin_amdgcn_mfma_f32_16x16x32_bf16(a1, fragB(j, 1), acc1[i][j], 0, 0, 0);
            }
        }
    }
    for (int kc = 0; kc < 4; ++kc) {
        __syncthreads();
        stageA64(erT + (long)m0 * 256 + kc * 64, 256);
        stageB256(Qg + kc * 64, 3072);
        __syncthreads();
#pragma unroll
        for (int i = 0; i < 4; ++i) {
            const bf16x8 a0 = fragA(i, 0), a1 = fragA(i, 1);
#pragma unroll
            for (int j = 0; j < 4; ++j) {
                acc2[i][j] = __builtin_amdgcn_mfma_f32_16x16x32_bf16(a0, fragB(j, 0), acc2[i][j], 0, 0, 0);
                acc2[i][j] = __builtin_amdgcn_mfma_f32_16x16x32_bf16(a1, fragB(j, 1), acc2[i][j], 0, 0, 0);
            }
        }
    }

    const float inv32 = 1.f / 32.f;
#pragma unroll
    for (int i = 0; i < 4; ++i)
#pragma unroll
        for (int q = 0; q < 4; ++q) {
            const int mg = m0 + i * 16 + l4 * 4 + q;
            const float dw = dwp[zn * 256 + mg];
#pragma unroll
            for (int j = 0; j < 4; ++j) {
                const int ng = wid * 64 + j * 16 + l15;
                acc1[i][j][q] = acc1[i][j][q] * inv32 + acc2[i][j][q]
                              + fabsf((float)(mg - ng)) * 0.5f * dw;
            }
        }

    float rmax[4][4], rsum[4][4];
#pragma unroll
    for (int i = 0; i < 4; ++i)
#pragma unroll
        for (int q = 0; q < 4; ++q) {
            float mv = fmaxf(fmaxf(acc1[i][0][q], acc1[i][1][q]),
                             fmaxf(acc1[i][2][q], acc1[i][3][q]));
#pragma unroll
            for (int off = 1; off <= 8; off <<= 1) mv = fmaxf(mv, __shfl_xor(mv, off, 64));
            rmax[i][q] = mv;
        }
    if (l15 == 0) {
#pragma unroll
        for (int i = 0; i < 4; ++i)
#pragma unroll
            for (int q = 0; q < 4; ++q)
                redM[wid][i * 16 + l4 * 4 + q] = rmax[i][q];
    }
    __syncthreads();
#pragma unroll
    for (int i = 0; i < 4; ++i)
#pragma unroll
        for (int q = 0; q < 4; ++q) {
            const int ml = i * 16 + l4 * 4 + q;
            rmax[i][q] = fmaxf(fmaxf(redM[0][ml], redM[1][ml]), fmaxf(redM[2][ml], redM[3][ml]));
        }
#pragma unroll
    for (int i = 0; i < 4; ++i)
#pragma unroll
        for (int q = 0; q < 4; ++q) {
            float sv = 0.f;
#pragma unroll
            for (int j = 0; j < 4; ++j) {
                const float e = __expf(acc1[i][j][q] - rmax[i][q]);
                acc1[i][j][q] = e;
                sv += e;
            }
#pragma unroll
            for (int off = 1; off <= 8; off <<= 1) sv += __shfl_xor(sv, off, 64);
            rsum[i][q] = sv;
        }
    if (l15 == 0) {
#pragma unroll
        for (int i = 0; i < 4; ++i)
#pragma unroll
            for (int q = 0; q < 4; ++q)
                redS[wid][i * 16 + l4 * 4 + q] = rsum[i][q];
    }
    __syncthreads();
#pragma unroll
    for (int i = 0; i < 4; ++i)
#pragma unroll
        for (int q = 0; q < 4; ++q) {
            const int ml = i * 16 + l4 * 4 + q;
            rsum[i][q] = redS[0][ml] + redS[1][ml] + redS[2][ml] + redS[3][ml];
        }
#pragma unroll
    for (int i = 0; i < 4; ++i)
#pragma unroll
        for (int q = 0; q < 4; ++q) {
            const float rinv = 1.f / rsum[i][q];
            const int ml = i * 16 + l4 * 4 + q;
#pragma unroll
            for (int j = 0; j < 4; ++j) {
                const int nc = j * 16 + l15;
                Pl[wid * 4096 + ml * 64 + (nc ^ (((ml >> 2) & 1) << 4))] = f2bf(acc1[i][j][q] * rinv);
            }
        }
    __syncthreads();

    f32x4 accO[4][4] = {};
    for (int kc = 0; kc < 4; ++kc) {
        __syncthreads();
        stageB256(Vt + (long)(z * 256) * 256 + kc * 64, 256);
        __syncthreads();
#pragma unroll
        for (int i = 0; i < 4; ++i) {
            const bf16x8 a0 = fragP(kc, i, 0), a1 = fragP(kc, i, 1);
#pragma unroll
            for (int j = 0; j < 4; ++j) {
                accO[i][j] = __builtin_amdgcn_mfma_f32_16x16x32_bf16(a0, fragB(j, 0), accO[i][j], 0, 0, 0);
                accO[i][j] = __builtin_amdgcn_mfma_f32_16x16x32_bf16(a1, fragB(j, 1), accO[i][j], 0, 0, 0);
            }
        }
    }

#pragma unroll
    for (int i = 0; i < 4; ++i)
#pragma unroll
        for (int j = 0; j < 4; ++j) {
            const int d = wid * 64 + j * 16 + l15;
#pragma unroll
            for (int q = 0; q < 4; ++q) {
                const int mg = m0 + i * 16 + l4 * 4 + q;
                Oc[(long)(zb * 256 + mg) * 1024 + zn * 256 + d] = f2bf(accO[i][j][q]);
            }
        }
}

// ---------------- GLU gate + residual + LN (bf16 chain, 2 bf16 partials) ----------------
__global__ __launch_bounds__(256)
void glu_ln_k(const u16* __restrict__ xs0, const u16* __restrict__ g2,
              const float* __restrict__ gam, const float* __restrict__ bet,
              u16* __restrict__ outb)
{
    const int t = blockIdx.x, tid = threadIdx.x;
    const int f0 = tid * 4;
    const long PS = 8388608;
    const float4 xv = bf4f(*(const ushort4*)&xs0[(long)t * 1024 + f0]);
    const float4 a0 = bf4f(*(const ushort4*)&g2[(long)t * 2048 + f0]);
    const float4 g0 = bf4f(*(const ushort4*)&g2[(long)t * 2048 + 1024 + f0]);
    const float4 a1 = bf4f(*(const ushort4*)&g2[PS + (long)t * 2048 + f0]);
    const float4 g1 = bf4f(*(const ushort4*)&g2[PS + (long)t * 2048 + 1024 + f0]);
    const float ax = a0.x + a1.x, ay = a0.y + a1.y, az = a0.z + a1.z, aw = a0.w + a1.w;
    const float gx = g0.x + g1.x, gy = g0.y + g1.y, gz = g0.z + g1.z, gw = g0.w + g1.w;
    float vals[4];
    vals[0] = xv.x + ax / (1.f + expf(-gx));
    vals[1] = xv.y + ay / (1.f + expf(-gy));
    vals[2] = xv.z + az / (1.f + expf(-gz));
    vals[3] = xv.w + aw / (1.f + expf(-gw));
    float s1 = vals[0] + vals[1] + vals[2] + vals[3];
    float s2 = vals[0]*vals[0] + vals[1]*vals[1] + vals[2]*vals[2] + vals[3]*vals[3];
    block_red2(s1, s2, tid);
    const float mean = s1 * (1.f / 1024.f);
    const float var  = s2 * (1.f / 1024.f) - mean * mean;
    const float rstd = rsqrtf(var + EPSF);
    const float4 gm = *(const float4*)&gam[f0];
    const float4 bt = *(const float4*)&bet[f0];
    *(ushort4*)&outb[(long)t * 1024 + f0] = f4bf(
        (vals[0] - mean) * rstd * gm.x + bt.x,
        (vals[1] - mean) * rstd * gm.y + bt.y,
        (vals[2] - mean) * rstd * gm.z + bt.z,
        (vals[3] - mean) * rstd * gm.w + bt.w);
}

// ---------------- residual add + LN width 1024 (bf16 chain, P bf16 partials, opt bias) ----------------
template<int P, int BIAS>
__global__ __launch_bounds__(256)
void add_ln1024_k(const u16* __restrict__ A, const u16* __restrict__ Bp,
                  const float* __restrict__ bias,
                  const float* __restrict__ gam, const float* __restrict__ bet,
                  u16* __restrict__ outb)
{
    const int t = blockIdx.x, tid = threadIdx.x;
    const int f0 = tid * 4;
    const long PS = 4194304;
    const float4 a = bf4f(*(const ushort4*)&A[(long)t * 1024 + f0]);
    float4 b = bf4f(*(const ushort4*)&Bp[(long)t * 1024 + f0]);
#pragma unroll
    for (int p = 1; p < P; ++p) {
        const float4 bp = bf4f(*(const ushort4*)&Bp[p * PS + (long)t * 1024 + f0]);
        b.x += bp.x; b.y += bp.y; b.z += bp.z; b.w += bp.w;
    }
    if (BIAS) {
        const float4 bb = *(const float4*)&bias[f0];
        b.x += bb.x; b.y += bb.y; b.z += bb.z; b.w += bb.w;
    }
    float vals[4] = {a.x + b.x, a.y + b.y, a.z + b.z, a.w + b.w};
    float s1 = vals[0] + vals[1] + vals[2] + vals[3];
    float s2 = vals[0]*vals[0] + vals[1]*vals[1] + vals[2]*vals[2] + vals[3]*vals[3];
    block_red2(s1, s2, tid);
    const float mean = s1 * (1.f / 1024.f);
    const float var  = s2 * (1.f / 1024.f) - mean * mean;
    const float rstd = rsqrtf(var + EPSF);
    const float4 gm = *(const float4*)&gam[f0];
    const float4 bt = *(const float4*)&bet[f0];
    *(ushort4*)&outb[(long)t * 1024 + f0] = f4bf(
        (vals[0] - mean) * rstd * gm.x + bt.x,
        (vals[1] - mean) * rstd * gm.y + bt.y,
        (vals[2] - mean) * rstd * gm.z + bt.z,
        (vals[3] - mean) * rstd * gm.w + bt.w);
}

// ---------------- n2: LN(c1L(bf16) + pad(relu(sum of 3 bf16 conv taps))) width 4096 ----------------
__global__ __launch_bounds__(256)
void add_ln4096_k(const u16* __restrict__ A, const u16* __restrict__ Bp,
                  const float* __restrict__ gam, const float* __restrict__ bet,
                  u16* __restrict__ outb)
{
    const int t = blockIdx.x, tid = threadIdx.x;
    const long PS = 4194304;
    const int f0 = tid * 16;
    float vals[16];
    const bf16x8 a0 = *(const bf16x8*)&A[(long)t * 4096 + f0];
    const bf16x8 a1 = *(const bf16x8*)&A[(long)t * 4096 + f0 + 8];
#pragma unroll
    for (int e = 0; e < 8; ++e) { vals[e] = bf2f((u16)a0[e]); vals[8 + e] = bf2f((u16)a1[e]); }
    if (tid < 64) {
#pragma unroll
        for (int c = 0; c < 4; ++c) {
            const int fc = f0 + c * 4;
            const float4 b0 = bf4f(*(const ushort4*)&Bp[(long)t * 1024 + fc]);
            const float4 b1 = bf4f(*(const ushort4*)&Bp[PS + (long)t * 1024 + fc]);
            const float4 b2 = bf4f(*(const ushort4*)&Bp[2 * PS + (long)t * 1024 + fc]);
            vals[c*4+0] += fmaxf(b0.x + b1.x + b2.x, 0.f);
            vals[c*4+1] += fmaxf(b0.y + b1.y + b2.y, 0.f);
            vals[c*4+2] += fmaxf(b0.z + b1.z + b2.z, 0.f);
            vals[c*4+3] += fmaxf(b0.w + b1.w + b2.w, 0.f);
        }
    }
    float s1 = 0.f, s2 = 0.f;
#pragma unroll
    for (int e = 0; e < 16; ++e) { s1 += vals[e]; s2 += vals[e] * vals[e]; }
    block_red2(s1, s2, tid);
    const float mean = s1 * (1.f / 4096.f);
    const float var  = s2 * (1.f / 4096.f) - mean * mean;
    const float rstd = rsqrtf(var + EPSF);
#pragma unroll
    for (int c = 0; c < 4; ++c) {
        const int fc = f0 + c * 4;
        const float4 gm = *(const float4*)&gam[fc];
        const float4 bt = *(const float4*)&bet[fc];
        *(ushort4*)&outb[(long)t * 4096 + fc] = f4bf(
            (vals[c*4+0] - mean) * rstd * gm.x + bt.x,
            (vals[c*4+1] - mean) * rstd * gm.y + bt.y,
            (vals[c*4+2] - mean) * rstd * gm.z + bt.z,
            (vals[c*4+3] - mean) * rstd * gm.w + bt.w);
    }
}

// ---------------- depthwise conv width-9, 8 channels/thread ----------------
__global__ __launch_bounds__(256)
void dwconv8_k(const u16* __restrict__ h, const float* __restrict__ wT,
               u16* __restrict__ out)
{
    const long idx = (long)blockIdx.x * 256 + threadIdx.x;
    const int cg = (int)(idx & 511);
    const int t  = (int)(idx >> 9);
    const int w  = t & 255;
    const int c0 = cg * 8;
    float acc[8] = {};
#pragma unroll
    for (int k = 0; k < 9; ++k) {
        const int wp = w + k - 4;
        if ((unsigned)wp < 256u) {
            const bf16x8 hv = *(const bf16x8*)&h[(long)(t + k - 4) * 4096 + c0];
            const float4 w0 = *(const float4*)&wT[k * 4096 + c0];
            const float4 w1 = *(const float4*)&wT[k * 4096 + c0 + 4];
            acc[0] += bf2f((u16)hv[0]) * w0.x;
            acc[1] += bf2f((u16)hv[1]) * w0.y;
            acc[2] += bf2f((u16)hv[2]) * w0.z;
            acc[3] += bf2f((u16)hv[3]) * w0.w;
            acc[4] += bf2f((u16)hv[4]) * w1.x;
            acc[5] += bf2f((u16)hv[5]) * w1.y;
            acc[6] += bf2f((u16)hv[6]) * w1.z;
            acc[7] += bf2f((u16)hv[7]) * w1.w;
        }
    }
    bf16x8 res;
#pragma unroll
    for (int j = 0; j < 8; ++j) res[j] = (short)f2bf(acc[j]);
    *(bf16x8*)&out[(long)t * 4096 + c0] = res;
}

// ---------------- V slice of QKVb -> Vt (z, d, w) bf16 ----------------
__global__ __launch_bounds__(256)
void vtrans_k(const u16* __restrict__ QKVb, u16* __restrict__ Vt)
{
    __shared__ u16 t[32][33];
    const int z = blockIdx.z, zb = z >> 2, zn = z & 3;
    const int w0 = blockIdx.x * 32, d0 = blockIdx.y * 32;
    const int tid = threadIdx.x, c = tid & 31, r = tid >> 5;
#pragma unroll
    for (int it = 0; it < 4; ++it) {
        const int wl = r + it * 8;
        t[wl][c] = QKVb[(long)(zb * 256 + w0 + wl) * 3072 + 2048 + zn * 256 + d0 + c];
    }
    __syncthreads();
#pragma unroll
    for (int it = 0; it < 4; ++it) {
        const int dl = r + it * 8;
        Vt[((long)z * 256 + d0 + dl) * 256 + w0 + c] = t[c][dl];
    }
}

// ---------------- final transpose: bf16 (tokens,1024) -> f32 (B,1,1024,256) ----------------
__global__ __launch_bounds__(256)
void transpose_out_k(const u16* __restrict__ xs, float* __restrict__ out)
{
    __shared__ u16 tile[32][34];
    const int b = blockIdx.z, f0 = blockIdx.y * 32, w0 = blockIdx.x * 32;
    const int tid = threadIdx.x, c = tid & 31, r = tid >> 5;
#pragma unroll
    for (int it = 0; it < 4; ++it) {
        const int w = w0 + r + it * 8;
        tile[r + it * 8][c] = xs[((long)b * 256 + w) * 1024 + f0 + c];
    }
    __syncthreads();
#pragma unroll
    for (int it = 0; it < 4; ++it) {
        const int fl = r + it * 8;
        out[((long)b * 1024 + f0 + fl) * 256 + w0 + c] = bf2f(tile[c][fl]);
    }
}

// =======================================================================
extern "C" void kernel_launch(void* const* d_in, const int* in_sizes, int n_in,
                              void* d_out, int out_size, void* d_ws, size_t ws_size,
                              hipStream_t stream)
{
    const float* x      = (const float*)d_in[0];
    const float* bott_w = (const float*)d_in[1];
    const float* bn_g   = (const float*)d_in[2];
    const float* bn_b   = (const float*)d_in[3];
    const float* bn_m   = (const float*)d_in[4];
    const float* bn_v   = (const float*)d_in[5];
    const float* glu_w  = (const float*)d_in[6];
    const float* n1g    = (const float*)d_in[7];
    const float* n1b    = (const float*)d_in[8];
    const float* c1L_w  = (const float*)d_in[9];
    const float* c1R_w  = (const float*)d_in[10];
    const float* n2g    = (const float*)d_in[11];
    const float* n2b    = (const float*)d_in[12];
    const float* c2dw_w = (const float*)d_in[13];
    const float* c2pw_w = (const float*)d_in[14];
    const float* n3g    = (const float*)d_in[15];
    const float* n3b    = (const float*)d_in[16];
    const float* qw     = (const float*)d_in[17];
    const float* qb     = (const float*)d_in[18];
    const float* kw     = (const float*)d_in[19];
    const float* kb     = (const float*)d_in[20];
    const float* vw     = (const float*)d_in[21];
    const float* vb     = (const float*)d_in[22];
    const float* ow     = (const float*)d_in[23];
    const float* ob     = (const float*)d_in[24];
    const float* er     = (const float*)d_in[25];
    const float* dist_w = (const float*)d_in[26];
    const float* n4g    = (const float*)d_in[27];
    const float* n4b    = (const float*)d_in[28];
    const float* c3_w   = (const float*)d_in[29];
    const float* c4_w   = (const float*)d_in[30];
    const float* n5g    = (const float*)d_in[31];
    const float* n5b    = (const float*)d_in[32];
    float* out = (float*)d_out;

    // ---- workspace layout (MiB offsets, bf16 residual chain) ----
    char* Wb_ = (char*)d_ws;
    auto Bf = [&](size_t mib) { return (u16*)(Wb_ + (mib << 20)); };
    u16* XA   = Bf(0);    // xs0 (1-3), xs2 (9-13), xs4 (16-17)  [8 MB]
    u16* XB   = Bf(8);    // xs1 (3-9), xs3 (13-16)              [8 MB]
    u16* H0b  = Bf(32);   // c1L out (4-6) / c3 out (14-15)      [32 MB]
    u16* Hglu = Bf(64);   // GLU 2 bf16 partials (2-3)
    u16* C3p  = Bf(64);   // conv3 3 bf16 partials (5-6)
    u16* P4   = Bf(64);   // c2pw/O-proj/c4 4 bf16 partials
    u16* H1b  = Bf(128);  // n2 out (6-7)
    u16* Hdw  = Bf(160);  // dwconv out (7-8)
    u16* QKVb = Bf(192);  // QKV out 4096x3072 (10-11)
    u16* Vt   = Bf(216);  // V transposed (10b-11)
    u16* S1b  = Bf(264);  // attn concat out (11-12)
    u16* wGLU = Bf(296); u16* wC1L = Bf(300); u16* wC1R = Bf(308);
    u16* wC2P = Bf(314); u16* wQKV = Bf(322); u16* wO   = Bf(328);
    u16* wC3  = Bf(330); u16* wC4  = Bf(338);
    u16* erT  = Bf(346);
    u16* zp   = (u16*)(Wb_ + (346u << 20) + 131072);
    float* wdwT = (float*)(Wb_ + (346u << 20) + 131072 + 16384);
    float* bQKV = (float*)(Wb_ + (346u << 20) + 131072 + 16384 + 147456);

    const dim3 blk(256);
    const dim3 blk8(512);
    const long PS1 = 4194304;   // 4096*1024 elements
    const size_t SH8 = 131072;  // 128 KiB dynamic LDS

    // 0. merged setup (one launch)
    SetupArgs sa;
    sa.ws[0] = glu_w;  sa.wd[0] = wGLU;            sa.wn[0] = 524288;
    sa.ws[1] = c1L_w;  sa.wd[1] = wC1L;            sa.wn[1] = 1048576;
    sa.ws[2] = c2pw_w; sa.wd[2] = wC2P;            sa.wn[2] = 1048576;
    sa.ws[3] = c3_w;   sa.wd[3] = wC3;             sa.wn[3] = 1048576;
    sa.ws[4] = c4_w;   sa.wd[4] = wC4;             sa.wn[4] = 1048576;
    sa.ws[5] = qw;     sa.wd[5] = wQKV;            sa.wn[5] = 262144;
    sa.ws[6] = kw;     sa.wd[6] = wQKV + 1048576;  sa.wn[6] = 262144;
    sa.ws[7] = vw;     sa.wd[7] = wQKV + 2097152;  sa.wn[7] = 262144;
    sa.ws[8] = ow;     sa.wd[8] = wO;              sa.wn[8] = 262144;
    sa.c1r = c1R_w; sa.c1rd = wC1R;
    sa.er  = er;    sa.erd  = erT;
    sa.dw  = c2dw_w; sa.dwd = wdwT;
    sa.qb = qb; sa.kb = kb; sa.vb = vb; sa.bcat = bQKV;
    sa.zp = zp;
    {
        int bc[14] = {2048, 4096, 4096, 4096, 4096, 1024, 1024, 1024, 1024,
                      12288, 256, 144, 12, 32};
        int acc = 0;
        for (int s = 0; s < 14; ++s) { sa.off[s] = acc; acc += bc[s]; }
        sa.off[14] = acc;
        setup_k<<<dim3(acc), blk, 0, stream>>>(sa);
    }

    // 1. bottleneck + BN + ReLU + transpose -> XA (xs0, bf16)
    bottleneck_k<<<dim3(8, 32, 16), blk, 0, stream>>>(x, bott_w, bn_g, bn_b, bn_m, bn_v, XA);

    // 2. GLU matmul, split-K=2 -> Hglu bf16 partials
    gemm8_k<0,0,0,2><<<dim3(8, 16, 2), blk8, SH8, stream>>>(XA, wGLU, nullptr, Hglu,
        2048, 512, 1024, 1024, (long)4096 * 2048);

    // 3. n1: LN(xs0 + a*sigmoid(g)) -> XB (xs1)
    glu_ln_k<<<dim3(4096), blk, 0, stream>>>(XA, Hglu, n1g, n1b, XB);

    // 4. c1L: relu -> H0b bf16 (4096x4096)
    gemm8_k<1,1,0,1><<<dim3(16, 16, 1), blk8, SH8, stream>>>(XB, wC1L, nullptr, H0b,
        4096, 1024, 1024, 1024, 0);

    // 5. c1R conv: 3 tap-slices -> C3p bf16 partials
    conv38_k<<<dim3(4, 16, 3), blk8, SH8, stream>>>(XB, wC1R, zp, C3p);

    // 6. n2: LN(H0b + pad(relu(sum taps))) -> H1b bf16
    add_ln4096_k<<<dim3(4096), blk, 0, stream>>>(H0b, C3p, n2g, n2b, H1b);

    // 7. depthwise conv9 (vectorized x8): H1b -> Hdw
    dwconv8_k<<<dim3(8192), blk, 0, stream>>>(H1b, wdwT, Hdw);

    // 8. c2pw, split-K=4 -> P4 bf16 partials
    gemm8_k<0,0,0,4><<<dim3(4, 16, 4), blk8, SH8, stream>>>(Hdw, wC2P, nullptr, P4,
        1024, 1024, 4096, 4096, PS1);

    // 9. n3: LN(xs1 + sum P4) -> XA (xs2)
    add_ln1024_k<4,0><<<dim3(4096), blk, 0, stream>>>(XB, P4, nullptr, n3g, n3b, XA);

    // 10. fused QKV projection (+concat bias) -> QKVb bf16 (4096x3072)
    gemm8_k<0,1,1,1><<<dim3(12, 16, 1), blk8, SH8, stream>>>(XA, wQKV, bQKV, QKVb,
        3072, 1024, 1024, 1024, 0);

    // 10b. V transpose per head -> Vt (z, d, w)
    vtrans_k<<<dim3(8, 8, 64), blk, 0, stream>>>(QKVb, Vt);

    // 11. fused attention: scores + softmax + PV -> S1b (concat layout)
    attn_fused_k<<<dim3(4, 64), blk, 0, stream>>>(QKVb, erT, Vt, dist_w, S1b);

    // 12. output projection, split-K=4 -> P4 bf16 partials (bias added in n4)
    gemm8_k<0,0,0,4><<<dim3(4, 16, 4), blk8, SH8, stream>>>(S1b, wO, nullptr, P4,
        1024, 256, 1024, 1024, PS1);

    // 13. n4: LN(xs2 + sum P4 + ob) -> XB (xs3)
    add_ln1024_k<4,1><<<dim3(4096), blk, 0, stream>>>(XA, P4, ob, n4g, n4b, XB);

    // 14. c3: relu -> H0b bf16
    gemm8_k<1,1,0,1><<<dim3(16, 16, 1), blk8, SH8, stream>>>(XB, wC3, nullptr, H0b,
        4096, 1024, 1024, 1024, 0);

    // 15. c4, split-K=4 -> P4 bf16 partials
    gemm8_k<0,0,0,4><<<dim3(4, 16, 4), blk8, SH8, stream>>>(H0b, wC4, nullptr, P4,
        1024, 1024, 4096, 4096, PS1);

    // 16. n5: LN(xs3 + sum P4) -> XA (xs4, bf16)
    add_ln1024_k<4,0><<<dim3(4096), blk, 0, stream>>>(XB, P4, nullptr, n5g, n5b, XA);

    // 17. transpose to (B, 1, 1024, 256) f32
    transpose_out_k<<<dim3(8, 32, 16), blk, 0, stream>>>(XA, out);

    (void)in_sizes; (void)n_in; (void)out_size; (void)ws_size;
}

// Round 9
// 486.836 us; speedup vs baseline: 7.1704x; 1.0197x over previous
//
#include <hip/hip_runtime.h>
#include <hip/hip_bf16.h>

// FrameTransformer: B=16, C=8, BINS=1024, W=256, FF=2048, NB=4
// tokens = B*W = 4096, feature width 1024, FF width 4096, head dim 256.
#define EPSF 1e-5f

typedef unsigned short u16;
typedef unsigned int   u32;
typedef __attribute__((ext_vector_type(8))) short bf16x8;
typedef __attribute__((ext_vector_type(4))) float f32x4;

__device__ __forceinline__ u16 f2bf(float f) {
    u32 u = __builtin_bit_cast(u32, f);
    u32 r = u + 0x7fffu + ((u >> 16) & 1u);
    return (u16)(r >> 16);
}
__device__ __forceinline__ float bf2f(u16 h) {
    return __builtin_bit_cast(float, (u32)h << 16);
}
__device__ __forceinline__ float4 bf4f(ushort4 v) {
    return make_float4(bf2f(v.x), bf2f(v.y), bf2f(v.z), bf2f(v.w));
}
__device__ __forceinline__ ushort4 f4bf(float a, float b, float c, float d) {
    ushort4 o; o.x = f2bf(a); o.y = f2bf(b); o.z = f2bf(c); o.w = f2bf(d); return o;
}
__device__ __forceinline__ void gld16(void* lds, const void* gsrc) {
    __builtin_amdgcn_global_load_lds(
        (const __attribute__((address_space(1))) u32*)gsrc,
        (__attribute__((address_space(3))) u32*)lds, 16, 0, 0);
}

__device__ __forceinline__ float wred_sum(float v) {
#pragma unroll
    for (int off = 32; off; off >>= 1) v += __shfl_xor(v, off, 64);
    return v;
}
__device__ __forceinline__ void block_red2(float& s1, float& s2, int tid) {
    __shared__ float red[8];
    s1 = wred_sum(s1); s2 = wred_sum(s2);
    const int lane = tid & 63, wid = tid >> 6;
    if (!lane) { red[wid] = s1; red[4 + wid] = s2; }
    __syncthreads();
    s1 = red[0] + red[1] + red[2] + red[3];
    s2 = red[4] + red[5] + red[6] + red[7];
}

// ---------------- merged setup: all weight conversions in one launch ----------------
// NOTE: kw (seg 6) and kb (bias middle third) are pre-scaled by 1/32 so the
// attention score GEMM needs no epilogue scale (skew fold, K=512 concat).
struct SetupArgs {
    const float* ws[9]; u16* wd[9]; int wn[9];
    const float* c1r; u16* c1rd;
    const float* er;  u16* erd;
    const float* dw;  float* dwd;
    const float* qb;  const float* kb; const float* vb; float* bcat;
    u16* zp;
    int off[15];
};
__global__ __launch_bounds__(256)
void setup_k(SetupArgs a)
{
    const int b = blockIdx.x;
    int seg = 0;
    while (seg < 13 && b >= a.off[seg + 1]) ++seg;
    const int i = (b - a.off[seg]) * 256 + threadIdx.x;
    if (seg < 9) {
        if (i < a.wn[seg]) {
            const float4 v = ((const float4*)a.ws[seg])[i];
            const float s = (seg == 6) ? 0.03125f : 1.f;
            ((ushort4*)a.wd[seg])[i] = f4bf(v.x * s, v.y * s, v.z * s, v.w * s);
        }
    } else if (seg == 9) {
        if (i < 3145728) {
            const int q = i / 3072, rem = i - q * 3072;
            const int ks = rem >> 10, ci = rem & 1023;
            a.c1rd[i] = f2bf(a.c1r[((long)q * 1024 + ci) * 3 + ks]);
        }
    } else if (seg == 10) {
        if (i < 65536) { const int c = i >> 8, d = i & 255; a.erd[i] = f2bf(a.er[d * 256 + c]); }
    } else if (seg == 11) {
        if (i < 36864) { const int k = i >> 12, c = i & 4095; a.dwd[i] = a.dw[c * 9 + k]; }
    } else if (seg == 12) {
        if (i < 3072) {
            const float* s = (i < 1024) ? a.qb : ((i < 2048) ? a.kb : a.vb);
            float v = s[i & 1023];
            if (i >= 1024 && i < 2048) v *= 0.03125f;
            a.bcat[i] = v;
        }
    } else {
        if (i < 8192) a.zp[i] = 0;
    }
}

// ---------------- stage 1: bottleneck 1x1 conv + BN + ReLU + transpose (bf16 out) ----------------
__global__ __launch_bounds__(256)
void bottleneck_k(const float* __restrict__ x, const float* __restrict__ bw,
                  const float* __restrict__ bn_g, const float* __restrict__ bn_b,
                  const float* __restrict__ bn_m, const float* __restrict__ bn_v,
                  u16* __restrict__ xsb)
{
    __shared__ float tile[32][33];
    const int b = blockIdx.z, h0 = blockIdx.y * 32, w0 = blockIdx.x * 32;
    const int tid = threadIdx.x, c = tid & 31, r = tid >> 5;
    float wreg[8];
#pragma unroll
    for (int ch = 0; ch < 8; ++ch) wreg[ch] = bw[ch];
    const float sc = bn_g[0] * rsqrtf(bn_v[0] + EPSF);
    const float sh = bn_b[0] - bn_m[0] * sc;
#pragma unroll
    for (int it = 0; it < 4; ++it) {
        const int h = h0 + r + it * 8;
        const int w = w0 + c;
        float acc = 0.f;
#pragma unroll
        for (int ch = 0; ch < 8; ++ch)
            acc += x[(((long)b * 8 + ch) * 1024 + h) * 256 + w] * wreg[ch];
        tile[r + it * 8][c] = fmaxf(acc * sc + sh, 0.f);
    }
    __syncthreads();
#pragma unroll
    for (int it = 0; it < 4; ++it) {
        const int wl = r + it * 8;
        xsb[((long)b * 256 + w0 + wl) * 1024 + h0 + c] = f2bf(tile[c][wl]);
    }
}

// ============ 8-phase 256x256 bf16 MFMA GEMM (T2+T3+T4+T5) ============
template<int ACT, int OUTBF, int BIAS, int SPLITK>
__global__ __launch_bounds__(512, 2)
void gemm8_k(const u16* __restrict__ A, const u16* __restrict__ B,
             const float* __restrict__ bias, void* __restrict__ Cout,
             int N, int K /*per slice*/, int lda, int ldb, long partStride)
{
    extern __shared__ u16 lds[];
    const int m0 = blockIdx.y * 256, n0 = blockIdx.x * 256;
    const int koff = (SPLITK > 1) ? blockIdx.z * K : 0;
    const int nt = K >> 6;
    const int tid = threadIdx.x;
    const int lane = tid & 63, wid = tid >> 6;
    const int wr = ((wid >> 2) & 1) * 128;
    const int wc = (wid & 3) * 64;
    const int l15 = lane & 15, l4 = lane >> 4;

    const u16* Ag = A + (long)m0 * lda + koff;
    const u16* Bg = B + (long)n0 * ldb + koff;

    auto stage = [&](const u16* g, int ld, int ldsbase, int kcol, int h) {
#pragma unroll
        for (int is = 0; is < 2; ++is) {
            const int r = h * 128 + is * 64 + (tid >> 3);
            const int sc = ((tid & 7) * 8) ^ (((r >> 2) & 1) << 4);
            gld16(&lds[ldsbase + h * 8192 + is * 4096 + tid * 8],
                  g + (long)r * ld + kcol + sc);
        }
    };
    auto frag = [&](int base, int row, int col) -> bf16x8 {
        return *(const bf16x8*)&lds[base + row * 64 + (col ^ (((row >> 2) & 1) << 4))];
    };

    f32x4 acc[8][4] = {};

    stage(Ag, lda, 0, 0, 0);
    stage(Ag, lda, 0, 0, 1);
    stage(Bg, ldb, 32768, 0, 0);
    stage(Bg, ldb, 32768, 0, 1);
    if (nt > 1) {
        stage(Bg, ldb, 49152, 64, 0);
        stage(Bg, ldb, 49152, 64, 1);
        stage(Ag, lda, 16384, 64, 0);
        asm volatile("s_waitcnt vmcnt(6)" ::: "memory");
    } else {
        asm volatile("s_waitcnt vmcnt(0)" ::: "memory");
    }
    __builtin_amdgcn_s_barrier();

    for (int kt = 0; kt < nt; ++kt) {
        const int cs = kt & 1;
        const int ab = cs * 16384;
        const int bb = 32768 + cs * 16384;
        const int abn = (cs ^ 1) * 16384;
        const int kc1 = (kt + 1) * 64, kc2 = (kt + 2) * 64;
        bf16x8 alo[4][2], ahi[4][2], b01[2][2], b23[2][2];

#pragma unroll
        for (int i = 0; i < 4; ++i)
#pragma unroll
            for (int kk = 0; kk < 2; ++kk)
                alo[i][kk] = frag(ab, wr + i * 16 + l15, kk * 32 + l4 * 8);
#pragma unroll
        for (int j = 0; j < 2; ++j)
#pragma unroll
            for (int kk = 0; kk < 2; ++kk)
                b01[j][kk] = frag(bb, wc + j * 16 + l15, kk * 32 + l4 * 8);
        if (kt + 1 < nt) stage(Ag, lda, abn, kc1, 1);
        __builtin_amdgcn_s_barrier();
        asm volatile("s_waitcnt lgkmcnt(0)" ::: "memory");
        __builtin_amdgcn_s_setprio(1);
#pragma unroll
        for (int i = 0; i < 4; ++i)
#pragma unroll
            for (int j = 0; j < 2; ++j)
#pragma unroll
                for (int kk = 0; kk < 2; ++kk)
                    acc[i][j] = __builtin_amdgcn_mfma_f32_16x16x32_bf16(alo[i][kk], b01[j][kk], acc[i][j], 0, 0, 0);
        __builtin_amdgcn_s_setprio(0);
        __builtin_amdgcn_s_barrier();

#pragma unroll
        for (int j = 0; j < 2; ++j)
#pragma unroll
            for (int kk = 0; kk < 2; ++kk)
                b23[j][kk] = frag(bb, wc + (j + 2) * 16 + l15, kk * 32 + l4 * 8);
        if (kt + 2 < nt) stage(Bg, ldb, bb, kc2, 0);
        __builtin_amdgcn_s_barrier();
        asm volatile("s_waitcnt lgkmcnt(0)" ::: "memory");
        __builtin_amdgcn_s_setprio(1);
#pragma unroll
        for (int i = 0; i < 4; ++i)
#pragma unroll
            for (int j = 0; j < 2; ++j)
#pragma unroll
                for (int kk = 0; kk < 2; ++kk)
                    acc[i][j + 2] = __builtin_amdgcn_mfma_f32_16x16x32_bf16(alo[i][kk], b23[j][kk], acc[i][j + 2], 0, 0, 0);
        __builtin_amdgcn_s_setprio(0);
        __builtin_amdgcn_s_barrier();

#pragma unroll
        for (int i = 0; i < 4; ++i)
#pragma unroll
            for (int kk = 0; kk < 2; ++kk)
                ahi[i][kk] = frag(ab, wr + (i + 4) * 16 + l15, kk * 32 + l4 * 8);
        if (kt + 2 < nt) stage(Bg, ldb, bb, kc2, 1);
        __builtin_amdgcn_s_barrier();
        asm volatile("s_waitcnt lgkmcnt(0)" ::: "memory");
        __builtin_amdgcn_s_setprio(1);
#pragma unroll
        for (int i = 0; i < 4; ++i)
#pragma unroll
            for (int j = 0; j < 2; ++j)
#pragma unroll
                for (int kk = 0; kk < 2; ++kk)
                    acc[i + 4][j + 2] = __builtin_amdgcn_mfma_f32_16x16x32_bf16(ahi[i][kk], b23[j][kk], acc[i + 4][j + 2], 0, 0, 0);
        __builtin_amdgcn_s_setprio(0);
        __builtin_amdgcn_s_barrier();

        if (kt + 2 < nt) stage(Ag, lda, ab, kc2, 0);
        __builtin_amdgcn_s_barrier();
        __builtin_amdgcn_s_setprio(1);
#pragma unroll
        for (int i = 0; i < 4; ++i)
#pragma unroll
            for (int j = 0; j < 2; ++j)
#pragma unroll
                for (int kk = 0; kk < 2; ++kk)
                    acc[i + 4][j] = __builtin_amdgcn_mfma_f32_16x16x32_bf16(ahi[i][kk], b01[j][kk], acc[i + 4][j], 0, 0, 0);
        __builtin_amdgcn_s_setprio(0);
        if (kt + 2 < nt) {
            asm volatile("s_waitcnt vmcnt(6)" ::: "memory");
        } else {
            asm volatile("s_waitcnt vmcnt(0)" ::: "memory");
        }
        __builtin_amdgcn_s_barrier();
    }

    if (SPLITK > 1) {
        u16* Cp = (u16*)Cout + (long)blockIdx.z * partStride;
#pragma unroll
        for (int i = 0; i < 8; ++i)
#pragma unroll
            for (int j = 0; j < 4; ++j) {
                const int n = n0 + wc + j * 16 + l15;
#pragma unroll
                for (int q = 0; q < 4; ++q) {
                    const int m = m0 + wr + i * 16 + l4 * 4 + q;
                    Cp[(long)m * N + n] = f2bf(acc[i][j][q]);
                }
            }
    } else {
        float* Cf = (float*)Cout;
        u16*   Cb = (u16*)Cout;
#pragma unroll
        for (int i = 0; i < 8; ++i)
#pragma unroll
            for (int j = 0; j < 4; ++j) {
                const int n = n0 + wc + j * 16 + l15;
                const float bv = BIAS ? bias[n] : 0.f;
#pragma unroll
                for (int q = 0; q < 4; ++q) {
                    const int m = m0 + wr + i * 16 + l4 * 4 + q;
                    float v = acc[i][j][q] + bv;
                    if (ACT) v = fmaxf(v, 0.f);
                    if (OUTBF) Cb[(long)m * N + n] = f2bf(v);
                    else       Cf[(long)m * N + n] = v;
                }
            }
    }
}

// ============ merged c1L + conv1R launch (8-phase body, K=1024, nt=16) ============
// blockIdx.x < 16: c1L N-tile (relu, out H0b N=4096).
// blockIdx.x >= 16: conv tap = (x-16)/4, ncol = (x-16)&3; shifted-A, raw bf16
// partial out to C3p + tap*4M. shift=0 for the GEMM role (OOB check never fires).
__global__ __launch_bounds__(512, 2)
void ffconv8_k(const u16* __restrict__ Xb, const u16* __restrict__ Wl,
               const u16* __restrict__ Wr, const u16* __restrict__ zp,
               u16* __restrict__ Hout, u16* __restrict__ Cp3)
{
    extern __shared__ u16 lds[];
    const int bx = blockIdx.x;
    const int m0 = blockIdx.y * 256;
    const bool conv = bx >= 16;
    const int tap  = conv ? ((bx - 16) >> 2) : 0;
    const int shift = conv ? (tap - 1) : 0;
    const int n0 = conv ? (((bx - 16) & 3) * 256) : (bx * 256);
    const u16* Bbase = conv ? (Wr + (long)n0 * 3072 + tap * 1024)
                            : (Wl + (long)n0 * 1024);
    const int ldb = conv ? 3072 : 1024;
    const int nt = 16;
    const int tid = threadIdx.x;
    const int lane = tid & 63, wid = tid >> 6;
    const int wr = ((wid >> 2) & 1) * 128;
    const int wc = (wid & 3) * 64;
    const int l15 = lane & 15, l4 = lane >> 4;

    auto stageA = [&](int ldsbase, int kcol, int h) {
#pragma unroll
        for (int is = 0; is < 2; ++is) {
            const int r = h * 128 + is * 64 + (tid >> 3);
            const int sc = ((tid & 7) * 8) ^ (((r >> 2) & 1) << 4);
            const int t = m0 + r;
            const int wp = (t & 255) + shift;
            const u16* src = ((unsigned)wp < 256u)
                ? Xb + (long)(t + shift) * 1024 + kcol + sc
                : zp;
            gld16(&lds[ldsbase + h * 8192 + is * 4096 + tid * 8], src);
        }
    };
    auto stageB = [&](int ldsbase, int kcol, int h) {
#pragma unroll
        for (int is = 0; is < 2; ++is) {
            const int r = h * 128 + is * 64 + (tid >> 3);
            const int sc = ((tid & 7) * 8) ^ (((r >> 2) & 1) << 4);
            gld16(&lds[ldsbase + h * 8192 + is * 4096 + tid * 8],
                  Bbase + (long)r * ldb + kcol + sc);
        }
    };
    auto frag = [&](int base, int row, int col) -> bf16x8 {
        return *(const bf16x8*)&lds[base + row * 64 + (col ^ (((row >> 2) & 1) << 4))];
    };

    f32x4 acc[8][4] = {};

    stageA(0, 0, 0);
    stageA(0, 0, 1);
    stageB(32768, 0, 0);
    stageB(32768, 0, 1);
    stageB(49152, 64, 0);
    stageB(49152, 64, 1);
    stageA(16384, 64, 0);
    asm volatile("s_waitcnt vmcnt(6)" ::: "memory");
    __builtin_amdgcn_s_barrier();

    for (int kt = 0; kt < nt; ++kt) {
        const int cs = kt & 1;
        const int ab = cs * 16384;
        const int bb = 32768 + cs * 16384;
        const int abn = (cs ^ 1) * 16384;
        const int kc1 = (kt + 1) * 64, kc2 = (kt + 2) * 64;
        bf16x8 alo[4][2], ahi[4][2], b01[2][2], b23[2][2];

#pragma unroll
        for (int i = 0; i < 4; ++i)
#pragma unroll
            for (int kk = 0; kk < 2; ++kk)
                alo[i][kk] = frag(ab, wr + i * 16 + l15, kk * 32 + l4 * 8);
#pragma unroll
        for (int j = 0; j < 2; ++j)
#pragma unroll
            for (int kk = 0; kk < 2; ++kk)
                b01[j][kk] = frag(bb, wc + j * 16 + l15, kk * 32 + l4 * 8);
        if (kt + 1 < nt) stageA(abn, kc1, 1);
        __builtin_amdgcn_s_barrier();
        asm volatile("s_waitcnt lgkmcnt(0)" ::: "memory");
        __builtin_amdgcn_s_setprio(1);
#pragma unroll
        for (int i = 0; i < 4; ++i)
#pragma unroll
            for (int j = 0; j < 2; ++j)
#pragma unroll
                for (int kk = 0; kk < 2; ++kk)
                    acc[i][j] = __builtin_amdgcn_mfma_f32_16x16x32_bf16(alo[i][kk], b01[j][kk], acc[i][j], 0, 0, 0);
        __builtin_amdgcn_s_setprio(0);
        __builtin_amdgcn_s_barrier();

#pragma unroll
        for (int j = 0; j < 2; ++j)
#pragma unroll
            for (int kk = 0; kk < 2; ++kk)
                b23[j][kk] = frag(bb, wc + (j + 2) * 16 + l15, kk * 32 + l4 * 8);
        if (kt + 2 < nt) stageB(bb, kc2, 0);
        __builtin_amdgcn_s_barrier();
        asm volatile("s_waitcnt lgkmcnt(0)" ::: "memory");
        __builtin_amdgcn_s_setprio(1);
#pragma unroll
        for (int i = 0; i < 4; ++i)
#pragma unroll
            for (int j = 0; j < 2; ++j)
#pragma unroll
                for (int kk = 0; kk < 2; ++kk)
                    acc[i][j + 2] = __builtin_amdgcn_mfma_f32_16x16x32_bf16(alo[i][kk], b23[j][kk], acc[i][j + 2], 0, 0, 0);
        __builtin_amdgcn_s_setprio(0);
        __builtin_amdgcn_s_barrier();

#pragma unroll
        for (int i = 0; i < 4; ++i)
#pragma unroll
            for (int kk = 0; kk < 2; ++kk)
                ahi[i][kk] = frag(ab, wr + (i + 4) * 16 + l15, kk * 32 + l4 * 8);
        if (kt + 2 < nt) stageB(bb, kc2, 1);
        __builtin_amdgcn_s_barrier();
        asm volatile("s_waitcnt lgkmcnt(0)" ::: "memory");
        __builtin_amdgcn_s_setprio(1);
#pragma unroll
        for (int i = 0; i < 4; ++i)
#pragma unroll
            for (int j = 0; j < 2; ++j)
#pragma unroll
                for (int kk = 0; kk < 2; ++kk)
                    acc[i + 4][j + 2] = __builtin_amdgcn_mfma_f32_16x16x32_bf16(ahi[i][kk], b23[j][kk], acc[i + 4][j + 2], 0, 0, 0);
        __builtin_amdgcn_s_setprio(0);
        __builtin_amdgcn_s_barrier();

        if (kt + 2 < nt) stageA(ab, kc2, 0);
        __builtin_amdgcn_s_barrier();
        __builtin_amdgcn_s_setprio(1);
#pragma unroll
        for (int i = 0; i < 4; ++i)
#pragma unroll
            for (int j = 0; j < 2; ++j)
#pragma unroll
                for (int kk = 0; kk < 2; ++kk)
                    acc[i + 4][j] = __builtin_amdgcn_mfma_f32_16x16x32_bf16(ahi[i][kk], b01[j][kk], acc[i + 4][j], 0, 0, 0);
        __builtin_amdgcn_s_setprio(0);
        if (kt + 2 < nt) {
            asm volatile("s_waitcnt vmcnt(6)" ::: "memory");
        } else {
            asm volatile("s_waitcnt vmcnt(0)" ::: "memory");
        }
        __builtin_amdgcn_s_barrier();
    }

    if (conv) {
        u16* Cp = Cp3 + (long)tap * 4194304;
#pragma unroll
        for (int i = 0; i < 8; ++i)
#pragma unroll
            for (int j = 0; j < 4; ++j) {
                const int n = n0 + wc + j * 16 + l15;
#pragma unroll
                for (int q = 0; q < 4; ++q) {
                    const int m = m0 + wr + i * 16 + l4 * 4 + q;
                    Cp[(long)m * 1024 + n] = f2bf(acc[i][j][q]);
                }
            }
    } else {
#pragma unroll
        for (int i = 0; i < 8; ++i)
#pragma unroll
            for (int j = 0; j < 4; ++j) {
                const int n = n0 + wc + j * 16 + l15;
#pragma unroll
                for (int q = 0; q < 4; ++q) {
                    const int m = m0 + wr + i * 16 + l4 * 4 + q;
                    Hout[(long)m * 4096 + n] = f2bf(fmaxf(acc[i][j][q], 0.f));
                }
            }
    }
}

// ============ fused attention: one K=512 concat score GEMM -> softmax -> PV ============
// scores[m,n] = sum_d Q[m,d]*(K[n,d]/32) + sum_d erT[m,d]*Q[n,d] + |m-n|/2*dw
// (K is pre-scaled by 1/32 at setup). A' = [Q_tile | erT_tile], B' = [K~ | Q].
__global__ __launch_bounds__(256, 2)
void attn_fused_k(const u16* __restrict__ QKVb, const u16* __restrict__ erT,
                  const u16* __restrict__ Vt, const float* __restrict__ dwp,
                  u16* __restrict__ Oc)
{
    __shared__ __align__(16) u16 As[4096];
    __shared__ __align__(16) u16 Bs[16384];
    __shared__ __align__(16) u16 Pl[16384];
    __shared__ float redM[4][64];
    __shared__ float redS[4][64];
    const int z = blockIdx.y, zb = z >> 2, zn = z & 3;
    const int m0 = blockIdx.x * 64;
    const int tid = threadIdx.x;
    const int lane = tid & 63, wid = tid >> 6;
    const int l15 = lane & 15, l4 = lane >> 4;

    const u16* Qg = QKVb + (long)(zb * 256) * 3072 + zn * 256;
    const u16* Kg = Qg + 1024;   // holds K/32

    auto stageA64 = [&](const u16* g, long ld) {
#pragma unroll
        for (int p = 0; p < 2; ++p) {
            const int e = p * 2048 + tid * 8;
            const int r = e >> 6, c = e & 63;
            const int sc = c ^ (((r >> 2) & 1) << 4);
            gld16(&As[e], g + (long)r * ld + sc);
        }
    };
    auto stageB256 = [&](const u16* g, long ld) {
#pragma unroll
        for (int p = 0; p < 8; ++p) {
            const int e = p * 2048 + tid * 8;
            const int r = e >> 6, c = e & 63;
            const int sc = c ^ (((r >> 2) & 1) << 4);
            gld16(&Bs[e], g + (long)r * ld + sc);
        }
    };
    auto fragA = [&](int i, int kk) -> bf16x8 {
        const int row = i * 16 + l15, col = kk * 32 + l4 * 8;
        return *(const bf16x8*)&As[row * 64 + (col ^ (((row >> 2) & 1) << 4))];
    };
    auto fragB = [&](int j, int kk) -> bf16x8 {
        const int row = wid * 64 + j * 16 + l15, col = kk * 32 + l4 * 8;
        return *(const bf16x8*)&Bs[row * 64 + (col ^ (((row >> 2) & 1) << 4))];
    };
    auto fragP = [&](int kc, int i, int kk) -> bf16x8 {
        const int row = i * 16 + l15, col = kk * 32 + l4 * 8;
        return *(const bf16x8*)&Pl[kc * 4096 + row * 64 + (col ^ (((row >> 2) & 1) << 4))];
    };

    f32x4 acc1[4][4] = {};

    // single K=512 concat loop: kc<4 -> Q x K~ ; kc>=4 -> erT x Q
    for (int kc = 0; kc < 8; ++kc) {
        __syncthreads();
        if (kc < 4) {
            stageA64(Qg + (long)m0 * 3072 + kc * 64, 3072);
            stageB256(Kg + kc * 64, 3072);
        } else {
            stageA64(erT + (long)m0 * 256 + (kc - 4) * 64, 256);
            stageB256(Qg + (kc - 4) * 64, 3072);
        }
        __syncthreads();
#pragma unroll
        for (int i = 0; i < 4; ++i) {
            const bf16x8 a0 = fragA(i, 0), a1 = fragA(i, 1);
#pragma unroll
            for (int j = 0; j < 4; ++j) {
                acc1[i][j] = __builtin_amdgcn_mfma_f32_16x16x32_bf16(a0, fragB(j, 0), acc1[i][j], 0, 0, 0);
                acc1[i][j] = __builtin_amdgcn_mfma_f32_16x16x32_bf16(a1, fragB(j, 1), acc1[i][j], 0, 0, 0);
            }
        }
    }

    // + dist term
#pragma unroll
    for (int i = 0; i < 4; ++i)
#pragma unroll
        for (int q = 0; q < 4; ++q) {
            const int mg = m0 + i * 16 + l4 * 4 + q;
            const float dw = dwp[zn * 256 + mg];
#pragma unroll
            for (int j = 0; j < 4; ++j) {
                const int ng = wid * 64 + j * 16 + l15;
                acc1[i][j][q] += fabsf((float)(mg - ng)) * 0.5f * dw;
            }
        }

    float rmax[4][4], rsum[4][4];
#pragma unroll
    for (int i = 0; i < 4; ++i)
#pragma unroll
        for (int q = 0; q < 4; ++q) {
            float mv = fmaxf(fmaxf(acc1[i][0][q], acc1[i][1][q]),
                             fmaxf(acc1[i][2][q], acc1[i][3][q]));
#pragma unroll
            for (int off = 1; off <= 8; off <<= 1) mv = fmaxf(mv, __shfl_xor(mv, off, 64));
            rmax[i][q] = mv;
        }
    if (l15 == 0) {
#pragma unroll
        for (int i = 0; i < 4; ++i)
#pragma unroll
            for (int q = 0; q < 4; ++q)
                redM[wid][i * 16 + l4 * 4 + q] = rmax[i][q];
    }
    __syncthreads();
#pragma unroll
    for (int i = 0; i < 4; ++i)
#pragma unroll
        for (int q = 0; q < 4; ++q) {
            const int ml = i * 16 + l4 * 4 + q;
            rmax[i][q] = fmaxf(fmaxf(redM[0][ml], redM[1][ml]), fmaxf(redM[2][ml], redM[3][ml]));
        }
#pragma unroll
    for (int i = 0; i < 4; ++i)
#pragma unroll
        for (int q = 0; q < 4; ++q) {
            float sv = 0.f;
#pragma unroll
            for (int j = 0; j < 4; ++j) {
                const float e = __expf(acc1[i][j][q] - rmax[i][q]);
                acc1[i][j][q] = e;
                sv += e;
            }
#pragma unroll
            for (int off = 1; off <= 8; off <<= 1) sv += __shfl_xor(sv, off, 64);
            rsum[i][q] = sv;
        }
    if (l15 == 0) {
#pragma unroll
        for (int i = 0; i < 4; ++i)
#pragma unroll
            for (int q = 0; q < 4; ++q)
                redS[wid][i * 16 + l4 * 4 + q] = rsum[i][q];
    }
    __syncthreads();
#pragma unroll
    for (int i = 0; i < 4; ++i)
#pragma unroll
        for (int q = 0; q < 4; ++q) {
            const int ml = i * 16 + l4 * 4 + q;
            rsum[i][q] = redS[0][ml] + redS[1][ml] + redS[2][ml] + redS[3][ml];
        }
#pragma unroll
    for (int i = 0; i < 4; ++i)
#pragma unroll
        for (int q = 0; q < 4; ++q) {
            const float rinv = 1.f / rsum[i][q];
            const int ml = i * 16 + l4 * 4 + q;
#pragma unroll
            for (int j = 0; j < 4; ++j) {
                const int nc = j * 16 + l15;
                Pl[wid * 4096 + ml * 64 + (nc ^ (((ml >> 2) & 1) << 4))] = f2bf(acc1[i][j][q] * rinv);
            }
        }
    __syncthreads();

    f32x4 accO[4][4] = {};
    for (int kc = 0; kc < 4; ++kc) {
        __syncthreads();
        stageB256(Vt + (long)(z * 256) * 256 + kc * 64, 256);
        __syncthreads();
#pragma unroll
        for (int i = 0; i < 4; ++i) {
            const bf16x8 a0 = fragP(kc, i, 0), a1 = fragP(kc, i, 1);
#pragma unroll
            for (int j = 0; j < 4; ++j) {
                accO[i][j] = __builtin_amdgcn_mfma_f32_16x16x32_bf16(a0, fragB(j, 0), accO[i][j], 0, 0, 0);
                accO[i][j] = __builtin_amdgcn_mfma_f32_16x16x32_bf16(a1, fragB(j, 1), accO[i][j], 0, 0, 0);
            }
        }
    }

#pragma unroll
    for (int i = 0; i < 4; ++i)
#pragma unroll
        for (int j = 0; j < 4; ++j) {
            const int d = wid * 64 + j * 16 + l15;
#pragma unroll
            for (int q = 0; q < 4; ++q) {
                const int mg = m0 + i * 16 + l4 * 4 + q;
                Oc[(long)(zb * 256 + mg) * 1024 + zn * 256 + d] = f2bf(accO[i][j][q]);
            }
        }
}

// ---------------- GLU gate + residual + LN (bf16 chain, 2 bf16 partials) ----------------
__global__ __launch_bounds__(256)
void glu_ln_k(const u16* __restrict__ xs0, const u16* __restrict__ g2,
              const float* __restrict__ gam, const float* __restrict__ bet,
              u16* __restrict__ outb)
{
    const int t = blockIdx.x, tid = threadIdx.x;
    const int f0 = tid * 4;
    const long PS = 8388608;
    const float4 xv = bf4f(*(const ushort4*)&xs0[(long)t * 1024 + f0]);
    const float4 a0 = bf4f(*(const ushort4*)&g2[(long)t * 2048 + f0]);
    const float4 g0 = bf4f(*(const ushort4*)&g2[(long)t * 2048 + 1024 + f0]);
    const float4 a1 = bf4f(*(const ushort4*)&g2[PS + (long)t * 2048 + f0]);
    const float4 g1 = bf4f(*(const ushort4*)&g2[PS + (long)t * 2048 + 1024 + f0]);
    const float ax = a0.x + a1.x, ay = a0.y + a1.y, az = a0.z + a1.z, aw = a0.w + a1.w;
    const float gx = g0.x + g1.x, gy = g0.y + g1.y, gz = g0.z + g1.z, gw = g0.w + g1.w;
    float vals[4];
    vals[0] = xv.x + ax / (1.f + expf(-gx));
    vals[1] = xv.y + ay / (1.f + expf(-gy));
    vals[2] = xv.z + az / (1.f + expf(-gz));
    vals[3] = xv.w + aw / (1.f + expf(-gw));
    float s1 = vals[0] + vals[1] + vals[2] + vals[3];
    float s2 = vals[0]*vals[0] + vals[1]*vals[1] + vals[2]*vals[2] + vals[3]*vals[3];
    block_red2(s1, s2, tid);
    const float mean = s1 * (1.f / 1024.f);
    const float var  = s2 * (1.f / 1024.f) - mean * mean;
    const float rstd = rsqrtf(var + EPSF);
    const float4 gm = *(const float4*)&gam[f0];
    const float4 bt = *(const float4*)&bet[f0];
    *(ushort4*)&outb[(long)t * 1024 + f0] = f4bf(
        (vals[0] - mean) * rstd * gm.x + bt.x,
        (vals[1] - mean) * rstd * gm.y + bt.y,
        (vals[2] - mean) * rstd * gm.z + bt.z,
        (vals[3] - mean) * rstd * gm.w + bt.w);
}

// ---------------- residual add + LN width 1024 (bf16 chain, P bf16 partials, opt bias) ----------------
template<int P, int BIAS>
__global__ __launch_bounds__(256)
void add_ln1024_k(const u16* __restrict__ A, const u16* __restrict__ Bp,
                  const float* __restrict__ bias,
                  const float* __restrict__ gam, const float* __restrict__ bet,
                  u16* __restrict__ outb)
{
    const int t = blockIdx.x, tid = threadIdx.x;
    const int f0 = tid * 4;
    const long PS = 4194304;
    const float4 a = bf4f(*(const ushort4*)&A[(long)t * 1024 + f0]);
    float4 b = bf4f(*(const ushort4*)&Bp[(long)t * 1024 + f0]);
#pragma unroll
    for (int p = 1; p < P; ++p) {
        const float4 bp = bf4f(*(const ushort4*)&Bp[p * PS + (long)t * 1024 + f0]);
        b.x += bp.x; b.y += bp.y; b.z += bp.z; b.w += bp.w;
    }
    if (BIAS) {
        const float4 bb = *(const float4*)&bias[f0];
        b.x += bb.x; b.y += bb.y; b.z += bb.z; b.w += bb.w;
    }
    float vals[4] = {a.x + b.x, a.y + b.y, a.z + b.z, a.w + b.w};
    float s1 = vals[0] + vals[1] + vals[2] + vals[3];
    float s2 = vals[0]*vals[0] + vals[1]*vals[1] + vals[2]*vals[2] + vals[3]*vals[3];
    block_red2(s1, s2, tid);
    const float mean = s1 * (1.f / 1024.f);
    const float var  = s2 * (1.f / 1024.f) - mean * mean;
    const float rstd = rsqrtf(var + EPSF);
    const float4 gm = *(const float4*)&gam[f0];
    const float4 bt = *(const float4*)&bet[f0];
    *(ushort4*)&outb[(long)t * 1024 + f0] = f4bf(
        (vals[0] - mean) * rstd * gm.x + bt.x,
        (vals[1] - mean) * rstd * gm.y + bt.y,
        (vals[2] - mean) * rstd * gm.z + bt.z,
        (vals[3] - mean) * rstd * gm.w + bt.w);
}

// ---------------- n2: LN(c1L(bf16) + pad(relu(sum of 3 bf16 conv taps))) width 4096 ----------------
__global__ __launch_bounds__(256)
void add_ln4096_k(const u16* __restrict__ A, const u16* __restrict__ Bp,
                  const float* __restrict__ gam, const float* __restrict__ bet,
                  u16* __restrict__ outb)
{
    const int t = blockIdx.x, tid = threadIdx.x;
    const long PS = 4194304;
    const int f0 = tid * 16;
    float vals[16];
    const bf16x8 a0 = *(const bf16x8*)&A[(long)t * 4096 + f0];
    const bf16x8 a1 = *(const bf16x8*)&A[(long)t * 4096 + f0 + 8];
#pragma unroll
    for (int e = 0; e < 8; ++e) { vals[e] = bf2f((u16)a0[e]); vals[8 + e] = bf2f((u16)a1[e]); }
    if (tid < 64) {
#pragma unroll
        for (int c = 0; c < 4; ++c) {
            const int fc = f0 + c * 4;
            const float4 b0 = bf4f(*(const ushort4*)&Bp[(long)t * 1024 + fc]);
            const float4 b1 = bf4f(*(const ushort4*)&Bp[PS + (long)t * 1024 + fc]);
            const float4 b2 = bf4f(*(const ushort4*)&Bp[2 * PS + (long)t * 1024 + fc]);
            vals[c*4+0] += fmaxf(b0.x + b1.x + b2.x, 0.f);
            vals[c*4+1] += fmaxf(b0.y + b1.y + b2.y, 0.f);
            vals[c*4+2] += fmaxf(b0.z + b1.z + b2.z, 0.f);
            vals[c*4+3] += fmaxf(b0.w + b1.w + b2.w, 0.f);
        }
    }
    float s1 = 0.f, s2 = 0.f;
#pragma unroll
    for (int e = 0; e < 16; ++e) { s1 += vals[e]; s2 += vals[e] * vals[e]; }
    block_red2(s1, s2, tid);
    const float mean = s1 * (1.f / 4096.f);
    const float var  = s2 * (1.f / 4096.f) - mean * mean;
    const float rstd = rsqrtf(var + EPSF);
#pragma unroll
    for (int c = 0; c < 4; ++c) {
        const int fc = f0 + c * 4;
        const float4 gm = *(const float4*)&gam[fc];
        const float4 bt = *(const float4*)&bet[fc];
        *(ushort4*)&outb[(long)t * 4096 + fc] = f4bf(
            (vals[c*4+0] - mean) * rstd * gm.x + bt.x,
            (vals[c*4+1] - mean) * rstd * gm.y + bt.y,
            (vals[c*4+2] - mean) * rstd * gm.z + bt.z,
            (vals[c*4+3] - mean) * rstd * gm.w + bt.w);
    }
}

// ---------------- depthwise conv width-9, 8 channels/thread ----------------
__global__ __launch_bounds__(256)
void dwconv8_k(const u16* __restrict__ h, const float* __restrict__ wT,
               u16* __restrict__ out)
{
    const long idx = (long)blockIdx.x * 256 + threadIdx.x;
    const int cg = (int)(idx & 511);
    const int t  = (int)(idx >> 9);
    const int w  = t & 255;
    const int c0 = cg * 8;
    float acc[8] = {};
#pragma unroll
    for (int k = 0; k < 9; ++k) {
        const int wp = w + k - 4;
        if ((unsigned)wp < 256u) {
            const bf16x8 hv = *(const bf16x8*)&h[(long)(t + k - 4) * 4096 + c0];
            const float4 w0 = *(const float4*)&wT[k * 4096 + c0];
            const float4 w1 = *(const float4*)&wT[k * 4096 + c0 + 4];
            acc[0] += bf2f((u16)hv[0]) * w0.x;
            acc[1] += bf2f((u16)hv[1]) * w0.y;
            acc[2] += bf2f((u16)hv[2]) * w0.z;
            acc[3] += bf2f((u16)hv[3]) * w0.w;
            acc[4] += bf2f((u16)hv[4]) * w1.x;
            acc[5] += bf2f((u16)hv[5]) * w1.y;
            acc[6] += bf2f((u16)hv[6]) * w1.z;
            acc[7] += bf2f((u16)hv[7]) * w1.w;
        }
    }
    bf16x8 res;
#pragma unroll
    for (int j = 0; j < 8; ++j) res[j] = (short)f2bf(acc[j]);
    *(bf16x8*)&out[(long)t * 4096 + c0] = res;
}

// ---------------- V slice of QKVb -> Vt (z, d, w) bf16 ----------------
__global__ __launch_bounds__(256)
void vtrans_k(const u16* __restrict__ QKVb, u16* __restrict__ Vt)
{
    __shared__ u16 t[32][33];
    const int z = blockIdx.z, zb = z >> 2, zn = z & 3;
    const int w0 = blockIdx.x * 32, d0 = blockIdx.y * 32;
    const int tid = threadIdx.x, c = tid & 31, r = tid >> 5;
#pragma unroll
    for (int it = 0; it < 4; ++it) {
        const int wl = r + it * 8;
        t[wl][c] = QKVb[(long)(zb * 256 + w0 + wl) * 3072 + 2048 + zn * 256 + d0 + c];
    }
    __syncthreads();
#pragma unroll
    for (int it = 0; it < 4; ++it) {
        const int dl = r + it * 8;
        Vt[((long)z * 256 + d0 + dl) * 256 + w0 + c] = t[c][dl];
    }
}

// ---------------- final transpose: bf16 (tokens,1024) -> f32 (B,1,1024,256) ----------------
__global__ __launch_bounds__(256)
void transpose_out_k(const u16* __restrict__ xs, float* __restrict__ out)
{
    __shared__ u16 tile[32][34];
    const int b = blockIdx.z, f0 = blockIdx.y * 32, w0 = blockIdx.x * 32;
    const int tid = threadIdx.x, c = tid & 31, r = tid >> 5;
#pragma unroll
    for (int it = 0; it < 4; ++it) {
        const int w = w0 + r + it * 8;
        tile[r + it * 8][c] = xs[((long)b * 256 + w) * 1024 + f0 + c];
    }
    __syncthreads();
#pragma unroll
    for (int it = 0; it < 4; ++it) {
        const int fl = r + it * 8;
        out[((long)b * 1024 + f0 + fl) * 256 + w0 + c] = bf2f(tile[c][fl]);
    }
}

// =======================================================================
extern "C" void kernel_launch(void* const* d_in, const int* in_sizes, int n_in,
                              void* d_out, int out_size, void* d_ws, size_t ws_size,
                              hipStream_t stream)
{
    const float* x      = (const float*)d_in[0];
    const float* bott_w = (const float*)d_in[1];
    const float* bn_g   = (const float*)d_in[2];
    const float* bn_b   = (const float*)d_in[3];
    const float* bn_m   = (const float*)d_in[4];
    const float* bn_v   = (const float*)d_in[5];
    const float* glu_w  = (const float*)d_in[6];
    const float* n1g    = (const float*)d_in[7];
    const float* n1b    = (const float*)d_in[8];
    const float* c1L_w  = (const float*)d_in[9];
    const float* c1R_w  = (const float*)d_in[10];
    const float* n2g    = (const float*)d_in[11];
    const float* n2b    = (const float*)d_in[12];
    const float* c2dw_w = (const float*)d_in[13];
    const float* c2pw_w = (const float*)d_in[14];
    const float* n3g    = (const float*)d_in[15];
    const float* n3b    = (const float*)d_in[16];
    const float* qw     = (const float*)d_in[17];
    const float* qb     = (const float*)d_in[18];
    const float* kw     = (const float*)d_in[19];
    const float* kb     = (const float*)d_in[20];
    const float* vw     = (const float*)d_in[21];
    const float* vb     = (const float*)d_in[22];
    const float* ow     = (const float*)d_in[23];
    const float* ob     = (const float*)d_in[24];
    const float* er     = (const float*)d_in[25];
    const float* dist_w = (const float*)d_in[26];
    const float* n4g    = (const float*)d_in[27];
    const float* n4b    = (const float*)d_in[28];
    const float* c3_w   = (const float*)d_in[29];
    const float* c4_w   = (const float*)d_in[30];
    const float* n5g    = (const float*)d_in[31];
    const float* n5b    = (const float*)d_in[32];
    float* out = (float*)d_out;

    // ---- workspace layout (MiB offsets, bf16 residual chain) ----
    char* Wb_ = (char*)d_ws;
    auto Bf = [&](size_t mib) { return (u16*)(Wb_ + (mib << 20)); };
    u16* XA   = Bf(0);    // xs0 (1-3), xs2 (9-13), xs4 (16-17)
    u16* XB   = Bf(8);    // xs1 (3-9), xs3 (13-16)
    u16* H0b  = Bf(32);   // c1L out (4-6) / c3 out (14-15)
    u16* Hglu = Bf(64);   // GLU 2 bf16 partials (2-3)
    u16* C3p  = Bf(64);   // conv3 3 bf16 partials (5-6)
    u16* P4   = Bf(64);   // c2pw/O-proj/c4 4 bf16 partials
    u16* H1b  = Bf(128);  // n2 out (6-7)
    u16* Hdw  = Bf(160);  // dwconv out (7-8)
    u16* QKVb = Bf(192);  // QKV out 4096x3072 (10-11)
    u16* Vt   = Bf(216);  // V transposed (10b-11)
    u16* S1b  = Bf(264);  // attn concat out (11-12)
    u16* wGLU = Bf(296); u16* wC1L = Bf(300); u16* wC1R = Bf(308);
    u16* wC2P = Bf(314); u16* wQKV = Bf(322); u16* wO   = Bf(328);
    u16* wC3  = Bf(330); u16* wC4  = Bf(338);
    u16* erT  = Bf(346);
    u16* zp   = (u16*)(Wb_ + (346u << 20) + 131072);
    float* wdwT = (float*)(Wb_ + (346u << 20) + 131072 + 16384);
    float* bQKV = (float*)(Wb_ + (346u << 20) + 131072 + 16384 + 147456);

    const dim3 blk(256);
    const dim3 blk8(512);
    const long PS1 = 4194304;   // 4096*1024 elements
    const size_t SH8 = 131072;  // 128 KiB dynamic LDS

    // 0. merged setup (one launch); kw/kb pre-scaled by 1/32
    SetupArgs sa;
    sa.ws[0] = glu_w;  sa.wd[0] = wGLU;            sa.wn[0] = 524288;
    sa.ws[1] = c1L_w;  sa.wd[1] = wC1L;            sa.wn[1] = 1048576;
    sa.ws[2] = c2pw_w; sa.wd[2] = wC2P;            sa.wn[2] = 1048576;
    sa.ws[3] = c3_w;   sa.wd[3] = wC3;             sa.wn[3] = 1048576;
    sa.ws[4] = c4_w;   sa.wd[4] = wC4;             sa.wn[4] = 1048576;
    sa.ws[5] = qw;     sa.wd[5] = wQKV;            sa.wn[5] = 262144;
    sa.ws[6] = kw;     sa.wd[6] = wQKV + 1048576;  sa.wn[6] = 262144;
    sa.ws[7] = vw;     sa.wd[7] = wQKV + 2097152;  sa.wn[7] = 262144;
    sa.ws[8] = ow;     sa.wd[8] = wO;              sa.wn[8] = 262144;
    sa.c1r = c1R_w; sa.c1rd = wC1R;
    sa.er  = er;    sa.erd  = erT;
    sa.dw  = c2dw_w; sa.dwd = wdwT;
    sa.qb = qb; sa.kb = kb; sa.vb = vb; sa.bcat = bQKV;
    sa.zp = zp;
    {
        int bc[14] = {2048, 4096, 4096, 4096, 4096, 1024, 1024, 1024, 1024,
                      12288, 256, 144, 12, 32};
        int acc = 0;
        for (int s = 0; s < 14; ++s) { sa.off[s] = acc; acc += bc[s]; }
        sa.off[14] = acc;
        setup_k<<<dim3(acc), blk, 0, stream>>>(sa);
    }

    // 1. bottleneck + BN + ReLU + transpose -> XA (xs0, bf16)
    bottleneck_k<<<dim3(8, 32, 16), blk, 0, stream>>>(x, bott_w, bn_g, bn_b, bn_m, bn_v, XA);

    // 2. GLU matmul, split-K=2 -> Hglu bf16 partials
    gemm8_k<0,0,0,2><<<dim3(8, 16, 2), blk8, SH8, stream>>>(XA, wGLU, nullptr, Hglu,
        2048, 512, 1024, 1024, (long)4096 * 2048);

    // 3. n1: LN(xs0 + a*sigmoid(g)) -> XB (xs1)
    glu_ln_k<<<dim3(4096), blk, 0, stream>>>(XA, Hglu, n1g, n1b, XB);

    // 4+5. merged c1L (relu -> H0b) + conv1R taps (-> C3p partials), one launch
    ffconv8_k<<<dim3(28, 16), blk8, SH8, stream>>>(XB, wC1L, wC1R, zp, H0b, C3p);

    // 6. n2: LN(H0b + pad(relu(sum taps))) -> H1b bf16
    add_ln4096_k<<<dim3(4096), blk, 0, stream>>>(H0b, C3p, n2g, n2b, H1b);

    // 7. depthwise conv9 (vectorized x8): H1b -> Hdw
    dwconv8_k<<<dim3(8192), blk, 0, stream>>>(H1b, wdwT, Hdw);

    // 8. c2pw, split-K=4 -> P4 bf16 partials
    gemm8_k<0,0,0,4><<<dim3(4, 16, 4), blk8, SH8, stream>>>(Hdw, wC2P, nullptr, P4,
        1024, 1024, 4096, 4096, PS1);

    // 9. n3: LN(xs1 + sum P4) -> XA (xs2)
    add_ln1024_k<4,0><<<dim3(4096), blk, 0, stream>>>(XB, P4, nullptr, n3g, n3b, XA);

    // 10. fused QKV projection (+concat bias; K-slice pre-scaled by 1/32) -> QKVb
    gemm8_k<0,1,1,1><<<dim3(12, 16, 1), blk8, SH8, stream>>>(XA, wQKV, bQKV, QKVb,
        3072, 1024, 1024, 1024, 0);

    // 10b. V transpose per head -> Vt (z, d, w)
    vtrans_k<<<dim3(8, 8, 64), blk, 0, stream>>>(QKVb, Vt);

    // 11. fused attention: K=512 concat scores + softmax + PV -> S1b
    attn_fused_k<<<dim3(4, 64), blk, 0, stream>>>(QKVb, erT, Vt, dist_w, S1b);

    // 12. output projection, split-K=4 -> P4 bf16 partials (bias added in n4)
    gemm8_k<0,0,0,4><<<dim3(4, 16, 4), blk8, SH8, stream>>>(S1b, wO, nullptr, P4,
        1024, 256, 1024, 1024, PS1);

    // 13. n4: LN(xs2 + sum P4 + ob) -> XB (xs3)
    add_ln1024_k<4,1><<<dim3(4096), blk, 0, stream>>>(XA, P4, ob, n4g, n4b, XB);

    // 14. c3: relu -> H0b bf16
    gemm8_k<1,1,0,1><<<dim3(16, 16, 1), blk8, SH8, stream>>>(XB, wC3, nullptr, H0b,
        4096, 1024, 1024, 1024, 0);

    // 15. c4, split-K=4 -> P4 bf16 partials
    gemm8_k<0,0,0,4><<<dim3(4, 16, 4), blk8, SH8, stream>>>(H0b, wC4, nullptr, P4,
        1024, 1024, 4096, 4096, PS1);

    // 16. n5: LN(xs3 + sum P4) -> XA (xs4, bf16)
    add_ln1024_k<4,0><<<dim3(4096), blk, 0, stream>>>(XB, P4, nullptr, n5g, n5b, XA);

    // 17. transpose to (B, 1, 1024, 256) f32
    transpose_out_k<<<dim3(8, 32, 16), blk, 0, stream>>>(XA, out);

    (void)in_sizes; (void)n_in; (void)out_size; (void)ws_size;
}

// Round 10
// 468.303 us; speedup vs baseline: 7.4542x; 1.0396x over previous
//
#include <hip/hip_runtime.h>
#include <hip/hip_bf16.h>

// FrameTransformer: B=16, C=8, BINS=1024, W=256, FF=2048, NB=4
// tokens = B*W = 4096, feature width 1024, FF width 4096, head dim 256.
#define EPSF 1e-5f

typedef unsigned short u16;
typedef unsigned int   u32;
typedef __attribute__((ext_vector_type(8))) short bf16x8;
typedef __attribute__((ext_vector_type(4))) float f32x4;

// 3-bit XOR swizzle for 64-elem (128 B) LDS rows: spreads 8 consecutive rows
// across all eight 16-B bank windows (2 lanes/window = conflict-free, m136).
#define SWZ(row) (((row) & 7) << 3)

__device__ __forceinline__ u16 f2bf(float f) {
    u32 u = __builtin_bit_cast(u32, f);
    u32 r = u + 0x7fffu + ((u >> 16) & 1u);
    return (u16)(r >> 16);
}
__device__ __forceinline__ float bf2f(u16 h) {
    return __builtin_bit_cast(float, (u32)h << 16);
}
__device__ __forceinline__ float4 bf4f(ushort4 v) {
    return make_float4(bf2f(v.x), bf2f(v.y), bf2f(v.z), bf2f(v.w));
}
__device__ __forceinline__ ushort4 f4bf(float a, float b, float c, float d) {
    ushort4 o; o.x = f2bf(a); o.y = f2bf(b); o.z = f2bf(c); o.w = f2bf(d); return o;
}
__device__ __forceinline__ void gld16(void* lds, const void* gsrc) {
    __builtin_amdgcn_global_load_lds(
        (const __attribute__((address_space(1))) u32*)gsrc,
        (__attribute__((address_space(3))) u32*)lds, 16, 0, 0);
}

__device__ __forceinline__ float wred_sum(float v) {
#pragma unroll
    for (int off = 32; off; off >>= 1) v += __shfl_xor(v, off, 64);
    return v;
}
__device__ __forceinline__ void block_red2(float& s1, float& s2, int tid) {
    __shared__ float red[8];
    s1 = wred_sum(s1); s2 = wred_sum(s2);
    const int lane = tid & 63, wid = tid >> 6;
    if (!lane) { red[wid] = s1; red[4 + wid] = s2; }
    __syncthreads();
    s1 = red[0] + red[1] + red[2] + red[3];
    s2 = red[4] + red[5] + red[6] + red[7];
}

// ---------------- merged setup: all weight conversions in one launch ----------------
// NOTE: kw (seg 6) and kb (bias middle third) are pre-scaled by 1/32 (skew fold).
struct SetupArgs {
    const float* ws[9]; u16* wd[9]; int wn[9];
    const float* c1r; u16* c1rd;
    const float* er;  u16* erd;
    const float* dw;  float* dwd;
    const float* qb;  const float* kb; const float* vb; float* bcat;
    u16* zp;
    int off[15];
};
__global__ __launch_bounds__(256)
void setup_k(SetupArgs a)
{
    const int b = blockIdx.x;
    int seg = 0;
    while (seg < 13 && b >= a.off[seg + 1]) ++seg;
    const int i = (b - a.off[seg]) * 256 + threadIdx.x;
    if (seg < 9) {
        if (i < a.wn[seg]) {
            const float4 v = ((const float4*)a.ws[seg])[i];
            const float s = (seg == 6) ? 0.03125f : 1.f;
            ((ushort4*)a.wd[seg])[i] = f4bf(v.x * s, v.y * s, v.z * s, v.w * s);
        }
    } else if (seg == 9) {
        if (i < 3145728) {
            const int q = i / 3072, rem = i - q * 3072;
            const int ks = rem >> 10, ci = rem & 1023;
            a.c1rd[i] = f2bf(a.c1r[((long)q * 1024 + ci) * 3 + ks]);
        }
    } else if (seg == 10) {
        if (i < 65536) { const int c = i >> 8, d = i & 255; a.erd[i] = f2bf(a.er[d * 256 + c]); }
    } else if (seg == 11) {
        if (i < 36864) { const int k = i >> 12, c = i & 4095; a.dwd[i] = a.dw[c * 9 + k]; }
    } else if (seg == 12) {
        if (i < 3072) {
            const float* s = (i < 1024) ? a.qb : ((i < 2048) ? a.kb : a.vb);
            float v = s[i & 1023];
            if (i >= 1024 && i < 2048) v *= 0.03125f;
            a.bcat[i] = v;
        }
    } else {
        if (i < 8192) a.zp[i] = 0;
    }
}

// ---------------- stage 1: bottleneck 1x1 conv + BN + ReLU + transpose (bf16 out) ----------------
__global__ __launch_bounds__(256)
void bottleneck_k(const float* __restrict__ x, const float* __restrict__ bw,
                  const float* __restrict__ bn_g, const float* __restrict__ bn_b,
                  const float* __restrict__ bn_m, const float* __restrict__ bn_v,
                  u16* __restrict__ xsb)
{
    __shared__ float tile[32][33];
    const int b = blockIdx.z, h0 = blockIdx.y * 32, w0 = blockIdx.x * 32;
    const int tid = threadIdx.x, c = tid & 31, r = tid >> 5;
    float wreg[8];
#pragma unroll
    for (int ch = 0; ch < 8; ++ch) wreg[ch] = bw[ch];
    const float sc = bn_g[0] * rsqrtf(bn_v[0] + EPSF);
    const float sh = bn_b[0] - bn_m[0] * sc;
#pragma unroll
    for (int it = 0; it < 4; ++it) {
        const int h = h0 + r + it * 8;
        const int w = w0 + c;
        float acc = 0.f;
#pragma unroll
        for (int ch = 0; ch < 8; ++ch)
            acc += x[(((long)b * 8 + ch) * 1024 + h) * 256 + w] * wreg[ch];
        tile[r + it * 8][c] = fmaxf(acc * sc + sh, 0.f);
    }
    __syncthreads();
#pragma unroll
    for (int it = 0; it < 4; ++it) {
        const int wl = r + it * 8;
        xsb[((long)b * 256 + w0 + wl) * 1024 + h0 + c] = f2bf(tile[c][wl]);
    }
}

// ============ 8-phase 256x256 bf16 MFMA GEMM (T2+T3+T4+T5) ============
template<int ACT, int OUTBF, int BIAS, int SPLITK>
__global__ __launch_bounds__(512, 2)
void gemm8_k(const u16* __restrict__ A, const u16* __restrict__ B,
             const float* __restrict__ bias, void* __restrict__ Cout,
             int N, int K /*per slice*/, int lda, int ldb, long partStride)
{
    extern __shared__ u16 lds[];
    const int m0 = blockIdx.y * 256, n0 = blockIdx.x * 256;
    const int koff = (SPLITK > 1) ? blockIdx.z * K : 0;
    const int nt = K >> 6;
    const int tid = threadIdx.x;
    const int lane = tid & 63, wid = tid >> 6;
    const int wr = ((wid >> 2) & 1) * 128;
    const int wc = (wid & 3) * 64;
    const int l15 = lane & 15, l4 = lane >> 4;

    const u16* Ag = A + (long)m0 * lda + koff;
    const u16* Bg = B + (long)n0 * ldb + koff;

    auto stage = [&](const u16* g, int ld, int ldsbase, int kcol, int h) {
#pragma unroll
        for (int is = 0; is < 2; ++is) {
            const int r = h * 128 + is * 64 + (tid >> 3);
            const int sc = ((tid & 7) * 8) ^ SWZ(r);
            gld16(&lds[ldsbase + h * 8192 + is * 4096 + tid * 8],
                  g + (long)r * ld + kcol + sc);
        }
    };
    auto frag = [&](int base, int row, int col) -> bf16x8 {
        return *(const bf16x8*)&lds[base + row * 64 + (col ^ SWZ(row))];
    };

    f32x4 acc[8][4] = {};

    stage(Ag, lda, 0, 0, 0);
    stage(Ag, lda, 0, 0, 1);
    stage(Bg, ldb, 32768, 0, 0);
    stage(Bg, ldb, 32768, 0, 1);
    if (nt > 1) {
        stage(Bg, ldb, 49152, 64, 0);
        stage(Bg, ldb, 49152, 64, 1);
        stage(Ag, lda, 16384, 64, 0);
        asm volatile("s_waitcnt vmcnt(6)" ::: "memory");
    } else {
        asm volatile("s_waitcnt vmcnt(0)" ::: "memory");
    }
    __builtin_amdgcn_s_barrier();

    for (int kt = 0; kt < nt; ++kt) {
        const int cs = kt & 1;
        const int ab = cs * 16384;
        const int bb = 32768 + cs * 16384;
        const int abn = (cs ^ 1) * 16384;
        const int kc1 = (kt + 1) * 64, kc2 = (kt + 2) * 64;
        bf16x8 alo[4][2], ahi[4][2], b01[2][2], b23[2][2];

#pragma unroll
        for (int i = 0; i < 4; ++i)
#pragma unroll
            for (int kk = 0; kk < 2; ++kk)
                alo[i][kk] = frag(ab, wr + i * 16 + l15, kk * 32 + l4 * 8);
#pragma unroll
        for (int j = 0; j < 2; ++j)
#pragma unroll
            for (int kk = 0; kk < 2; ++kk)
                b01[j][kk] = frag(bb, wc + j * 16 + l15, kk * 32 + l4 * 8);
        if (kt + 1 < nt) stage(Ag, lda, abn, kc1, 1);
        __builtin_amdgcn_s_barrier();
        asm volatile("s_waitcnt lgkmcnt(0)" ::: "memory");
        __builtin_amdgcn_s_setprio(1);
#pragma unroll
        for (int i = 0; i < 4; ++i)
#pragma unroll
            for (int j = 0; j < 2; ++j)
#pragma unroll
                for (int kk = 0; kk < 2; ++kk)
                    acc[i][j] = __builtin_amdgcn_mfma_f32_16x16x32_bf16(alo[i][kk], b01[j][kk], acc[i][j], 0, 0, 0);
        __builtin_amdgcn_s_setprio(0);
        __builtin_amdgcn_s_barrier();

#pragma unroll
        for (int j = 0; j < 2; ++j)
#pragma unroll
            for (int kk = 0; kk < 2; ++kk)
                b23[j][kk] = frag(bb, wc + (j + 2) * 16 + l15, kk * 32 + l4 * 8);
        if (kt + 2 < nt) stage(Bg, ldb, bb, kc2, 0);
        __builtin_amdgcn_s_barrier();
        asm volatile("s_waitcnt lgkmcnt(0)" ::: "memory");
        __builtin_amdgcn_s_setprio(1);
#pragma unroll
        for (int i = 0; i < 4; ++i)
#pragma unroll
            for (int j = 0; j < 2; ++j)
#pragma unroll
                for (int kk = 0; kk < 2; ++kk)
                    acc[i][j + 2] = __builtin_amdgcn_mfma_f32_16x16x32_bf16(alo[i][kk], b23[j][kk], acc[i][j + 2], 0, 0, 0);
        __builtin_amdgcn_s_setprio(0);
        __builtin_amdgcn_s_barrier();

#pragma unroll
        for (int i = 0; i < 4; ++i)
#pragma unroll
            for (int kk = 0; kk < 2; ++kk)
                ahi[i][kk] = frag(ab, wr + (i + 4) * 16 + l15, kk * 32 + l4 * 8);
        if (kt + 2 < nt) stage(Bg, ldb, bb, kc2, 1);
        __builtin_amdgcn_s_barrier();
        asm volatile("s_waitcnt lgkmcnt(0)" ::: "memory");
        __builtin_amdgcn_s_setprio(1);
#pragma unroll
        for (int i = 0; i < 4; ++i)
#pragma unroll
            for (int j = 0; j < 2; ++j)
#pragma unroll
                for (int kk = 0; kk < 2; ++kk)
                    acc[i + 4][j + 2] = __builtin_amdgcn_mfma_f32_16x16x32_bf16(ahi[i][kk], b23[j][kk], acc[i + 4][j + 2], 0, 0, 0);
        __builtin_amdgcn_s_setprio(0);
        __builtin_amdgcn_s_barrier();

        if (kt + 2 < nt) stage(Ag, lda, ab, kc2, 0);
        __builtin_amdgcn_s_barrier();
        __builtin_amdgcn_s_setprio(1);
#pragma unroll
        for (int i = 0; i < 4; ++i)
#pragma unroll
            for (int j = 0; j < 2; ++j)
#pragma unroll
                for (int kk = 0; kk < 2; ++kk)
                    acc[i + 4][j] = __builtin_amdgcn_mfma_f32_16x16x32_bf16(ahi[i][kk], b01[j][kk], acc[i + 4][j], 0, 0, 0);
        __builtin_amdgcn_s_setprio(0);
        if (kt + 2 < nt) {
            asm volatile("s_waitcnt vmcnt(6)" ::: "memory");
        } else {
            asm volatile("s_waitcnt vmcnt(0)" ::: "memory");
        }
        __builtin_amdgcn_s_barrier();
    }

    if (SPLITK > 1) {
        u16* Cp = (u16*)Cout + (long)blockIdx.z * partStride;
#pragma unroll
        for (int i = 0; i < 8; ++i)
#pragma unroll
            for (int j = 0; j < 4; ++j) {
                const int n = n0 + wc + j * 16 + l15;
#pragma unroll
                for (int q = 0; q < 4; ++q) {
                    const int m = m0 + wr + i * 16 + l4 * 4 + q;
                    Cp[(long)m * N + n] = f2bf(acc[i][j][q]);
                }
            }
    } else {
        float* Cf = (float*)Cout;
        u16*   Cb = (u16*)Cout;
#pragma unroll
        for (int i = 0; i < 8; ++i)
#pragma unroll
            for (int j = 0; j < 4; ++j) {
                const int n = n0 + wc + j * 16 + l15;
                const float bv = BIAS ? bias[n] : 0.f;
#pragma unroll
                for (int q = 0; q < 4; ++q) {
                    const int m = m0 + wr + i * 16 + l4 * 4 + q;
                    float v = acc[i][j][q] + bv;
                    if (ACT) v = fmaxf(v, 0.f);
                    if (OUTBF) Cb[(long)m * N + n] = f2bf(v);
                    else       Cf[(long)m * N + n] = v;
                }
            }
    }
}

// ============ merged c1L + conv1R launch (8-phase body, K=1024, nt=16) ============
__global__ __launch_bounds__(512, 2)
void ffconv8_k(const u16* __restrict__ Xb, const u16* __restrict__ Wl,
               const u16* __restrict__ Wr, const u16* __restrict__ zp,
               u16* __restrict__ Hout, u16* __restrict__ Cp3)
{
    extern __shared__ u16 lds[];
    const int bx = blockIdx.x;
    const int m0 = blockIdx.y * 256;
    const bool conv = bx >= 16;
    const int tap  = conv ? ((bx - 16) >> 2) : 0;
    const int shift = conv ? (tap - 1) : 0;
    const int n0 = conv ? (((bx - 16) & 3) * 256) : (bx * 256);
    const u16* Bbase = conv ? (Wr + (long)n0 * 3072 + tap * 1024)
                            : (Wl + (long)n0 * 1024);
    const int ldb = conv ? 3072 : 1024;
    const int nt = 16;
    const int tid = threadIdx.x;
    const int lane = tid & 63, wid = tid >> 6;
    const int wr = ((wid >> 2) & 1) * 128;
    const int wc = (wid & 3) * 64;
    const int l15 = lane & 15, l4 = lane >> 4;

    auto stageA = [&](int ldsbase, int kcol, int h) {
#pragma unroll
        for (int is = 0; is < 2; ++is) {
            const int r = h * 128 + is * 64 + (tid >> 3);
            const int sc = ((tid & 7) * 8) ^ SWZ(r);
            const int t = m0 + r;
            const int wp = (t & 255) + shift;
            const u16* src = ((unsigned)wp < 256u)
                ? Xb + (long)(t + shift) * 1024 + kcol + sc
                : zp;
            gld16(&lds[ldsbase + h * 8192 + is * 4096 + tid * 8], src);
        }
    };
    auto stageB = [&](int ldsbase, int kcol, int h) {
#pragma unroll
        for (int is = 0; is < 2; ++is) {
            const int r = h * 128 + is * 64 + (tid >> 3);
            const int sc = ((tid & 7) * 8) ^ SWZ(r);
            gld16(&lds[ldsbase + h * 8192 + is * 4096 + tid * 8],
                  Bbase + (long)r * ldb + kcol + sc);
        }
    };
    auto frag = [&](int base, int row, int col) -> bf16x8 {
        return *(const bf16x8*)&lds[base + row * 64 + (col ^ SWZ(row))];
    };

    f32x4 acc[8][4] = {};

    stageA(0, 0, 0);
    stageA(0, 0, 1);
    stageB(32768, 0, 0);
    stageB(32768, 0, 1);
    stageB(49152, 64, 0);
    stageB(49152, 64, 1);
    stageA(16384, 64, 0);
    asm volatile("s_waitcnt vmcnt(6)" ::: "memory");
    __builtin_amdgcn_s_barrier();

    for (int kt = 0; kt < nt; ++kt) {
        const int cs = kt & 1;
        const int ab = cs * 16384;
        const int bb = 32768 + cs * 16384;
        const int abn = (cs ^ 1) * 16384;
        const int kc1 = (kt + 1) * 64, kc2 = (kt + 2) * 64;
        bf16x8 alo[4][2], ahi[4][2], b01[2][2], b23[2][2];

#pragma unroll
        for (int i = 0; i < 4; ++i)
#pragma unroll
            for (int kk = 0; kk < 2; ++kk)
                alo[i][kk] = frag(ab, wr + i * 16 + l15, kk * 32 + l4 * 8);
#pragma unroll
        for (int j = 0; j < 2; ++j)
#pragma unroll
            for (int kk = 0; kk < 2; ++kk)
                b01[j][kk] = frag(bb, wc + j * 16 + l15, kk * 32 + l4 * 8);
        if (kt + 1 < nt) stageA(abn, kc1, 1);
        __builtin_amdgcn_s_barrier();
        asm volatile("s_waitcnt lgkmcnt(0)" ::: "memory");
        __builtin_amdgcn_s_setprio(1);
#pragma unroll
        for (int i = 0; i < 4; ++i)
#pragma unroll
            for (int j = 0; j < 2; ++j)
#pragma unroll
                for (int kk = 0; kk < 2; ++kk)
                    acc[i][j] = __builtin_amdgcn_mfma_f32_16x16x32_bf16(alo[i][kk], b01[j][kk], acc[i][j], 0, 0, 0);
        __builtin_amdgcn_s_setprio(0);
        __builtin_amdgcn_s_barrier();

#pragma unroll
        for (int j = 0; j < 2; ++j)
#pragma unroll
            for (int kk = 0; kk < 2; ++kk)
                b23[j][kk] = frag(bb, wc + (j + 2) * 16 + l15, kk * 32 + l4 * 8);
        if (kt + 2 < nt) stageB(bb, kc2, 0);
        __builtin_amdgcn_s_barrier();
        asm volatile("s_waitcnt lgkmcnt(0)" ::: "memory");
        __builtin_amdgcn_s_setprio(1);
#pragma unroll
        for (int i = 0; i < 4; ++i)
#pragma unroll
            for (int j = 0; j < 2; ++j)
#pragma unroll
                for (int kk = 0; kk < 2; ++kk)
                    acc[i][j + 2] = __builtin_amdgcn_mfma_f32_16x16x32_bf16(alo[i][kk], b23[j][kk], acc[i][j + 2], 0, 0, 0);
        __builtin_amdgcn_s_setprio(0);
        __builtin_amdgcn_s_barrier();

#pragma unroll
        for (int i = 0; i < 4; ++i)
#pragma unroll
            for (int kk = 0; kk < 2; ++kk)
                ahi[i][kk] = frag(ab, wr + (i + 4) * 16 + l15, kk * 32 + l4 * 8);
        if (kt + 2 < nt) stageB(bb, kc2, 1);
        __builtin_amdgcn_s_barrier();
        asm volatile("s_waitcnt lgkmcnt(0)" ::: "memory");
        __builtin_amdgcn_s_setprio(1);
#pragma unroll
        for (int i = 0; i < 4; ++i)
#pragma unroll
            for (int j = 0; j < 2; ++j)
#pragma unroll
                for (int kk = 0; kk < 2; ++kk)
                    acc[i + 4][j + 2] = __builtin_amdgcn_mfma_f32_16x16x32_bf16(ahi[i][kk], b23[j][kk], acc[i + 4][j + 2], 0, 0, 0);
        __builtin_amdgcn_s_setprio(0);
        __builtin_amdgcn_s_barrier();

        if (kt + 2 < nt) stageA(ab, kc2, 0);
        __builtin_amdgcn_s_barrier();
        __builtin_amdgcn_s_setprio(1);
#pragma unroll
        for (int i = 0; i < 4; ++i)
#pragma unroll
            for (int j = 0; j < 2; ++j)
#pragma unroll
                for (int kk = 0; kk < 2; ++kk)
                    acc[i + 4][j] = __builtin_amdgcn_mfma_f32_16x16x32_bf16(ahi[i][kk], b01[j][kk], acc[i + 4][j], 0, 0, 0);
        __builtin_amdgcn_s_setprio(0);
        if (kt + 2 < nt) {
            asm volatile("s_waitcnt vmcnt(6)" ::: "memory");
        } else {
            asm volatile("s_waitcnt vmcnt(0)" ::: "memory");
        }
        __builtin_amdgcn_s_barrier();
    }

    if (conv) {
        u16* Cp = Cp3 + (long)tap * 4194304;
#pragma unroll
        for (int i = 0; i < 8; ++i)
#pragma unroll
            for (int j = 0; j < 4; ++j) {
                const int n = n0 + wc + j * 16 + l15;
#pragma unroll
                for (int q = 0; q < 4; ++q) {
                    const int m = m0 + wr + i * 16 + l4 * 4 + q;
                    Cp[(long)m * 1024 + n] = f2bf(acc[i][j][q]);
                }
            }
    } else {
#pragma unroll
        for (int i = 0; i < 8; ++i)
#pragma unroll
            for (int j = 0; j < 4; ++j) {
                const int n = n0 + wc + j * 16 + l15;
#pragma unroll
                for (int q = 0; q < 4; ++q) {
                    const int m = m0 + wr + i * 16 + l4 * 4 + q;
                    Hout[(long)m * 4096 + n] = f2bf(fmaxf(acc[i][j][q], 0.f));
                }
            }
    }
}

// ============ fused attention: one K=512 concat score GEMM -> softmax -> PV ============
__global__ __launch_bounds__(256, 2)
void attn_fused_k(const u16* __restrict__ QKVb, const u16* __restrict__ erT,
                  const u16* __restrict__ Vt, const float* __restrict__ dwp,
                  u16* __restrict__ Oc)
{
    __shared__ __align__(16) u16 As[4096];
    __shared__ __align__(16) u16 Bs[16384];
    __shared__ __align__(16) u16 Pl[16384];
    __shared__ float redM[4][64];
    __shared__ float redS[4][64];
    const int z = blockIdx.y, zb = z >> 2, zn = z & 3;
    const int m0 = blockIdx.x * 64;
    const int tid = threadIdx.x;
    const int lane = tid & 63, wid = tid >> 6;
    const int l15 = lane & 15, l4 = lane >> 4;

    const u16* Qg = QKVb + (long)(zb * 256) * 3072 + zn * 256;
    const u16* Kg = Qg + 1024;   // holds K/32

    auto stageA64 = [&](const u16* g, long ld) {
#pragma unroll
        for (int p = 0; p < 2; ++p) {
            const int e = p * 2048 + tid * 8;
            const int r = e >> 6, c = e & 63;
            const int sc = c ^ SWZ(r);
            gld16(&As[e], g + (long)r * ld + sc);
        }
    };
    auto stageB256 = [&](const u16* g, long ld) {
#pragma unroll
        for (int p = 0; p < 8; ++p) {
            const int e = p * 2048 + tid * 8;
            const int r = e >> 6, c = e & 63;
            const int sc = c ^ SWZ(r);
            gld16(&Bs[e], g + (long)r * ld + sc);
        }
    };
    auto fragA = [&](int i, int kk) -> bf16x8 {
        const int row = i * 16 + l15, col = kk * 32 + l4 * 8;
        return *(const bf16x8*)&As[row * 64 + (col ^ SWZ(row))];
    };
    auto fragB = [&](int j, int kk) -> bf16x8 {
        const int row = wid * 64 + j * 16 + l15, col = kk * 32 + l4 * 8;
        return *(const bf16x8*)&Bs[row * 64 + (col ^ SWZ(row))];
    };
    auto fragP = [&](int kc, int i, int kk) -> bf16x8 {
        const int row = i * 16 + l15, col = kk * 32 + l4 * 8;
        return *(const bf16x8*)&Pl[kc * 4096 + row * 64 + (col ^ SWZ(row))];
    };

    f32x4 acc1[4][4] = {};

    // single K=512 concat loop: kc<4 -> Q x K~ ; kc>=4 -> erT x Q
    for (int kc = 0; kc < 8; ++kc) {
        __syncthreads();
        if (kc < 4) {
            stageA64(Qg + (long)m0 * 3072 + kc * 64, 3072);
            stageB256(Kg + kc * 64, 3072);
        } else {
            stageA64(erT + (long)m0 * 256 + (kc - 4) * 64, 256);
            stageB256(Qg + (kc - 4) * 64, 3072);
        }
        __syncthreads();
#pragma unroll
        for (int i = 0; i < 4; ++i) {
            const bf16x8 a0 = fragA(i, 0), a1 = fragA(i, 1);
#pragma unroll
            for (int j = 0; j < 4; ++j) {
                acc1[i][j] = __builtin_amdgcn_mfma_f32_16x16x32_bf16(a0, fragB(j, 0), acc1[i][j], 0, 0, 0);
                acc1[i][j] = __builtin_amdgcn_mfma_f32_16x16x32_bf16(a1, fragB(j, 1), acc1[i][j], 0, 0, 0);
            }
        }
    }

    // + dist term
#pragma unroll
    for (int i = 0; i < 4; ++i)
#pragma unroll
        for (int q = 0; q < 4; ++q) {
            const int mg = m0 + i * 16 + l4 * 4 + q;
            const float dw = dwp[zn * 256 + mg];
#pragma unroll
            for (int j = 0; j < 4; ++j) {
                const int ng = wid * 64 + j * 16 + l15;
                acc1[i][j][q] += fabsf((float)(mg - ng)) * 0.5f * dw;
            }
        }

    float rmax[4][4], rsum[4][4];
#pragma unroll
    for (int i = 0; i < 4; ++i)
#pragma unroll
        for (int q = 0; q < 4; ++q) {
            float mv = fmaxf(fmaxf(acc1[i][0][q], acc1[i][1][q]),
                             fmaxf(acc1[i][2][q], acc1[i][3][q]));
#pragma unroll
            for (int off = 1; off <= 8; off <<= 1) mv = fmaxf(mv, __shfl_xor(mv, off, 64));
            rmax[i][q] = mv;
        }
    if (l15 == 0) {
#pragma unroll
        for (int i = 0; i < 4; ++i)
#pragma unroll
            for (int q = 0; q < 4; ++q)
                redM[wid][i * 16 + l4 * 4 + q] = rmax[i][q];
    }
    __syncthreads();
#pragma unroll
    for (int i = 0; i < 4; ++i)
#pragma unroll
        for (int q = 0; q < 4; ++q) {
            const int ml = i * 16 + l4 * 4 + q;
            rmax[i][q] = fmaxf(fmaxf(redM[0][ml], redM[1][ml]), fmaxf(redM[2][ml], redM[3][ml]));
        }
#pragma unroll
    for (int i = 0; i < 4; ++i)
#pragma unroll
        for (int q = 0; q < 4; ++q) {
            float sv = 0.f;
#pragma unroll
            for (int j = 0; j < 4; ++j) {
                const float e = __expf(acc1[i][j][q] - rmax[i][q]);
                acc1[i][j][q] = e;
                sv += e;
            }
#pragma unroll
            for (int off = 1; off <= 8; off <<= 1) sv += __shfl_xor(sv, off, 64);
            rsum[i][q] = sv;
        }
    if (l15 == 0) {
#pragma unroll
        for (int i = 0; i < 4; ++i)
#pragma unroll
            for (int q = 0; q < 4; ++q)
                redS[wid][i * 16 + l4 * 4 + q] = rsum[i][q];
    }
    __syncthreads();
#pragma unroll
    for (int i = 0; i < 4; ++i)
#pragma unroll
        for (int q = 0; q < 4; ++q) {
            const int ml = i * 16 + l4 * 4 + q;
            rsum[i][q] = redS[0][ml] + redS[1][ml] + redS[2][ml] + redS[3][ml];
        }
#pragma unroll
    for (int i = 0; i < 4; ++i)
#pragma unroll
        for (int q = 0; q < 4; ++q) {
            const float rinv = 1.f / rsum[i][q];
            const int ml = i * 16 + l4 * 4 + q;
#pragma unroll
            for (int j = 0; j < 4; ++j) {
                const int nc = j * 16 + l15;
                Pl[wid * 4096 + ml * 64 + (nc ^ SWZ(ml))] = f2bf(acc1[i][j][q] * rinv);
            }
        }
    __syncthreads();

    f32x4 accO[4][4] = {};
    for (int kc = 0; kc < 4; ++kc) {
        __syncthreads();
        stageB256(Vt + (long)(z * 256) * 256 + kc * 64, 256);
        __syncthreads();
#pragma unroll
        for (int i = 0; i < 4; ++i) {
            const bf16x8 a0 = fragP(kc, i, 0), a1 = fragP(kc, i, 1);
#pragma unroll
            for (int j = 0; j < 4; ++j) {
                accO[i][j] = __builtin_amdgcn_mfma_f32_16x16x32_bf16(a0, fragB(j, 0), accO[i][j], 0, 0, 0);
                accO[i][j] = __builtin_amdgcn_mfma_f32_16x16x32_bf16(a1, fragB(j, 1), accO[i][j], 0, 0, 0);
            }
        }
    }

#pragma unroll
    for (int i = 0; i < 4; ++i)
#pragma unroll
        for (int j = 0; j < 4; ++j) {
            const int d = wid * 64 + j * 16 + l15;
#pragma unroll
            for (int q = 0; q < 4; ++q) {
                const int mg = m0 + i * 16 + l4 * 4 + q;
                Oc[(long)(zb * 256 + mg) * 1024 + zn * 256 + d] = f2bf(accO[i][j][q]);
            }
        }
}

// ---------------- GLU gate + residual + LN (bf16 chain, 2 bf16 partials) ----------------
__global__ __launch_bounds__(256)
void glu_ln_k(const u16* __restrict__ xs0, const u16* __restrict__ g2,
              const float* __restrict__ gam, const float* __restrict__ bet,
              u16* __restrict__ outb)
{
    const int t = blockIdx.x, tid = threadIdx.x;
    const int f0 = tid * 4;
    const long PS = 8388608;
    const float4 xv = bf4f(*(const ushort4*)&xs0[(long)t * 1024 + f0]);
    const float4 a0 = bf4f(*(const ushort4*)&g2[(long)t * 2048 + f0]);
    const float4 g0 = bf4f(*(const ushort4*)&g2[(long)t * 2048 + 1024 + f0]);
    const float4 a1 = bf4f(*(const ushort4*)&g2[PS + (long)t * 2048 + f0]);
    const float4 g1 = bf4f(*(const ushort4*)&g2[PS + (long)t * 2048 + 1024 + f0]);
    const float ax = a0.x + a1.x, ay = a0.y + a1.y, az = a0.z + a1.z, aw = a0.w + a1.w;
    const float gx = g0.x + g1.x, gy = g0.y + g1.y, gz = g0.z + g1.z, gw = g0.w + g1.w;
    float vals[4];
    vals[0] = xv.x + ax / (1.f + expf(-gx));
    vals[1] = xv.y + ay / (1.f + expf(-gy));
    vals[2] = xv.z + az / (1.f + expf(-gz));
    vals[3] = xv.w + aw / (1.f + expf(-gw));
    float s1 = vals[0] + vals[1] + vals[2] + vals[3];
    float s2 = vals[0]*vals[0] + vals[1]*vals[1] + vals[2]*vals[2] + vals[3]*vals[3];
    block_red2(s1, s2, tid);
    const float mean = s1 * (1.f / 1024.f);
    const float var  = s2 * (1.f / 1024.f) - mean * mean;
    const float rstd = rsqrtf(var + EPSF);
    const float4 gm = *(const float4*)&gam[f0];
    const float4 bt = *(const float4*)&bet[f0];
    *(ushort4*)&outb[(long)t * 1024 + f0] = f4bf(
        (vals[0] - mean) * rstd * gm.x + bt.x,
        (vals[1] - mean) * rstd * gm.y + bt.y,
        (vals[2] - mean) * rstd * gm.z + bt.z,
        (vals[3] - mean) * rstd * gm.w + bt.w);
}

// ---------------- residual add + LN width 1024 (bf16 chain, P bf16 partials, opt bias) ----------------
template<int P, int BIAS>
__global__ __launch_bounds__(256)
void add_ln1024_k(const u16* __restrict__ A, const u16* __restrict__ Bp,
                  const float* __restrict__ bias,
                  const float* __restrict__ gam, const float* __restrict__ bet,
                  u16* __restrict__ outb)
{
    const int t = blockIdx.x, tid = threadIdx.x;
    const int f0 = tid * 4;
    const long PS = 4194304;
    const float4 a = bf4f(*(const ushort4*)&A[(long)t * 1024 + f0]);
    float4 b = bf4f(*(const ushort4*)&Bp[(long)t * 1024 + f0]);
#pragma unroll
    for (int p = 1; p < P; ++p) {
        const float4 bp = bf4f(*(const ushort4*)&Bp[p * PS + (long)t * 1024 + f0]);
        b.x += bp.x; b.y += bp.y; b.z += bp.z; b.w += bp.w;
    }
    if (BIAS) {
        const float4 bb = *(const float4*)&bias[f0];
        b.x += bb.x; b.y += bb.y; b.z += bb.z; b.w += bb.w;
    }
    float vals[4] = {a.x + b.x, a.y + b.y, a.z + b.z, a.w + b.w};
    float s1 = vals[0] + vals[1] + vals[2] + vals[3];
    float s2 = vals[0]*vals[0] + vals[1]*vals[1] + vals[2]*vals[2] + vals[3]*vals[3];
    block_red2(s1, s2, tid);
    const float mean = s1 * (1.f / 1024.f);
    const float var  = s2 * (1.f / 1024.f) - mean * mean;
    const float rstd = rsqrtf(var + EPSF);
    const float4 gm = *(const float4*)&gam[f0];
    const float4 bt = *(const float4*)&bet[f0];
    *(ushort4*)&outb[(long)t * 1024 + f0] = f4bf(
        (vals[0] - mean) * rstd * gm.x + bt.x,
        (vals[1] - mean) * rstd * gm.y + bt.y,
        (vals[2] - mean) * rstd * gm.z + bt.z,
        (vals[3] - mean) * rstd * gm.w + bt.w);
}

// ---------------- n2: LN(c1L(bf16) + pad(relu(sum of 3 bf16 conv taps))) width 4096 ----------------
__global__ __launch_bounds__(256)
void add_ln4096_k(const u16* __restrict__ A, const u16* __restrict__ Bp,
                  const float* __restrict__ gam, const float* __restrict__ bet,
                  u16* __restrict__ outb)
{
    const int t = blockIdx.x, tid = threadIdx.x;
    const long PS = 4194304;
    const int f0 = tid * 16;
    float vals[16];
    const bf16x8 a0 = *(const bf16x8*)&A[(long)t * 4096 + f0];
    const bf16x8 a1 = *(const bf16x8*)&A[(long)t * 4096 + f0 + 8];
#pragma unroll
    for (int e = 0; e < 8; ++e) { vals[e] = bf2f((u16)a0[e]); vals[8 + e] = bf2f((u16)a1[e]); }
    if (tid < 64) {
#pragma unroll
        for (int c = 0; c < 4; ++c) {
            const int fc = f0 + c * 4;
            const float4 b0 = bf4f(*(const ushort4*)&Bp[(long)t * 1024 + fc]);
            const float4 b1 = bf4f(*(const ushort4*)&Bp[PS + (long)t * 1024 + fc]);
            const float4 b2 = bf4f(*(const ushort4*)&Bp[2 * PS + (long)t * 1024 + fc]);
            vals[c*4+0] += fmaxf(b0.x + b1.x + b2.x, 0.f);
            vals[c*4+1] += fmaxf(b0.y + b1.y + b2.y, 0.f);
            vals[c*4+2] += fmaxf(b0.z + b1.z + b2.z, 0.f);
            vals[c*4+3] += fmaxf(b0.w + b1.w + b2.w, 0.f);
        }
    }
    float s1 = 0.f, s2 = 0.f;
#pragma unroll
    for (int e = 0; e < 16; ++e) { s1 += vals[e]; s2 += vals[e] * vals[e]; }
    block_red2(s1, s2, tid);
    const float mean = s1 * (1.f / 4096.f);
    const float var  = s2 * (1.f / 4096.f) - mean * mean;
    const float rstd = rsqrtf(var + EPSF);
#pragma unroll
    for (int c = 0; c < 4; ++c) {
        const int fc = f0 + c * 4;
        const float4 gm = *(const float4*)&gam[fc];
        const float4 bt = *(const float4*)&bet[fc];
        *(ushort4*)&outb[(long)t * 4096 + fc] = f4bf(
            (vals[c*4+0] - mean) * rstd * gm.x + bt.x,
            (vals[c*4+1] - mean) * rstd * gm.y + bt.y,
            (vals[c*4+2] - mean) * rstd * gm.z + bt.z,
            (vals[c*4+3] - mean) * rstd * gm.w + bt.w);
    }
}

// ---------------- depthwise conv width-9, 8 channels/thread ----------------
__global__ __launch_bounds__(256)
void dwconv8_k(const u16* __restrict__ h, const float* __restrict__ wT,
               u16* __restrict__ out)
{
    const long idx = (long)blockIdx.x * 256 + threadIdx.x;
    const int cg = (int)(idx & 511);
    const int t  = (int)(idx >> 9);
    const int w  = t & 255;
    const int c0 = cg * 8;
    float acc[8] = {};
#pragma unroll
    for (int k = 0; k < 9; ++k) {
        const int wp = w + k - 4;
        if ((unsigned)wp < 256u) {
            const bf16x8 hv = *(const bf16x8*)&h[(long)(t + k - 4) * 4096 + c0];
            const float4 w0 = *(const float4*)&wT[k * 4096 + c0];
            const float4 w1 = *(const float4*)&wT[k * 4096 + c0 + 4];
            acc[0] += bf2f((u16)hv[0]) * w0.x;
            acc[1] += bf2f((u16)hv[1]) * w0.y;
            acc[2] += bf2f((u16)hv[2]) * w0.z;
            acc[3] += bf2f((u16)hv[3]) * w0.w;
            acc[4] += bf2f((u16)hv[4]) * w1.x;
            acc[5] += bf2f((u16)hv[5]) * w1.y;
            acc[6] += bf2f((u16)hv[6]) * w1.z;
            acc[7] += bf2f((u16)hv[7]) * w1.w;
        }
    }
    bf16x8 res;
#pragma unroll
    for (int j = 0; j < 8; ++j) res[j] = (short)f2bf(acc[j]);
    *(bf16x8*)&out[(long)t * 4096 + c0] = res;
}

// ---------------- V slice of QKVb -> Vt (z, d, w) bf16 ----------------
__global__ __launch_bounds__(256)
void vtrans_k(const u16* __restrict__ QKVb, u16* __restrict__ Vt)
{
    __shared__ u16 t[32][33];
    const int z = blockIdx.z, zb = z >> 2, zn = z & 3;
    const int w0 = blockIdx.x * 32, d0 = blockIdx.y * 32;
    const int tid = threadIdx.x, c = tid & 31, r = tid >> 5;
#pragma unroll
    for (int it = 0; it < 4; ++it) {
        const int wl = r + it * 8;
        t[wl][c] = QKVb[(long)(zb * 256 + w0 + wl) * 3072 + 2048 + zn * 256 + d0 + c];
    }
    __syncthreads();
#pragma unroll
    for (int it = 0; it < 4; ++it) {
        const int dl = r + it * 8;
        Vt[((long)z * 256 + d0 + dl) * 256 + w0 + c] = t[c][dl];
    }
}

// ---------------- final transpose: bf16 (tokens,1024) -> f32 (B,1,1024,256) ----------------
__global__ __launch_bounds__(256)
void transpose_out_k(const u16* __restrict__ xs, float* __restrict__ out)
{
    __shared__ u16 tile[32][34];
    const int b = blockIdx.z, f0 = blockIdx.y * 32, w0 = blockIdx.x * 32;
    const int tid = threadIdx.x, c = tid & 31, r = tid >> 5;
#pragma unroll
    for (int it = 0; it < 4; ++it) {
        const int w = w0 + r + it * 8;
        tile[r + it * 8][c] = xs[((long)b * 256 + w) * 1024 + f0 + c];
    }
    __syncthreads();
#pragma unroll
    for (int it = 0; it < 4; ++it) {
        const int fl = r + it * 8;
        out[((long)b * 1024 + f0 + fl) * 256 + w0 + c] = bf2f(tile[c][fl]);
    }
}

// =======================================================================
extern "C" void kernel_launch(void* const* d_in, const int* in_sizes, int n_in,
                              void* d_out, int out_size, void* d_ws, size_t ws_size,
                              hipStream_t stream)
{
    const float* x      = (const float*)d_in[0];
    const float* bott_w = (const float*)d_in[1];
    const float* bn_g   = (const float*)d_in[2];
    const float* bn_b   = (const float*)d_in[3];
    const float* bn_m   = (const float*)d_in[4];
    const float* bn_v   = (const float*)d_in[5];
    const float* glu_w  = (const float*)d_in[6];
    const float* n1g    = (const float*)d_in[7];
    const float* n1b    = (const float*)d_in[8];
    const float* c1L_w  = (const float*)d_in[9];
    const float* c1R_w  = (const float*)d_in[10];
    const float* n2g    = (const float*)d_in[11];
    const float* n2b    = (const float*)d_in[12];
    const float* c2dw_w = (const float*)d_in[13];
    const float* c2pw_w = (const float*)d_in[14];
    const float* n3g    = (const float*)d_in[15];
    const float* n3b    = (const float*)d_in[16];
    const float* qw     = (const float*)d_in[17];
    const float* qb     = (const float*)d_in[18];
    const float* kw     = (const float*)d_in[19];
    const float* kb     = (const float*)d_in[20];
    const float* vw     = (const float*)d_in[21];
    const float* vb     = (const float*)d_in[22];
    const float* ow     = (const float*)d_in[23];
    const float* ob     = (const float*)d_in[24];
    const float* er     = (const float*)d_in[25];
    const float* dist_w = (const float*)d_in[26];
    const float* n4g    = (const float*)d_in[27];
    const float* n4b    = (const float*)d_in[28];
    const float* c3_w   = (const float*)d_in[29];
    const float* c4_w   = (const float*)d_in[30];
    const float* n5g    = (const float*)d_in[31];
    const float* n5b    = (const float*)d_in[32];
    float* out = (float*)d_out;

    // ---- workspace layout (MiB offsets, bf16 residual chain) ----
    char* Wb_ = (char*)d_ws;
    auto Bf = [&](size_t mib) { return (u16*)(Wb_ + (mib << 20)); };
    u16* XA   = Bf(0);    // xs0 (1-3), xs2 (9-13), xs4 (16-17)
    u16* XB   = Bf(8);    // xs1 (3-9), xs3 (13-16)
    u16* H0b  = Bf(32);   // c1L out (4-6) / c3 out (14-15)
    u16* Hglu = Bf(64);   // GLU 2 bf16 partials (2-3)
    u16* C3p  = Bf(64);   // conv3 3 bf16 partials (5-6)
    u16* P4   = Bf(64);   // c2pw/O-proj/c4 4 bf16 partials
    u16* H1b  = Bf(128);  // n2 out (6-7)
    u16* Hdw  = Bf(160);  // dwconv out (7-8)
    u16* QKVb = Bf(192);  // QKV out 4096x3072 (10-11)
    u16* Vt   = Bf(216);  // V transposed (10b-11)
    u16* S1b  = Bf(264);  // attn concat out (11-12)
    u16* wGLU = Bf(296); u16* wC1L = Bf(300); u16* wC1R = Bf(308);
    u16* wC2P = Bf(314); u16* wQKV = Bf(322); u16* wO   = Bf(328);
    u16* wC3  = Bf(330); u16* wC4  = Bf(338);
    u16* erT  = Bf(346);
    u16* zp   = (u16*)(Wb_ + (346u << 20) + 131072);
    float* wdwT = (float*)(Wb_ + (346u << 20) + 131072 + 16384);
    float* bQKV = (float*)(Wb_ + (346u << 20) + 131072 + 16384 + 147456);

    const dim3 blk(256);
    const dim3 blk8(512);
    const long PS1 = 4194304;   // 4096*1024 elements
    const size_t SH8 = 131072;  // 128 KiB dynamic LDS

    // 0. merged setup (one launch); kw/kb pre-scaled by 1/32
    SetupArgs sa;
    sa.ws[0] = glu_w;  sa.wd[0] = wGLU;            sa.wn[0] = 524288;
    sa.ws[1] = c1L_w;  sa.wd[1] = wC1L;            sa.wn[1] = 1048576;
    sa.ws[2] = c2pw_w; sa.wd[2] = wC2P;            sa.wn[2] = 1048576;
    sa.ws[3] = c3_w;   sa.wd[3] = wC3;             sa.wn[3] = 1048576;
    sa.ws[4] = c4_w;   sa.wd[4] = wC4;             sa.wn[4] = 1048576;
    sa.ws[5] = qw;     sa.wd[5] = wQKV;            sa.wn[5] = 262144;
    sa.ws[6] = kw;     sa.wd[6] = wQKV + 1048576;  sa.wn[6] = 262144;
    sa.ws[7] = vw;     sa.wd[7] = wQKV + 2097152;  sa.wn[7] = 262144;
    sa.ws[8] = ow;     sa.wd[8] = wO;              sa.wn[8] = 262144;
    sa.c1r = c1R_w; sa.c1rd = wC1R;
    sa.er  = er;    sa.erd  = erT;
    sa.dw  = c2dw_w; sa.dwd = wdwT;
    sa.qb = qb; sa.kb = kb; sa.vb = vb; sa.bcat = bQKV;
    sa.zp = zp;
    {
        int bc[14] = {2048, 4096, 4096, 4096, 4096, 1024, 1024, 1024, 1024,
                      12288, 256, 144, 12, 32};
        int acc = 0;
        for (int s = 0; s < 14; ++s) { sa.off[s] = acc; acc += bc[s]; }
        sa.off[14] = acc;
        setup_k<<<dim3(acc), blk, 0, stream>>>(sa);
    }

    // 1. bottleneck + BN + ReLU + transpose -> XA (xs0, bf16)
    bottleneck_k<<<dim3(8, 32, 16), blk, 0, stream>>>(x, bott_w, bn_g, bn_b, bn_m, bn_v, XA);

    // 2. GLU matmul, split-K=2 -> Hglu bf16 partials
    gemm8_k<0,0,0,2><<<dim3(8, 16, 2), blk8, SH8, stream>>>(XA, wGLU, nullptr, Hglu,
        2048, 512, 1024, 1024, (long)4096 * 2048);

    // 3. n1: LN(xs0 + a*sigmoid(g)) -> XB (xs1)
    glu_ln_k<<<dim3(4096), blk, 0, stream>>>(XA, Hglu, n1g, n1b, XB);

    // 4+5. merged c1L (relu -> H0b) + conv1R taps (-> C3p partials), one launch
    ffconv8_k<<<dim3(28, 16), blk8, SH8, stream>>>(XB, wC1L, wC1R, zp, H0b, C3p);

    // 6. n2: LN(H0b + pad(relu(sum taps))) -> H1b bf16
    add_ln4096_k<<<dim3(4096), blk, 0, stream>>>(H0b, C3p, n2g, n2b, H1b);

    // 7. depthwise conv9 (vectorized x8): H1b -> Hdw
    dwconv8_k<<<dim3(8192), blk, 0, stream>>>(H1b, wdwT, Hdw);

    // 8. c2pw, split-K=4 -> P4 bf16 partials
    gemm8_k<0,0,0,4><<<dim3(4, 16, 4), blk8, SH8, stream>>>(Hdw, wC2P, nullptr, P4,
        1024, 1024, 4096, 4096, PS1);

    // 9. n3: LN(xs1 + sum P4) -> XA (xs2)
    add_ln1024_k<4,0><<<dim3(4096), blk, 0, stream>>>(XB, P4, nullptr, n3g, n3b, XA);

    // 10. fused QKV projection (+concat bias; K-slice pre-scaled by 1/32) -> QKVb
    gemm8_k<0,1,1,1><<<dim3(12, 16, 1), blk8, SH8, stream>>>(XA, wQKV, bQKV, QKVb,
        3072, 1024, 1024, 1024, 0);

    // 10b. V transpose per head -> Vt (z, d, w)
    vtrans_k<<<dim3(8, 8, 64), blk, 0, stream>>>(QKVb, Vt);

    // 11. fused attention: K=512 concat scores + softmax + PV -> S1b
    attn_fused_k<<<dim3(4, 64), blk, 0, stream>>>(QKVb, erT, Vt, dist_w, S1b);

    // 12. output projection, split-K=4 -> P4 bf16 partials (bias added in n4)
    gemm8_k<0,0,0,4><<<dim3(4, 16, 4), blk8, SH8, stream>>>(S1b, wO, nullptr, P4,
        1024, 256, 1024, 1024, PS1);

    // 13. n4: LN(xs2 + sum P4 + ob) -> XB (xs3)
    add_ln1024_k<4,1><<<dim3(4096), blk, 0, stream>>>(XA, P4, ob, n4g, n4b, XB);

    // 14. c3: relu -> H0b bf16
    gemm8_k<1,1,0,1><<<dim3(16, 16, 1), blk8, SH8, stream>>>(XB, wC3, nullptr, H0b,
        4096, 1024, 1024, 1024, 0);

    // 15. c4, split-K=4 -> P4 bf16 partials
    gemm8_k<0,0,0,4><<<dim3(4, 16, 4), blk8, SH8, stream>>>(H0b, wC4, nullptr, P4,
        1024, 1024, 4096, 4096, PS1);

    // 16. n5: LN(xs3 + sum P4) -> XA (xs4, bf16)
    add_ln1024_k<4,0><<<dim3(4096), blk, 0, stream>>>(XB, P4, nullptr, n5g, n5b, XA);

    // 17. transpose to (B, 1, 1024, 256) f32
    transpose_out_k<<<dim3(8, 32, 16), blk, 0, stream>>>(XA, out);

    (void)in_sizes; (void)n_in; (void)out_size; (void)ws_size;
}

// Round 11
// 465.172 us; speedup vs baseline: 7.5044x; 1.0067x over previous
//
#include <hip/hip_runtime.h>
#include <hip/hip_bf16.h>

// FrameTransformer: B=16, C=8, BINS=1024, W=256, FF=2048, NB=4
// tokens = B*W = 4096, feature width 1024, FF width 4096, head dim 256.
#define EPSF 1e-5f

typedef unsigned short u16;
typedef unsigned int   u32;
typedef __attribute__((ext_vector_type(8))) short bf16x8;
typedef __attribute__((ext_vector_type(4))) float f32x4;

// 3-bit XOR swizzle for 64-elem (128 B) LDS rows.
#define SWZ(row) (((row) & 7) << 3)

__device__ __forceinline__ u16 f2bf(float f) {
    u32 u = __builtin_bit_cast(u32, f);
    u32 r = u + 0x7fffu + ((u >> 16) & 1u);
    return (u16)(r >> 16);
}
__device__ __forceinline__ float bf2f(u16 h) {
    return __builtin_bit_cast(float, (u32)h << 16);
}
__device__ __forceinline__ float4 bf4f(ushort4 v) {
    return make_float4(bf2f(v.x), bf2f(v.y), bf2f(v.z), bf2f(v.w));
}
__device__ __forceinline__ ushort4 f4bf(float a, float b, float c, float d) {
    ushort4 o; o.x = f2bf(a); o.y = f2bf(b); o.z = f2bf(c); o.w = f2bf(d); return o;
}
__device__ __forceinline__ void gld16(void* lds, const void* gsrc) {
    __builtin_amdgcn_global_load_lds(
        (const __attribute__((address_space(1))) u32*)gsrc,
        (__attribute__((address_space(3))) u32*)lds, 16, 0, 0);
}

__device__ __forceinline__ float wred_sum(float v) {
#pragma unroll
    for (int off = 32; off; off >>= 1) v += __shfl_xor(v, off, 64);
    return v;
}
__device__ __forceinline__ void block_red2(float& s1, float& s2, int tid) {
    __shared__ float red[8];
    s1 = wred_sum(s1); s2 = wred_sum(s2);
    const int lane = tid & 63, wid = tid >> 6;
    if (!lane) { red[wid] = s1; red[4 + wid] = s2; }
    __syncthreads();
    s1 = red[0] + red[1] + red[2] + red[3];
    s2 = red[4] + red[5] + red[6] + red[7];
}

// ---------------- merged setup: all weight conversions in one launch ----------------
// kw (seg 6) and kb (bias middle third) pre-scaled by 1/32 (skew fold).
struct SetupArgs {
    const float* ws[9]; u16* wd[9]; int wn[9];
    const float* c1r; u16* c1rd;
    const float* er;  u16* erd;
    const float* dw;  float* dwd;
    const float* qb;  const float* kb; const float* vb; float* bcat;
    u16* zp;
    int off[15];
};
__global__ __launch_bounds__(256)
void setup_k(SetupArgs a)
{
    const int b = blockIdx.x;
    int seg = 0;
    while (seg < 13 && b >= a.off[seg + 1]) ++seg;
    const int i = (b - a.off[seg]) * 256 + threadIdx.x;
    if (seg < 9) {
        if (i < a.wn[seg]) {
            const float4 v = ((const float4*)a.ws[seg])[i];
            const float s = (seg == 6) ? 0.03125f : 1.f;
            ((ushort4*)a.wd[seg])[i] = f4bf(v.x * s, v.y * s, v.z * s, v.w * s);
        }
    } else if (seg == 9) {
        if (i < 3145728) {
            const int q = i / 3072, rem = i - q * 3072;
            const int ks = rem >> 10, ci = rem & 1023;
            a.c1rd[i] = f2bf(a.c1r[((long)q * 1024 + ci) * 3 + ks]);
        }
    } else if (seg == 10) {
        if (i < 65536) { const int c = i >> 8, d = i & 255; a.erd[i] = f2bf(a.er[d * 256 + c]); }
    } else if (seg == 11) {
        if (i < 36864) { const int k = i >> 12, c = i & 4095; a.dwd[i] = a.dw[c * 9 + k]; }
    } else if (seg == 12) {
        if (i < 3072) {
            const float* s = (i < 1024) ? a.qb : ((i < 2048) ? a.kb : a.vb);
            float v = s[i & 1023];
            if (i >= 1024 && i < 2048) v *= 0.03125f;
            a.bcat[i] = v;
        }
    } else {
        if (i < 8192) a.zp[i] = 0;
    }
}

// ---------------- stage 1: bottleneck 1x1 conv + BN + ReLU + transpose (bf16 out) ----------------
// float4-vectorized x loads: thread (tw=tid&7, th=tid>>3) covers 4 w at row th.
__global__ __launch_bounds__(256)
void bottleneck_k(const float* __restrict__ x, const float* __restrict__ bw,
                  const float* __restrict__ bn_g, const float* __restrict__ bn_b,
                  const float* __restrict__ bn_m, const float* __restrict__ bn_v,
                  u16* __restrict__ xsb)
{
    __shared__ float tile[32][33];
    const int b = blockIdx.z, h0 = blockIdx.y * 32, w0 = blockIdx.x * 32;
    const int tid = threadIdx.x;
    const int tw = tid & 7, th = tid >> 3;            // 8 w-groups x 32 h-rows
    float wreg[8];
#pragma unroll
    for (int ch = 0; ch < 8; ++ch) wreg[ch] = bw[ch];
    const float sc = bn_g[0] * rsqrtf(bn_v[0] + EPSF);
    const float sh = bn_b[0] - bn_m[0] * sc;
    float4 acc = make_float4(0.f, 0.f, 0.f, 0.f);
#pragma unroll
    for (int ch = 0; ch < 8; ++ch) {
        const float4 v = *(const float4*)&x[(((long)b * 8 + ch) * 1024 + h0 + th) * 256 + w0 + tw * 4];
        acc.x += v.x * wreg[ch]; acc.y += v.y * wreg[ch];
        acc.z += v.z * wreg[ch]; acc.w += v.w * wreg[ch];
    }
    tile[th][tw * 4 + 0] = fmaxf(acc.x * sc + sh, 0.f);
    tile[th][tw * 4 + 1] = fmaxf(acc.y * sc + sh, 0.f);
    tile[th][tw * 4 + 2] = fmaxf(acc.z * sc + sh, 0.f);
    tile[th][tw * 4 + 3] = fmaxf(acc.w * sc + sh, 0.f);
    __syncthreads();
    const int c = tid & 31, r = tid >> 5;
#pragma unroll
    for (int it = 0; it < 4; ++it) {
        const int wl = r + it * 8;
        xsb[((long)b * 256 + w0 + wl) * 1024 + h0 + c] = f2bf(tile[c][wl]);
    }
}

// ============ 8-phase 256x256 bf16 MFMA GEMM (T2+T3+T4+T5) ============
// VOUT: for N-tiles with n0>=2048 (V region of fused QKV), write the output
// transposed per head into Vtp[(z*256+d)*256+w] instead of Cout.
template<int ACT, int OUTBF, int BIAS, int SPLITK, int VOUT>
__global__ __launch_bounds__(512, 2)
void gemm8_k(const u16* __restrict__ A, const u16* __restrict__ B,
             const float* __restrict__ bias, void* __restrict__ Cout,
             int N, int K /*per slice*/, int lda, int ldb, long partStride,
             u16* __restrict__ Vtp)
{
    extern __shared__ u16 lds[];
    const int m0 = blockIdx.y * 256, n0 = blockIdx.x * 256;
    const int koff = (SPLITK > 1) ? blockIdx.z * K : 0;
    const int nt = K >> 6;
    const int tid = threadIdx.x;
    const int lane = tid & 63, wid = tid >> 6;
    const int wr = ((wid >> 2) & 1) * 128;
    const int wc = (wid & 3) * 64;
    const int l15 = lane & 15, l4 = lane >> 4;

    const u16* Ag = A + (long)m0 * lda + koff;
    const u16* Bg = B + (long)n0 * ldb + koff;

    auto stage = [&](const u16* g, int ld, int ldsbase, int kcol, int h) {
#pragma unroll
        for (int is = 0; is < 2; ++is) {
            const int r = h * 128 + is * 64 + (tid >> 3);
            const int sc = ((tid & 7) * 8) ^ SWZ(r);
            gld16(&lds[ldsbase + h * 8192 + is * 4096 + tid * 8],
                  g + (long)r * ld + kcol + sc);
        }
    };
    auto frag = [&](int base, int row, int col) -> bf16x8 {
        return *(const bf16x8*)&lds[base + row * 64 + (col ^ SWZ(row))];
    };

    f32x4 acc[8][4] = {};

    stage(Ag, lda, 0, 0, 0);
    stage(Ag, lda, 0, 0, 1);
    stage(Bg, ldb, 32768, 0, 0);
    stage(Bg, ldb, 32768, 0, 1);
    if (nt > 1) {
        stage(Bg, ldb, 49152, 64, 0);
        stage(Bg, ldb, 49152, 64, 1);
        stage(Ag, lda, 16384, 64, 0);
        asm volatile("s_waitcnt vmcnt(6)" ::: "memory");
    } else {
        asm volatile("s_waitcnt vmcnt(0)" ::: "memory");
    }
    __builtin_amdgcn_s_barrier();

    for (int kt = 0; kt < nt; ++kt) {
        const int cs = kt & 1;
        const int ab = cs * 16384;
        const int bb = 32768 + cs * 16384;
        const int abn = (cs ^ 1) * 16384;
        const int kc1 = (kt + 1) * 64, kc2 = (kt + 2) * 64;
        bf16x8 alo[4][2], ahi[4][2], b01[2][2], b23[2][2];

#pragma unroll
        for (int i = 0; i < 4; ++i)
#pragma unroll
            for (int kk = 0; kk < 2; ++kk)
                alo[i][kk] = frag(ab, wr + i * 16 + l15, kk * 32 + l4 * 8);
#pragma unroll
        for (int j = 0; j < 2; ++j)
#pragma unroll
            for (int kk = 0; kk < 2; ++kk)
                b01[j][kk] = frag(bb, wc + j * 16 + l15, kk * 32 + l4 * 8);
        if (kt + 1 < nt) stage(Ag, lda, abn, kc1, 1);
        __builtin_amdgcn_s_barrier();
        asm volatile("s_waitcnt lgkmcnt(0)" ::: "memory");
        __builtin_amdgcn_s_setprio(1);
#pragma unroll
        for (int i = 0; i < 4; ++i)
#pragma unroll
            for (int j = 0; j < 2; ++j)
#pragma unroll
                for (int kk = 0; kk < 2; ++kk)
                    acc[i][j] = __builtin_amdgcn_mfma_f32_16x16x32_bf16(alo[i][kk], b01[j][kk], acc[i][j], 0, 0, 0);
        __builtin_amdgcn_s_setprio(0);
        __builtin_amdgcn_s_barrier();

#pragma unroll
        for (int j = 0; j < 2; ++j)
#pragma unroll
            for (int kk = 0; kk < 2; ++kk)
                b23[j][kk] = frag(bb, wc + (j + 2) * 16 + l15, kk * 32 + l4 * 8);
        if (kt + 2 < nt) stage(Bg, ldb, bb, kc2, 0);
        __builtin_amdgcn_s_barrier();
        asm volatile("s_waitcnt lgkmcnt(0)" ::: "memory");
        __builtin_amdgcn_s_setprio(1);
#pragma unroll
        for (int i = 0; i < 4; ++i)
#pragma unroll
            for (int j = 0; j < 2; ++j)
#pragma unroll
                for (int kk = 0; kk < 2; ++kk)
                    acc[i][j + 2] = __builtin_amdgcn_mfma_f32_16x16x32_bf16(alo[i][kk], b23[j][kk], acc[i][j + 2], 0, 0, 0);
        __builtin_amdgcn_s_setprio(0);
        __builtin_amdgcn_s_barrier();

#pragma unroll
        for (int i = 0; i < 4; ++i)
#pragma unroll
            for (int kk = 0; kk < 2; ++kk)
                ahi[i][kk] = frag(ab, wr + (i + 4) * 16 + l15, kk * 32 + l4 * 8);
        if (kt + 2 < nt) stage(Bg, ldb, bb, kc2, 1);
        __builtin_amdgcn_s_barrier();
        asm volatile("s_waitcnt lgkmcnt(0)" ::: "memory");
        __builtin_amdgcn_s_setprio(1);
#pragma unroll
        for (int i = 0; i < 4; ++i)
#pragma unroll
            for (int j = 0; j < 2; ++j)
#pragma unroll
                for (int kk = 0; kk < 2; ++kk)
                    acc[i + 4][j + 2] = __builtin_amdgcn_mfma_f32_16x16x32_bf16(ahi[i][kk], b23[j][kk], acc[i + 4][j + 2], 0, 0, 0);
        __builtin_amdgcn_s_setprio(0);
        __builtin_amdgcn_s_barrier();

        if (kt + 2 < nt) stage(Ag, lda, ab, kc2, 0);
        __builtin_amdgcn_s_barrier();
        __builtin_amdgcn_s_setprio(1);
#pragma unroll
        for (int i = 0; i < 4; ++i)
#pragma unroll
            for (int j = 0; j < 2; ++j)
#pragma unroll
                for (int kk = 0; kk < 2; ++kk)
                    acc[i + 4][j] = __builtin_amdgcn_mfma_f32_16x16x32_bf16(ahi[i][kk], b01[j][kk], acc[i + 4][j], 0, 0, 0);
        __builtin_amdgcn_s_setprio(0);
        if (kt + 2 < nt) {
            asm volatile("s_waitcnt vmcnt(6)" ::: "memory");
        } else {
            asm volatile("s_waitcnt vmcnt(0)" ::: "memory");
        }
        __builtin_amdgcn_s_barrier();
    }

    if (VOUT && n0 >= 2048) {
        // V region of fused QKV: write transposed per head.
        const int zb4 = (m0 >> 8) * 4;
#pragma unroll
        for (int i = 0; i < 8; ++i)
#pragma unroll
            for (int j = 0; j < 4; ++j) {
                const int n = n0 + wc + j * 16 + l15;
                const int d = n - 2048, zn = d >> 8, dl = d & 255;
                const float bv = BIAS ? bias[n] : 0.f;
                const int w = wr + i * 16 + l4 * 4;
                ushort4 st = f4bf(acc[i][j][0] + bv, acc[i][j][1] + bv,
                                  acc[i][j][2] + bv, acc[i][j][3] + bv);
                *(ushort4*)&Vtp[((long)(zb4 + zn) * 256 + dl) * 256 + w] = st;
            }
    } else if (SPLITK > 1) {
        u16* Cp = (u16*)Cout + (long)blockIdx.z * partStride;
#pragma unroll
        for (int i = 0; i < 8; ++i)
#pragma unroll
            for (int j = 0; j < 4; ++j) {
                const int n = n0 + wc + j * 16 + l15;
#pragma unroll
                for (int q = 0; q < 4; ++q) {
                    const int m = m0 + wr + i * 16 + l4 * 4 + q;
                    Cp[(long)m * N + n] = f2bf(acc[i][j][q]);
                }
            }
    } else {
        float* Cf = (float*)Cout;
        u16*   Cb = (u16*)Cout;
#pragma unroll
        for (int i = 0; i < 8; ++i)
#pragma unroll
            for (int j = 0; j < 4; ++j) {
                const int n = n0 + wc + j * 16 + l15;
                const float bv = BIAS ? bias[n] : 0.f;
#pragma unroll
                for (int q = 0; q < 4; ++q) {
                    const int m = m0 + wr + i * 16 + l4 * 4 + q;
                    float v = acc[i][j][q] + bv;
                    if (ACT) v = fmaxf(v, 0.f);
                    if (OUTBF) Cb[(long)m * N + n] = f2bf(v);
                    else       Cf[(long)m * N + n] = v;
                }
            }
    }
}

// ============ merged c1L + conv1R launch (8-phase body, K=1024, nt=16) ============
__global__ __launch_bounds__(512, 2)
void ffconv8_k(const u16* __restrict__ Xb, const u16* __restrict__ Wl,
               const u16* __restrict__ Wr, const u16* __restrict__ zp,
               u16* __restrict__ Hout, u16* __restrict__ Cp3)
{
    extern __shared__ u16 lds[];
    const int bx = blockIdx.x;
    const int m0 = blockIdx.y * 256;
    const bool conv = bx >= 16;
    const int tap  = conv ? ((bx - 16) >> 2) : 0;
    const int shift = conv ? (tap - 1) : 0;
    const int n0 = conv ? (((bx - 16) & 3) * 256) : (bx * 256);
    const u16* Bbase = conv ? (Wr + (long)n0 * 3072 + tap * 1024)
                            : (Wl + (long)n0 * 1024);
    const int ldb = conv ? 3072 : 1024;
    const int nt = 16;
    const int tid = threadIdx.x;
    const int lane = tid & 63, wid = tid >> 6;
    const int wr = ((wid >> 2) & 1) * 128;
    const int wc = (wid & 3) * 64;
    const int l15 = lane & 15, l4 = lane >> 4;

    auto stageA = [&](int ldsbase, int kcol, int h) {
#pragma unroll
        for (int is = 0; is < 2; ++is) {
            const int r = h * 128 + is * 64 + (tid >> 3);
            const int sc = ((tid & 7) * 8) ^ SWZ(r);
            const int t = m0 + r;
            const int wp = (t & 255) + shift;
            const u16* src = ((unsigned)wp < 256u)
                ? Xb + (long)(t + shift) * 1024 + kcol + sc
                : zp;
            gld16(&lds[ldsbase + h * 8192 + is * 4096 + tid * 8], src);
        }
    };
    auto stageB = [&](int ldsbase, int kcol, int h) {
#pragma unroll
        for (int is = 0; is < 2; ++is) {
            const int r = h * 128 + is * 64 + (tid >> 3);
            const int sc = ((tid & 7) * 8) ^ SWZ(r);
            gld16(&lds[ldsbase + h * 8192 + is * 4096 + tid * 8],
                  Bbase + (long)r * ldb + kcol + sc);
        }
    };
    auto frag = [&](int base, int row, int col) -> bf16x8 {
        return *(const bf16x8*)&lds[base + row * 64 + (col ^ SWZ(row))];
    };

    f32x4 acc[8][4] = {};

    stageA(0, 0, 0);
    stageA(0, 0, 1);
    stageB(32768, 0, 0);
    stageB(32768, 0, 1);
    stageB(49152, 64, 0);
    stageB(49152, 64, 1);
    stageA(16384, 64, 0);
    asm volatile("s_waitcnt vmcnt(6)" ::: "memory");
    __builtin_amdgcn_s_barrier();

    for (int kt = 0; kt < nt; ++kt) {
        const int cs = kt & 1;
        const int ab = cs * 16384;
        const int bb = 32768 + cs * 16384;
        const int abn = (cs ^ 1) * 16384;
        const int kc1 = (kt + 1) * 64, kc2 = (kt + 2) * 64;
        bf16x8 alo[4][2], ahi[4][2], b01[2][2], b23[2][2];

#pragma unroll
        for (int i = 0; i < 4; ++i)
#pragma unroll
            for (int kk = 0; kk < 2; ++kk)
                alo[i][kk] = frag(ab, wr + i * 16 + l15, kk * 32 + l4 * 8);
#pragma unroll
        for (int j = 0; j < 2; ++j)
#pragma unroll
            for (int kk = 0; kk < 2; ++kk)
                b01[j][kk] = frag(bb, wc + j * 16 + l15, kk * 32 + l4 * 8);
        if (kt + 1 < nt) stageA(abn, kc1, 1);
        __builtin_amdgcn_s_barrier();
        asm volatile("s_waitcnt lgkmcnt(0)" ::: "memory");
        __builtin_amdgcn_s_setprio(1);
#pragma unroll
        for (int i = 0; i < 4; ++i)
#pragma unroll
            for (int j = 0; j < 2; ++j)
#pragma unroll
                for (int kk = 0; kk < 2; ++kk)
                    acc[i][j] = __builtin_amdgcn_mfma_f32_16x16x32_bf16(alo[i][kk], b01[j][kk], acc[i][j], 0, 0, 0);
        __builtin_amdgcn_s_setprio(0);
        __builtin_amdgcn_s_barrier();

#pragma unroll
        for (int j = 0; j < 2; ++j)
#pragma unroll
            for (int kk = 0; kk < 2; ++kk)
                b23[j][kk] = frag(bb, wc + (j + 2) * 16 + l15, kk * 32 + l4 * 8);
        if (kt + 2 < nt) stageB(bb, kc2, 0);
        __builtin_amdgcn_s_barrier();
        asm volatile("s_waitcnt lgkmcnt(0)" ::: "memory");
        __builtin_amdgcn_s_setprio(1);
#pragma unroll
        for (int i = 0; i < 4; ++i)
#pragma unroll
            for (int j = 0; j < 2; ++j)
#pragma unroll
                for (int kk = 0; kk < 2; ++kk)
                    acc[i][j + 2] = __builtin_amdgcn_mfma_f32_16x16x32_bf16(alo[i][kk], b23[j][kk], acc[i][j + 2], 0, 0, 0);
        __builtin_amdgcn_s_setprio(0);
        __builtin_amdgcn_s_barrier();

#pragma unroll
        for (int i = 0; i < 4; ++i)
#pragma unroll
            for (int kk = 0; kk < 2; ++kk)
                ahi[i][kk] = frag(ab, wr + (i + 4) * 16 + l15, kk * 32 + l4 * 8);
        if (kt + 2 < nt) stageB(bb, kc2, 1);
        __builtin_amdgcn_s_barrier();
        asm volatile("s_waitcnt lgkmcnt(0)" ::: "memory");
        __builtin_amdgcn_s_setprio(1);
#pragma unroll
        for (int i = 0; i < 4; ++i)
#pragma unroll
            for (int j = 0; j < 2; ++j)
#pragma unroll
                for (int kk = 0; kk < 2; ++kk)
                    acc[i + 4][j + 2] = __builtin_amdgcn_mfma_f32_16x16x32_bf16(ahi[i][kk], b23[j][kk], acc[i + 4][j + 2], 0, 0, 0);
        __builtin_amdgcn_s_setprio(0);
        __builtin_amdgcn_s_barrier();

        if (kt + 2 < nt) stageA(ab, kc2, 0);
        __builtin_amdgcn_s_barrier();
        __builtin_amdgcn_s_setprio(1);
#pragma unroll
        for (int i = 0; i < 4; ++i)
#pragma unroll
            for (int j = 0; j < 2; ++j)
#pragma unroll
                for (int kk = 0; kk < 2; ++kk)
                    acc[i + 4][j] = __builtin_amdgcn_mfma_f32_16x16x32_bf16(ahi[i][kk], b01[j][kk], acc[i + 4][j], 0, 0, 0);
        __builtin_amdgcn_s_setprio(0);
        if (kt + 2 < nt) {
            asm volatile("s_waitcnt vmcnt(6)" ::: "memory");
        } else {
            asm volatile("s_waitcnt vmcnt(0)" ::: "memory");
        }
        __builtin_amdgcn_s_barrier();
    }

    if (conv) {
        u16* Cp = Cp3 + (long)tap * 4194304;
#pragma unroll
        for (int i = 0; i < 8; ++i)
#pragma unroll
            for (int j = 0; j < 4; ++j) {
                const int n = n0 + wc + j * 16 + l15;
#pragma unroll
                for (int q = 0; q < 4; ++q) {
                    const int m = m0 + wr + i * 16 + l4 * 4 + q;
                    Cp[(long)m * 1024 + n] = f2bf(acc[i][j][q]);
                }
            }
    } else {
#pragma unroll
        for (int i = 0; i < 8; ++i)
#pragma unroll
            for (int j = 0; j < 4; ++j) {
                const int n = n0 + wc + j * 16 + l15;
#pragma unroll
                for (int q = 0; q < 4; ++q) {
                    const int m = m0 + wr + i * 16 + l4 * 4 + q;
                    Hout[(long)m * 4096 + n] = f2bf(fmaxf(acc[i][j][q], 0.f));
                }
            }
    }
}

// ============ fused attention: one K=512 concat score GEMM -> softmax -> PV ============
__global__ __launch_bounds__(256, 2)
void attn_fused_k(const u16* __restrict__ QKVb, const u16* __restrict__ erT,
                  const u16* __restrict__ Vt, const float* __restrict__ dwp,
                  u16* __restrict__ Oc)
{
    __shared__ __align__(16) u16 As[4096];
    __shared__ __align__(16) u16 Bs[16384];
    __shared__ __align__(16) u16 Pl[16384];
    __shared__ float redM[4][64];
    __shared__ float redS[4][64];
    const int z = blockIdx.y, zb = z >> 2, zn = z & 3;
    const int m0 = blockIdx.x * 64;
    const int tid = threadIdx.x;
    const int lane = tid & 63, wid = tid >> 6;
    const int l15 = lane & 15, l4 = lane >> 4;

    const u16* Qg = QKVb + (long)(zb * 256) * 3072 + zn * 256;
    const u16* Kg = Qg + 1024;   // holds K/32

    auto stageA64 = [&](const u16* g, long ld) {
#pragma unroll
        for (int p = 0; p < 2; ++p) {
            const int e = p * 2048 + tid * 8;
            const int r = e >> 6, c = e & 63;
            const int sc = c ^ SWZ(r);
            gld16(&As[e], g + (long)r * ld + sc);
        }
    };
    auto stageB256 = [&](const u16* g, long ld) {
#pragma unroll
        for (int p = 0; p < 8; ++p) {
            const int e = p * 2048 + tid * 8;
            const int r = e >> 6, c = e & 63;
            const int sc = c ^ SWZ(r);
            gld16(&Bs[e], g + (long)r * ld + sc);
        }
    };
    auto fragA = [&](int i, int kk) -> bf16x8 {
        const int row = i * 16 + l15, col = kk * 32 + l4 * 8;
        return *(const bf16x8*)&As[row * 64 + (col ^ SWZ(row))];
    };
    auto fragB = [&](int j, int kk) -> bf16x8 {
        const int row = wid * 64 + j * 16 + l15, col = kk * 32 + l4 * 8;
        return *(const bf16x8*)&Bs[row * 64 + (col ^ SWZ(row))];
    };
    auto fragP = [&](int kc, int i, int kk) -> bf16x8 {
        const int row = i * 16 + l15, col = kk * 32 + l4 * 8;
        return *(const bf16x8*)&Pl[kc * 4096 + row * 64 + (col ^ SWZ(row))];
    };

    f32x4 acc1[4][4] = {};

    for (int kc = 0; kc < 8; ++kc) {
        __syncthreads();
        if (kc < 4) {
            stageA64(Qg + (long)m0 * 3072 + kc * 64, 3072);
            stageB256(Kg + kc * 64, 3072);
        } else {
            stageA64(erT + (long)m0 * 256 + (kc - 4) * 64, 256);
            stageB256(Qg + (kc - 4) * 64, 3072);
        }
        __syncthreads();
#pragma unroll
        for (int i = 0; i < 4; ++i) {
            const bf16x8 a0 = fragA(i, 0), a1 = fragA(i, 1);
#pragma unroll
            for (int j = 0; j < 4; ++j) {
                acc1[i][j] = __builtin_amdgcn_mfma_f32_16x16x32_bf16(a0, fragB(j, 0), acc1[i][j], 0, 0, 0);
                acc1[i][j] = __builtin_amdgcn_mfma_f32_16x16x32_bf16(a1, fragB(j, 1), acc1[i][j], 0, 0, 0);
            }
        }
    }

#pragma unroll
    for (int i = 0; i < 4; ++i)
#pragma unroll
        for (int q = 0; q < 4; ++q) {
            const int mg = m0 + i * 16 + l4 * 4 + q;
            const float dw = dwp[zn * 256 + mg];
#pragma unroll
            for (int j = 0; j < 4; ++j) {
                const int ng = wid * 64 + j * 16 + l15;
                acc1[i][j][q] += fabsf((float)(mg - ng)) * 0.5f * dw;
            }
        }

    float rmax[4][4], rsum[4][4];
#pragma unroll
    for (int i = 0; i < 4; ++i)
#pragma unroll
        for (int q = 0; q < 4; ++q) {
            float mv = fmaxf(fmaxf(acc1[i][0][q], acc1[i][1][q]),
                             fmaxf(acc1[i][2][q], acc1[i][3][q]));
#pragma unroll
            for (int off = 1; off <= 8; off <<= 1) mv = fmaxf(mv, __shfl_xor(mv, off, 64));
            rmax[i][q] = mv;
        }
    if (l15 == 0) {
#pragma unroll
        for (int i = 0; i < 4; ++i)
#pragma unroll
            for (int q = 0; q < 4; ++q)
                redM[wid][i * 16 + l4 * 4 + q] = rmax[i][q];
    }
    __syncthreads();
#pragma unroll
    for (int i = 0; i < 4; ++i)
#pragma unroll
        for (int q = 0; q < 4; ++q) {
            const int ml = i * 16 + l4 * 4 + q;
            rmax[i][q] = fmaxf(fmaxf(redM[0][ml], redM[1][ml]), fmaxf(redM[2][ml], redM[3][ml]));
        }
#pragma unroll
    for (int i = 0; i < 4; ++i)
#pragma unroll
        for (int q = 0; q < 4; ++q) {
            float sv = 0.f;
#pragma unroll
            for (int j = 0; j < 4; ++j) {
                const float e = __expf(acc1[i][j][q] - rmax[i][q]);
                acc1[i][j][q] = e;
                sv += e;
            }
#pragma unroll
            for (int off = 1; off <= 8; off <<= 1) sv += __shfl_xor(sv, off, 64);
            rsum[i][q] = sv;
        }
    if (l15 == 0) {
#pragma unroll
        for (int i = 0; i < 4; ++i)
#pragma unroll
            for (int q = 0; q < 4; ++q)
                redS[wid][i * 16 + l4 * 4 + q] = rsum[i][q];
    }
    __syncthreads();
#pragma unroll
    for (int i = 0; i < 4; ++i)
#pragma unroll
        for (int q = 0; q < 4; ++q) {
            const int ml = i * 16 + l4 * 4 + q;
            rsum[i][q] = redS[0][ml] + redS[1][ml] + redS[2][ml] + redS[3][ml];
        }
#pragma unroll
    for (int i = 0; i < 4; ++i)
#pragma unroll
        for (int q = 0; q < 4; ++q) {
            const float rinv = 1.f / rsum[i][q];
            const int ml = i * 16 + l4 * 4 + q;
#pragma unroll
            for (int j = 0; j < 4; ++j) {
                const int nc = j * 16 + l15;
                Pl[wid * 4096 + ml * 64 + (nc ^ SWZ(ml))] = f2bf(acc1[i][j][q] * rinv);
            }
        }
    __syncthreads();

    f32x4 accO[4][4] = {};
    for (int kc = 0; kc < 4; ++kc) {
        __syncthreads();
        stageB256(Vt + (long)(z * 256) * 256 + kc * 64, 256);
        __syncthreads();
#pragma unroll
        for (int i = 0; i < 4; ++i) {
            const bf16x8 a0 = fragP(kc, i, 0), a1 = fragP(kc, i, 1);
#pragma unroll
            for (int j = 0; j < 4; ++j) {
                accO[i][j] = __builtin_amdgcn_mfma_f32_16x16x32_bf16(a0, fragB(j, 0), accO[i][j], 0, 0, 0);
                accO[i][j] = __builtin_amdgcn_mfma_f32_16x16x32_bf16(a1, fragB(j, 1), accO[i][j], 0, 0, 0);
            }
        }
    }

#pragma unroll
    for (int i = 0; i < 4; ++i)
#pragma unroll
        for (int j = 0; j < 4; ++j) {
            const int d = wid * 64 + j * 16 + l15;
#pragma unroll
            for (int q = 0; q < 4; ++q) {
                const int mg = m0 + i * 16 + l4 * 4 + q;
                Oc[(long)(zb * 256 + mg) * 1024 + zn * 256 + d] = f2bf(accO[i][j][q]);
            }
        }
}

// ---------------- GLU gate + residual + LN (bf16 chain, 2 bf16 partials) ----------------
__global__ __launch_bounds__(256)
void glu_ln_k(const u16* __restrict__ xs0, const u16* __restrict__ g2,
              const float* __restrict__ gam, const float* __restrict__ bet,
              u16* __restrict__ outb)
{
    const int t = blockIdx.x, tid = threadIdx.x;
    const int f0 = tid * 4;
    const long PS = 8388608;
    const float4 xv = bf4f(*(const ushort4*)&xs0[(long)t * 1024 + f0]);
    const float4 a0 = bf4f(*(const ushort4*)&g2[(long)t * 2048 + f0]);
    const float4 g0 = bf4f(*(const ushort4*)&g2[(long)t * 2048 + 1024 + f0]);
    const float4 a1 = bf4f(*(const ushort4*)&g2[PS + (long)t * 2048 + f0]);
    const float4 g1 = bf4f(*(const ushort4*)&g2[PS + (long)t * 2048 + 1024 + f0]);
    const float ax = a0.x + a1.x, ay = a0.y + a1.y, az = a0.z + a1.z, aw = a0.w + a1.w;
    const float gx = g0.x + g1.x, gy = g0.y + g1.y, gz = g0.z + g1.z, gw = g0.w + g1.w;
    float vals[4];
    vals[0] = xv.x + ax / (1.f + expf(-gx));
    vals[1] = xv.y + ay / (1.f + expf(-gy));
    vals[2] = xv.z + az / (1.f + expf(-gz));
    vals[3] = xv.w + aw / (1.f + expf(-gw));
    float s1 = vals[0] + vals[1] + vals[2] + vals[3];
    float s2 = vals[0]*vals[0] + vals[1]*vals[1] + vals[2]*vals[2] + vals[3]*vals[3];
    block_red2(s1, s2, tid);
    const float mean = s1 * (1.f / 1024.f);
    const float var  = s2 * (1.f / 1024.f) - mean * mean;
    const float rstd = rsqrtf(var + EPSF);
    const float4 gm = *(const float4*)&gam[f0];
    const float4 bt = *(const float4*)&bet[f0];
    *(ushort4*)&outb[(long)t * 1024 + f0] = f4bf(
        (vals[0] - mean) * rstd * gm.x + bt.x,
        (vals[1] - mean) * rstd * gm.y + bt.y,
        (vals[2] - mean) * rstd * gm.z + bt.z,
        (vals[3] - mean) * rstd * gm.w + bt.w);
}

// ---------------- residual add + LN width 1024 (bf16 chain, P bf16 partials, opt bias) ----------------
template<int P, int BIAS>
__global__ __launch_bounds__(256)
void add_ln1024_k(const u16* __restrict__ A, const u16* __restrict__ Bp,
                  const float* __restrict__ bias,
                  const float* __restrict__ gam, const float* __restrict__ bet,
                  u16* __restrict__ outb)
{
    const int t = blockIdx.x, tid = threadIdx.x;
    const int f0 = tid * 4;
    const long PS = 4194304;
    const float4 a = bf4f(*(const ushort4*)&A[(long)t * 1024 + f0]);
    float4 b = bf4f(*(const ushort4*)&Bp[(long)t * 1024 + f0]);
#pragma unroll
    for (int p = 1; p < P; ++p) {
        const float4 bp = bf4f(*(const ushort4*)&Bp[p * PS + (long)t * 1024 + f0]);
        b.x += bp.x; b.y += bp.y; b.z += bp.z; b.w += bp.w;
    }
    if (BIAS) {
        const float4 bb = *(const float4*)&bias[f0];
        b.x += bb.x; b.y += bb.y; b.z += bb.z; b.w += bb.w;
    }
    float vals[4] = {a.x + b.x, a.y + b.y, a.z + b.z, a.w + b.w};
    float s1 = vals[0] + vals[1] + vals[2] + vals[3];
    float s2 = vals[0]*vals[0] + vals[1]*vals[1] + vals[2]*vals[2] + vals[3]*vals[3];
    block_red2(s1, s2, tid);
    const float mean = s1 * (1.f / 1024.f);
    const float var  = s2 * (1.f / 1024.f) - mean * mean;
    const float rstd = rsqrtf(var + EPSF);
    const float4 gm = *(const float4*)&gam[f0];
    const float4 bt = *(const float4*)&bet[f0];
    *(ushort4*)&outb[(long)t * 1024 + f0] = f4bf(
        (vals[0] - mean) * rstd * gm.x + bt.x,
        (vals[1] - mean) * rstd * gm.y + bt.y,
        (vals[2] - mean) * rstd * gm.z + bt.z,
        (vals[3] - mean) * rstd * gm.w + bt.w);
}

// ---------------- n2: LN(c1L(bf16) + pad(relu(sum of 3 bf16 conv taps))) width 4096 ----------------
__global__ __launch_bounds__(256)
void add_ln4096_k(const u16* __restrict__ A, const u16* __restrict__ Bp,
                  const float* __restrict__ gam, const float* __restrict__ bet,
                  u16* __restrict__ outb)
{
    const int t = blockIdx.x, tid = threadIdx.x;
    const long PS = 4194304;
    const int f0 = tid * 16;
    float vals[16];
    const bf16x8 a0 = *(const bf16x8*)&A[(long)t * 4096 + f0];
    const bf16x8 a1 = *(const bf16x8*)&A[(long)t * 4096 + f0 + 8];
#pragma unroll
    for (int e = 0; e < 8; ++e) { vals[e] = bf2f((u16)a0[e]); vals[8 + e] = bf2f((u16)a1[e]); }
    if (tid < 64) {
#pragma unroll
        for (int c = 0; c < 4; ++c) {
            const int fc = f0 + c * 4;
            const float4 b0 = bf4f(*(const ushort4*)&Bp[(long)t * 1024 + fc]);
            const float4 b1 = bf4f(*(const ushort4*)&Bp[PS + (long)t * 1024 + fc]);
            const float4 b2 = bf4f(*(const ushort4*)&Bp[2 * PS + (long)t * 1024 + fc]);
            vals[c*4+0] += fmaxf(b0.x + b1.x + b2.x, 0.f);
            vals[c*4+1] += fmaxf(b0.y + b1.y + b2.y, 0.f);
            vals[c*4+2] += fmaxf(b0.z + b1.z + b2.z, 0.f);
            vals[c*4+3] += fmaxf(b0.w + b1.w + b2.w, 0.f);
        }
    }
    float s1 = 0.f, s2 = 0.f;
#pragma unroll
    for (int e = 0; e < 16; ++e) { s1 += vals[e]; s2 += vals[e] * vals[e]; }
    block_red2(s1, s2, tid);
    const float mean = s1 * (1.f / 4096.f);
    const float var  = s2 * (1.f / 4096.f) - mean * mean;
    const float rstd = rsqrtf(var + EPSF);
#pragma unroll
    for (int c = 0; c < 4; ++c) {
        const int fc = f0 + c * 4;
        const float4 gm = *(const float4*)&gam[fc];
        const float4 bt = *(const float4*)&bet[fc];
        *(ushort4*)&outb[(long)t * 4096 + fc] = f4bf(
            (vals[c*4+0] - mean) * rstd * gm.x + bt.x,
            (vals[c*4+1] - mean) * rstd * gm.y + bt.y,
            (vals[c*4+2] - mean) * rstd * gm.z + bt.z,
            (vals[c*4+3] - mean) * rstd * gm.w + bt.w);
    }
}

// ---------------- depthwise conv width-9, 8 channels/thread ----------------
__global__ __launch_bounds__(256)
void dwconv8_k(const u16* __restrict__ h, const float* __restrict__ wT,
               u16* __restrict__ out)
{
    const long idx = (long)blockIdx.x * 256 + threadIdx.x;
    const int cg = (int)(idx & 511);
    const int t  = (int)(idx >> 9);
    const int w  = t & 255;
    const int c0 = cg * 8;
    float acc[8] = {};
#pragma unroll
    for (int k = 0; k < 9; ++k) {
        const int wp = w + k - 4;
        if ((unsigned)wp < 256u) {
            const bf16x8 hv = *(const bf16x8*)&h[(long)(t + k - 4) * 4096 + c0];
            const float4 w0 = *(const float4*)&wT[k * 4096 + c0];
            const float4 w1 = *(const float4*)&wT[k * 4096 + c0 + 4];
            acc[0] += bf2f((u16)hv[0]) * w0.x;
            acc[1] += bf2f((u16)hv[1]) * w0.y;
            acc[2] += bf2f((u16)hv[2]) * w0.z;
            acc[3] += bf2f((u16)hv[3]) * w0.w;
            acc[4] += bf2f((u16)hv[4]) * w1.x;
            acc[5] += bf2f((u16)hv[5]) * w1.y;
            acc[6] += bf2f((u16)hv[6]) * w1.z;
            acc[7] += bf2f((u16)hv[7]) * w1.w;
        }
    }
    bf16x8 res;
#pragma unroll
    for (int j = 0; j < 8; ++j) res[j] = (short)f2bf(acc[j]);
    *(bf16x8*)&out[(long)t * 4096 + c0] = res;
}

// ---------------- final transpose: bf16 (tokens,1024) -> f32 (B,1,1024,256) ----------------
__global__ __launch_bounds__(256)
void transpose_out_k(const u16* __restrict__ xs, float* __restrict__ out)
{
    __shared__ u16 tile[32][34];
    const int b = blockIdx.z, f0 = blockIdx.y * 32, w0 = blockIdx.x * 32;
    const int tid = threadIdx.x, c = tid & 31, r = tid >> 5;
#pragma unroll
    for (int it = 0; it < 4; ++it) {
        const int w = w0 + r + it * 8;
        tile[r + it * 8][c] = xs[((long)b * 256 + w) * 1024 + f0 + c];
    }
    __syncthreads();
#pragma unroll
    for (int it = 0; it < 4; ++it) {
        const int fl = r + it * 8;
        out[((long)b * 1024 + f0 + fl) * 256 + w0 + c] = bf2f(tile[c][fl]);
    }
}

// =======================================================================
extern "C" void kernel_launch(void* const* d_in, const int* in_sizes, int n_in,
                              void* d_out, int out_size, void* d_ws, size_t ws_size,
                              hipStream_t stream)
{
    const float* x      = (const float*)d_in[0];
    const float* bott_w = (const float*)d_in[1];
    const float* bn_g   = (const float*)d_in[2];
    const float* bn_b   = (const float*)d_in[3];
    const float* bn_m   = (const float*)d_in[4];
    const float* bn_v   = (const float*)d_in[5];
    const float* glu_w  = (const float*)d_in[6];
    const float* n1g    = (const float*)d_in[7];
    const float* n1b    = (const float*)d_in[8];
    const float* c1L_w  = (const float*)d_in[9];
    const float* c1R_w  = (const float*)d_in[10];
    const float* n2g    = (const float*)d_in[11];
    const float* n2b    = (const float*)d_in[12];
    const float* c2dw_w = (const float*)d_in[13];
    const float* c2pw_w = (const float*)d_in[14];
    const float* n3g    = (const float*)d_in[15];
    const float* n3b    = (const float*)d_in[16];
    const float* qw     = (const float*)d_in[17];
    const float* qb     = (const float*)d_in[18];
    const float* kw     = (const float*)d_in[19];
    const float* kb     = (const float*)d_in[20];
    const float* vw     = (const float*)d_in[21];
    const float* vb     = (const float*)d_in[22];
    const float* ow     = (const float*)d_in[23];
    const float* ob     = (const float*)d_in[24];
    const float* er     = (const float*)d_in[25];
    const float* dist_w = (const float*)d_in[26];
    const float* n4g    = (const float*)d_in[27];
    const float* n4b    = (const float*)d_in[28];
    const float* c3_w   = (const float*)d_in[29];
    const float* c4_w   = (const float*)d_in[30];
    const float* n5g    = (const float*)d_in[31];
    const float* n5b    = (const float*)d_in[32];
    float* out = (float*)d_out;

    // ---- workspace layout (MiB offsets, bf16 residual chain) ----
    char* Wb_ = (char*)d_ws;
    auto Bf = [&](size_t mib) { return (u16*)(Wb_ + (mib << 20)); };
    u16* XA   = Bf(0);    // xs0 (1-3), xs2 (9-13), xs4 (16-17)
    u16* XB   = Bf(8);    // xs1 (3-9), xs3 (13-16)
    u16* H0b  = Bf(32);   // c1L out (4-6) / c3 out (14-15)
    u16* Hglu = Bf(64);   // GLU 2 bf16 partials (2-3)
    u16* C3p  = Bf(64);   // conv3 3 bf16 partials (5-6)
    u16* P4   = Bf(64);   // c2pw/O-proj/c4 4 bf16 partials
    u16* H1b  = Bf(128);  // n2 out (6-7)
    u16* Hdw  = Bf(160);  // dwconv out (7-8)
    u16* QKVb = Bf(192);  // QKV out 4096x3072 (10-11; V cols dead, written to Vt)
    u16* Vt   = Bf(216);  // V transposed (10-11)
    u16* S1b  = Bf(264);  // attn concat out (11-12)
    u16* wGLU = Bf(296); u16* wC1L = Bf(300); u16* wC1R = Bf(308);
    u16* wC2P = Bf(314); u16* wQKV = Bf(322); u16* wO   = Bf(328);
    u16* wC3  = Bf(330); u16* wC4  = Bf(338);
    u16* erT  = Bf(346);
    u16* zp   = (u16*)(Wb_ + (346u << 20) + 131072);
    float* wdwT = (float*)(Wb_ + (346u << 20) + 131072 + 16384);
    float* bQKV = (float*)(Wb_ + (346u << 20) + 131072 + 16384 + 147456);

    const dim3 blk(256);
    const dim3 blk8(512);
    const long PS1 = 4194304;   // 4096*1024 elements
    const size_t SH8 = 131072;  // 128 KiB dynamic LDS

    // 0. merged setup (one launch); kw/kb pre-scaled by 1/32
    SetupArgs sa;
    sa.ws[0] = glu_w;  sa.wd[0] = wGLU;            sa.wn[0] = 524288;
    sa.ws[1] = c1L_w;  sa.wd[1] = wC1L;            sa.wn[1] = 1048576;
    sa.ws[2] = c2pw_w; sa.wd[2] = wC2P;            sa.wn[2] = 1048576;
    sa.ws[3] = c3_w;   sa.wd[3] = wC3;             sa.wn[3] = 1048576;
    sa.ws[4] = c4_w;   sa.wd[4] = wC4;             sa.wn[4] = 1048576;
    sa.ws[5] = qw;     sa.wd[5] = wQKV;            sa.wn[5] = 262144;
    sa.ws[6] = kw;     sa.wd[6] = wQKV + 1048576;  sa.wn[6] = 262144;
    sa.ws[7] = vw;     sa.wd[7] = wQKV + 2097152;  sa.wn[7] = 262144;
    sa.ws[8] = ow;     sa.wd[8] = wO;              sa.wn[8] = 262144;
    sa.c1r = c1R_w; sa.c1rd = wC1R;
    sa.er  = er;    sa.erd  = erT;
    sa.dw  = c2dw_w; sa.dwd = wdwT;
    sa.qb = qb; sa.kb = kb; sa.vb = vb; sa.bcat = bQKV;
    sa.zp = zp;
    {
        int bc[14] = {2048, 4096, 4096, 4096, 4096, 1024, 1024, 1024, 1024,
                      12288, 256, 144, 12, 32};
        int acc = 0;
        for (int s = 0; s < 14; ++s) { sa.off[s] = acc; acc += bc[s]; }
        sa.off[14] = acc;
        setup_k<<<dim3(acc), blk, 0, stream>>>(sa);
    }

    // 1. bottleneck + BN + ReLU + transpose -> XA (xs0, bf16)
    bottleneck_k<<<dim3(8, 32, 16), blk, 0, stream>>>(x, bott_w, bn_g, bn_b, bn_m, bn_v, XA);

    // 2. GLU matmul, split-K=2 -> Hglu bf16 partials
    gemm8_k<0,0,0,2,0><<<dim3(8, 16, 2), blk8, SH8, stream>>>(XA, wGLU, nullptr, Hglu,
        2048, 512, 1024, 1024, (long)4096 * 2048, nullptr);

    // 3. n1: LN(xs0 + a*sigmoid(g)) -> XB (xs1)
    glu_ln_k<<<dim3(4096), blk, 0, stream>>>(XA, Hglu, n1g, n1b, XB);

    // 4+5. merged c1L (relu -> H0b) + conv1R taps (-> C3p partials), one launch
    ffconv8_k<<<dim3(28, 16), blk8, SH8, stream>>>(XB, wC1L, wC1R, zp, H0b, C3p);

    // 6. n2: LN(H0b + pad(relu(sum taps))) -> H1b bf16
    add_ln4096_k<<<dim3(4096), blk, 0, stream>>>(H0b, C3p, n2g, n2b, H1b);

    // 7. depthwise conv9 (vectorized x8): H1b -> Hdw
    dwconv8_k<<<dim3(8192), blk, 0, stream>>>(H1b, wdwT, Hdw);

    // 8. c2pw, split-K=4 -> P4 bf16 partials
    gemm8_k<0,0,0,4,0><<<dim3(4, 16, 4), blk8, SH8, stream>>>(Hdw, wC2P, nullptr, P4,
        1024, 1024, 4096, 4096, PS1, nullptr);

    // 9. n3: LN(xs1 + sum P4) -> XA (xs2)
    add_ln1024_k<4,0><<<dim3(4096), blk, 0, stream>>>(XB, P4, nullptr, n3g, n3b, XA);

    // 10. fused QKV projection; V-tiles written transposed to Vt in-epilogue
    gemm8_k<0,1,1,1,1><<<dim3(12, 16, 1), blk8, SH8, stream>>>(XA, wQKV, bQKV, QKVb,
        3072, 1024, 1024, 1024, 0, Vt);

    // 11. fused attention: K=512 concat scores + softmax + PV -> S1b
    attn_fused_k<<<dim3(4, 64), blk, 0, stream>>>(QKVb, erT, Vt, dist_w, S1b);

    // 12. output projection, split-K=4 -> P4 bf16 partials (bias added in n4)
    gemm8_k<0,0,0,4,0><<<dim3(4, 16, 4), blk8, SH8, stream>>>(S1b, wO, nullptr, P4,
        1024, 256, 1024, 1024, PS1, nullptr);

    // 13. n4: LN(xs2 + sum P4 + ob) -> XB (xs3)
    add_ln1024_k<4,1><<<dim3(4096), blk, 0, stream>>>(XA, P4, ob, n4g, n4b, XB);

    // 14. c3: relu -> H0b bf16
    gemm8_k<1,1,0,1,0><<<dim3(16, 16, 1), blk8, SH8, stream>>>(XB, wC3, nullptr, H0b,
        4096, 1024, 1024, 1024, 0, nullptr);

    // 15. c4, split-K=4 -> P4 bf16 partials
    gemm8_k<0,0,0,4,0><<<dim3(4, 16, 4), blk8, SH8, stream>>>(H0b, wC4, nullptr, P4,
        1024, 1024, 4096, 4096, PS1, nullptr);

    // 16. n5: LN(xs3 + sum P4) -> XA (xs4, bf16)
    add_ln1024_k<4,0><<<dim3(4096), blk, 0, stream>>>(XB, P4, nullptr, n5g, n5b, XA);

    // 17. transpose to (B, 1, 1024, 256) f32
    transpose_out_k<<<dim3(8, 32, 16), blk, 0, stream>>>(XA, out);

    (void)in_sizes; (void)n_in; (void)out_size; (void)ws_size;
}